// Round 1
// baseline (551.572 us; speedup 1.0000x reference)
//
#include <hip/hip_runtime.h>
#include <stdint.h>

typedef unsigned short u16;

#define BB 2
#define NN 2048
#define MM 2048
#define CC 512
#define KK 16
#define KK1 8
#define KEY 1024

typedef __attribute__((ext_vector_type(8))) short bf16x8;
typedef __attribute__((ext_vector_type(4))) float f32x4;

__device__ __forceinline__ float b2f(u16 u){ return __uint_as_float(((uint32_t)u) << 16); }
__device__ __forceinline__ u16 f2b(float f){
  uint32_t x = __float_as_uint(f);
  uint32_t r = x + 0x7FFFu + ((x >> 16) & 1u);
  return (u16)(r >> 16);
}
__device__ __forceinline__ float sane(float v){ return (fabsf(v) < 1e30f) ? v : 1e30f; }

// all-thread block reduction, 256 threads. op: 0=sum 1=min 2=max
__device__ __forceinline__ float blockRed(float v, float* red, int t, int op){
  red[t] = v; __syncthreads();
  #pragma unroll
  for (int s = 128; s > 0; s >>= 1){
    if (t < s){
      float a = red[t], b = red[t + s];
      red[t] = (op == 0) ? (a + b) : ((op == 1) ? fminf(a, b) : fmaxf(a, b));
    }
    __syncthreads();
  }
  float r = red[0]; __syncthreads();
  return r;
}

// ---- K0: transpose f32 (B,C,N) -> split-bf16 (B,N,C) hi/lo pairs -------------------
__global__ __launch_bounds__(256) void k_trans(const float* __restrict__ semb, const float* __restrict__ temb,
                                               u16* __restrict__ Ah, u16* __restrict__ Al,
                                               u16* __restrict__ Bh, u16* __restrict__ Bl){
  __shared__ float tile[32][33];
  int b = blockIdx.z & 1, which = blockIdx.z >> 1;
  const float* in = which ? temb : semb;
  u16* oh = which ? Bh : Ah;
  u16* ol = which ? Bl : Al;
  int c0 = blockIdx.x * 32, n0 = blockIdx.y * 32;
  int tx = threadIdx.x, ty = threadIdx.y;
  #pragma unroll
  for (int i = 0; i < 4; i++){
    int r = ty + 8 * i;
    tile[r][tx] = in[((b * CC + c0 + r) * NN) + n0 + tx];
  }
  __syncthreads();
  #pragma unroll
  for (int i = 0; i < 4; i++){
    int r = ty + 8 * i;
    float v = tile[tx][r];
    u16 hi = f2b(v);
    float lo = v - b2f(hi);
    size_t o = ((size_t)(b * NN + n0 + r) * CC) + c0 + tx;
    oh[o] = hi;
    ol[o] = f2b(lo);
  }
}

// ---- K1: exact f32 row squared norms from (B,C,N) layout (coalesced over n) --------
__global__ __launch_bounds__(256) void k_sq(const float* __restrict__ semb, const float* __restrict__ temb,
                                            float* __restrict__ xx, float* __restrict__ yy){
  int which = blockIdx.y;
  const float* in = which ? temb : semb;
  float* out = which ? yy : xx;
  int gid = blockIdx.x * 256 + threadIdx.x;   // 0..4095
  int b = gid >> 11, n = gid & 2047;
  float acc = 0.f;
  for (int c = 0; c < CC; c++){
    float v = in[((size_t)(b * CC + c)) * NN + n];
    acc += v * v;
  }
  out[gid] = acc;
}

// ---- K2: dist = xx - 2*A.B^T + yy, split-bf16 MFMA (hi*hi + hi*lo + lo*hi) ---------
__global__ __launch_bounds__(256) void k_gemm(const u16* __restrict__ Ah, const u16* __restrict__ Al,
                                              const u16* __restrict__ Bh, const u16* __restrict__ Bl,
                                              const float* __restrict__ xx, const float* __restrict__ yy,
                                              float* __restrict__ dist){
  __shared__ __align__(16) u16 lAh[128 * 64];
  __shared__ __align__(16) u16 lAl[128 * 64];
  __shared__ __align__(16) u16 lBh[128 * 64];
  __shared__ __align__(16) u16 lBl[128 * 64];
  int n0 = blockIdx.y * 128, m0 = blockIdx.x * 128;
  int t = threadIdx.x;
  f32x4 acc[4][4];
  #pragma unroll
  for (int i = 0; i < 4; i++)
    #pragma unroll
    for (int j = 0; j < 4; j++){ f32x4 z = {0.f, 0.f, 0.f, 0.f}; acc[i][j] = z; }
  int w = t >> 6, lane = t & 63, lr = lane & 15, quad = lane >> 4;
  int wn = (w >> 1) * 64, wm = (w & 1) * 64;
  for (int kt = 0; kt < 8; kt++){
    int k0 = kt * 64;
    bf16x8 vah[4], val[4], vbh[4], vbl[4];
    #pragma unroll
    for (int s = 0; s < 4; s++){
      int ch = t + 256 * s;
      int rn = ch >> 3, k8 = (ch & 7) * 8;
      size_t oa = (size_t)(n0 + rn) * CC + k0 + k8;
      size_t ob = (size_t)(m0 + rn) * CC + k0 + k8;
      vah[s] = *(const bf16x8*)(Ah + oa);
      val[s] = *(const bf16x8*)(Al + oa);
      vbh[s] = *(const bf16x8*)(Bh + ob);
      vbl[s] = *(const bf16x8*)(Bl + ob);
    }
    __syncthreads();
    #pragma unroll
    for (int s = 0; s < 4; s++){
      int ch = t + 256 * s;
      *(bf16x8*)&lAh[ch * 8] = vah[s];
      *(bf16x8*)&lAl[ch * 8] = val[s];
      *(bf16x8*)&lBh[ch * 8] = vbh[s];
      *(bf16x8*)&lBl[ch * 8] = vbl[s];
    }
    __syncthreads();
    #pragma unroll
    for (int kk = 0; kk < 2; kk++){
      int off = kk * 32 + quad * 8;
      bf16x8 afh[4], afl[4], bfh[4], bfl[4];
      #pragma unroll
      for (int i = 0; i < 4; i++){
        int ra = (wn + i * 16 + lr) * 64 + off;
        afh[i] = *(const bf16x8*)&lAh[ra];
        afl[i] = *(const bf16x8*)&lAl[ra];
      }
      #pragma unroll
      for (int j = 0; j < 4; j++){
        int rb = (wm + j * 16 + lr) * 64 + off;
        bfh[j] = *(const bf16x8*)&lBh[rb];
        bfl[j] = *(const bf16x8*)&lBl[rb];
      }
      #pragma unroll
      for (int i = 0; i < 4; i++)
        #pragma unroll
        for (int j = 0; j < 4; j++){
          acc[i][j] = __builtin_amdgcn_mfma_f32_16x16x32_bf16(afh[i], bfh[j], acc[i][j], 0, 0, 0);
          acc[i][j] = __builtin_amdgcn_mfma_f32_16x16x32_bf16(afh[i], bfl[j], acc[i][j], 0, 0, 0);
          acc[i][j] = __builtin_amdgcn_mfma_f32_16x16x32_bf16(afl[i], bfh[j], acc[i][j], 0, 0, 0);
        }
    }
  }
  #pragma unroll
  for (int i = 0; i < 4; i++){
    int nbase = n0 + wn + i * 16 + quad * 4;
    #pragma unroll
    for (int j = 0; j < 4; j++){
      int m = m0 + wm + j * 16 + lr;
      float yv = yy[m];
      #pragma unroll
      for (int r = 0; r < 4; r++){
        dist[((size_t)(nbase + r)) * MM + m] = xx[nbase + r] + yv - 2.0f * acc[i][j][r];
      }
    }
  }
}

// ---- K3: per-row min & softmax(-dist) denominator ----------------------------------
__global__ __launch_bounds__(256) void k_rowstats(const float* __restrict__ dist,
                                                  float* __restrict__ mnA, float* __restrict__ Zr){
  __shared__ float red[256];
  int row = blockIdx.x, t = threadIdx.x;
  const float* dr = dist + (size_t)row * MM;
  float d[8];
  float mn = 3.4e38f;
  #pragma unroll
  for (int i = 0; i < 8; i++){ d[i] = sane(dr[t + 256 * i]); mn = fminf(mn, d[i]); }
  mn = blockRed(mn, red, t, 1);
  float z = 0.f;
  #pragma unroll
  for (int i = 0; i < 8; i++) z += expf(mn - d[i]);
  z = blockRed(z, red, t, 0);
  if (t == 0){ mnA[row] = mn; Zr[row] = fmaxf(z, 1e-30f); }
}

// ---- K4: fused T/S/refined/rmm/src_corr/loss per row n (per batch) -----------------
__global__ __launch_bounds__(256) void k_fused(const float* __restrict__ dist, const float* __restrict__ mnA,
                                               const float* __restrict__ Zr, const int* __restrict__ sidx1b,
                                               const int* __restrict__ idx2b, const float* __restrict__ tgtb,
                                               float* __restrict__ s_corrb, float* __restrict__ lossb){
  __shared__ float Trow[MM];
  __shared__ float red[256];
  int n = blockIdx.x, t = threadIdx.x;
  const float* dn_p = dist + (size_t)n * MM;
  float dn[8];
  #pragma unroll
  for (int i = 0; i < 8; i++) dn[i] = sane(dn_p[t + 256 * i]);
  float tacc[8] = {0, 0, 0, 0, 0, 0, 0, 0};
  const int* i1 = sidx1b + n * KK1;
  for (int j = 1; j < KK1; j++){
    int r = i1[j] & 2047;
    float mnj = mnA[r];
    float izj = 1.0f / Zr[r];
    const float* drp = dist + (size_t)r * MM;
    #pragma unroll
    for (int i = 0; i < 8; i++) tacc[i] += expf(mnj - sane(drp[t + 256 * i])) * izj;
  }
  #pragma unroll
  for (int i = 0; i < 8; i++) Trow[t + 256 * i] = tacc[i];
  __syncthreads();
  float rloc[8];
  float lmin = 3.4e38f;
  #pragma unroll
  for (int i = 0; i < 8; i++){
    int m = t + 256 * i;
    const int* ip = idx2b + m * KK1;
    float S = 0.f;
    #pragma unroll
    for (int j = 1; j < KK1; j++) S += Trow[ip[j] & 2047];
    float rv = sane(expf(1.0f - S / 7.0f) * dn[i]);
    rloc[i] = rv;
    lmin = fminf(lmin, rv);
  }
  float rmin = blockRed(lmin, red, t, 1);
  float z = 0.f, s0 = 0.f, s1 = 0.f, s2 = 0.f;
  #pragma unroll
  for (int i = 0; i < 8; i++){
    int m = t + 256 * i;
    float p = expf(rmin - rloc[i]);
    z  += p;
    s0 += tgtb[0 * MM + m] * p;
    s1 += tgtb[1 * MM + m] * p;
    s2 += tgtb[2 * MM + m] * p;
  }
  z  = blockRed(z,  red, t, 0);
  s0 = blockRed(s0, red, t, 0);
  s1 = blockRed(s1, red, t, 0);
  s2 = blockRed(s2, red, t, 0);
  if (t == 0){
    float iZ = 1.0f / fmaxf(z, 1e-30f);
    s_corrb[0 * NN + n] = s0 * iZ;
    s_corrb[1 * NN + n] = s1 * iZ;
    s_corrb[2 * NN + n] = s2 * iZ;
    lossb[n] = -logf(fminf(iZ, 1.0f) + 1e-15f);  // pred at onehot == rowmax(rmm) == 1/Z
  }
}

// ---- K5: discriminator MLP — occupancy-restructured, FP chains VERBATIM ------------
// R13: old shape (1 thread = 1 point, h0..h15 live across e-loop) compiled to
// VGPR=40 -> h went through AGPR/scratch shuffles, and grid was only 1024 waves
// (1 wave/SIMD) -> 72us at 17% VALUBusy. New shape: block = (b,n), 256 threads.
//  phase1: 16 thr/point compute h[d] (L1D chain verbatim) -> LDS (padded, f32x4)
//  phase2: thread (k,el) owns 8 e-chains; d-chunk OUTER loop: one broadcast
//          ds_read_b128 of h per chunk, W2 streamed from L1 (32KB, CU-resident).
//          a[ee] accumulates d-ascending with the IDENTICAL statement ->
//          identical contraction -> identical values.
//  phase3: store relu(a) exactly; one lane per k does the serial e=0..127
//          left-fold 'sacc += W3[e]*relu' (identical expression), clamp, then
//          16-lane max tree (exact for finite floats).
// 4096 blocks x 4 waves, ~12.6KB LDS -> 8 blocks/CU resident.
__global__ __launch_bounds__(256) void k_disc(const float* __restrict__ s_corr, const float* __restrict__ src,
                                              const float* __restrict__ sknn, const int* __restrict__ sidx,
                                              const float* __restrict__ W1, const float* __restrict__ b1,
                                              const float* __restrict__ W2, const float* __restrict__ b2,
                                              const float* __restrict__ W3, const float* __restrict__ b3,
                                              float* __restrict__ sArr){
  __shared__ f32x4 hl[16][17];      // [k][dgroup], pad 17 -> phase2 broadcast reads conflict-free
  __shared__ float term[16][129];   // [k][e], pad 129 -> fold reads conflict-free
  int t = threadIdx.x;
  int b = blockIdx.y;
  int n = blockIdx.x;
  int k = t >> 4;       // point (k of this n)
  int dg = t & 15;      // d-group: d = 4*dg .. 4*dg+3
  // ---- phase 1: f + 4 h values, expressions verbatim from R12 ----
  int nk = sidx[((b * NN + n) * KK) + k] & 2047;
  float f[6];
  #pragma unroll
  for (int c = 0; c < 3; c++){
    f[c]     = s_corr[(b * 3 + c) * NN + n] - s_corr[(b * 3 + c) * NN + nk];
    f[3 + c] = src[(b * 3 + c) * NN + n] - sknn[((size_t)(b * NN + n) * KK + k) * 3 + c];
  }
  #define L1D(d) ({ float a_ = b1[(d)];              \
                    a_ += f[0] * W1[(d) * 6 + 0];    \
                    a_ += f[1] * W1[(d) * 6 + 1];    \
                    a_ += f[2] * W1[(d) * 6 + 2];    \
                    a_ += f[3] * W1[(d) * 6 + 3];    \
                    a_ += f[4] * W1[(d) * 6 + 4];    \
                    a_ += f[5] * W1[(d) * 6 + 5];    \
                    fmaxf(a_, 0.f); })
  {
    f32x4 hv;
    hv.x = L1D(4 * dg + 0);
    hv.y = L1D(4 * dg + 1);
    hv.z = L1D(4 * dg + 2);
    hv.w = L1D(4 * dg + 3);
    hl[k][dg] = hv;
  }
  #undef L1D
  __syncthreads();
  // ---- phase 2: 8 e-chains per thread, d-chunk outer with hv hoisted ----
  {
    int el = t & 15;    // e = el + 16*ee
    float a[8];
    #pragma unroll
    for (int ee = 0; ee < 8; ee++) a[ee] = b2[el + 16 * ee];
    #pragma unroll
    for (int i = 0; i < 16; i++){
      f32x4 hv = hl[k][i];   // broadcast across the 16 lanes of this k
      #pragma unroll
      for (int ee = 0; ee < 8; ee++){
        f32x4 wv = *(const f32x4*)&W2[(el + 16 * ee) * 64 + 4 * i];
        a[ee] += wv.x * hv.x + wv.y * hv.y + wv.z * hv.z + wv.w * hv.w;
      }
    }
    #pragma unroll
    for (int ee = 0; ee < 8; ee++) term[k][el + 16 * ee] = fmaxf(a[ee], 0.f);
  }
  __syncthreads();
  // ---- phase 3: serial left-fold per k in e-order (verbatim), then k-max ----
  if (t < 16){
    float sacc = b3[0];
    #pragma unroll 4
    for (int e = 0; e < 128; e++) sacc += W3[e] * term[t][e];
    if (!(fabsf(sacc) < 1e30f)) sacc = -1e30f;
    #pragma unroll
    for (int off = 1; off < 16; off <<= 1) sacc = fmaxf(sacc, __shfl_xor(sacc, off, 16));
    if (t == 0) sArr[b * NN + n] = sacc;
  }
}

// ---- K6: weight = softmax(s) over n ------------------------------------------------
__global__ __launch_bounds__(256) void k_softw(const float* __restrict__ sArr, float* __restrict__ wArr){
  __shared__ float red[256];
  int b = blockIdx.x, t = threadIdx.x;
  const float* sp = sArr + b * NN;
  float sv[8];
  float mx = -3.4e38f;
  #pragma unroll
  for (int i = 0; i < 8; i++){
    float v = sp[t + 256 * i];
    if (!(fabsf(v) < 1e30f)) v = -1e30f;
    sv[i] = v; mx = fmaxf(mx, v);
  }
  mx = blockRed(mx, red, t, 2);
  float z = 0.f;
  #pragma unroll
  for (int i = 0; i < 8; i++) z += expf(sv[i] - mx);
  z = blockRed(z, red, t, 0);
  float iz = 1.0f / fmaxf(z, 1e-30f);
  #pragma unroll
  for (int i = 0; i < 8; i++) wArr[b * NN + t + 256 * i] = expf(sv[i] - mx) * iz;
}

// ---- K7: stable descending rank -> topi --------------------------------------------
__global__ __launch_bounds__(256) void k_rank(const float* __restrict__ wArr, int* __restrict__ topi){
  __shared__ float wrow[NN];
  int b = blockIdx.y, t = threadIdx.x;
  for (int i = t; i < NN; i += 256) wrow[i] = wArr[b * NN + i];
  __syncthreads();
  int n = blockIdx.x * 256 + t;
  float wn = wrow[n];
  int cnt = 0;
  for (int j = 0; j < NN; j++){
    float wj = wrow[j];
    cnt += (wj > wn) || ((wj == wn) && (j < n));
  }
  if (cnt < KEY) topi[b * KEY + cnt] = n;
}

// ---- K8: weighted centroids, H, 3x3 SVD (f64 Jacobi), R/t --------------------------
__device__ __forceinline__ double det3d(const double A[3][3]){
  return A[0][0] * (A[1][1] * A[2][2] - A[1][2] * A[2][1])
       - A[0][1] * (A[1][0] * A[2][2] - A[1][2] * A[2][0])
       + A[0][2] * (A[1][0] * A[2][1] - A[1][1] * A[2][0]);
}

__global__ __launch_bounds__(256) void k_rigid(const float* __restrict__ src, const float* __restrict__ s_corr,
                                               const float* __restrict__ wArr, float* __restrict__ Rt,
                                               float* __restrict__ out){
  __shared__ float red[256];
  int b = blockIdx.x, t = threadIdx.x;
  float wsum = 0, a0 = 0, a1 = 0, a2 = 0, c0 = 0, c1 = 0, c2 = 0;
  for (int n = t; n < NN; n += 256){
    float wv = wArr[b * NN + n];
    float s0 = src[(b * 3 + 0) * NN + n];
    float s1 = src[(b * 3 + 1) * NN + n];
    float s2 = src[(b * 3 + 2) * NN + n];
    float q0 = s_corr[(b * 3 + 0) * NN + n];
    float q1 = s_corr[(b * 3 + 1) * NN + n];
    float q2 = s_corr[(b * 3 + 2) * NN + n];
    wsum += wv; a0 += wv * s0; a1 += wv * s1; a2 += wv * s2;
    c0 += wv * q0; c1 += wv * q1; c2 += wv * q2;
  }
  wsum = blockRed(wsum, red, t, 0);
  a0 = blockRed(a0, red, t, 0); a1 = blockRed(a1, red, t, 0); a2 = blockRed(a2, red, t, 0);
  c0 = blockRed(c0, red, t, 0); c1 = blockRed(c1, red, t, 0); c2 = blockRed(c2, red, t, 0);
  float inv = 1.0f / fmaxf(wsum, 1e-30f);
  float cs0 = a0 * inv, cs1 = a1 * inv, cs2 = a2 * inv;
  float ct0 = c0 * inv, ct1 = c1 * inv, ct2 = c2 * inv;
  float h[9] = {0, 0, 0, 0, 0, 0, 0, 0, 0};
  for (int n = t; n < NN; n += 256){
    float wv = wArr[b * NN + n];
    float ds0 = src[(b * 3 + 0) * NN + n] - cs0;
    float ds1 = src[(b * 3 + 1) * NN + n] - cs1;
    float ds2 = src[(b * 3 + 2) * NN + n] - cs2;
    float dc0 = s_corr[(b * 3 + 0) * NN + n] - ct0;
    float dc1 = s_corr[(b * 3 + 1) * NN + n] - ct1;
    float dc2 = s_corr[(b * 3 + 2) * NN + n] - ct2;
    h[0] += wv * ds0 * dc0; h[1] += wv * ds0 * dc1; h[2] += wv * ds0 * dc2;
    h[3] += wv * ds1 * dc0; h[4] += wv * ds1 * dc1; h[5] += wv * ds1 * dc2;
    h[6] += wv * ds2 * dc0; h[7] += wv * ds2 * dc1; h[8] += wv * ds2 * dc2;
  }
  for (int i = 0; i < 9; i++) h[i] = blockRed(h[i], red, t, 0);
  if (t == 0){
    double Hm[3][3];
    for (int i = 0; i < 3; i++)
      for (int j = 0; j < 3; j++) Hm[i][j] = (double)h[i * 3 + j];
    double Km[3][3], V[3][3] = {{1, 0, 0}, {0, 1, 0}, {0, 0, 1}};
    for (int i = 0; i < 3; i++)
      for (int j = 0; j < 3; j++){
        double s = 0;
        for (int a = 0; a < 3; a++) s += Hm[a][i] * Hm[a][j];
        Km[i][j] = s;
      }
    double ksc = fabs(Km[0][0]) + fabs(Km[1][1]) + fabs(Km[2][2]) + 1e-300;
    for (int sweep = 0; sweep < 60; sweep++){
      int p = 0, q = 1; double mx = fabs(Km[0][1]);
      if (fabs(Km[0][2]) > mx){ mx = fabs(Km[0][2]); p = 0; q = 2; }
      if (fabs(Km[1][2]) > mx){ mx = fabs(Km[1][2]); p = 1; q = 2; }
      if (mx <= 1e-15 * ksc) break;
      double app = Km[p][p], aqq = Km[q][q], apq = Km[p][q];
      double tau = (aqq - app) / (2.0 * apq);
      double tt = ((tau >= 0) ? 1.0 : -1.0) / (fabs(tau) + sqrt(1.0 + tau * tau));
      double cc = 1.0 / sqrt(1.0 + tt * tt), sn = tt * cc;
      for (int k2 = 0; k2 < 3; k2++){
        double akp = Km[k2][p], akq = Km[k2][q];
        Km[k2][p] = cc * akp - sn * akq; Km[k2][q] = sn * akp + cc * akq;
      }
      for (int k2 = 0; k2 < 3; k2++){
        double apk = Km[p][k2], aqk = Km[q][k2];
        Km[p][k2] = cc * apk - sn * aqk; Km[q][k2] = sn * apk + cc * aqk;
      }
      for (int k2 = 0; k2 < 3; k2++){
        double vkp = V[k2][p], vkq = V[k2][q];
        V[k2][p] = cc * vkp - sn * vkq; V[k2][q] = sn * vkp + cc * vkq;
      }
    }
    double lam[3] = {Km[0][0], Km[1][1], Km[2][2]};
    int id0 = 0, id1 = 1, id2 = 2, tmp;
    if (lam[id0] < lam[id1]){ tmp = id0; id0 = id1; id1 = tmp; }
    if (lam[id0] < lam[id2]){ tmp = id0; id0 = id2; id2 = tmp; }
    if (lam[id1] < lam[id2]){ tmp = id1; id1 = id2; id2 = tmp; }
    int idx[3] = {id0, id1, id2};
    double Vs[3][3], U[3][3] = {{0, 0, 0}, {0, 0, 0}, {0, 0, 0}};
    for (int jj = 0; jj < 3; jj++){
      int j = idx[jj];
      for (int i2 = 0; i2 < 3; i2++) Vs[i2][jj] = V[i2][j];
      double u0 = 0, u1 = 0, u2 = 0;
      for (int i2 = 0; i2 < 3; i2++){
        u0 += Hm[0][i2] * V[i2][j];
        u1 += Hm[1][i2] * V[i2][j];
        u2 += Hm[2][i2] * V[i2][j];
      }
      double nrm = sqrt(u0 * u0 + u1 * u1 + u2 * u2);
      if (nrm > 1e-20){
        U[0][jj] = u0 / nrm; U[1][jj] = u1 / nrm; U[2][jj] = u2 / nrm;
      } else {
        double x0 = U[1][0] * U[2][1] - U[2][0] * U[1][1];
        double x1 = U[2][0] * U[0][1] - U[0][0] * U[2][1];
        double x2 = U[0][0] * U[1][1] - U[1][0] * U[0][1];
        double nn2 = sqrt(x0 * x0 + x1 * x1 + x2 * x2);
        if (nn2 < 1e-20){ x0 = 1; x1 = 0; x2 = 0; nn2 = 1; }
        U[0][jj] = x0 / nn2; U[1][jj] = x1 / nn2; U[2][jj] = x2 / nn2;
      }
    }
    double dd = det3d(U) * det3d(Vs);
    double Rm[3][3];
    for (int i2 = 0; i2 < 3; i2++)
      for (int k2 = 0; k2 < 3; k2++)
        Rm[i2][k2] = Vs[i2][0] * U[k2][0] + Vs[i2][1] * U[k2][1] + dd * Vs[i2][2] * U[k2][2];
    double cs[3] = {cs0, cs1, cs2}, ct[3] = {ct0, ct1, ct2};
    double tv[3];
    for (int i2 = 0; i2 < 3; i2++)
      tv[i2] = ct[i2] - (Rm[i2][0] * cs[0] + Rm[i2][1] * cs[1] + Rm[i2][2] * cs[2]);
    for (int i2 = 0; i2 < 3; i2++)
      for (int k2 = 0; k2 < 3; k2++){
        Rt[b * 12 + i2 * 3 + k2] = (float)Rm[i2][k2];
        out[b * 9 + i2 * 3 + k2] = (float)Rm[i2][k2];
      }
    for (int i2 = 0; i2 < 3; i2++){
      Rt[b * 12 + 9 + i2] = (float)tv[i2];
      out[18 + b * 3 + i2] = (float)tv[i2];
    }
  }
}

// ---- K10: gather keypoint outputs, with src_transformed fused inline ---------------
// (k_st eliminated: st values computed at the gathered indices with the identical
// expression R[c*3+0]*s0 + R[c*3+1]*s1 + R[c*3+2]*s2 + R[9+c] -> bitwise-same out)
__global__ __launch_bounds__(256) void k_out(const int* __restrict__ topi, const int* __restrict__ sidx,
                                             const float* __restrict__ src, const float* __restrict__ s_corr,
                                             const float* __restrict__ Rt, float* __restrict__ out){
  int b = blockIdx.y, t = threadIdx.x;
  int rr = t >> 4, kk = t & 15;
  int r = blockIdx.x * 16 + rr;
  int ns = topi[b * KEY + r] & 2047;
  int nk = sidx[(b * NN + ns) * KK + kk] & 2047;
  const float* R = Rt + b * 12;
  float sns0 = src[(b * 3 + 0) * NN + ns];
  float sns1 = src[(b * 3 + 1) * NN + ns];
  float sns2 = src[(b * 3 + 2) * NN + ns];
  float snk0 = src[(b * 3 + 0) * NN + nk];
  float snk1 = src[(b * 3 + 1) * NN + nk];
  float snk2 = src[(b * 3 + 2) * NN + nk];
  float* o_sk  = out + 24;
  float* o_tk  = out + 6168;
  float* o_skk = out + 12312;
  float* o_tkk = out + 110616;
  #pragma unroll
  for (int c = 0; c < 3; c++){
    float cv  = s_corr[(b * 3 + c) * NN + ns];
    float ck  = s_corr[(b * 3 + c) * NN + nk];
    o_tkk[(((b * 3 + c) * KEY + r) * KK) + kk] = cv - ck;
    float sv  = R[c * 3 + 0] * sns0 + R[c * 3 + 1] * sns1 + R[c * 3 + 2] * sns2 + R[9 + c];
    float sk2 = R[c * 3 + 0] * snk0 + R[c * 3 + 1] * snk1 + R[c * 3 + 2] * snk2 + R[9 + c];
    o_skk[(((b * 3 + c) * KEY + r) * KK) + kk] = sv - sk2;
    if (kk == 0){
      o_sk[(b * 3 + c) * KEY + r] = sns0 * (c == 0) + sns1 * (c == 1) + sns2 * (c == 2);
      o_tk[(b * 3 + c) * KEY + r] = cv;
    }
  }
}

// ---- K11: loss_scl -----------------------------------------------------------------
__global__ __launch_bounds__(256) void k_loss(const float* __restrict__ loss_row, const int* __restrict__ topi,
                                              float* __restrict__ out){
  __shared__ float red[256];
  int t = threadIdx.x;
  float acc = 0.f;
  for (int i = t; i < BB * KEY; i += 256){
    int b = i >> 10, r = i & 1023;
    int n = topi[b * KEY + r] & 2047;
    acc += loss_row[b * NN + n];
  }
  acc = blockRed(acc, red, t, 0);
  if (t == 0) out[208920] = acc / 2048.0f;
}

extern "C" void kernel_launch(void* const* d_in, const int* in_sizes, int n_in,
                              void* d_out, int out_size, void* d_ws, size_t ws_size,
                              hipStream_t stream){
  const float* src  = (const float*)d_in[0];
  const float* tgt  = (const float*)d_in[1];
  const float* semb = (const float*)d_in[2];
  const float* temb = (const float*)d_in[3];
  const float* sknn = (const float*)d_in[4];
  const float* W1 = (const float*)d_in[6];
  const float* b1 = (const float*)d_in[7];
  const float* W2 = (const float*)d_in[8];
  const float* b2 = (const float*)d_in[9];
  const float* W3 = (const float*)d_in[10];
  const float* b3 = (const float*)d_in[11];
  const int* sidx  = (const int*)d_in[12];
  const int* sidx1 = (const int*)d_in[13];
  const int* idx2  = (const int*)d_in[14];
  float* out = (float*)d_out;

  // workspace layout (peak ~33.4 MB)
  char* w = (char*)d_ws;
  u16* Ah = (u16*)(w);                               // 4 MB each (B,N,C) bf16 split
  u16* Al = Ah + (size_t)BB * NN * CC;
  u16* Bh = Al + (size_t)BB * NN * CC;
  u16* Bl = Bh + (size_t)BB * MM * CC;
  float* dist = (float*)(Bl + (size_t)BB * MM * CC); // 16.78 MB (N,M) f32, per-batch reuse
  char* tail = (char*)(dist + (size_t)NN * MM);
  float* xx = (float*)tail;                          // B*N
  float* yy = xx + BB * NN;                          // B*M
  float* mnA = yy + BB * MM;                         // B*N
  float* Zr = mnA + BB * NN;                         // B*N
  float* s_corr = Zr + BB * NN;                      // B*3*N
  float* loss_row = s_corr + BB * 3 * NN;            // B*N
  float* sArr = loss_row + BB * NN;                  // B*N
  float* wArr = sArr + BB * NN;                      // B*N
  int* topi = (int*)(wArr + BB * NN);                // B*KEY
  float* Rt = (float*)(topi + BB * KEY);             // B*12

  k_trans<<<dim3(16, 64, 4), dim3(32, 8), 0, stream>>>(semb, temb, Ah, Al, Bh, Bl);
  k_sq<<<dim3(16, 2), 256, 0, stream>>>(semb, temb, xx, yy);
  for (int b = 0; b < BB; b++){
    k_gemm<<<dim3(16, 16), 256, 0, stream>>>(Ah + (size_t)b * NN * CC, Al + (size_t)b * NN * CC,
                                             Bh + (size_t)b * MM * CC, Bl + (size_t)b * MM * CC,
                                             xx + b * NN, yy + b * MM, dist);
    k_rowstats<<<NN, 256, 0, stream>>>(dist, mnA + b * NN, Zr + b * NN);
    k_fused<<<NN, 256, 0, stream>>>(dist, mnA + b * NN, Zr + b * NN,
                                    sidx1 + (size_t)b * NN * KK1, idx2 + (size_t)b * MM * KK1,
                                    tgt + (size_t)b * 3 * MM, s_corr + (size_t)b * 3 * NN,
                                    loss_row + b * NN);
  }
  k_disc<<<dim3(NN, BB), 256, 0, stream>>>(s_corr, src, sknn, sidx, W1, b1, W2, b2, W3, b3, sArr);
  k_softw<<<BB, 256, 0, stream>>>(sArr, wArr);
  k_rank<<<dim3(8, BB), 256, 0, stream>>>(wArr, topi);
  k_rigid<<<BB, 256, 0, stream>>>(src, s_corr, wArr, Rt, out);
  k_out<<<dim3(64, BB), 256, 0, stream>>>(topi, sidx, src, s_corr, Rt, out);
  k_loss<<<1, 256, 0, stream>>>(loss_row, topi, out);
}

// Round 2
// 346.269 us; speedup vs baseline: 1.5929x; 1.5929x over previous
//
#include <hip/hip_runtime.h>
#include <stdint.h>

typedef unsigned short u16;

#define BB 2
#define NN 2048
#define MM 2048
#define CC 512
#define KK 16
#define KK1 8
#define KEY 1024

typedef __attribute__((ext_vector_type(8))) short bf16x8;
typedef __attribute__((ext_vector_type(4))) float f32x4;

__device__ __forceinline__ float b2f(u16 u){ return __uint_as_float(((uint32_t)u) << 16); }
__device__ __forceinline__ u16 f2b(float f){
  uint32_t x = __float_as_uint(f);
  uint32_t r = x + 0x7FFFu + ((x >> 16) & 1u);
  return (u16)(r >> 16);
}
__device__ __forceinline__ float sane(float v){ return (fabsf(v) < 1e30f) ? v : 1e30f; }

// all-thread block reduction, 256 threads. op: 0=sum 1=min 2=max
__device__ __forceinline__ float blockRed(float v, float* red, int t, int op){
  red[t] = v; __syncthreads();
  #pragma unroll
  for (int s = 128; s > 0; s >>= 1){
    if (t < s){
      float a = red[t], b = red[t + s];
      red[t] = (op == 0) ? (a + b) : ((op == 1) ? fminf(a, b) : fmaxf(a, b));
    }
    __syncthreads();
  }
  float r = red[0]; __syncthreads();
  return r;
}

// ---- K0: transpose f32 (B,C,N) -> split-bf16 (B,N,C) hi/lo pairs -------------------
__global__ __launch_bounds__(256) void k_trans(const float* __restrict__ semb, const float* __restrict__ temb,
                                               u16* __restrict__ Ah, u16* __restrict__ Al,
                                               u16* __restrict__ Bh, u16* __restrict__ Bl){
  __shared__ float tile[32][33];
  int b = blockIdx.z & 1, which = blockIdx.z >> 1;
  const float* in = which ? temb : semb;
  u16* oh = which ? Bh : Ah;
  u16* ol = which ? Bl : Al;
  int c0 = blockIdx.x * 32, n0 = blockIdx.y * 32;
  int tx = threadIdx.x, ty = threadIdx.y;
  #pragma unroll
  for (int i = 0; i < 4; i++){
    int r = ty + 8 * i;
    tile[r][tx] = in[((b * CC + c0 + r) * NN) + n0 + tx];
  }
  __syncthreads();
  #pragma unroll
  for (int i = 0; i < 4; i++){
    int r = ty + 8 * i;
    float v = tile[tx][r];
    u16 hi = f2b(v);
    float lo = v - b2f(hi);
    size_t o = ((size_t)(b * NN + n0 + r) * CC) + c0 + tx;
    oh[o] = hi;
    ol[o] = f2b(lo);
  }
}

// ---- K1: exact f32 row squared norms from (B,C,N) layout (coalesced over n) --------
__global__ __launch_bounds__(256) void k_sq(const float* __restrict__ semb, const float* __restrict__ temb,
                                            float* __restrict__ xx, float* __restrict__ yy){
  int which = blockIdx.y;
  const float* in = which ? temb : semb;
  float* out = which ? yy : xx;
  int gid = blockIdx.x * 256 + threadIdx.x;   // 0..4095
  int b = gid >> 11, n = gid & 2047;
  float acc = 0.f;
  for (int c = 0; c < CC; c++){
    float v = in[((size_t)(b * CC + c)) * NN + n];
    acc += v * v;
  }
  out[gid] = acc;
}

// ---- K2: dist = xx - 2*A.B^T + yy, split-bf16 MFMA (hi*hi + hi*lo + lo*hi) ---------
__global__ __launch_bounds__(256) void k_gemm(const u16* __restrict__ Ah, const u16* __restrict__ Al,
                                              const u16* __restrict__ Bh, const u16* __restrict__ Bl,
                                              const float* __restrict__ xx, const float* __restrict__ yy,
                                              float* __restrict__ dist){
  __shared__ __align__(16) u16 lAh[128 * 64];
  __shared__ __align__(16) u16 lAl[128 * 64];
  __shared__ __align__(16) u16 lBh[128 * 64];
  __shared__ __align__(16) u16 lBl[128 * 64];
  int n0 = blockIdx.y * 128, m0 = blockIdx.x * 128;
  int t = threadIdx.x;
  f32x4 acc[4][4];
  #pragma unroll
  for (int i = 0; i < 4; i++)
    #pragma unroll
    for (int j = 0; j < 4; j++){ f32x4 z = {0.f, 0.f, 0.f, 0.f}; acc[i][j] = z; }
  int w = t >> 6, lane = t & 63, lr = lane & 15, quad = lane >> 4;
  int wn = (w >> 1) * 64, wm = (w & 1) * 64;
  for (int kt = 0; kt < 8; kt++){
    int k0 = kt * 64;
    bf16x8 vah[4], val[4], vbh[4], vbl[4];
    #pragma unroll
    for (int s = 0; s < 4; s++){
      int ch = t + 256 * s;
      int rn = ch >> 3, k8 = (ch & 7) * 8;
      size_t oa = (size_t)(n0 + rn) * CC + k0 + k8;
      size_t ob = (size_t)(m0 + rn) * CC + k0 + k8;
      vah[s] = *(const bf16x8*)(Ah + oa);
      val[s] = *(const bf16x8*)(Al + oa);
      vbh[s] = *(const bf16x8*)(Bh + ob);
      vbl[s] = *(const bf16x8*)(Bl + ob);
    }
    __syncthreads();
    #pragma unroll
    for (int s = 0; s < 4; s++){
      int ch = t + 256 * s;
      *(bf16x8*)&lAh[ch * 8] = vah[s];
      *(bf16x8*)&lAl[ch * 8] = val[s];
      *(bf16x8*)&lBh[ch * 8] = vbh[s];
      *(bf16x8*)&lBl[ch * 8] = vbl[s];
    }
    __syncthreads();
    #pragma unroll
    for (int kk = 0; kk < 2; kk++){
      int off = kk * 32 + quad * 8;
      bf16x8 afh[4], afl[4], bfh[4], bfl[4];
      #pragma unroll
      for (int i = 0; i < 4; i++){
        int ra = (wn + i * 16 + lr) * 64 + off;
        afh[i] = *(const bf16x8*)&lAh[ra];
        afl[i] = *(const bf16x8*)&lAl[ra];
      }
      #pragma unroll
      for (int j = 0; j < 4; j++){
        int rb = (wm + j * 16 + lr) * 64 + off;
        bfh[j] = *(const bf16x8*)&lBh[rb];
        bfl[j] = *(const bf16x8*)&lBl[rb];
      }
      #pragma unroll
      for (int i = 0; i < 4; i++)
        #pragma unroll
        for (int j = 0; j < 4; j++){
          acc[i][j] = __builtin_amdgcn_mfma_f32_16x16x32_bf16(afh[i], bfh[j], acc[i][j], 0, 0, 0);
          acc[i][j] = __builtin_amdgcn_mfma_f32_16x16x32_bf16(afh[i], bfl[j], acc[i][j], 0, 0, 0);
          acc[i][j] = __builtin_amdgcn_mfma_f32_16x16x32_bf16(afl[i], bfh[j], acc[i][j], 0, 0, 0);
        }
    }
  }
  #pragma unroll
  for (int i = 0; i < 4; i++){
    int nbase = n0 + wn + i * 16 + quad * 4;
    #pragma unroll
    for (int j = 0; j < 4; j++){
      int m = m0 + wm + j * 16 + lr;
      float yv = yy[m];
      #pragma unroll
      for (int r = 0; r < 4; r++){
        dist[((size_t)(nbase + r)) * MM + m] = xx[nbase + r] + yv - 2.0f * acc[i][j][r];
      }
    }
  }
}

// ---- K3: per-row min & softmax(-dist) denominator ----------------------------------
__global__ __launch_bounds__(256) void k_rowstats(const float* __restrict__ dist,
                                                  float* __restrict__ mnA, float* __restrict__ Zr){
  __shared__ float red[256];
  int row = blockIdx.x, t = threadIdx.x;
  const float* dr = dist + (size_t)row * MM;
  float d[8];
  float mn = 3.4e38f;
  #pragma unroll
  for (int i = 0; i < 8; i++){ d[i] = sane(dr[t + 256 * i]); mn = fminf(mn, d[i]); }
  mn = blockRed(mn, red, t, 1);
  float z = 0.f;
  #pragma unroll
  for (int i = 0; i < 8; i++) z += expf(mn - d[i]);
  z = blockRed(z, red, t, 0);
  if (t == 0){ mnA[row] = mn; Zr[row] = fmaxf(z, 1e-30f); }
}

// ---- K4: fused T/S/refined/rmm/src_corr/loss per row n (per batch) -----------------
__global__ __launch_bounds__(256) void k_fused(const float* __restrict__ dist, const float* __restrict__ mnA,
                                               const float* __restrict__ Zr, const int* __restrict__ sidx1b,
                                               const int* __restrict__ idx2b, const float* __restrict__ tgtb,
                                               float* __restrict__ s_corrb, float* __restrict__ lossb){
  __shared__ float Trow[MM];
  __shared__ float red[256];
  int n = blockIdx.x, t = threadIdx.x;
  const float* dn_p = dist + (size_t)n * MM;
  float dn[8];
  #pragma unroll
  for (int i = 0; i < 8; i++) dn[i] = sane(dn_p[t + 256 * i]);
  float tacc[8] = {0, 0, 0, 0, 0, 0, 0, 0};
  const int* i1 = sidx1b + n * KK1;
  for (int j = 1; j < KK1; j++){
    int r = i1[j] & 2047;
    float mnj = mnA[r];
    float izj = 1.0f / Zr[r];
    const float* drp = dist + (size_t)r * MM;
    #pragma unroll
    for (int i = 0; i < 8; i++) tacc[i] += expf(mnj - sane(drp[t + 256 * i])) * izj;
  }
  #pragma unroll
  for (int i = 0; i < 8; i++) Trow[t + 256 * i] = tacc[i];
  __syncthreads();
  float rloc[8];
  float lmin = 3.4e38f;
  #pragma unroll
  for (int i = 0; i < 8; i++){
    int m = t + 256 * i;
    const int* ip = idx2b + m * KK1;
    float S = 0.f;
    #pragma unroll
    for (int j = 1; j < KK1; j++) S += Trow[ip[j] & 2047];
    float rv = sane(expf(1.0f - S / 7.0f) * dn[i]);
    rloc[i] = rv;
    lmin = fminf(lmin, rv);
  }
  float rmin = blockRed(lmin, red, t, 1);
  float z = 0.f, s0 = 0.f, s1 = 0.f, s2 = 0.f;
  #pragma unroll
  for (int i = 0; i < 8; i++){
    int m = t + 256 * i;
    float p = expf(rmin - rloc[i]);
    z  += p;
    s0 += tgtb[0 * MM + m] * p;
    s1 += tgtb[1 * MM + m] * p;
    s2 += tgtb[2 * MM + m] * p;
  }
  z  = blockRed(z,  red, t, 0);
  s0 = blockRed(s0, red, t, 0);
  s1 = blockRed(s1, red, t, 0);
  s2 = blockRed(s2, red, t, 0);
  if (t == 0){
    float iZ = 1.0f / fmaxf(z, 1e-30f);
    s_corrb[0 * NN + n] = s0 * iZ;
    s_corrb[1 * NN + n] = s1 * iZ;
    s_corrb[2 * NN + n] = s2 * iZ;
    lossb[n] = -logf(fminf(iZ, 1.0f) + 1e-15f);  // pred at onehot == rowmax(rmm) == 1/Z
  }
}

// ---- K5: discriminator MLP — R14: scalar-W2 restored + e-range wave split ----------
// R12 (72us): thread=point, e-loop uniform -> W2 via s_load (SGPR_Count=112), but
//   only 1024 waves (1/SIMD) -> latency exposed, VALUBusy 17%.
// R13 (238us, FAILED): W2 address became lane-dependent -> 128 scattered
//   global_load_dwordx4/thread, latency-bound, VALUBusy 9%. Lesson: keep W2 scalar.
// R14: block = 4 waves x 64 points (lane=point). Wave w owns e in [32w,32w+32):
//   e made provably wave-uniform via readfirstlane -> W2/b2 stay s_load.
//   Each lane computes all 64 h in regs (L1D/HSET verbatim; 4x redundant, ~450
//   VALU/thread, cheap). 32 independent e-chains/thread (QSTEP verbatim), terms
//   relu(a) -> LDS [64][129] (banks (p+e)%32 -> 2-way, free). Wave 0 folds
//   e=0..127 serially per point (verbatim), clamp, 16-lane max tree (exact).
// 1024 blocks x 4 waves = 4096 waves = 16/CU; LDS 33KB -> 4 blocks/CU;
// launch_bounds(256,4) caps VGPR at 128 (~100 needed: 64 h + misc).
__global__ __launch_bounds__(256, 4) void k_disc(const float* __restrict__ s_corr, const float* __restrict__ src,
                                                 const float* __restrict__ sknn, const int* __restrict__ sidx,
                                                 const float* __restrict__ W1, const float* __restrict__ b1,
                                                 const float* __restrict__ W2, const float* __restrict__ b2,
                                                 const float* __restrict__ W3, const float* __restrict__ b3,
                                                 float* __restrict__ sArr){
  __shared__ float term[64][129];
  int t = threadIdx.x;
  int b = blockIdx.y;
  int p = t & 63;                      // point within block (lane)
  int n = blockIdx.x * 4 + (p >> 4);   // 4 n-rows per block
  int kk = p & 15;
  int eh = t >> 6;                     // wave id = e-quarter
  int nk = sidx[((b * NN + n) * KK) + kk] & 2047;
  float f[6];
  #pragma unroll
  for (int c = 0; c < 3; c++){
    f[c]     = s_corr[(b * 3 + c) * NN + n] - s_corr[(b * 3 + c) * NN + nk];
    f[3 + c] = src[(b * 3 + c) * NN + n] - sknn[((size_t)(b * NN + n) * KK + kk) * 3 + c];
  }
  // layer 1: per-d expressions verbatim (a = b1[d]; a += f[c]*W1[d*6+c] x6; relu)
  #define L1D(d) ({ float a_ = b1[(d)];              \
                    a_ += f[0] * W1[(d) * 6 + 0];    \
                    a_ += f[1] * W1[(d) * 6 + 1];    \
                    a_ += f[2] * W1[(d) * 6 + 2];    \
                    a_ += f[3] * W1[(d) * 6 + 3];    \
                    a_ += f[4] * W1[(d) * 6 + 4];    \
                    a_ += f[5] * W1[(d) * 6 + 5];    \
                    fmaxf(a_, 0.f); })
  #define HSET(i) f32x4 h##i;                  \
                  h##i.x = L1D(4 * (i) + 0);   \
                  h##i.y = L1D(4 * (i) + 1);   \
                  h##i.z = L1D(4 * (i) + 2);   \
                  h##i.w = L1D(4 * (i) + 3);
  HSET(0) HSET(1) HSET(2) HSET(3) HSET(4) HSET(5) HSET(6) HSET(7)
  HSET(8) HSET(9) HSET(10) HSET(11) HSET(12) HSET(13) HSET(14) HSET(15)
  #undef HSET
  #undef L1D
  // layer 2: this wave's 32 e-chains, e wave-uniform so W2/b2 are scalar loads
  int e0 = __builtin_amdgcn_readfirstlane(eh * 32);
  for (int j = 0; j < 32; j++){
    int e = e0 + j;
    float a = b2[e];
    const f32x4* w4 = (const f32x4*)&W2[e * 64];
    #define QSTEP(i) { f32x4 wv = w4[i]; a += wv.x * h##i.x + wv.y * h##i.y + wv.z * h##i.z + wv.w * h##i.w; }
    QSTEP(0) QSTEP(1) QSTEP(2) QSTEP(3) QSTEP(4) QSTEP(5) QSTEP(6) QSTEP(7)
    QSTEP(8) QSTEP(9) QSTEP(10) QSTEP(11) QSTEP(12) QSTEP(13) QSTEP(14) QSTEP(15)
    #undef QSTEP
    term[p][e] = fmaxf(a, 0.f);
  }
  __syncthreads();
  // layer 3: serial left-fold per point in e-order (verbatim), then 16-lane max
  if (t < 64){
    float sacc = b3[0];
    #pragma unroll 4
    for (int e = 0; e < 128; e++) sacc += W3[e] * term[t][e];
    if (!(fabsf(sacc) < 1e30f)) sacc = -1e30f;
    #pragma unroll
    for (int off = 1; off < 16; off <<= 1) sacc = fmaxf(sacc, __shfl_xor(sacc, off, 16));
    if (kk == 0) sArr[b * NN + n] = sacc;
  }
}

// ---- K6: weight = softmax(s) over n ------------------------------------------------
__global__ __launch_bounds__(256) void k_softw(const float* __restrict__ sArr, float* __restrict__ wArr){
  __shared__ float red[256];
  int b = blockIdx.x, t = threadIdx.x;
  const float* sp = sArr + b * NN;
  float sv[8];
  float mx = -3.4e38f;
  #pragma unroll
  for (int i = 0; i < 8; i++){
    float v = sp[t + 256 * i];
    if (!(fabsf(v) < 1e30f)) v = -1e30f;
    sv[i] = v; mx = fmaxf(mx, v);
  }
  mx = blockRed(mx, red, t, 2);
  float z = 0.f;
  #pragma unroll
  for (int i = 0; i < 8; i++) z += expf(sv[i] - mx);
  z = blockRed(z, red, t, 0);
  float iz = 1.0f / fmaxf(z, 1e-30f);
  #pragma unroll
  for (int i = 0; i < 8; i++) wArr[b * NN + t + 256 * i] = expf(sv[i] - mx) * iz;
}

// ---- K7: stable descending rank -> topi --------------------------------------------
__global__ __launch_bounds__(256) void k_rank(const float* __restrict__ wArr, int* __restrict__ topi){
  __shared__ float wrow[NN];
  int b = blockIdx.y, t = threadIdx.x;
  for (int i = t; i < NN; i += 256) wrow[i] = wArr[b * NN + i];
  __syncthreads();
  int n = blockIdx.x * 256 + t;
  float wn = wrow[n];
  int cnt = 0;
  for (int j = 0; j < NN; j++){
    float wj = wrow[j];
    cnt += (wj > wn) || ((wj == wn) && (j < n));
  }
  if (cnt < KEY) topi[b * KEY + cnt] = n;
}

// ---- K8: weighted centroids, H, 3x3 SVD (f64 Jacobi), R/t --------------------------
__device__ __forceinline__ double det3d(const double A[3][3]){
  return A[0][0] * (A[1][1] * A[2][2] - A[1][2] * A[2][1])
       - A[0][1] * (A[1][0] * A[2][2] - A[1][2] * A[2][0])
       + A[0][2] * (A[1][0] * A[2][1] - A[1][1] * A[2][0]);
}

__global__ __launch_bounds__(256) void k_rigid(const float* __restrict__ src, const float* __restrict__ s_corr,
                                               const float* __restrict__ wArr, float* __restrict__ Rt,
                                               float* __restrict__ out){
  __shared__ float red[256];
  int b = blockIdx.x, t = threadIdx.x;
  float wsum = 0, a0 = 0, a1 = 0, a2 = 0, c0 = 0, c1 = 0, c2 = 0;
  for (int n = t; n < NN; n += 256){
    float wv = wArr[b * NN + n];
    float s0 = src[(b * 3 + 0) * NN + n];
    float s1 = src[(b * 3 + 1) * NN + n];
    float s2 = src[(b * 3 + 2) * NN + n];
    float q0 = s_corr[(b * 3 + 0) * NN + n];
    float q1 = s_corr[(b * 3 + 1) * NN + n];
    float q2 = s_corr[(b * 3 + 2) * NN + n];
    wsum += wv; a0 += wv * s0; a1 += wv * s1; a2 += wv * s2;
    c0 += wv * q0; c1 += wv * q1; c2 += wv * q2;
  }
  wsum = blockRed(wsum, red, t, 0);
  a0 = blockRed(a0, red, t, 0); a1 = blockRed(a1, red, t, 0); a2 = blockRed(a2, red, t, 0);
  c0 = blockRed(c0, red, t, 0); c1 = blockRed(c1, red, t, 0); c2 = blockRed(c2, red, t, 0);
  float inv = 1.0f / fmaxf(wsum, 1e-30f);
  float cs0 = a0 * inv, cs1 = a1 * inv, cs2 = a2 * inv;
  float ct0 = c0 * inv, ct1 = c1 * inv, ct2 = c2 * inv;
  float h[9] = {0, 0, 0, 0, 0, 0, 0, 0, 0};
  for (int n = t; n < NN; n += 256){
    float wv = wArr[b * NN + n];
    float ds0 = src[(b * 3 + 0) * NN + n] - cs0;
    float ds1 = src[(b * 3 + 1) * NN + n] - cs1;
    float ds2 = src[(b * 3 + 2) * NN + n] - cs2;
    float dc0 = s_corr[(b * 3 + 0) * NN + n] - ct0;
    float dc1 = s_corr[(b * 3 + 1) * NN + n] - ct1;
    float dc2 = s_corr[(b * 3 + 2) * NN + n] - ct2;
    h[0] += wv * ds0 * dc0; h[1] += wv * ds0 * dc1; h[2] += wv * ds0 * dc2;
    h[3] += wv * ds1 * dc0; h[4] += wv * ds1 * dc1; h[5] += wv * ds1 * dc2;
    h[6] += wv * ds2 * dc0; h[7] += wv * ds2 * dc1; h[8] += wv * ds2 * dc2;
  }
  for (int i = 0; i < 9; i++) h[i] = blockRed(h[i], red, t, 0);
  if (t == 0){
    double Hm[3][3];
    for (int i = 0; i < 3; i++)
      for (int j = 0; j < 3; j++) Hm[i][j] = (double)h[i * 3 + j];
    double Km[3][3], V[3][3] = {{1, 0, 0}, {0, 1, 0}, {0, 0, 1}};
    for (int i = 0; i < 3; i++)
      for (int j = 0; j < 3; j++){
        double s = 0;
        for (int a = 0; a < 3; a++) s += Hm[a][i] * Hm[a][j];
        Km[i][j] = s;
      }
    double ksc = fabs(Km[0][0]) + fabs(Km[1][1]) + fabs(Km[2][2]) + 1e-300;
    for (int sweep = 0; sweep < 60; sweep++){
      int p = 0, q = 1; double mx = fabs(Km[0][1]);
      if (fabs(Km[0][2]) > mx){ mx = fabs(Km[0][2]); p = 0; q = 2; }
      if (fabs(Km[1][2]) > mx){ mx = fabs(Km[1][2]); p = 1; q = 2; }
      if (mx <= 1e-15 * ksc) break;
      double app = Km[p][p], aqq = Km[q][q], apq = Km[p][q];
      double tau = (aqq - app) / (2.0 * apq);
      double tt = ((tau >= 0) ? 1.0 : -1.0) / (fabs(tau) + sqrt(1.0 + tau * tau));
      double cc = 1.0 / sqrt(1.0 + tt * tt), sn = tt * cc;
      for (int k2 = 0; k2 < 3; k2++){
        double akp = Km[k2][p], akq = Km[k2][q];
        Km[k2][p] = cc * akp - sn * akq; Km[k2][q] = sn * akp + cc * akq;
      }
      for (int k2 = 0; k2 < 3; k2++){
        double apk = Km[p][k2], aqk = Km[q][k2];
        Km[p][k2] = cc * apk - sn * aqk; Km[q][k2] = sn * apk + cc * aqk;
      }
      for (int k2 = 0; k2 < 3; k2++){
        double vkp = V[k2][p], vkq = V[k2][q];
        V[k2][p] = cc * vkp - sn * vkq; V[k2][q] = sn * vkp + cc * vkq;
      }
    }
    double lam[3] = {Km[0][0], Km[1][1], Km[2][2]};
    int id0 = 0, id1 = 1, id2 = 2, tmp;
    if (lam[id0] < lam[id1]){ tmp = id0; id0 = id1; id1 = tmp; }
    if (lam[id0] < lam[id2]){ tmp = id0; id0 = id2; id2 = tmp; }
    if (lam[id1] < lam[id2]){ tmp = id1; id1 = id2; id2 = tmp; }
    int idx[3] = {id0, id1, id2};
    double Vs[3][3], U[3][3] = {{0, 0, 0}, {0, 0, 0}, {0, 0, 0}};
    for (int jj = 0; jj < 3; jj++){
      int j = idx[jj];
      for (int i2 = 0; i2 < 3; i2++) Vs[i2][jj] = V[i2][j];
      double u0 = 0, u1 = 0, u2 = 0;
      for (int i2 = 0; i2 < 3; i2++){
        u0 += Hm[0][i2] * V[i2][j];
        u1 += Hm[1][i2] * V[i2][j];
        u2 += Hm[2][i2] * V[i2][j];
      }
      double nrm = sqrt(u0 * u0 + u1 * u1 + u2 * u2);
      if (nrm > 1e-20){
        U[0][jj] = u0 / nrm; U[1][jj] = u1 / nrm; U[2][jj] = u2 / nrm;
      } else {
        double x0 = U[1][0] * U[2][1] - U[2][0] * U[1][1];
        double x1 = U[2][0] * U[0][1] - U[0][0] * U[2][1];
        double x2 = U[0][0] * U[1][1] - U[1][0] * U[0][1];
        double nn2 = sqrt(x0 * x0 + x1 * x1 + x2 * x2);
        if (nn2 < 1e-20){ x0 = 1; x1 = 0; x2 = 0; nn2 = 1; }
        U[0][jj] = x0 / nn2; U[1][jj] = x1 / nn2; U[2][jj] = x2 / nn2;
      }
    }
    double dd = det3d(U) * det3d(Vs);
    double Rm[3][3];
    for (int i2 = 0; i2 < 3; i2++)
      for (int k2 = 0; k2 < 3; k2++)
        Rm[i2][k2] = Vs[i2][0] * U[k2][0] + Vs[i2][1] * U[k2][1] + dd * Vs[i2][2] * U[k2][2];
    double cs[3] = {cs0, cs1, cs2}, ct[3] = {ct0, ct1, ct2};
    double tv[3];
    for (int i2 = 0; i2 < 3; i2++)
      tv[i2] = ct[i2] - (Rm[i2][0] * cs[0] + Rm[i2][1] * cs[1] + Rm[i2][2] * cs[2]);
    for (int i2 = 0; i2 < 3; i2++)
      for (int k2 = 0; k2 < 3; k2++){
        Rt[b * 12 + i2 * 3 + k2] = (float)Rm[i2][k2];
        out[b * 9 + i2 * 3 + k2] = (float)Rm[i2][k2];
      }
    for (int i2 = 0; i2 < 3; i2++){
      Rt[b * 12 + 9 + i2] = (float)tv[i2];
      out[18 + b * 3 + i2] = (float)tv[i2];
    }
  }
}

// ---- K10: gather keypoint outputs, with src_transformed fused inline ---------------
// (k_st eliminated: st values computed at the gathered indices with the identical
// expression R[c*3+0]*s0 + R[c*3+1]*s1 + R[c*3+2]*s2 + R[9+c] -> bitwise-same out)
__global__ __launch_bounds__(256) void k_out(const int* __restrict__ topi, const int* __restrict__ sidx,
                                             const float* __restrict__ src, const float* __restrict__ s_corr,
                                             const float* __restrict__ Rt, float* __restrict__ out){
  int b = blockIdx.y, t = threadIdx.x;
  int rr = t >> 4, kk = t & 15;
  int r = blockIdx.x * 16 + rr;
  int ns = topi[b * KEY + r] & 2047;
  int nk = sidx[(b * NN + ns) * KK + kk] & 2047;
  const float* R = Rt + b * 12;
  float sns0 = src[(b * 3 + 0) * NN + ns];
  float sns1 = src[(b * 3 + 1) * NN + ns];
  float sns2 = src[(b * 3 + 2) * NN + ns];
  float snk0 = src[(b * 3 + 0) * NN + nk];
  float snk1 = src[(b * 3 + 1) * NN + nk];
  float snk2 = src[(b * 3 + 2) * NN + nk];
  float* o_sk  = out + 24;
  float* o_tk  = out + 6168;
  float* o_skk = out + 12312;
  float* o_tkk = out + 110616;
  #pragma unroll
  for (int c = 0; c < 3; c++){
    float cv  = s_corr[(b * 3 + c) * NN + ns];
    float ck  = s_corr[(b * 3 + c) * NN + nk];
    o_tkk[(((b * 3 + c) * KEY + r) * KK) + kk] = cv - ck;
    float sv  = R[c * 3 + 0] * sns0 + R[c * 3 + 1] * sns1 + R[c * 3 + 2] * sns2 + R[9 + c];
    float sk2 = R[c * 3 + 0] * snk0 + R[c * 3 + 1] * snk1 + R[c * 3 + 2] * snk2 + R[9 + c];
    o_skk[(((b * 3 + c) * KEY + r) * KK) + kk] = sv - sk2;
    if (kk == 0){
      o_sk[(b * 3 + c) * KEY + r] = sns0 * (c == 0) + sns1 * (c == 1) + sns2 * (c == 2);
      o_tk[(b * 3 + c) * KEY + r] = cv;
    }
  }
}

// ---- K11: loss_scl -----------------------------------------------------------------
__global__ __launch_bounds__(256) void k_loss(const float* __restrict__ loss_row, const int* __restrict__ topi,
                                              float* __restrict__ out){
  __shared__ float red[256];
  int t = threadIdx.x;
  float acc = 0.f;
  for (int i = t; i < BB * KEY; i += 256){
    int b = i >> 10, r = i & 1023;
    int n = topi[b * KEY + r] & 2047;
    acc += loss_row[b * NN + n];
  }
  acc = blockRed(acc, red, t, 0);
  if (t == 0) out[208920] = acc / 2048.0f;
}

extern "C" void kernel_launch(void* const* d_in, const int* in_sizes, int n_in,
                              void* d_out, int out_size, void* d_ws, size_t ws_size,
                              hipStream_t stream){
  const float* src  = (const float*)d_in[0];
  const float* tgt  = (const float*)d_in[1];
  const float* semb = (const float*)d_in[2];
  const float* temb = (const float*)d_in[3];
  const float* sknn = (const float*)d_in[4];
  const float* W1 = (const float*)d_in[6];
  const float* b1 = (const float*)d_in[7];
  const float* W2 = (const float*)d_in[8];
  const float* b2 = (const float*)d_in[9];
  const float* W3 = (const float*)d_in[10];
  const float* b3 = (const float*)d_in[11];
  const int* sidx  = (const int*)d_in[12];
  const int* sidx1 = (const int*)d_in[13];
  const int* idx2  = (const int*)d_in[14];
  float* out = (float*)d_out;

  // workspace layout (peak ~33.4 MB)
  char* w = (char*)d_ws;
  u16* Ah = (u16*)(w);                               // 4 MB each (B,N,C) bf16 split
  u16* Al = Ah + (size_t)BB * NN * CC;
  u16* Bh = Al + (size_t)BB * NN * CC;
  u16* Bl = Bh + (size_t)BB * MM * CC;
  float* dist = (float*)(Bl + (size_t)BB * MM * CC); // 16.78 MB (N,M) f32, per-batch reuse
  char* tail = (char*)(dist + (size_t)NN * MM);
  float* xx = (float*)tail;                          // B*N
  float* yy = xx + BB * NN;                          // B*M
  float* mnA = yy + BB * MM;                         // B*N
  float* Zr = mnA + BB * NN;                         // B*N
  float* s_corr = Zr + BB * NN;                      // B*3*N
  float* loss_row = s_corr + BB * 3 * NN;            // B*N
  float* sArr = loss_row + BB * NN;                  // B*N
  float* wArr = sArr + BB * NN;                      // B*N
  int* topi = (int*)(wArr + BB * NN);                // B*KEY
  float* Rt = (float*)(topi + BB * KEY);             // B*12

  k_trans<<<dim3(16, 64, 4), dim3(32, 8), 0, stream>>>(semb, temb, Ah, Al, Bh, Bl);
  k_sq<<<dim3(16, 2), 256, 0, stream>>>(semb, temb, xx, yy);
  for (int b = 0; b < BB; b++){
    k_gemm<<<dim3(16, 16), 256, 0, stream>>>(Ah + (size_t)b * NN * CC, Al + (size_t)b * NN * CC,
                                             Bh + (size_t)b * MM * CC, Bl + (size_t)b * MM * CC,
                                             xx + b * NN, yy + b * MM, dist);
    k_rowstats<<<NN, 256, 0, stream>>>(dist, mnA + b * NN, Zr + b * NN);
    k_fused<<<NN, 256, 0, stream>>>(dist, mnA + b * NN, Zr + b * NN,
                                    sidx1 + (size_t)b * NN * KK1, idx2 + (size_t)b * MM * KK1,
                                    tgt + (size_t)b * 3 * MM, s_corr + (size_t)b * 3 * NN,
                                    loss_row + b * NN);
  }
  k_disc<<<dim3(NN / 4, BB), 256, 0, stream>>>(s_corr, src, sknn, sidx, W1, b1, W2, b2, W3, b3, sArr);
  k_softw<<<BB, 256, 0, stream>>>(sArr, wArr);
  k_rank<<<dim3(8, BB), 256, 0, stream>>>(wArr, topi);
  k_rigid<<<BB, 256, 0, stream>>>(src, s_corr, wArr, Rt, out);
  k_out<<<dim3(64, BB), 256, 0, stream>>>(topi, sidx, src, s_corr, Rt, out);
  k_loss<<<1, 256, 0, stream>>>(loss_row, topi, out);
}

// Round 3
// 309.986 us; speedup vs baseline: 1.7793x; 1.1170x over previous
//
#include <hip/hip_runtime.h>
#include <stdint.h>

typedef unsigned short u16;

#define BB 2
#define NN 2048
#define MM 2048
#define CC 512
#define KK 16
#define KK1 8
#define KEY 1024

typedef __attribute__((ext_vector_type(8))) short bf16x8;
typedef __attribute__((ext_vector_type(4))) float f32x4;

__device__ __forceinline__ float b2f(u16 u){ return __uint_as_float(((uint32_t)u) << 16); }
__device__ __forceinline__ u16 f2b(float f){
  uint32_t x = __float_as_uint(f);
  uint32_t r = x + 0x7FFFu + ((x >> 16) & 1u);
  return (u16)(r >> 16);
}
__device__ __forceinline__ float sane(float v){ return (fabsf(v) < 1e30f) ? v : 1e30f; }

// all-thread block reduction, 256 threads. op: 0=sum 1=min 2=max
__device__ __forceinline__ float blockRed(float v, float* red, int t, int op){
  red[t] = v; __syncthreads();
  #pragma unroll
  for (int s = 128; s > 0; s >>= 1){
    if (t < s){
      float a = red[t], b = red[t + s];
      red[t] = (op == 0) ? (a + b) : ((op == 1) ? fminf(a, b) : fmaxf(a, b));
    }
    __syncthreads();
  }
  float r = red[0]; __syncthreads();
  return r;
}

// ---- K0: transpose f32 (B,C,N) -> split-bf16 (B,N,C) hi/lo pairs -------------------
__global__ __launch_bounds__(256) void k_trans(const float* __restrict__ semb, const float* __restrict__ temb,
                                               u16* __restrict__ Ah, u16* __restrict__ Al,
                                               u16* __restrict__ Bh, u16* __restrict__ Bl){
  __shared__ float tile[32][33];
  int b = blockIdx.z & 1, which = blockIdx.z >> 1;
  const float* in = which ? temb : semb;
  u16* oh = which ? Bh : Ah;
  u16* ol = which ? Bl : Al;
  int c0 = blockIdx.x * 32, n0 = blockIdx.y * 32;
  int tx = threadIdx.x, ty = threadIdx.y;
  #pragma unroll
  for (int i = 0; i < 4; i++){
    int r = ty + 8 * i;
    tile[r][tx] = in[((b * CC + c0 + r) * NN) + n0 + tx];
  }
  __syncthreads();
  #pragma unroll
  for (int i = 0; i < 4; i++){
    int r = ty + 8 * i;
    float v = tile[tx][r];
    u16 hi = f2b(v);
    float lo = v - b2f(hi);
    size_t o = ((size_t)(b * NN + n0 + r) * CC) + c0 + tx;
    oh[o] = hi;
    ol[o] = f2b(lo);
  }
}

// ---- K1: exact f32 row squared norms from (B,C,N) layout (coalesced over n) --------
__global__ __launch_bounds__(256) void k_sq(const float* __restrict__ semb, const float* __restrict__ temb,
                                            float* __restrict__ xx, float* __restrict__ yy){
  int which = blockIdx.y;
  const float* in = which ? temb : semb;
  float* out = which ? yy : xx;
  int gid = blockIdx.x * 256 + threadIdx.x;   // 0..4095
  int b = gid >> 11, n = gid & 2047;
  float acc = 0.f;
  for (int c = 0; c < CC; c++){
    float v = in[((size_t)(b * CC + c)) * NN + n];
    acc += v * v;
  }
  out[gid] = acc;
}

// ---- K2: dist = xx - 2*A.B^T + yy, split-bf16 MFMA (hi*hi + hi*lo + lo*hi) ---------
__global__ __launch_bounds__(256) void k_gemm(const u16* __restrict__ Ah, const u16* __restrict__ Al,
                                              const u16* __restrict__ Bh, const u16* __restrict__ Bl,
                                              const float* __restrict__ xx, const float* __restrict__ yy,
                                              float* __restrict__ dist){
  __shared__ __align__(16) u16 lAh[128 * 64];
  __shared__ __align__(16) u16 lAl[128 * 64];
  __shared__ __align__(16) u16 lBh[128 * 64];
  __shared__ __align__(16) u16 lBl[128 * 64];
  int n0 = blockIdx.y * 128, m0 = blockIdx.x * 128;
  int t = threadIdx.x;
  f32x4 acc[4][4];
  #pragma unroll
  for (int i = 0; i < 4; i++)
    #pragma unroll
    for (int j = 0; j < 4; j++){ f32x4 z = {0.f, 0.f, 0.f, 0.f}; acc[i][j] = z; }
  int w = t >> 6, lane = t & 63, lr = lane & 15, quad = lane >> 4;
  int wn = (w >> 1) * 64, wm = (w & 1) * 64;
  for (int kt = 0; kt < 8; kt++){
    int k0 = kt * 64;
    bf16x8 vah[4], val[4], vbh[4], vbl[4];
    #pragma unroll
    for (int s = 0; s < 4; s++){
      int ch = t + 256 * s;
      int rn = ch >> 3, k8 = (ch & 7) * 8;
      size_t oa = (size_t)(n0 + rn) * CC + k0 + k8;
      size_t ob = (size_t)(m0 + rn) * CC + k0 + k8;
      vah[s] = *(const bf16x8*)(Ah + oa);
      val[s] = *(const bf16x8*)(Al + oa);
      vbh[s] = *(const bf16x8*)(Bh + ob);
      vbl[s] = *(const bf16x8*)(Bl + ob);
    }
    __syncthreads();
    #pragma unroll
    for (int s = 0; s < 4; s++){
      int ch = t + 256 * s;
      *(bf16x8*)&lAh[ch * 8] = vah[s];
      *(bf16x8*)&lAl[ch * 8] = val[s];
      *(bf16x8*)&lBh[ch * 8] = vbh[s];
      *(bf16x8*)&lBl[ch * 8] = vbl[s];
    }
    __syncthreads();
    #pragma unroll
    for (int kk = 0; kk < 2; kk++){
      int off = kk * 32 + quad * 8;
      bf16x8 afh[4], afl[4], bfh[4], bfl[4];
      #pragma unroll
      for (int i = 0; i < 4; i++){
        int ra = (wn + i * 16 + lr) * 64 + off;
        afh[i] = *(const bf16x8*)&lAh[ra];
        afl[i] = *(const bf16x8*)&lAl[ra];
      }
      #pragma unroll
      for (int j = 0; j < 4; j++){
        int rb = (wm + j * 16 + lr) * 64 + off;
        bfh[j] = *(const bf16x8*)&lBh[rb];
        bfl[j] = *(const bf16x8*)&lBl[rb];
      }
      #pragma unroll
      for (int i = 0; i < 4; i++)
        #pragma unroll
        for (int j = 0; j < 4; j++){
          acc[i][j] = __builtin_amdgcn_mfma_f32_16x16x32_bf16(afh[i], bfh[j], acc[i][j], 0, 0, 0);
          acc[i][j] = __builtin_amdgcn_mfma_f32_16x16x32_bf16(afh[i], bfl[j], acc[i][j], 0, 0, 0);
          acc[i][j] = __builtin_amdgcn_mfma_f32_16x16x32_bf16(afl[i], bfh[j], acc[i][j], 0, 0, 0);
        }
    }
  }
  #pragma unroll
  for (int i = 0; i < 4; i++){
    int nbase = n0 + wn + i * 16 + quad * 4;
    #pragma unroll
    for (int j = 0; j < 4; j++){
      int m = m0 + wm + j * 16 + lr;
      float yv = yy[m];
      #pragma unroll
      for (int r = 0; r < 4; r++){
        dist[((size_t)(nbase + r)) * MM + m] = xx[nbase + r] + yv - 2.0f * acc[i][j][r];
      }
    }
  }
}

// ---- K3: per-row min & softmax(-dist) denominator ----------------------------------
__global__ __launch_bounds__(256) void k_rowstats(const float* __restrict__ dist,
                                                  float* __restrict__ mnA, float* __restrict__ Zr){
  __shared__ float red[256];
  int row = blockIdx.x, t = threadIdx.x;
  const float* dr = dist + (size_t)row * MM;
  float d[8];
  float mn = 3.4e38f;
  #pragma unroll
  for (int i = 0; i < 8; i++){ d[i] = sane(dr[t + 256 * i]); mn = fminf(mn, d[i]); }
  mn = blockRed(mn, red, t, 1);
  float z = 0.f;
  #pragma unroll
  for (int i = 0; i < 8; i++) z += expf(mn - d[i]);
  z = blockRed(z, red, t, 0);
  if (t == 0){ mnA[row] = mn; Zr[row] = fmaxf(z, 1e-30f); }
}

// ---- K4: fused T/S/refined/rmm/src_corr/loss per row n (per batch) -----------------
__global__ __launch_bounds__(256) void k_fused(const float* __restrict__ dist, const float* __restrict__ mnA,
                                               const float* __restrict__ Zr, const int* __restrict__ sidx1b,
                                               const int* __restrict__ idx2b, const float* __restrict__ tgtb,
                                               float* __restrict__ s_corrb, float* __restrict__ lossb){
  __shared__ float Trow[MM];
  __shared__ float red[256];
  int n = blockIdx.x, t = threadIdx.x;
  const float* dn_p = dist + (size_t)n * MM;
  float dn[8];
  #pragma unroll
  for (int i = 0; i < 8; i++) dn[i] = sane(dn_p[t + 256 * i]);
  float tacc[8] = {0, 0, 0, 0, 0, 0, 0, 0};
  const int* i1 = sidx1b + n * KK1;
  for (int j = 1; j < KK1; j++){
    int r = i1[j] & 2047;
    float mnj = mnA[r];
    float izj = 1.0f / Zr[r];
    const float* drp = dist + (size_t)r * MM;
    #pragma unroll
    for (int i = 0; i < 8; i++) tacc[i] += expf(mnj - sane(drp[t + 256 * i])) * izj;
  }
  #pragma unroll
  for (int i = 0; i < 8; i++) Trow[t + 256 * i] = tacc[i];
  __syncthreads();
  float rloc[8];
  float lmin = 3.4e38f;
  #pragma unroll
  for (int i = 0; i < 8; i++){
    int m = t + 256 * i;
    const int* ip = idx2b + m * KK1;
    float S = 0.f;
    #pragma unroll
    for (int j = 1; j < KK1; j++) S += Trow[ip[j] & 2047];
    float rv = sane(expf(1.0f - S / 7.0f) * dn[i]);
    rloc[i] = rv;
    lmin = fminf(lmin, rv);
  }
  float rmin = blockRed(lmin, red, t, 1);
  float z = 0.f, s0 = 0.f, s1 = 0.f, s2 = 0.f;
  #pragma unroll
  for (int i = 0; i < 8; i++){
    int m = t + 256 * i;
    float p = expf(rmin - rloc[i]);
    z  += p;
    s0 += tgtb[0 * MM + m] * p;
    s1 += tgtb[1 * MM + m] * p;
    s2 += tgtb[2 * MM + m] * p;
  }
  z  = blockRed(z,  red, t, 0);
  s0 = blockRed(s0, red, t, 0);
  s1 = blockRed(s1, red, t, 0);
  s2 = blockRed(s2, red, t, 0);
  if (t == 0){
    float iZ = 1.0f / fmaxf(z, 1e-30f);
    s_corrb[0 * NN + n] = s0 * iZ;
    s_corrb[1 * NN + n] = s1 * iZ;
    s_corrb[2 * NN + n] = s2 * iZ;
    lossb[n] = -logf(fminf(iZ, 1.0f) + 1e-15f);  // pred at onehot == rowmax(rmm) == 1/Z
  }
}

// ---- K5: discriminator MLP — R14: scalar-W2 + e-range wave split (see R14 notes) ---
__global__ __launch_bounds__(256, 4) void k_disc(const float* __restrict__ s_corr, const float* __restrict__ src,
                                                 const float* __restrict__ sknn, const int* __restrict__ sidx,
                                                 const float* __restrict__ W1, const float* __restrict__ b1,
                                                 const float* __restrict__ W2, const float* __restrict__ b2,
                                                 const float* __restrict__ W3, const float* __restrict__ b3,
                                                 float* __restrict__ sArr){
  __shared__ float term[64][129];
  int t = threadIdx.x;
  int b = blockIdx.y;
  int p = t & 63;                      // point within block (lane)
  int n = blockIdx.x * 4 + (p >> 4);   // 4 n-rows per block
  int kk = p & 15;
  int eh = t >> 6;                     // wave id = e-quarter
  int nk = sidx[((b * NN + n) * KK) + kk] & 2047;
  float f[6];
  #pragma unroll
  for (int c = 0; c < 3; c++){
    f[c]     = s_corr[(b * 3 + c) * NN + n] - s_corr[(b * 3 + c) * NN + nk];
    f[3 + c] = src[(b * 3 + c) * NN + n] - sknn[((size_t)(b * NN + n) * KK + kk) * 3 + c];
  }
  // layer 1: per-d expressions verbatim (a = b1[d]; a += f[c]*W1[d*6+c] x6; relu)
  #define L1D(d) ({ float a_ = b1[(d)];              \
                    a_ += f[0] * W1[(d) * 6 + 0];    \
                    a_ += f[1] * W1[(d) * 6 + 1];    \
                    a_ += f[2] * W1[(d) * 6 + 2];    \
                    a_ += f[3] * W1[(d) * 6 + 3];    \
                    a_ += f[4] * W1[(d) * 6 + 4];    \
                    a_ += f[5] * W1[(d) * 6 + 5];    \
                    fmaxf(a_, 0.f); })
  #define HSET(i) f32x4 h##i;                  \
                  h##i.x = L1D(4 * (i) + 0);   \
                  h##i.y = L1D(4 * (i) + 1);   \
                  h##i.z = L1D(4 * (i) + 2);   \
                  h##i.w = L1D(4 * (i) + 3);
  HSET(0) HSET(1) HSET(2) HSET(3) HSET(4) HSET(5) HSET(6) HSET(7)
  HSET(8) HSET(9) HSET(10) HSET(11) HSET(12) HSET(13) HSET(14) HSET(15)
  #undef HSET
  #undef L1D
  // layer 2: this wave's 32 e-chains, e wave-uniform so W2/b2 are scalar loads
  int e0 = __builtin_amdgcn_readfirstlane(eh * 32);
  for (int j = 0; j < 32; j++){
    int e = e0 + j;
    float a = b2[e];
    const f32x4* w4 = (const f32x4*)&W2[e * 64];
    #define QSTEP(i) { f32x4 wv = w4[i]; a += wv.x * h##i.x + wv.y * h##i.y + wv.z * h##i.z + wv.w * h##i.w; }
    QSTEP(0) QSTEP(1) QSTEP(2) QSTEP(3) QSTEP(4) QSTEP(5) QSTEP(6) QSTEP(7)
    QSTEP(8) QSTEP(9) QSTEP(10) QSTEP(11) QSTEP(12) QSTEP(13) QSTEP(14) QSTEP(15)
    #undef QSTEP
    term[p][e] = fmaxf(a, 0.f);
  }
  __syncthreads();
  // layer 3: serial left-fold per point in e-order (verbatim), then 16-lane max
  if (t < 64){
    float sacc = b3[0];
    #pragma unroll 4
    for (int e = 0; e < 128; e++) sacc += W3[e] * term[t][e];
    if (!(fabsf(sacc) < 1e30f)) sacc = -1e30f;
    #pragma unroll
    for (int off = 1; off < 16; off <<= 1) sacc = fmaxf(sacc, __shfl_xor(sacc, off, 16));
    if (kk == 0) sArr[b * NN + n] = sacc;
  }
}

// ---- K6: weight = softmax(s) over n ------------------------------------------------
__global__ __launch_bounds__(256) void k_softw(const float* __restrict__ sArr, float* __restrict__ wArr){
  __shared__ float red[256];
  int b = blockIdx.x, t = threadIdx.x;
  const float* sp = sArr + b * NN;
  float sv[8];
  float mx = -3.4e38f;
  #pragma unroll
  for (int i = 0; i < 8; i++){
    float v = sp[t + 256 * i];
    if (!(fabsf(v) < 1e30f)) v = -1e30f;
    sv[i] = v; mx = fmaxf(mx, v);
  }
  mx = blockRed(mx, red, t, 2);
  float z = 0.f;
  #pragma unroll
  for (int i = 0; i < 8; i++) z += expf(sv[i] - mx);
  z = blockRed(z, red, t, 0);
  float iz = 1.0f / fmaxf(z, 1e-30f);
  #pragma unroll
  for (int i = 0; i < 8; i++) wArr[b * NN + t + 256 * i] = expf(sv[i] - mx) * iz;
}

// ---- K7: stable descending rank -> topi --------------------------------------------
// R15: was 16 blocks x serial-2048 scalar ds_read loop -> 52us at 0.66% occupancy,
// latency-bound. Now: 64 n/block (grid 32xBB=64 blocks), j-loop split across the
// 4 waves (512 j each) and vectorized f32x4 (128 iters/thread, independent -> ILP).
// f32x4 address is uniform across the 64 n-lanes of a j-chunk -> LDS broadcast,
// conflict-free. Integer partial counts summed via LDS — associative, exact ->
// topi bit-identical.
__global__ __launch_bounds__(256) void k_rank(const float* __restrict__ wArr, int* __restrict__ topi){
  __shared__ float wrow[NN];
  __shared__ int pc[4][64];
  int b = blockIdx.y, t = threadIdx.x;
  for (int i = t; i < NN; i += 256) wrow[i] = wArr[b * NN + i];
  __syncthreads();
  int tn = t & 63, tj = t >> 6;
  int n = blockIdx.x * 64 + tn;
  float wn = wrow[n];
  int j0 = tj * 512;
  const f32x4* w4 = (const f32x4*)&wrow[j0];
  int cnt = 0;
  #pragma unroll 4
  for (int q = 0; q < 128; q++){
    f32x4 wv = w4[q];
    int j = j0 + q * 4;
    cnt += (wv.x > wn) || ((wv.x == wn) && (j + 0 < n));
    cnt += (wv.y > wn) || ((wv.y == wn) && (j + 1 < n));
    cnt += (wv.z > wn) || ((wv.z == wn) && (j + 2 < n));
    cnt += (wv.w > wn) || ((wv.w == wn) && (j + 3 < n));
  }
  pc[tj][tn] = cnt;
  __syncthreads();
  if (t < 64){
    int c = pc[0][t] + pc[1][t] + pc[2][t] + pc[3][t];
    if (c < KEY) topi[b * KEY + c] = blockIdx.x * 64 + t;
  }
}

// ---- K8: weighted centroids, H, 3x3 SVD (f64 Jacobi), R/t --------------------------
__device__ __forceinline__ double det3d(const double A[3][3]){
  return A[0][0] * (A[1][1] * A[2][2] - A[1][2] * A[2][1])
       - A[0][1] * (A[1][0] * A[2][2] - A[1][2] * A[2][0])
       + A[0][2] * (A[1][0] * A[2][1] - A[1][1] * A[2][0]);
}

__global__ __launch_bounds__(256) void k_rigid(const float* __restrict__ src, const float* __restrict__ s_corr,
                                               const float* __restrict__ wArr, float* __restrict__ Rt,
                                               float* __restrict__ out){
  __shared__ float red[256];
  int b = blockIdx.x, t = threadIdx.x;
  float wsum = 0, a0 = 0, a1 = 0, a2 = 0, c0 = 0, c1 = 0, c2 = 0;
  for (int n = t; n < NN; n += 256){
    float wv = wArr[b * NN + n];
    float s0 = src[(b * 3 + 0) * NN + n];
    float s1 = src[(b * 3 + 1) * NN + n];
    float s2 = src[(b * 3 + 2) * NN + n];
    float q0 = s_corr[(b * 3 + 0) * NN + n];
    float q1 = s_corr[(b * 3 + 1) * NN + n];
    float q2 = s_corr[(b * 3 + 2) * NN + n];
    wsum += wv; a0 += wv * s0; a1 += wv * s1; a2 += wv * s2;
    c0 += wv * q0; c1 += wv * q1; c2 += wv * q2;
  }
  wsum = blockRed(wsum, red, t, 0);
  a0 = blockRed(a0, red, t, 0); a1 = blockRed(a1, red, t, 0); a2 = blockRed(a2, red, t, 0);
  c0 = blockRed(c0, red, t, 0); c1 = blockRed(c1, red, t, 0); c2 = blockRed(c2, red, t, 0);
  float inv = 1.0f / fmaxf(wsum, 1e-30f);
  float cs0 = a0 * inv, cs1 = a1 * inv, cs2 = a2 * inv;
  float ct0 = c0 * inv, ct1 = c1 * inv, ct2 = c2 * inv;
  float h[9] = {0, 0, 0, 0, 0, 0, 0, 0, 0};
  for (int n = t; n < NN; n += 256){
    float wv = wArr[b * NN + n];
    float ds0 = src[(b * 3 + 0) * NN + n] - cs0;
    float ds1 = src[(b * 3 + 1) * NN + n] - cs1;
    float ds2 = src[(b * 3 + 2) * NN + n] - cs2;
    float dc0 = s_corr[(b * 3 + 0) * NN + n] - ct0;
    float dc1 = s_corr[(b * 3 + 1) * NN + n] - ct1;
    float dc2 = s_corr[(b * 3 + 2) * NN + n] - ct2;
    h[0] += wv * ds0 * dc0; h[1] += wv * ds0 * dc1; h[2] += wv * ds0 * dc2;
    h[3] += wv * ds1 * dc0; h[4] += wv * ds1 * dc1; h[5] += wv * ds1 * dc2;
    h[6] += wv * ds2 * dc0; h[7] += wv * ds2 * dc1; h[8] += wv * ds2 * dc2;
  }
  for (int i = 0; i < 9; i++) h[i] = blockRed(h[i], red, t, 0);
  if (t == 0){
    double Hm[3][3];
    for (int i = 0; i < 3; i++)
      for (int j = 0; j < 3; j++) Hm[i][j] = (double)h[i * 3 + j];
    double Km[3][3], V[3][3] = {{1, 0, 0}, {0, 1, 0}, {0, 0, 1}};
    for (int i = 0; i < 3; i++)
      for (int j = 0; j < 3; j++){
        double s = 0;
        for (int a = 0; a < 3; a++) s += Hm[a][i] * Hm[a][j];
        Km[i][j] = s;
      }
    double ksc = fabs(Km[0][0]) + fabs(Km[1][1]) + fabs(Km[2][2]) + 1e-300;
    for (int sweep = 0; sweep < 60; sweep++){
      int p = 0, q = 1; double mx = fabs(Km[0][1]);
      if (fabs(Km[0][2]) > mx){ mx = fabs(Km[0][2]); p = 0; q = 2; }
      if (fabs(Km[1][2]) > mx){ mx = fabs(Km[1][2]); p = 1; q = 2; }
      if (mx <= 1e-15 * ksc) break;
      double app = Km[p][p], aqq = Km[q][q], apq = Km[p][q];
      double tau = (aqq - app) / (2.0 * apq);
      double tt = ((tau >= 0) ? 1.0 : -1.0) / (fabs(tau) + sqrt(1.0 + tau * tau));
      double cc = 1.0 / sqrt(1.0 + tt * tt), sn = tt * cc;
      for (int k2 = 0; k2 < 3; k2++){
        double akp = Km[k2][p], akq = Km[k2][q];
        Km[k2][p] = cc * akp - sn * akq; Km[k2][q] = sn * akp + cc * akq;
      }
      for (int k2 = 0; k2 < 3; k2++){
        double apk = Km[p][k2], aqk = Km[q][k2];
        Km[p][k2] = cc * apk - sn * aqk; Km[q][k2] = sn * apk + cc * aqk;
      }
      for (int k2 = 0; k2 < 3; k2++){
        double vkp = V[k2][p], vkq = V[k2][q];
        V[k2][p] = cc * vkp - sn * vkq; V[k2][q] = sn * vkp + cc * vkq;
      }
    }
    double lam[3] = {Km[0][0], Km[1][1], Km[2][2]};
    int id0 = 0, id1 = 1, id2 = 2, tmp;
    if (lam[id0] < lam[id1]){ tmp = id0; id0 = id1; id1 = tmp; }
    if (lam[id0] < lam[id2]){ tmp = id0; id0 = id2; id2 = tmp; }
    if (lam[id1] < lam[id2]){ tmp = id1; id1 = id2; id2 = tmp; }
    int idx[3] = {id0, id1, id2};
    double Vs[3][3], U[3][3] = {{0, 0, 0}, {0, 0, 0}, {0, 0, 0}};
    for (int jj = 0; jj < 3; jj++){
      int j = idx[jj];
      for (int i2 = 0; i2 < 3; i2++) Vs[i2][jj] = V[i2][j];
      double u0 = 0, u1 = 0, u2 = 0;
      for (int i2 = 0; i2 < 3; i2++){
        u0 += Hm[0][i2] * V[i2][j];
        u1 += Hm[1][i2] * V[i2][j];
        u2 += Hm[2][i2] * V[i2][j];
      }
      double nrm = sqrt(u0 * u0 + u1 * u1 + u2 * u2);
      if (nrm > 1e-20){
        U[0][jj] = u0 / nrm; U[1][jj] = u1 / nrm; U[2][jj] = u2 / nrm;
      } else {
        double x0 = U[1][0] * U[2][1] - U[2][0] * U[1][1];
        double x1 = U[2][0] * U[0][1] - U[0][0] * U[2][1];
        double x2 = U[0][0] * U[1][1] - U[1][0] * U[0][1];
        double nn2 = sqrt(x0 * x0 + x1 * x1 + x2 * x2);
        if (nn2 < 1e-20){ x0 = 1; x1 = 0; x2 = 0; nn2 = 1; }
        U[0][jj] = x0 / nn2; U[1][jj] = x1 / nn2; U[2][jj] = x2 / nn2;
      }
    }
    double dd = det3d(U) * det3d(Vs);
    double Rm[3][3];
    for (int i2 = 0; i2 < 3; i2++)
      for (int k2 = 0; k2 < 3; k2++)
        Rm[i2][k2] = Vs[i2][0] * U[k2][0] + Vs[i2][1] * U[k2][1] + dd * Vs[i2][2] * U[k2][2];
    double cs[3] = {cs0, cs1, cs2}, ct[3] = {ct0, ct1, ct2};
    double tv[3];
    for (int i2 = 0; i2 < 3; i2++)
      tv[i2] = ct[i2] - (Rm[i2][0] * cs[0] + Rm[i2][1] * cs[1] + Rm[i2][2] * cs[2]);
    for (int i2 = 0; i2 < 3; i2++)
      for (int k2 = 0; k2 < 3; k2++){
        Rt[b * 12 + i2 * 3 + k2] = (float)Rm[i2][k2];
        out[b * 9 + i2 * 3 + k2] = (float)Rm[i2][k2];
      }
    for (int i2 = 0; i2 < 3; i2++){
      Rt[b * 12 + 9 + i2] = (float)tv[i2];
      out[18 + b * 3 + i2] = (float)tv[i2];
    }
  }
}

// ---- K10: gather keypoint outputs, with src_transformed fused inline ---------------
// (k_st eliminated: st values computed at the gathered indices with the identical
// expression R[c*3+0]*s0 + R[c*3+1]*s1 + R[c*3+2]*s2 + R[9+c] -> bitwise-same out)
__global__ __launch_bounds__(256) void k_out(const int* __restrict__ topi, const int* __restrict__ sidx,
                                             const float* __restrict__ src, const float* __restrict__ s_corr,
                                             const float* __restrict__ Rt, float* __restrict__ out){
  int b = blockIdx.y, t = threadIdx.x;
  int rr = t >> 4, kk = t & 15;
  int r = blockIdx.x * 16 + rr;
  int ns = topi[b * KEY + r] & 2047;
  int nk = sidx[(b * NN + ns) * KK + kk] & 2047;
  const float* R = Rt + b * 12;
  float sns0 = src[(b * 3 + 0) * NN + ns];
  float sns1 = src[(b * 3 + 1) * NN + ns];
  float sns2 = src[(b * 3 + 2) * NN + ns];
  float snk0 = src[(b * 3 + 0) * NN + nk];
  float snk1 = src[(b * 3 + 1) * NN + nk];
  float snk2 = src[(b * 3 + 2) * NN + nk];
  float* o_sk  = out + 24;
  float* o_tk  = out + 6168;
  float* o_skk = out + 12312;
  float* o_tkk = out + 110616;
  #pragma unroll
  for (int c = 0; c < 3; c++){
    float cv  = s_corr[(b * 3 + c) * NN + ns];
    float ck  = s_corr[(b * 3 + c) * NN + nk];
    o_tkk[(((b * 3 + c) * KEY + r) * KK) + kk] = cv - ck;
    float sv  = R[c * 3 + 0] * sns0 + R[c * 3 + 1] * sns1 + R[c * 3 + 2] * sns2 + R[9 + c];
    float sk2 = R[c * 3 + 0] * snk0 + R[c * 3 + 1] * snk1 + R[c * 3 + 2] * snk2 + R[9 + c];
    o_skk[(((b * 3 + c) * KEY + r) * KK) + kk] = sv - sk2;
    if (kk == 0){
      o_sk[(b * 3 + c) * KEY + r] = sns0 * (c == 0) + sns1 * (c == 1) + sns2 * (c == 2);
      o_tk[(b * 3 + c) * KEY + r] = cv;
    }
  }
}

// ---- K11: loss_scl -----------------------------------------------------------------
__global__ __launch_bounds__(256) void k_loss(const float* __restrict__ loss_row, const int* __restrict__ topi,
                                              float* __restrict__ out){
  __shared__ float red[256];
  int t = threadIdx.x;
  float acc = 0.f;
  for (int i = t; i < BB * KEY; i += 256){
    int b = i >> 10, r = i & 1023;
    int n = topi[b * KEY + r] & 2047;
    acc += loss_row[b * NN + n];
  }
  acc = blockRed(acc, red, t, 0);
  if (t == 0) out[208920] = acc / 2048.0f;
}

extern "C" void kernel_launch(void* const* d_in, const int* in_sizes, int n_in,
                              void* d_out, int out_size, void* d_ws, size_t ws_size,
                              hipStream_t stream){
  const float* src  = (const float*)d_in[0];
  const float* tgt  = (const float*)d_in[1];
  const float* semb = (const float*)d_in[2];
  const float* temb = (const float*)d_in[3];
  const float* sknn = (const float*)d_in[4];
  const float* W1 = (const float*)d_in[6];
  const float* b1 = (const float*)d_in[7];
  const float* W2 = (const float*)d_in[8];
  const float* b2 = (const float*)d_in[9];
  const float* W3 = (const float*)d_in[10];
  const float* b3 = (const float*)d_in[11];
  const int* sidx  = (const int*)d_in[12];
  const int* sidx1 = (const int*)d_in[13];
  const int* idx2  = (const int*)d_in[14];
  float* out = (float*)d_out;

  // workspace layout (peak ~33.4 MB)
  char* w = (char*)d_ws;
  u16* Ah = (u16*)(w);                               // 4 MB each (B,N,C) bf16 split
  u16* Al = Ah + (size_t)BB * NN * CC;
  u16* Bh = Al + (size_t)BB * NN * CC;
  u16* Bl = Bh + (size_t)BB * MM * CC;
  float* dist = (float*)(Bl + (size_t)BB * MM * CC); // 16.78 MB (N,M) f32, per-batch reuse
  char* tail = (char*)(dist + (size_t)NN * MM);
  float* xx = (float*)tail;                          // B*N
  float* yy = xx + BB * NN;                          // B*M
  float* mnA = yy + BB * MM;                         // B*N
  float* Zr = mnA + BB * NN;                         // B*N
  float* s_corr = Zr + BB * NN;                      // B*3*N
  float* loss_row = s_corr + BB * 3 * NN;            // B*N
  float* sArr = loss_row + BB * NN;                  // B*N
  float* wArr = sArr + BB * NN;                      // B*N
  int* topi = (int*)(wArr + BB * NN);                // B*KEY
  float* Rt = (float*)(topi + BB * KEY);             // B*12

  k_trans<<<dim3(16, 64, 4), dim3(32, 8), 0, stream>>>(semb, temb, Ah, Al, Bh, Bl);
  k_sq<<<dim3(16, 2), 256, 0, stream>>>(semb, temb, xx, yy);
  for (int b = 0; b < BB; b++){
    k_gemm<<<dim3(16, 16), 256, 0, stream>>>(Ah + (size_t)b * NN * CC, Al + (size_t)b * NN * CC,
                                             Bh + (size_t)b * MM * CC, Bl + (size_t)b * MM * CC,
                                             xx + b * NN, yy + b * MM, dist);
    k_rowstats<<<NN, 256, 0, stream>>>(dist, mnA + b * NN, Zr + b * NN);
    k_fused<<<NN, 256, 0, stream>>>(dist, mnA + b * NN, Zr + b * NN,
                                    sidx1 + (size_t)b * NN * KK1, idx2 + (size_t)b * MM * KK1,
                                    tgt + (size_t)b * 3 * MM, s_corr + (size_t)b * 3 * NN,
                                    loss_row + b * NN);
  }
  k_disc<<<dim3(NN / 4, BB), 256, 0, stream>>>(s_corr, src, sknn, sidx, W1, b1, W2, b2, W3, b3, sArr);
  k_softw<<<BB, 256, 0, stream>>>(sArr, wArr);
  k_rank<<<dim3(32, BB), 256, 0, stream>>>(wArr, topi);
  k_rigid<<<BB, 256, 0, stream>>>(src, s_corr, wArr, Rt, out);
  k_out<<<dim3(64, BB), 256, 0, stream>>>(topi, sidx, src, s_corr, Rt, out);
  k_loss<<<1, 256, 0, stream>>>(loss_row, topi, out);
}

// Round 4
// 287.565 us; speedup vs baseline: 1.9181x; 1.0780x over previous
//
#include <hip/hip_runtime.h>
#include <stdint.h>

typedef unsigned short u16;

#define BB 2
#define NN 2048
#define MM 2048
#define CC 512
#define KK 16
#define KK1 8
#define KEY 1024

typedef __attribute__((ext_vector_type(8))) short bf16x8;
typedef __attribute__((ext_vector_type(4))) float f32x4;

__device__ __forceinline__ float b2f(u16 u){ return __uint_as_float(((uint32_t)u) << 16); }
__device__ __forceinline__ u16 f2b(float f){
  uint32_t x = __float_as_uint(f);
  uint32_t r = x + 0x7FFFu + ((x >> 16) & 1u);
  return (u16)(r >> 16);
}
__device__ __forceinline__ float sane(float v){ return (fabsf(v) < 1e30f) ? v : 1e30f; }

// all-thread block reduction, 256 threads. op: 0=sum 1=min 2=max
__device__ __forceinline__ float blockRed(float v, float* red, int t, int op){
  red[t] = v; __syncthreads();
  #pragma unroll
  for (int s = 128; s > 0; s >>= 1){
    if (t < s){
      float a = red[t], b = red[t + s];
      red[t] = (op == 0) ? (a + b) : ((op == 1) ? fminf(a, b) : fmaxf(a, b));
    }
    __syncthreads();
  }
  float r = red[0]; __syncthreads();
  return r;
}

// ---- K0: transpose f32 (B,C,N) -> split-bf16 (B,N,C) hi/lo pairs -------------------
__global__ __launch_bounds__(256) void k_trans(const float* __restrict__ semb, const float* __restrict__ temb,
                                               u16* __restrict__ Ah, u16* __restrict__ Al,
                                               u16* __restrict__ Bh, u16* __restrict__ Bl){
  __shared__ float tile[32][33];
  int b = blockIdx.z & 1, which = blockIdx.z >> 1;
  const float* in = which ? temb : semb;
  u16* oh = which ? Bh : Ah;
  u16* ol = which ? Bl : Al;
  int c0 = blockIdx.x * 32, n0 = blockIdx.y * 32;
  int tx = threadIdx.x, ty = threadIdx.y;
  #pragma unroll
  for (int i = 0; i < 4; i++){
    int r = ty + 8 * i;
    tile[r][tx] = in[((b * CC + c0 + r) * NN) + n0 + tx];
  }
  __syncthreads();
  #pragma unroll
  for (int i = 0; i < 4; i++){
    int r = ty + 8 * i;
    float v = tile[tx][r];
    u16 hi = f2b(v);
    float lo = v - b2f(hi);
    size_t o = ((size_t)(b * NN + n0 + r) * CC) + c0 + tx;
    oh[o] = hi;
    ol[o] = f2b(lo);
  }
}

// ---- K1: exact f32 row squared norms from (B,C,N) layout (coalesced over n) --------
__global__ __launch_bounds__(256) void k_sq(const float* __restrict__ semb, const float* __restrict__ temb,
                                            float* __restrict__ xx, float* __restrict__ yy){
  int which = blockIdx.y;
  const float* in = which ? temb : semb;
  float* out = which ? yy : xx;
  int gid = blockIdx.x * 256 + threadIdx.x;   // 0..4095
  int b = gid >> 11, n = gid & 2047;
  float acc = 0.f;
  for (int c = 0; c < CC; c++){
    float v = in[((size_t)(b * CC + c)) * NN + n];
    acc += v * v;
  }
  out[gid] = acc;
}

// ---- K2: dist = xx - 2*A.B^T + yy, split-bf16 MFMA (hi*hi + hi*lo + lo*hi) ---------
// R16: both batches in one dispatch (grid z=BB): 512 blocks = 2 blocks/CU, which is
// exactly the 64KB-LDS residency cap. Co-resident block hides the barrier-drain
// stall (measured wave-overlap: MFMA+VALU co-schedule ~ max, not sum). Per-block
// instruction stream identical to the per-batch version -> bit-identical dist.
__global__ __launch_bounds__(256) void k_gemm(const u16* __restrict__ Ah, const u16* __restrict__ Al,
                                              const u16* __restrict__ Bh, const u16* __restrict__ Bl,
                                              const float* __restrict__ xx, const float* __restrict__ yy,
                                              float* __restrict__ dist){
  __shared__ __align__(16) u16 lAh[128 * 64];
  __shared__ __align__(16) u16 lAl[128 * 64];
  __shared__ __align__(16) u16 lBh[128 * 64];
  __shared__ __align__(16) u16 lBl[128 * 64];
  int bz = blockIdx.z;
  const u16* Ahb = Ah + (size_t)bz * NN * CC;
  const u16* Alb = Al + (size_t)bz * NN * CC;
  const u16* Bhb = Bh + (size_t)bz * MM * CC;
  const u16* Blb = Bl + (size_t)bz * MM * CC;
  const float* xxb = xx + bz * NN;
  const float* yyb = yy + bz * MM;
  float* distb = dist + (size_t)bz * NN * MM;
  int n0 = blockIdx.y * 128, m0 = blockIdx.x * 128;
  int t = threadIdx.x;
  f32x4 acc[4][4];
  #pragma unroll
  for (int i = 0; i < 4; i++)
    #pragma unroll
    for (int j = 0; j < 4; j++){ f32x4 z = {0.f, 0.f, 0.f, 0.f}; acc[i][j] = z; }
  int w = t >> 6, lane = t & 63, lr = lane & 15, quad = lane >> 4;
  int wn = (w >> 1) * 64, wm = (w & 1) * 64;
  for (int kt = 0; kt < 8; kt++){
    int k0 = kt * 64;
    bf16x8 vah[4], val[4], vbh[4], vbl[4];
    #pragma unroll
    for (int s = 0; s < 4; s++){
      int ch = t + 256 * s;
      int rn = ch >> 3, k8 = (ch & 7) * 8;
      size_t oa = (size_t)(n0 + rn) * CC + k0 + k8;
      size_t ob = (size_t)(m0 + rn) * CC + k0 + k8;
      vah[s] = *(const bf16x8*)(Ahb + oa);
      val[s] = *(const bf16x8*)(Alb + oa);
      vbh[s] = *(const bf16x8*)(Bhb + ob);
      vbl[s] = *(const bf16x8*)(Blb + ob);
    }
    __syncthreads();
    #pragma unroll
    for (int s = 0; s < 4; s++){
      int ch = t + 256 * s;
      *(bf16x8*)&lAh[ch * 8] = vah[s];
      *(bf16x8*)&lAl[ch * 8] = val[s];
      *(bf16x8*)&lBh[ch * 8] = vbh[s];
      *(bf16x8*)&lBl[ch * 8] = vbl[s];
    }
    __syncthreads();
    #pragma unroll
    for (int kk = 0; kk < 2; kk++){
      int off = kk * 32 + quad * 8;
      bf16x8 afh[4], afl[4], bfh[4], bfl[4];
      #pragma unroll
      for (int i = 0; i < 4; i++){
        int ra = (wn + i * 16 + lr) * 64 + off;
        afh[i] = *(const bf16x8*)&lAh[ra];
        afl[i] = *(const bf16x8*)&lAl[ra];
      }
      #pragma unroll
      for (int j = 0; j < 4; j++){
        int rb = (wm + j * 16 + lr) * 64 + off;
        bfh[j] = *(const bf16x8*)&lBh[rb];
        bfl[j] = *(const bf16x8*)&lBl[rb];
      }
      #pragma unroll
      for (int i = 0; i < 4; i++)
        #pragma unroll
        for (int j = 0; j < 4; j++){
          acc[i][j] = __builtin_amdgcn_mfma_f32_16x16x32_bf16(afh[i], bfh[j], acc[i][j], 0, 0, 0);
          acc[i][j] = __builtin_amdgcn_mfma_f32_16x16x32_bf16(afh[i], bfl[j], acc[i][j], 0, 0, 0);
          acc[i][j] = __builtin_amdgcn_mfma_f32_16x16x32_bf16(afl[i], bfh[j], acc[i][j], 0, 0, 0);
        }
    }
  }
  #pragma unroll
  for (int i = 0; i < 4; i++){
    int nbase = n0 + wn + i * 16 + quad * 4;
    #pragma unroll
    for (int j = 0; j < 4; j++){
      int m = m0 + wm + j * 16 + lr;
      float yv = yyb[m];
      #pragma unroll
      for (int r = 0; r < 4; r++){
        distb[((size_t)(nbase + r)) * MM + m] = xxb[nbase + r] + yv - 2.0f * acc[i][j][r];
      }
    }
  }
}

// ---- K3: per-row min & softmax(-dist) denominator (grid y = batch) -----------------
__global__ __launch_bounds__(256) void k_rowstats(const float* __restrict__ dist,
                                                  float* __restrict__ mnA, float* __restrict__ Zr){
  __shared__ float red[256];
  int row = blockIdx.x, b = blockIdx.y, t = threadIdx.x;
  const float* dr = dist + ((size_t)b * NN + row) * MM;
  float d[8];
  float mn = 3.4e38f;
  #pragma unroll
  for (int i = 0; i < 8; i++){ d[i] = sane(dr[t + 256 * i]); mn = fminf(mn, d[i]); }
  mn = blockRed(mn, red, t, 1);
  float z = 0.f;
  #pragma unroll
  for (int i = 0; i < 8; i++) z += expf(mn - d[i]);
  z = blockRed(z, red, t, 0);
  if (t == 0){ mnA[b * NN + row] = mn; Zr[b * NN + row] = fmaxf(z, 1e-30f); }
}

// ---- K4: fused T/S/refined/rmm/src_corr/loss per row n (grid y = batch) ------------
__global__ __launch_bounds__(256) void k_fused(const float* __restrict__ dist, const float* __restrict__ mnA,
                                               const float* __restrict__ Zr, const int* __restrict__ sidx1,
                                               const int* __restrict__ idx2, const float* __restrict__ tgt,
                                               float* __restrict__ s_corr, float* __restrict__ lossr){
  __shared__ float Trow[MM];
  __shared__ float red[256];
  int n = blockIdx.x, b = blockIdx.y, t = threadIdx.x;
  const float* distb = dist + (size_t)b * NN * MM;
  const float* mnAb = mnA + b * NN;
  const float* Zrb = Zr + b * NN;
  const int* sidx1b = sidx1 + (size_t)b * NN * KK1;
  const int* idx2b = idx2 + (size_t)b * MM * KK1;
  const float* tgtb = tgt + (size_t)b * 3 * MM;
  float* s_corrb = s_corr + (size_t)b * 3 * NN;
  float* lossb = lossr + b * NN;
  const float* dn_p = distb + (size_t)n * MM;
  float dn[8];
  #pragma unroll
  for (int i = 0; i < 8; i++) dn[i] = sane(dn_p[t + 256 * i]);
  float tacc[8] = {0, 0, 0, 0, 0, 0, 0, 0};
  const int* i1 = sidx1b + n * KK1;
  for (int j = 1; j < KK1; j++){
    int r = i1[j] & 2047;
    float mnj = mnAb[r];
    float izj = 1.0f / Zrb[r];
    const float* drp = distb + (size_t)r * MM;
    #pragma unroll
    for (int i = 0; i < 8; i++) tacc[i] += expf(mnj - sane(drp[t + 256 * i])) * izj;
  }
  #pragma unroll
  for (int i = 0; i < 8; i++) Trow[t + 256 * i] = tacc[i];
  __syncthreads();
  float rloc[8];
  float lmin = 3.4e38f;
  #pragma unroll
  for (int i = 0; i < 8; i++){
    int m = t + 256 * i;
    const int* ip = idx2b + m * KK1;
    float S = 0.f;
    #pragma unroll
    for (int j = 1; j < KK1; j++) S += Trow[ip[j] & 2047];
    float rv = sane(expf(1.0f - S / 7.0f) * dn[i]);
    rloc[i] = rv;
    lmin = fminf(lmin, rv);
  }
  float rmin = blockRed(lmin, red, t, 1);
  float z = 0.f, s0 = 0.f, s1 = 0.f, s2 = 0.f;
  #pragma unroll
  for (int i = 0; i < 8; i++){
    int m = t + 256 * i;
    float p = expf(rmin - rloc[i]);
    z  += p;
    s0 += tgtb[0 * MM + m] * p;
    s1 += tgtb[1 * MM + m] * p;
    s2 += tgtb[2 * MM + m] * p;
  }
  z  = blockRed(z,  red, t, 0);
  s0 = blockRed(s0, red, t, 0);
  s1 = blockRed(s1, red, t, 0);
  s2 = blockRed(s2, red, t, 0);
  if (t == 0){
    float iZ = 1.0f / fmaxf(z, 1e-30f);
    s_corrb[0 * NN + n] = s0 * iZ;
    s_corrb[1 * NN + n] = s1 * iZ;
    s_corrb[2 * NN + n] = s2 * iZ;
    lossb[n] = -logf(fminf(iZ, 1.0f) + 1e-15f);  // pred at onehot == rowmax(rmm) == 1/Z
  }
}

// ---- K5: discriminator MLP — R14: scalar-W2 + e-range wave split (see R14 notes) ---
__global__ __launch_bounds__(256, 4) void k_disc(const float* __restrict__ s_corr, const float* __restrict__ src,
                                                 const float* __restrict__ sknn, const int* __restrict__ sidx,
                                                 const float* __restrict__ W1, const float* __restrict__ b1,
                                                 const float* __restrict__ W2, const float* __restrict__ b2,
                                                 const float* __restrict__ W3, const float* __restrict__ b3,
                                                 float* __restrict__ sArr){
  __shared__ float term[64][129];
  int t = threadIdx.x;
  int b = blockIdx.y;
  int p = t & 63;                      // point within block (lane)
  int n = blockIdx.x * 4 + (p >> 4);   // 4 n-rows per block
  int kk = p & 15;
  int eh = t >> 6;                     // wave id = e-quarter
  int nk = sidx[((b * NN + n) * KK) + kk] & 2047;
  float f[6];
  #pragma unroll
  for (int c = 0; c < 3; c++){
    f[c]     = s_corr[(b * 3 + c) * NN + n] - s_corr[(b * 3 + c) * NN + nk];
    f[3 + c] = src[(b * 3 + c) * NN + n] - sknn[((size_t)(b * NN + n) * KK + kk) * 3 + c];
  }
  // layer 1: per-d expressions verbatim (a = b1[d]; a += f[c]*W1[d*6+c] x6; relu)
  #define L1D(d) ({ float a_ = b1[(d)];              \
                    a_ += f[0] * W1[(d) * 6 + 0];    \
                    a_ += f[1] * W1[(d) * 6 + 1];    \
                    a_ += f[2] * W1[(d) * 6 + 2];    \
                    a_ += f[3] * W1[(d) * 6 + 3];    \
                    a_ += f[4] * W1[(d) * 6 + 4];    \
                    a_ += f[5] * W1[(d) * 6 + 5];    \
                    fmaxf(a_, 0.f); })
  #define HSET(i) f32x4 h##i;                  \
                  h##i.x = L1D(4 * (i) + 0);   \
                  h##i.y = L1D(4 * (i) + 1);   \
                  h##i.z = L1D(4 * (i) + 2);   \
                  h##i.w = L1D(4 * (i) + 3);
  HSET(0) HSET(1) HSET(2) HSET(3) HSET(4) HSET(5) HSET(6) HSET(7)
  HSET(8) HSET(9) HSET(10) HSET(11) HSET(12) HSET(13) HSET(14) HSET(15)
  #undef HSET
  #undef L1D
  // layer 2: this wave's 32 e-chains, e wave-uniform so W2/b2 are scalar loads
  int e0 = __builtin_amdgcn_readfirstlane(eh * 32);
  for (int j = 0; j < 32; j++){
    int e = e0 + j;
    float a = b2[e];
    const f32x4* w4 = (const f32x4*)&W2[e * 64];
    #define QSTEP(i) { f32x4 wv = w4[i]; a += wv.x * h##i.x + wv.y * h##i.y + wv.z * h##i.z + wv.w * h##i.w; }
    QSTEP(0) QSTEP(1) QSTEP(2) QSTEP(3) QSTEP(4) QSTEP(5) QSTEP(6) QSTEP(7)
    QSTEP(8) QSTEP(9) QSTEP(10) QSTEP(11) QSTEP(12) QSTEP(13) QSTEP(14) QSTEP(15)
    #undef QSTEP
    term[p][e] = fmaxf(a, 0.f);
  }
  __syncthreads();
  // layer 3: serial left-fold per point in e-order (verbatim), then 16-lane max
  if (t < 64){
    float sacc = b3[0];
    #pragma unroll 4
    for (int e = 0; e < 128; e++) sacc += W3[e] * term[t][e];
    if (!(fabsf(sacc) < 1e30f)) sacc = -1e30f;
    #pragma unroll
    for (int off = 1; off < 16; off <<= 1) sacc = fmaxf(sacc, __shfl_xor(sacc, off, 16));
    if (kk == 0) sArr[b * NN + n] = sacc;
  }
}

// ---- K6: weight = softmax(s) over n ------------------------------------------------
__global__ __launch_bounds__(256) void k_softw(const float* __restrict__ sArr, float* __restrict__ wArr){
  __shared__ float red[256];
  int b = blockIdx.x, t = threadIdx.x;
  const float* sp = sArr + b * NN;
  float sv[8];
  float mx = -3.4e38f;
  #pragma unroll
  for (int i = 0; i < 8; i++){
    float v = sp[t + 256 * i];
    if (!(fabsf(v) < 1e30f)) v = -1e30f;
    sv[i] = v; mx = fmaxf(mx, v);
  }
  mx = blockRed(mx, red, t, 2);
  float z = 0.f;
  #pragma unroll
  for (int i = 0; i < 8; i++) z += expf(sv[i] - mx);
  z = blockRed(z, red, t, 0);
  float iz = 1.0f / fmaxf(z, 1e-30f);
  #pragma unroll
  for (int i = 0; i < 8; i++) wArr[b * NN + t + 256 * i] = expf(sv[i] - mx) * iz;
}

// ---- K7: stable descending rank -> topi (R15: wave-split + f32x4, exact) -----------
__global__ __launch_bounds__(256) void k_rank(const float* __restrict__ wArr, int* __restrict__ topi){
  __shared__ float wrow[NN];
  __shared__ int pc[4][64];
  int b = blockIdx.y, t = threadIdx.x;
  for (int i = t; i < NN; i += 256) wrow[i] = wArr[b * NN + i];
  __syncthreads();
  int tn = t & 63, tj = t >> 6;
  int n = blockIdx.x * 64 + tn;
  float wn = wrow[n];
  int j0 = tj * 512;
  const f32x4* w4 = (const f32x4*)&wrow[j0];
  int cnt = 0;
  #pragma unroll 4
  for (int q = 0; q < 128; q++){
    f32x4 wv = w4[q];
    int j = j0 + q * 4;
    cnt += (wv.x > wn) || ((wv.x == wn) && (j + 0 < n));
    cnt += (wv.y > wn) || ((wv.y == wn) && (j + 1 < n));
    cnt += (wv.z > wn) || ((wv.z == wn) && (j + 2 < n));
    cnt += (wv.w > wn) || ((wv.w == wn) && (j + 3 < n));
  }
  pc[tj][tn] = cnt;
  __syncthreads();
  if (t < 64){
    int c = pc[0][t] + pc[1][t] + pc[2][t] + pc[3][t];
    if (c < KEY) topi[b * KEY + c] = blockIdx.x * 64 + t;
  }
}

// ---- K8: weighted centroids, H, 3x3 SVD (f64 Jacobi), R/t --------------------------
__device__ __forceinline__ double det3d(const double A[3][3]){
  return A[0][0] * (A[1][1] * A[2][2] - A[1][2] * A[2][1])
       - A[0][1] * (A[1][0] * A[2][2] - A[1][2] * A[2][0])
       + A[0][2] * (A[1][0] * A[2][1] - A[1][1] * A[2][0]);
}

__global__ __launch_bounds__(256) void k_rigid(const float* __restrict__ src, const float* __restrict__ s_corr,
                                               const float* __restrict__ wArr, float* __restrict__ Rt,
                                               float* __restrict__ out){
  __shared__ float red[256];
  int b = blockIdx.x, t = threadIdx.x;
  float wsum = 0, a0 = 0, a1 = 0, a2 = 0, c0 = 0, c1 = 0, c2 = 0;
  for (int n = t; n < NN; n += 256){
    float wv = wArr[b * NN + n];
    float s0 = src[(b * 3 + 0) * NN + n];
    float s1 = src[(b * 3 + 1) * NN + n];
    float s2 = src[(b * 3 + 2) * NN + n];
    float q0 = s_corr[(b * 3 + 0) * NN + n];
    float q1 = s_corr[(b * 3 + 1) * NN + n];
    float q2 = s_corr[(b * 3 + 2) * NN + n];
    wsum += wv; a0 += wv * s0; a1 += wv * s1; a2 += wv * s2;
    c0 += wv * q0; c1 += wv * q1; c2 += wv * q2;
  }
  wsum = blockRed(wsum, red, t, 0);
  a0 = blockRed(a0, red, t, 0); a1 = blockRed(a1, red, t, 0); a2 = blockRed(a2, red, t, 0);
  c0 = blockRed(c0, red, t, 0); c1 = blockRed(c1, red, t, 0); c2 = blockRed(c2, red, t, 0);
  float inv = 1.0f / fmaxf(wsum, 1e-30f);
  float cs0 = a0 * inv, cs1 = a1 * inv, cs2 = a2 * inv;
  float ct0 = c0 * inv, ct1 = c1 * inv, ct2 = c2 * inv;
  float h[9] = {0, 0, 0, 0, 0, 0, 0, 0, 0};
  for (int n = t; n < NN; n += 256){
    float wv = wArr[b * NN + n];
    float ds0 = src[(b * 3 + 0) * NN + n] - cs0;
    float ds1 = src[(b * 3 + 1) * NN + n] - cs1;
    float ds2 = src[(b * 3 + 2) * NN + n] - cs2;
    float dc0 = s_corr[(b * 3 + 0) * NN + n] - ct0;
    float dc1 = s_corr[(b * 3 + 1) * NN + n] - ct1;
    float dc2 = s_corr[(b * 3 + 2) * NN + n] - ct2;
    h[0] += wv * ds0 * dc0; h[1] += wv * ds0 * dc1; h[2] += wv * ds0 * dc2;
    h[3] += wv * ds1 * dc0; h[4] += wv * ds1 * dc1; h[5] += wv * ds1 * dc2;
    h[6] += wv * ds2 * dc0; h[7] += wv * ds2 * dc1; h[8] += wv * ds2 * dc2;
  }
  for (int i = 0; i < 9; i++) h[i] = blockRed(h[i], red, t, 0);
  if (t == 0){
    double Hm[3][3];
    for (int i = 0; i < 3; i++)
      for (int j = 0; j < 3; j++) Hm[i][j] = (double)h[i * 3 + j];
    double Km[3][3], V[3][3] = {{1, 0, 0}, {0, 1, 0}, {0, 0, 1}};
    for (int i = 0; i < 3; i++)
      for (int j = 0; j < 3; j++){
        double s = 0;
        for (int a = 0; a < 3; a++) s += Hm[a][i] * Hm[a][j];
        Km[i][j] = s;
      }
    double ksc = fabs(Km[0][0]) + fabs(Km[1][1]) + fabs(Km[2][2]) + 1e-300;
    for (int sweep = 0; sweep < 60; sweep++){
      int p = 0, q = 1; double mx = fabs(Km[0][1]);
      if (fabs(Km[0][2]) > mx){ mx = fabs(Km[0][2]); p = 0; q = 2; }
      if (fabs(Km[1][2]) > mx){ mx = fabs(Km[1][2]); p = 1; q = 2; }
      if (mx <= 1e-15 * ksc) break;
      double app = Km[p][p], aqq = Km[q][q], apq = Km[p][q];
      double tau = (aqq - app) / (2.0 * apq);
      double tt = ((tau >= 0) ? 1.0 : -1.0) / (fabs(tau) + sqrt(1.0 + tau * tau));
      double cc = 1.0 / sqrt(1.0 + tt * tt), sn = tt * cc;
      for (int k2 = 0; k2 < 3; k2++){
        double akp = Km[k2][p], akq = Km[k2][q];
        Km[k2][p] = cc * akp - sn * akq; Km[k2][q] = sn * akp + cc * akq;
      }
      for (int k2 = 0; k2 < 3; k2++){
        double apk = Km[p][k2], aqk = Km[q][k2];
        Km[p][k2] = cc * apk - sn * aqk; Km[q][k2] = sn * apk + cc * aqk;
      }
      for (int k2 = 0; k2 < 3; k2++){
        double vkp = V[k2][p], vkq = V[k2][q];
        V[k2][p] = cc * vkp - sn * vkq; V[k2][q] = sn * vkp + cc * vkq;
      }
    }
    double lam[3] = {Km[0][0], Km[1][1], Km[2][2]};
    int id0 = 0, id1 = 1, id2 = 2, tmp;
    if (lam[id0] < lam[id1]){ tmp = id0; id0 = id1; id1 = tmp; }
    if (lam[id0] < lam[id2]){ tmp = id0; id0 = id2; id2 = tmp; }
    if (lam[id1] < lam[id2]){ tmp = id1; id1 = id2; id2 = tmp; }
    int idx[3] = {id0, id1, id2};
    double Vs[3][3], U[3][3] = {{0, 0, 0}, {0, 0, 0}, {0, 0, 0}};
    for (int jj = 0; jj < 3; jj++){
      int j = idx[jj];
      for (int i2 = 0; i2 < 3; i2++) Vs[i2][jj] = V[i2][j];
      double u0 = 0, u1 = 0, u2 = 0;
      for (int i2 = 0; i2 < 3; i2++){
        u0 += Hm[0][i2] * V[i2][j];
        u1 += Hm[1][i2] * V[i2][j];
        u2 += Hm[2][i2] * V[i2][j];
      }
      double nrm = sqrt(u0 * u0 + u1 * u1 + u2 * u2);
      if (nrm > 1e-20){
        U[0][jj] = u0 / nrm; U[1][jj] = u1 / nrm; U[2][jj] = u2 / nrm;
      } else {
        double x0 = U[1][0] * U[2][1] - U[2][0] * U[1][1];
        double x1 = U[2][0] * U[0][1] - U[0][0] * U[2][1];
        double x2 = U[0][0] * U[1][1] - U[1][0] * U[0][1];
        double nn2 = sqrt(x0 * x0 + x1 * x1 + x2 * x2);
        if (nn2 < 1e-20){ x0 = 1; x1 = 0; x2 = 0; nn2 = 1; }
        U[0][jj] = x0 / nn2; U[1][jj] = x1 / nn2; U[2][jj] = x2 / nn2;
      }
    }
    double dd = det3d(U) * det3d(Vs);
    double Rm[3][3];
    for (int i2 = 0; i2 < 3; i2++)
      for (int k2 = 0; k2 < 3; k2++)
        Rm[i2][k2] = Vs[i2][0] * U[k2][0] + Vs[i2][1] * U[k2][1] + dd * Vs[i2][2] * U[k2][2];
    double cs[3] = {cs0, cs1, cs2}, ct[3] = {ct0, ct1, ct2};
    double tv[3];
    for (int i2 = 0; i2 < 3; i2++)
      tv[i2] = ct[i2] - (Rm[i2][0] * cs[0] + Rm[i2][1] * cs[1] + Rm[i2][2] * cs[2]);
    for (int i2 = 0; i2 < 3; i2++)
      for (int k2 = 0; k2 < 3; k2++){
        Rt[b * 12 + i2 * 3 + k2] = (float)Rm[i2][k2];
        out[b * 9 + i2 * 3 + k2] = (float)Rm[i2][k2];
      }
    for (int i2 = 0; i2 < 3; i2++){
      Rt[b * 12 + 9 + i2] = (float)tv[i2];
      out[18 + b * 3 + i2] = (float)tv[i2];
    }
  }
}

// ---- K10: gather keypoint outputs, with src_transformed fused inline ---------------
__global__ __launch_bounds__(256) void k_out(const int* __restrict__ topi, const int* __restrict__ sidx,
                                             const float* __restrict__ src, const float* __restrict__ s_corr,
                                             const float* __restrict__ Rt, float* __restrict__ out){
  int b = blockIdx.y, t = threadIdx.x;
  int rr = t >> 4, kk = t & 15;
  int r = blockIdx.x * 16 + rr;
  int ns = topi[b * KEY + r] & 2047;
  int nk = sidx[(b * NN + ns) * KK + kk] & 2047;
  const float* R = Rt + b * 12;
  float sns0 = src[(b * 3 + 0) * NN + ns];
  float sns1 = src[(b * 3 + 1) * NN + ns];
  float sns2 = src[(b * 3 + 2) * NN + ns];
  float snk0 = src[(b * 3 + 0) * NN + nk];
  float snk1 = src[(b * 3 + 1) * NN + nk];
  float snk2 = src[(b * 3 + 2) * NN + nk];
  float* o_sk  = out + 24;
  float* o_tk  = out + 6168;
  float* o_skk = out + 12312;
  float* o_tkk = out + 110616;
  #pragma unroll
  for (int c = 0; c < 3; c++){
    float cv  = s_corr[(b * 3 + c) * NN + ns];
    float ck  = s_corr[(b * 3 + c) * NN + nk];
    o_tkk[(((b * 3 + c) * KEY + r) * KK) + kk] = cv - ck;
    float sv  = R[c * 3 + 0] * sns0 + R[c * 3 + 1] * sns1 + R[c * 3 + 2] * sns2 + R[9 + c];
    float sk2 = R[c * 3 + 0] * snk0 + R[c * 3 + 1] * snk1 + R[c * 3 + 2] * snk2 + R[9 + c];
    o_skk[(((b * 3 + c) * KEY + r) * KK) + kk] = sv - sk2;
    if (kk == 0){
      o_sk[(b * 3 + c) * KEY + r] = sns0 * (c == 0) + sns1 * (c == 1) + sns2 * (c == 2);
      o_tk[(b * 3 + c) * KEY + r] = cv;
    }
  }
}

// ---- K11: loss_scl -----------------------------------------------------------------
__global__ __launch_bounds__(256) void k_loss(const float* __restrict__ loss_row, const int* __restrict__ topi,
                                              float* __restrict__ out){
  __shared__ float red[256];
  int t = threadIdx.x;
  float acc = 0.f;
  for (int i = t; i < BB * KEY; i += 256){
    int b = i >> 10, r = i & 1023;
    int n = topi[b * KEY + r] & 2047;
    acc += loss_row[b * NN + n];
  }
  acc = blockRed(acc, red, t, 0);
  if (t == 0) out[208920] = acc / 2048.0f;
}

extern "C" void kernel_launch(void* const* d_in, const int* in_sizes, int n_in,
                              void* d_out, int out_size, void* d_ws, size_t ws_size,
                              hipStream_t stream){
  const float* src  = (const float*)d_in[0];
  const float* tgt  = (const float*)d_in[1];
  const float* semb = (const float*)d_in[2];
  const float* temb = (const float*)d_in[3];
  const float* sknn = (const float*)d_in[4];
  const float* W1 = (const float*)d_in[6];
  const float* b1 = (const float*)d_in[7];
  const float* W2 = (const float*)d_in[8];
  const float* b2 = (const float*)d_in[9];
  const float* W3 = (const float*)d_in[10];
  const float* b3 = (const float*)d_in[11];
  const int* sidx  = (const int*)d_in[12];
  const int* sidx1 = (const int*)d_in[13];
  const int* idx2  = (const int*)d_in[14];
  float* out = (float*)d_out;

  // workspace layout (peak ~50.3 MB; harness allocates 256 MiB per fill evidence)
  char* w = (char*)d_ws;
  u16* Ah = (u16*)(w);                               // 4 MB each (B,N,C) bf16 split
  u16* Al = Ah + (size_t)BB * NN * CC;
  u16* Bh = Al + (size_t)BB * NN * CC;
  u16* Bl = Bh + (size_t)BB * MM * CC;
  float* dist = (float*)(Bl + (size_t)BB * MM * CC); // 33.55 MB (B,N,M) f32
  char* tail = (char*)(dist + (size_t)BB * NN * MM);
  float* xx = (float*)tail;                          // B*N
  float* yy = xx + BB * NN;                          // B*M
  float* mnA = yy + BB * MM;                         // B*N
  float* Zr = mnA + BB * NN;                         // B*N
  float* s_corr = Zr + BB * NN;                      // B*3*N
  float* loss_row = s_corr + BB * 3 * NN;            // B*N
  float* sArr = loss_row + BB * NN;                  // B*N
  float* wArr = sArr + BB * NN;                      // B*N
  int* topi = (int*)(wArr + BB * NN);                // B*KEY
  float* Rt = (float*)(topi + BB * KEY);             // B*12

  k_trans<<<dim3(16, 64, 4), dim3(32, 8), 0, stream>>>(semb, temb, Ah, Al, Bh, Bl);
  k_sq<<<dim3(16, 2), 256, 0, stream>>>(semb, temb, xx, yy);
  k_gemm<<<dim3(16, 16, BB), 256, 0, stream>>>(Ah, Al, Bh, Bl, xx, yy, dist);
  k_rowstats<<<dim3(NN, BB), 256, 0, stream>>>(dist, mnA, Zr);
  k_fused<<<dim3(NN, BB), 256, 0, stream>>>(dist, mnA, Zr, sidx1, idx2, tgt, s_corr, loss_row);
  k_disc<<<dim3(NN / 4, BB), 256, 0, stream>>>(s_corr, src, sknn, sidx, W1, b1, W2, b2, W3, b3, sArr);
  k_softw<<<BB, 256, 0, stream>>>(sArr, wArr);
  k_rank<<<dim3(32, BB), 256, 0, stream>>>(wArr, topi);
  k_rigid<<<BB, 256, 0, stream>>>(src, s_corr, wArr, Rt, out);
  k_out<<<dim3(64, BB), 256, 0, stream>>>(topi, sidx, src, s_corr, Rt, out);
  k_loss<<<1, 256, 0, stream>>>(loss_row, topi, out);
}

// Round 5
// 285.376 us; speedup vs baseline: 1.9328x; 1.0077x over previous
//
#include <hip/hip_runtime.h>
#include <stdint.h>

typedef unsigned short u16;

#define BB 2
#define NN 2048
#define MM 2048
#define CC 512
#define KK 16
#define KK1 8
#define KEY 1024

typedef __attribute__((ext_vector_type(8))) short bf16x8;
typedef __attribute__((ext_vector_type(4))) float f32x4;

__device__ __forceinline__ float b2f(u16 u){ return __uint_as_float(((uint32_t)u) << 16); }
__device__ __forceinline__ u16 f2b(float f){
  uint32_t x = __float_as_uint(f);
  uint32_t r = x + 0x7FFFu + ((x >> 16) & 1u);
  return (u16)(r >> 16);
}
__device__ __forceinline__ float sane(float v){ return (fabsf(v) < 1e30f) ? v : 1e30f; }

// all-thread block reduction, 256 threads. op: 0=sum 1=min 2=max
__device__ __forceinline__ float blockRed(float v, float* red, int t, int op){
  red[t] = v; __syncthreads();
  #pragma unroll
  for (int s = 128; s > 0; s >>= 1){
    if (t < s){
      float a = red[t], b = red[t + s];
      red[t] = (op == 0) ? (a + b) : ((op == 1) ? fminf(a, b) : fmaxf(a, b));
    }
    __syncthreads();
  }
  float r = red[0]; __syncthreads();
  return r;
}

// ---- K0: transpose f32 (B,C,N) -> split-bf16 (B,N,C) hi/lo pairs -------------------
__global__ __launch_bounds__(256) void k_trans(const float* __restrict__ semb, const float* __restrict__ temb,
                                               u16* __restrict__ Ah, u16* __restrict__ Al,
                                               u16* __restrict__ Bh, u16* __restrict__ Bl){
  __shared__ float tile[32][33];
  int b = blockIdx.z & 1, which = blockIdx.z >> 1;
  const float* in = which ? temb : semb;
  u16* oh = which ? Bh : Ah;
  u16* ol = which ? Bl : Al;
  int c0 = blockIdx.x * 32, n0 = blockIdx.y * 32;
  int tx = threadIdx.x, ty = threadIdx.y;
  #pragma unroll
  for (int i = 0; i < 4; i++){
    int r = ty + 8 * i;
    tile[r][tx] = in[((b * CC + c0 + r) * NN) + n0 + tx];
  }
  __syncthreads();
  #pragma unroll
  for (int i = 0; i < 4; i++){
    int r = ty + 8 * i;
    float v = tile[tx][r];
    u16 hi = f2b(v);
    float lo = v - b2f(hi);
    size_t o = ((size_t)(b * NN + n0 + r) * CC) + c0 + tx;
    oh[o] = hi;
    ol[o] = f2b(lo);
  }
}

// ---- K1: exact f32 row squared norms from (B,C,N) layout (coalesced over n) --------
__global__ __launch_bounds__(256) void k_sq(const float* __restrict__ semb, const float* __restrict__ temb,
                                            float* __restrict__ xx, float* __restrict__ yy){
  int which = blockIdx.y;
  const float* in = which ? temb : semb;
  float* out = which ? yy : xx;
  int gid = blockIdx.x * 256 + threadIdx.x;   // 0..4095
  int b = gid >> 11, n = gid & 2047;
  float acc = 0.f;
  for (int c = 0; c < CC; c++){
    float v = in[((size_t)(b * CC + c)) * NN + n];
    acc += v * v;
  }
  out[gid] = acc;
}

// ---- K2: dist = xx - 2*A.B^T + yy, split-bf16 MFMA (hi*hi + hi*lo + lo*hi) ---------
// R16: both batches in one dispatch (grid z=BB): 512 blocks = 2 blocks/CU (LDS cap).
__global__ __launch_bounds__(256) void k_gemm(const u16* __restrict__ Ah, const u16* __restrict__ Al,
                                              const u16* __restrict__ Bh, const u16* __restrict__ Bl,
                                              const float* __restrict__ xx, const float* __restrict__ yy,
                                              float* __restrict__ dist){
  __shared__ __align__(16) u16 lAh[128 * 64];
  __shared__ __align__(16) u16 lAl[128 * 64];
  __shared__ __align__(16) u16 lBh[128 * 64];
  __shared__ __align__(16) u16 lBl[128 * 64];
  int bz = blockIdx.z;
  const u16* Ahb = Ah + (size_t)bz * NN * CC;
  const u16* Alb = Al + (size_t)bz * NN * CC;
  const u16* Bhb = Bh + (size_t)bz * MM * CC;
  const u16* Blb = Bl + (size_t)bz * MM * CC;
  const float* xxb = xx + bz * NN;
  const float* yyb = yy + bz * MM;
  float* distb = dist + (size_t)bz * NN * MM;
  int n0 = blockIdx.y * 128, m0 = blockIdx.x * 128;
  int t = threadIdx.x;
  f32x4 acc[4][4];
  #pragma unroll
  for (int i = 0; i < 4; i++)
    #pragma unroll
    for (int j = 0; j < 4; j++){ f32x4 z = {0.f, 0.f, 0.f, 0.f}; acc[i][j] = z; }
  int w = t >> 6, lane = t & 63, lr = lane & 15, quad = lane >> 4;
  int wn = (w >> 1) * 64, wm = (w & 1) * 64;
  for (int kt = 0; kt < 8; kt++){
    int k0 = kt * 64;
    bf16x8 vah[4], val[4], vbh[4], vbl[4];
    #pragma unroll
    for (int s = 0; s < 4; s++){
      int ch = t + 256 * s;
      int rn = ch >> 3, k8 = (ch & 7) * 8;
      size_t oa = (size_t)(n0 + rn) * CC + k0 + k8;
      size_t ob = (size_t)(m0 + rn) * CC + k0 + k8;
      vah[s] = *(const bf16x8*)(Ahb + oa);
      val[s] = *(const bf16x8*)(Alb + oa);
      vbh[s] = *(const bf16x8*)(Bhb + ob);
      vbl[s] = *(const bf16x8*)(Blb + ob);
    }
    __syncthreads();
    #pragma unroll
    for (int s = 0; s < 4; s++){
      int ch = t + 256 * s;
      *(bf16x8*)&lAh[ch * 8] = vah[s];
      *(bf16x8*)&lAl[ch * 8] = val[s];
      *(bf16x8*)&lBh[ch * 8] = vbh[s];
      *(bf16x8*)&lBl[ch * 8] = vbl[s];
    }
    __syncthreads();
    #pragma unroll
    for (int kk = 0; kk < 2; kk++){
      int off = kk * 32 + quad * 8;
      bf16x8 afh[4], afl[4], bfh[4], bfl[4];
      #pragma unroll
      for (int i = 0; i < 4; i++){
        int ra = (wn + i * 16 + lr) * 64 + off;
        afh[i] = *(const bf16x8*)&lAh[ra];
        afl[i] = *(const bf16x8*)&lAl[ra];
      }
      #pragma unroll
      for (int j = 0; j < 4; j++){
        int rb = (wm + j * 16 + lr) * 64 + off;
        bfh[j] = *(const bf16x8*)&lBh[rb];
        bfl[j] = *(const bf16x8*)&lBl[rb];
      }
      #pragma unroll
      for (int i = 0; i < 4; i++)
        #pragma unroll
        for (int j = 0; j < 4; j++){
          acc[i][j] = __builtin_amdgcn_mfma_f32_16x16x32_bf16(afh[i], bfh[j], acc[i][j], 0, 0, 0);
          acc[i][j] = __builtin_amdgcn_mfma_f32_16x16x32_bf16(afh[i], bfl[j], acc[i][j], 0, 0, 0);
          acc[i][j] = __builtin_amdgcn_mfma_f32_16x16x32_bf16(afl[i], bfh[j], acc[i][j], 0, 0, 0);
        }
    }
  }
  #pragma unroll
  for (int i = 0; i < 4; i++){
    int nbase = n0 + wn + i * 16 + quad * 4;
    #pragma unroll
    for (int j = 0; j < 4; j++){
      int m = m0 + wm + j * 16 + lr;
      float yv = yyb[m];
      #pragma unroll
      for (int r = 0; r < 4; r++){
        distb[((size_t)(nbase + r)) * MM + m] = xxb[nbase + r] + yv - 2.0f * acc[i][j][r];
      }
    }
  }
}

// ---- K3: per-row min, softmax denom, AND scores row (R17) --------------------------
// R17: k_fused was 54.7us at 82% VALUBusy — ~56 of its 72 expf/thread recomputed
// scores[r][m] = expf(mn_r - d_r[m])/Z_r, each row ~7x redundantly. k_rowstats
// already computes those exact exp values for the z-sum; keep them in regs and
// store p[i]*iz to a scores slab. Expression tree identical (expf(mn - sane(d))
// then * (1/fmaxf(z,1e-30))) -> bit-identical values downstream.
__global__ __launch_bounds__(256) void k_rowstats(const float* __restrict__ dist,
                                                  float* __restrict__ mnA, float* __restrict__ Zr,
                                                  float* __restrict__ scores){
  __shared__ float red[256];
  int row = blockIdx.x, b = blockIdx.y, t = threadIdx.x;
  const float* dr = dist + ((size_t)b * NN + row) * MM;
  float* sr = scores + ((size_t)b * NN + row) * MM;
  float d[8];
  float mn = 3.4e38f;
  #pragma unroll
  for (int i = 0; i < 8; i++){ d[i] = sane(dr[t + 256 * i]); mn = fminf(mn, d[i]); }
  mn = blockRed(mn, red, t, 1);
  float p[8];
  float z = 0.f;
  #pragma unroll
  for (int i = 0; i < 8; i++){ p[i] = expf(mn - d[i]); z += p[i]; }
  z = blockRed(z, red, t, 0);
  float zc = fmaxf(z, 1e-30f);
  if (t == 0){ mnA[b * NN + row] = mn; Zr[b * NN + row] = zc; }
  float iz = 1.0f / zc;
  #pragma unroll
  for (int i = 0; i < 8; i++) sr[t + 256 * i] = p[i] * iz;
}

// ---- K4: fused T/S/refined/rmm/src_corr/loss per row n (grid y = batch) ------------
// R17: tacc loop now loads precomputed scores rows (bit-identical values) instead
// of recomputing expf — VALU drops ~4x, kernel goes memory-bound.
__global__ __launch_bounds__(256) void k_fused(const float* __restrict__ dist, const float* __restrict__ scores,
                                               const int* __restrict__ sidx1,
                                               const int* __restrict__ idx2, const float* __restrict__ tgt,
                                               float* __restrict__ s_corr, float* __restrict__ lossr){
  __shared__ float Trow[MM];
  __shared__ float red[256];
  int n = blockIdx.x, b = blockIdx.y, t = threadIdx.x;
  const float* distb = dist + (size_t)b * NN * MM;
  const float* scoresb = scores + (size_t)b * NN * MM;
  const int* sidx1b = sidx1 + (size_t)b * NN * KK1;
  const int* idx2b = idx2 + (size_t)b * MM * KK1;
  const float* tgtb = tgt + (size_t)b * 3 * MM;
  float* s_corrb = s_corr + (size_t)b * 3 * NN;
  float* lossb = lossr + b * NN;
  const float* dn_p = distb + (size_t)n * MM;
  float dn[8];
  #pragma unroll
  for (int i = 0; i < 8; i++) dn[i] = sane(dn_p[t + 256 * i]);
  float tacc[8] = {0, 0, 0, 0, 0, 0, 0, 0};
  const int* i1 = sidx1b + n * KK1;
  for (int j = 1; j < KK1; j++){
    int r = i1[j] & 2047;
    const float* srp = scoresb + (size_t)r * MM;
    #pragma unroll
    for (int i = 0; i < 8; i++) tacc[i] += srp[t + 256 * i];
  }
  #pragma unroll
  for (int i = 0; i < 8; i++) Trow[t + 256 * i] = tacc[i];
  __syncthreads();
  float rloc[8];
  float lmin = 3.4e38f;
  #pragma unroll
  for (int i = 0; i < 8; i++){
    int m = t + 256 * i;
    const int* ip = idx2b + m * KK1;
    float S = 0.f;
    #pragma unroll
    for (int j = 1; j < KK1; j++) S += Trow[ip[j] & 2047];
    float rv = sane(expf(1.0f - S / 7.0f) * dn[i]);
    rloc[i] = rv;
    lmin = fminf(lmin, rv);
  }
  float rmin = blockRed(lmin, red, t, 1);
  float z = 0.f, s0 = 0.f, s1 = 0.f, s2 = 0.f;
  #pragma unroll
  for (int i = 0; i < 8; i++){
    int m = t + 256 * i;
    float p = expf(rmin - rloc[i]);
    z  += p;
    s0 += tgtb[0 * MM + m] * p;
    s1 += tgtb[1 * MM + m] * p;
    s2 += tgtb[2 * MM + m] * p;
  }
  z  = blockRed(z,  red, t, 0);
  s0 = blockRed(s0, red, t, 0);
  s1 = blockRed(s1, red, t, 0);
  s2 = blockRed(s2, red, t, 0);
  if (t == 0){
    float iZ = 1.0f / fmaxf(z, 1e-30f);
    s_corrb[0 * NN + n] = s0 * iZ;
    s_corrb[1 * NN + n] = s1 * iZ;
    s_corrb[2 * NN + n] = s2 * iZ;
    lossb[n] = -logf(fminf(iZ, 1.0f) + 1e-15f);  // pred at onehot == rowmax(rmm) == 1/Z
  }
}

// ---- K5: discriminator MLP — R14: scalar-W2 + e-range wave split (see R14 notes) ---
__global__ __launch_bounds__(256, 4) void k_disc(const float* __restrict__ s_corr, const float* __restrict__ src,
                                                 const float* __restrict__ sknn, const int* __restrict__ sidx,
                                                 const float* __restrict__ W1, const float* __restrict__ b1,
                                                 const float* __restrict__ W2, const float* __restrict__ b2,
                                                 const float* __restrict__ W3, const float* __restrict__ b3,
                                                 float* __restrict__ sArr){
  __shared__ float term[64][129];
  int t = threadIdx.x;
  int b = blockIdx.y;
  int p = t & 63;                      // point within block (lane)
  int n = blockIdx.x * 4 + (p >> 4);   // 4 n-rows per block
  int kk = p & 15;
  int eh = t >> 6;                     // wave id = e-quarter
  int nk = sidx[((b * NN + n) * KK) + kk] & 2047;
  float f[6];
  #pragma unroll
  for (int c = 0; c < 3; c++){
    f[c]     = s_corr[(b * 3 + c) * NN + n] - s_corr[(b * 3 + c) * NN + nk];
    f[3 + c] = src[(b * 3 + c) * NN + n] - sknn[((size_t)(b * NN + n) * KK + kk) * 3 + c];
  }
  // layer 1: per-d expressions verbatim (a = b1[d]; a += f[c]*W1[d*6+c] x6; relu)
  #define L1D(d) ({ float a_ = b1[(d)];              \
                    a_ += f[0] * W1[(d) * 6 + 0];    \
                    a_ += f[1] * W1[(d) * 6 + 1];    \
                    a_ += f[2] * W1[(d) * 6 + 2];    \
                    a_ += f[3] * W1[(d) * 6 + 3];    \
                    a_ += f[4] * W1[(d) * 6 + 4];    \
                    a_ += f[5] * W1[(d) * 6 + 5];    \
                    fmaxf(a_, 0.f); })
  #define HSET(i) f32x4 h##i;                  \
                  h##i.x = L1D(4 * (i) + 0);   \
                  h##i.y = L1D(4 * (i) + 1);   \
                  h##i.z = L1D(4 * (i) + 2);   \
                  h##i.w = L1D(4 * (i) + 3);
  HSET(0) HSET(1) HSET(2) HSET(3) HSET(4) HSET(5) HSET(6) HSET(7)
  HSET(8) HSET(9) HSET(10) HSET(11) HSET(12) HSET(13) HSET(14) HSET(15)
  #undef HSET
  #undef L1D
  // layer 2: this wave's 32 e-chains, e wave-uniform so W2/b2 are scalar loads
  int e0 = __builtin_amdgcn_readfirstlane(eh * 32);
  for (int j = 0; j < 32; j++){
    int e = e0 + j;
    float a = b2[e];
    const f32x4* w4 = (const f32x4*)&W2[e * 64];
    #define QSTEP(i) { f32x4 wv = w4[i]; a += wv.x * h##i.x + wv.y * h##i.y + wv.z * h##i.z + wv.w * h##i.w; }
    QSTEP(0) QSTEP(1) QSTEP(2) QSTEP(3) QSTEP(4) QSTEP(5) QSTEP(6) QSTEP(7)
    QSTEP(8) QSTEP(9) QSTEP(10) QSTEP(11) QSTEP(12) QSTEP(13) QSTEP(14) QSTEP(15)
    #undef QSTEP
    term[p][e] = fmaxf(a, 0.f);
  }
  __syncthreads();
  // layer 3: serial left-fold per point in e-order (verbatim), then 16-lane max
  if (t < 64){
    float sacc = b3[0];
    #pragma unroll 4
    for (int e = 0; e < 128; e++) sacc += W3[e] * term[t][e];
    if (!(fabsf(sacc) < 1e30f)) sacc = -1e30f;
    #pragma unroll
    for (int off = 1; off < 16; off <<= 1) sacc = fmaxf(sacc, __shfl_xor(sacc, off, 16));
    if (kk == 0) sArr[b * NN + n] = sacc;
  }
}

// ---- K6: weight = softmax(s) over n ------------------------------------------------
__global__ __launch_bounds__(256) void k_softw(const float* __restrict__ sArr, float* __restrict__ wArr){
  __shared__ float red[256];
  int b = blockIdx.x, t = threadIdx.x;
  const float* sp = sArr + b * NN;
  float sv[8];
  float mx = -3.4e38f;
  #pragma unroll
  for (int i = 0; i < 8; i++){
    float v = sp[t + 256 * i];
    if (!(fabsf(v) < 1e30f)) v = -1e30f;
    sv[i] = v; mx = fmaxf(mx, v);
  }
  mx = blockRed(mx, red, t, 2);
  float z = 0.f;
  #pragma unroll
  for (int i = 0; i < 8; i++) z += expf(sv[i] - mx);
  z = blockRed(z, red, t, 0);
  float iz = 1.0f / fmaxf(z, 1e-30f);
  #pragma unroll
  for (int i = 0; i < 8; i++) wArr[b * NN + t + 256 * i] = expf(sv[i] - mx) * iz;
}

// ---- K7: stable descending rank -> topi (R15: wave-split + f32x4, exact) -----------
__global__ __launch_bounds__(256) void k_rank(const float* __restrict__ wArr, int* __restrict__ topi){
  __shared__ float wrow[NN];
  __shared__ int pc[4][64];
  int b = blockIdx.y, t = threadIdx.x;
  for (int i = t; i < NN; i += 256) wrow[i] = wArr[b * NN + i];
  __syncthreads();
  int tn = t & 63, tj = t >> 6;
  int n = blockIdx.x * 64 + tn;
  float wn = wrow[n];
  int j0 = tj * 512;
  const f32x4* w4 = (const f32x4*)&wrow[j0];
  int cnt = 0;
  #pragma unroll 4
  for (int q = 0; q < 128; q++){
    f32x4 wv = w4[q];
    int j = j0 + q * 4;
    cnt += (wv.x > wn) || ((wv.x == wn) && (j + 0 < n));
    cnt += (wv.y > wn) || ((wv.y == wn) && (j + 1 < n));
    cnt += (wv.z > wn) || ((wv.z == wn) && (j + 2 < n));
    cnt += (wv.w > wn) || ((wv.w == wn) && (j + 3 < n));
  }
  pc[tj][tn] = cnt;
  __syncthreads();
  if (t < 64){
    int c = pc[0][t] + pc[1][t] + pc[2][t] + pc[3][t];
    if (c < KEY) topi[b * KEY + c] = blockIdx.x * 64 + t;
  }
}

// ---- K8: weighted centroids, H, 3x3 SVD (f64 Jacobi), R/t --------------------------
__device__ __forceinline__ double det3d(const double A[3][3]){
  return A[0][0] * (A[1][1] * A[2][2] - A[1][2] * A[2][1])
       - A[0][1] * (A[1][0] * A[2][2] - A[1][2] * A[2][0])
       + A[0][2] * (A[1][0] * A[2][1] - A[1][1] * A[2][0]);
}

__global__ __launch_bounds__(256) void k_rigid(const float* __restrict__ src, const float* __restrict__ s_corr,
                                               const float* __restrict__ wArr, float* __restrict__ Rt,
                                               float* __restrict__ out){
  __shared__ float red[256];
  int b = blockIdx.x, t = threadIdx.x;
  float wsum = 0, a0 = 0, a1 = 0, a2 = 0, c0 = 0, c1 = 0, c2 = 0;
  for (int n = t; n < NN; n += 256){
    float wv = wArr[b * NN + n];
    float s0 = src[(b * 3 + 0) * NN + n];
    float s1 = src[(b * 3 + 1) * NN + n];
    float s2 = src[(b * 3 + 2) * NN + n];
    float q0 = s_corr[(b * 3 + 0) * NN + n];
    float q1 = s_corr[(b * 3 + 1) * NN + n];
    float q2 = s_corr[(b * 3 + 2) * NN + n];
    wsum += wv; a0 += wv * s0; a1 += wv * s1; a2 += wv * s2;
    c0 += wv * q0; c1 += wv * q1; c2 += wv * q2;
  }
  wsum = blockRed(wsum, red, t, 0);
  a0 = blockRed(a0, red, t, 0); a1 = blockRed(a1, red, t, 0); a2 = blockRed(a2, red, t, 0);
  c0 = blockRed(c0, red, t, 0); c1 = blockRed(c1, red, t, 0); c2 = blockRed(c2, red, t, 0);
  float inv = 1.0f / fmaxf(wsum, 1e-30f);
  float cs0 = a0 * inv, cs1 = a1 * inv, cs2 = a2 * inv;
  float ct0 = c0 * inv, ct1 = c1 * inv, ct2 = c2 * inv;
  float h[9] = {0, 0, 0, 0, 0, 0, 0, 0, 0};
  for (int n = t; n < NN; n += 256){
    float wv = wArr[b * NN + n];
    float ds0 = src[(b * 3 + 0) * NN + n] - cs0;
    float ds1 = src[(b * 3 + 1) * NN + n] - cs1;
    float ds2 = src[(b * 3 + 2) * NN + n] - cs2;
    float dc0 = s_corr[(b * 3 + 0) * NN + n] - ct0;
    float dc1 = s_corr[(b * 3 + 1) * NN + n] - ct1;
    float dc2 = s_corr[(b * 3 + 2) * NN + n] - ct2;
    h[0] += wv * ds0 * dc0; h[1] += wv * ds0 * dc1; h[2] += wv * ds0 * dc2;
    h[3] += wv * ds1 * dc0; h[4] += wv * ds1 * dc1; h[5] += wv * ds1 * dc2;
    h[6] += wv * ds2 * dc0; h[7] += wv * ds2 * dc1; h[8] += wv * ds2 * dc2;
  }
  for (int i = 0; i < 9; i++) h[i] = blockRed(h[i], red, t, 0);
  if (t == 0){
    double Hm[3][3];
    for (int i = 0; i < 3; i++)
      for (int j = 0; j < 3; j++) Hm[i][j] = (double)h[i * 3 + j];
    double Km[3][3], V[3][3] = {{1, 0, 0}, {0, 1, 0}, {0, 0, 1}};
    for (int i = 0; i < 3; i++)
      for (int j = 0; j < 3; j++){
        double s = 0;
        for (int a = 0; a < 3; a++) s += Hm[a][i] * Hm[a][j];
        Km[i][j] = s;
      }
    double ksc = fabs(Km[0][0]) + fabs(Km[1][1]) + fabs(Km[2][2]) + 1e-300;
    for (int sweep = 0; sweep < 60; sweep++){
      int p = 0, q = 1; double mx = fabs(Km[0][1]);
      if (fabs(Km[0][2]) > mx){ mx = fabs(Km[0][2]); p = 0; q = 2; }
      if (fabs(Km[1][2]) > mx){ mx = fabs(Km[1][2]); p = 1; q = 2; }
      if (mx <= 1e-15 * ksc) break;
      double app = Km[p][p], aqq = Km[q][q], apq = Km[p][q];
      double tau = (aqq - app) / (2.0 * apq);
      double tt = ((tau >= 0) ? 1.0 : -1.0) / (fabs(tau) + sqrt(1.0 + tau * tau));
      double cc = 1.0 / sqrt(1.0 + tt * tt), sn = tt * cc;
      for (int k2 = 0; k2 < 3; k2++){
        double akp = Km[k2][p], akq = Km[k2][q];
        Km[k2][p] = cc * akp - sn * akq; Km[k2][q] = sn * akp + cc * akq;
      }
      for (int k2 = 0; k2 < 3; k2++){
        double apk = Km[p][k2], aqk = Km[q][k2];
        Km[p][k2] = cc * apk - sn * aqk; Km[q][k2] = sn * apk + cc * aqk;
      }
      for (int k2 = 0; k2 < 3; k2++){
        double vkp = V[k2][p], vkq = V[k2][q];
        V[k2][p] = cc * vkp - sn * vkq; V[k2][q] = sn * vkp + cc * vkq;
      }
    }
    double lam[3] = {Km[0][0], Km[1][1], Km[2][2]};
    int id0 = 0, id1 = 1, id2 = 2, tmp;
    if (lam[id0] < lam[id1]){ tmp = id0; id0 = id1; id1 = tmp; }
    if (lam[id0] < lam[id2]){ tmp = id0; id0 = id2; id2 = tmp; }
    if (lam[id1] < lam[id2]){ tmp = id1; id1 = id2; id2 = tmp; }
    int idx[3] = {id0, id1, id2};
    double Vs[3][3], U[3][3] = {{0, 0, 0}, {0, 0, 0}, {0, 0, 0}};
    for (int jj = 0; jj < 3; jj++){
      int j = idx[jj];
      for (int i2 = 0; i2 < 3; i2++) Vs[i2][jj] = V[i2][j];
      double u0 = 0, u1 = 0, u2 = 0;
      for (int i2 = 0; i2 < 3; i2++){
        u0 += Hm[0][i2] * V[i2][j];
        u1 += Hm[1][i2] * V[i2][j];
        u2 += Hm[2][i2] * V[i2][j];
      }
      double nrm = sqrt(u0 * u0 + u1 * u1 + u2 * u2);
      if (nrm > 1e-20){
        U[0][jj] = u0 / nrm; U[1][jj] = u1 / nrm; U[2][jj] = u2 / nrm;
      } else {
        double x0 = U[1][0] * U[2][1] - U[2][0] * U[1][1];
        double x1 = U[2][0] * U[0][1] - U[0][0] * U[2][1];
        double x2 = U[0][0] * U[1][1] - U[1][0] * U[0][1];
        double nn2 = sqrt(x0 * x0 + x1 * x1 + x2 * x2);
        if (nn2 < 1e-20){ x0 = 1; x1 = 0; x2 = 0; nn2 = 1; }
        U[0][jj] = x0 / nn2; U[1][jj] = x1 / nn2; U[2][jj] = x2 / nn2;
      }
    }
    double dd = det3d(U) * det3d(Vs);
    double Rm[3][3];
    for (int i2 = 0; i2 < 3; i2++)
      for (int k2 = 0; k2 < 3; k2++)
        Rm[i2][k2] = Vs[i2][0] * U[k2][0] + Vs[i2][1] * U[k2][1] + dd * Vs[i2][2] * U[k2][2];
    double cs[3] = {cs0, cs1, cs2}, ct[3] = {ct0, ct1, ct2};
    double tv[3];
    for (int i2 = 0; i2 < 3; i2++)
      tv[i2] = ct[i2] - (Rm[i2][0] * cs[0] + Rm[i2][1] * cs[1] + Rm[i2][2] * cs[2]);
    for (int i2 = 0; i2 < 3; i2++)
      for (int k2 = 0; k2 < 3; k2++){
        Rt[b * 12 + i2 * 3 + k2] = (float)Rm[i2][k2];
        out[b * 9 + i2 * 3 + k2] = (float)Rm[i2][k2];
      }
    for (int i2 = 0; i2 < 3; i2++){
      Rt[b * 12 + 9 + i2] = (float)tv[i2];
      out[18 + b * 3 + i2] = (float)tv[i2];
    }
  }
}

// ---- K10: gather keypoint outputs, with src_transformed fused inline ---------------
__global__ __launch_bounds__(256) void k_out(const int* __restrict__ topi, const int* __restrict__ sidx,
                                             const float* __restrict__ src, const float* __restrict__ s_corr,
                                             const float* __restrict__ Rt, float* __restrict__ out){
  int b = blockIdx.y, t = threadIdx.x;
  int rr = t >> 4, kk = t & 15;
  int r = blockIdx.x * 16 + rr;
  int ns = topi[b * KEY + r] & 2047;
  int nk = sidx[(b * NN + ns) * KK + kk] & 2047;
  const float* R = Rt + b * 12;
  float sns0 = src[(b * 3 + 0) * NN + ns];
  float sns1 = src[(b * 3 + 1) * NN + ns];
  float sns2 = src[(b * 3 + 2) * NN + ns];
  float snk0 = src[(b * 3 + 0) * NN + nk];
  float snk1 = src[(b * 3 + 1) * NN + nk];
  float snk2 = src[(b * 3 + 2) * NN + nk];
  float* o_sk  = out + 24;
  float* o_tk  = out + 6168;
  float* o_skk = out + 12312;
  float* o_tkk = out + 110616;
  #pragma unroll
  for (int c = 0; c < 3; c++){
    float cv  = s_corr[(b * 3 + c) * NN + ns];
    float ck  = s_corr[(b * 3 + c) * NN + nk];
    o_tkk[(((b * 3 + c) * KEY + r) * KK) + kk] = cv - ck;
    float sv  = R[c * 3 + 0] * sns0 + R[c * 3 + 1] * sns1 + R[c * 3 + 2] * sns2 + R[9 + c];
    float sk2 = R[c * 3 + 0] * snk0 + R[c * 3 + 1] * snk1 + R[c * 3 + 2] * snk2 + R[9 + c];
    o_skk[(((b * 3 + c) * KEY + r) * KK) + kk] = sv - sk2;
    if (kk == 0){
      o_sk[(b * 3 + c) * KEY + r] = sns0 * (c == 0) + sns1 * (c == 1) + sns2 * (c == 2);
      o_tk[(b * 3 + c) * KEY + r] = cv;
    }
  }
}

// ---- K11: loss_scl -----------------------------------------------------------------
__global__ __launch_bounds__(256) void k_loss(const float* __restrict__ loss_row, const int* __restrict__ topi,
                                              float* __restrict__ out){
  __shared__ float red[256];
  int t = threadIdx.x;
  float acc = 0.f;
  for (int i = t; i < BB * KEY; i += 256){
    int b = i >> 10, r = i & 1023;
    int n = topi[b * KEY + r] & 2047;
    acc += loss_row[b * NN + n];
  }
  acc = blockRed(acc, red, t, 0);
  if (t == 0) out[208920] = acc / 2048.0f;
}

extern "C" void kernel_launch(void* const* d_in, const int* in_sizes, int n_in,
                              void* d_out, int out_size, void* d_ws, size_t ws_size,
                              hipStream_t stream){
  const float* src  = (const float*)d_in[0];
  const float* tgt  = (const float*)d_in[1];
  const float* semb = (const float*)d_in[2];
  const float* temb = (const float*)d_in[3];
  const float* sknn = (const float*)d_in[4];
  const float* W1 = (const float*)d_in[6];
  const float* b1 = (const float*)d_in[7];
  const float* W2 = (const float*)d_in[8];
  const float* b2 = (const float*)d_in[9];
  const float* W3 = (const float*)d_in[10];
  const float* b3 = (const float*)d_in[11];
  const int* sidx  = (const int*)d_in[12];
  const int* sidx1 = (const int*)d_in[13];
  const int* idx2  = (const int*)d_in[14];
  float* out = (float*)d_out;

  // workspace layout (peak ~84 MB; harness allocates 256 MiB per fill evidence)
  char* w = (char*)d_ws;
  u16* Ah = (u16*)(w);                               // 4 MB each (B,N,C) bf16 split
  u16* Al = Ah + (size_t)BB * NN * CC;
  u16* Bh = Al + (size_t)BB * NN * CC;
  u16* Bl = Bh + (size_t)BB * MM * CC;
  float* dist = (float*)(Bl + (size_t)BB * MM * CC); // 33.55 MB (B,N,M) f32
  float* scores = dist + (size_t)BB * NN * MM;       // 33.55 MB (B,N,M) f32
  char* tail = (char*)(scores + (size_t)BB * NN * MM);
  float* xx = (float*)tail;                          // B*N
  float* yy = xx + BB * NN;                          // B*M
  float* mnA = yy + BB * MM;                         // B*N
  float* Zr = mnA + BB * NN;                         // B*N
  float* s_corr = Zr + BB * NN;                      // B*3*N
  float* loss_row = s_corr + BB * 3 * NN;            // B*N
  float* sArr = loss_row + BB * NN;                  // B*N
  float* wArr = sArr + BB * NN;                      // B*N
  int* topi = (int*)(wArr + BB * NN);                // B*KEY
  float* Rt = (float*)(topi + BB * KEY);             // B*12

  k_trans<<<dim3(16, 64, 4), dim3(32, 8), 0, stream>>>(semb, temb, Ah, Al, Bh, Bl);
  k_sq<<<dim3(16, 2), 256, 0, stream>>>(semb, temb, xx, yy);
  k_gemm<<<dim3(16, 16, BB), 256, 0, stream>>>(Ah, Al, Bh, Bl, xx, yy, dist);
  k_rowstats<<<dim3(NN, BB), 256, 0, stream>>>(dist, mnA, Zr, scores);
  k_fused<<<dim3(NN, BB), 256, 0, stream>>>(dist, scores, sidx1, idx2, tgt, s_corr, loss_row);
  k_disc<<<dim3(NN / 4, BB), 256, 0, stream>>>(s_corr, src, sknn, sidx, W1, b1, W2, b2, W3, b3, sArr);
  k_softw<<<BB, 256, 0, stream>>>(sArr, wArr);
  k_rank<<<dim3(32, BB), 256, 0, stream>>>(wArr, topi);
  k_rigid<<<BB, 256, 0, stream>>>(src, s_corr, wArr, Rt, out);
  k_out<<<dim3(64, BB), 256, 0, stream>>>(topi, sidx, src, s_corr, Rt, out);
  k_loss<<<1, 256, 0, stream>>>(loss_row, topi, out);
}

// Round 7
// 281.414 us; speedup vs baseline: 1.9600x; 1.0141x over previous
//
#include <hip/hip_runtime.h>
#include <stdint.h>

typedef unsigned short u16;

#define BB 2
#define NN 2048
#define MM 2048
#define CC 512
#define KK 16
#define KK1 8
#define KEY 1024

typedef __attribute__((ext_vector_type(8))) short bf16x8;
typedef __attribute__((ext_vector_type(4))) float f32x4;

__device__ __forceinline__ float b2f(u16 u){ return __uint_as_float(((uint32_t)u) << 16); }
__device__ __forceinline__ u16 f2b(float f){
  uint32_t x = __float_as_uint(f);
  uint32_t r = x + 0x7FFFu + ((x >> 16) & 1u);
  return (u16)(r >> 16);
}
__device__ __forceinline__ float sane(float v){ return (fabsf(v) < 1e30f) ? v : 1e30f; }

// all-thread block reduction, 256 threads. op: 0=sum 1=min 2=max
__device__ __forceinline__ float blockRed(float v, float* red, int t, int op){
  red[t] = v; __syncthreads();
  #pragma unroll
  for (int s = 128; s > 0; s >>= 1){
    if (t < s){
      float a = red[t], b = red[t + s];
      red[t] = (op == 0) ? (a + b) : ((op == 1) ? fminf(a, b) : fmaxf(a, b));
    }
    __syncthreads();
  }
  float r = red[0]; __syncthreads();
  return r;
}

// ---- K0: transpose f32 (B,C,N) -> split-bf16 (B,N,C) hi/lo pairs -------------------
__global__ __launch_bounds__(256) void k_trans(const float* __restrict__ semb, const float* __restrict__ temb,
                                               u16* __restrict__ Ah, u16* __restrict__ Al,
                                               u16* __restrict__ Bh, u16* __restrict__ Bl){
  __shared__ float tile[32][33];
  int b = blockIdx.z & 1, which = blockIdx.z >> 1;
  const float* in = which ? temb : semb;
  u16* oh = which ? Bh : Ah;
  u16* ol = which ? Bl : Al;
  int c0 = blockIdx.x * 32, n0 = blockIdx.y * 32;
  int tx = threadIdx.x, ty = threadIdx.y;
  #pragma unroll
  for (int i = 0; i < 4; i++){
    int r = ty + 8 * i;
    tile[r][tx] = in[((b * CC + c0 + r) * NN) + n0 + tx];
  }
  __syncthreads();
  #pragma unroll
  for (int i = 0; i < 4; i++){
    int r = ty + 8 * i;
    float v = tile[tx][r];
    u16 hi = f2b(v);
    float lo = v - b2f(hi);
    size_t o = ((size_t)(b * NN + n0 + r) * CC) + c0 + tx;
    oh[o] = hi;
    ol[o] = f2b(lo);
  }
}

// ---- K1: exact f32 row squared norms (R19: reverted to exact serial c-loop) --------
// R18 LESSON: the 4-way c-split perturbed xx/yy by ~1ulp -> chained into wArr ->
// flipped near-tie comparisons in k_rank -> different topi -> O(1) output error
// (src_keypoints absmax 1.68). NO FP change ahead of a discrete selection; only
// bit-identical transforms are admissible on that path.
__global__ __launch_bounds__(256) void k_sq(const float* __restrict__ semb, const float* __restrict__ temb,
                                            float* __restrict__ xx, float* __restrict__ yy){
  int which = blockIdx.y;
  const float* in = which ? temb : semb;
  float* out = which ? yy : xx;
  int gid = blockIdx.x * 256 + threadIdx.x;   // 0..4095
  int b = gid >> 11, n = gid & 2047;
  float acc = 0.f;
  for (int c = 0; c < CC; c++){
    float v = in[((size_t)(b * CC + c)) * NN + n];
    acc += v * v;
  }
  out[gid] = acc;
}

// ---- K2: dist = xx - 2*A.B^T + yy, split-bf16 MFMA (hi*hi + hi*lo + lo*hi) ---------
// R16: both batches in one dispatch (grid z=BB): 512 blocks = 2 blocks/CU (LDS cap).
__global__ __launch_bounds__(256) void k_gemm(const u16* __restrict__ Ah, const u16* __restrict__ Al,
                                              const u16* __restrict__ Bh, const u16* __restrict__ Bl,
                                              const float* __restrict__ xx, const float* __restrict__ yy,
                                              float* __restrict__ dist){
  __shared__ __align__(16) u16 lAh[128 * 64];
  __shared__ __align__(16) u16 lAl[128 * 64];
  __shared__ __align__(16) u16 lBh[128 * 64];
  __shared__ __align__(16) u16 lBl[128 * 64];
  int bz = blockIdx.z;
  const u16* Ahb = Ah + (size_t)bz * NN * CC;
  const u16* Alb = Al + (size_t)bz * NN * CC;
  const u16* Bhb = Bh + (size_t)bz * MM * CC;
  const u16* Blb = Bl + (size_t)bz * MM * CC;
  const float* xxb = xx + bz * NN;
  const float* yyb = yy + bz * MM;
  float* distb = dist + (size_t)bz * NN * MM;
  int n0 = blockIdx.y * 128, m0 = blockIdx.x * 128;
  int t = threadIdx.x;
  f32x4 acc[4][4];
  #pragma unroll
  for (int i = 0; i < 4; i++)
    #pragma unroll
    for (int j = 0; j < 4; j++){ f32x4 z = {0.f, 0.f, 0.f, 0.f}; acc[i][j] = z; }
  int w = t >> 6, lane = t & 63, lr = lane & 15, quad = lane >> 4;
  int wn = (w >> 1) * 64, wm = (w & 1) * 64;
  for (int kt = 0; kt < 8; kt++){
    int k0 = kt * 64;
    bf16x8 vah[4], val[4], vbh[4], vbl[4];
    #pragma unroll
    for (int s = 0; s < 4; s++){
      int ch = t + 256 * s;
      int rn = ch >> 3, k8 = (ch & 7) * 8;
      size_t oa = (size_t)(n0 + rn) * CC + k0 + k8;
      size_t ob = (size_t)(m0 + rn) * CC + k0 + k8;
      vah[s] = *(const bf16x8*)(Ahb + oa);
      val[s] = *(const bf16x8*)(Alb + oa);
      vbh[s] = *(const bf16x8*)(Bhb + ob);
      vbl[s] = *(const bf16x8*)(Blb + ob);
    }
    __syncthreads();
    #pragma unroll
    for (int s = 0; s < 4; s++){
      int ch = t + 256 * s;
      *(bf16x8*)&lAh[ch * 8] = vah[s];
      *(bf16x8*)&lAl[ch * 8] = val[s];
      *(bf16x8*)&lBh[ch * 8] = vbh[s];
      *(bf16x8*)&lBl[ch * 8] = vbl[s];
    }
    __syncthreads();
    #pragma unroll
    for (int kk = 0; kk < 2; kk++){
      int off = kk * 32 + quad * 8;
      bf16x8 afh[4], afl[4], bfh[4], bfl[4];
      #pragma unroll
      for (int i = 0; i < 4; i++){
        int ra = (wn + i * 16 + lr) * 64 + off;
        afh[i] = *(const bf16x8*)&lAh[ra];
        afl[i] = *(const bf16x8*)&lAl[ra];
      }
      #pragma unroll
      for (int j = 0; j < 4; j++){
        int rb = (wm + j * 16 + lr) * 64 + off;
        bfh[j] = *(const bf16x8*)&lBh[rb];
        bfl[j] = *(const bf16x8*)&lBl[rb];
      }
      #pragma unroll
      for (int i = 0; i < 4; i++)
        #pragma unroll
        for (int j = 0; j < 4; j++){
          acc[i][j] = __builtin_amdgcn_mfma_f32_16x16x32_bf16(afh[i], bfh[j], acc[i][j], 0, 0, 0);
          acc[i][j] = __builtin_amdgcn_mfma_f32_16x16x32_bf16(afh[i], bfl[j], acc[i][j], 0, 0, 0);
          acc[i][j] = __builtin_amdgcn_mfma_f32_16x16x32_bf16(afl[i], bfh[j], acc[i][j], 0, 0, 0);
        }
    }
  }
  #pragma unroll
  for (int i = 0; i < 4; i++){
    int nbase = n0 + wn + i * 16 + quad * 4;
    #pragma unroll
    for (int j = 0; j < 4; j++){
      int m = m0 + wm + j * 16 + lr;
      float yv = yyb[m];
      #pragma unroll
      for (int r = 0; r < 4; r++){
        distb[((size_t)(nbase + r)) * MM + m] = xxb[nbase + r] + yv - 2.0f * acc[i][j][r];
      }
    }
  }
}

// ---- K3: per-row min, softmax denom, AND scores row (R17) --------------------------
__global__ __launch_bounds__(256) void k_rowstats(const float* __restrict__ dist,
                                                  float* __restrict__ mnA, float* __restrict__ Zr,
                                                  float* __restrict__ scores){
  __shared__ float red[256];
  int row = blockIdx.x, b = blockIdx.y, t = threadIdx.x;
  const float* dr = dist + ((size_t)b * NN + row) * MM;
  float* sr = scores + ((size_t)b * NN + row) * MM;
  float d[8];
  float mn = 3.4e38f;
  #pragma unroll
  for (int i = 0; i < 8; i++){ d[i] = sane(dr[t + 256 * i]); mn = fminf(mn, d[i]); }
  mn = blockRed(mn, red, t, 1);
  float p[8];
  float z = 0.f;
  #pragma unroll
  for (int i = 0; i < 8; i++){ p[i] = expf(mn - d[i]); z += p[i]; }
  z = blockRed(z, red, t, 0);
  float zc = fmaxf(z, 1e-30f);
  if (t == 0){ mnA[b * NN + row] = mn; Zr[b * NN + row] = zc; }
  float iz = 1.0f / zc;
  #pragma unroll
  for (int i = 0; i < 8; i++) sr[t + 256 * i] = p[i] * iz;
}

// ---- K4: fused T/S/refined/rmm/src_corr/loss per row n (grid y = batch) ------------
// R18-safe parts kept: idx loads vectorized as int4 pairs (same values, same j-order
// -> bit-identical); dist row via nontemporal load (pure cache hint).
__global__ __launch_bounds__(256) void k_fused(const float* __restrict__ dist, const float* __restrict__ scores,
                                               const int* __restrict__ sidx1,
                                               const int* __restrict__ idx2, const float* __restrict__ tgt,
                                               float* __restrict__ s_corr, float* __restrict__ lossr){
  __shared__ float Trow[MM];
  __shared__ float red[256];
  int n = blockIdx.x, b = blockIdx.y, t = threadIdx.x;
  const float* distb = dist + (size_t)b * NN * MM;
  const float* scoresb = scores + (size_t)b * NN * MM;
  const int* sidx1b = sidx1 + (size_t)b * NN * KK1;
  const int* idx2b = idx2 + (size_t)b * MM * KK1;
  const float* tgtb = tgt + (size_t)b * 3 * MM;
  float* s_corrb = s_corr + (size_t)b * 3 * NN;
  float* lossb = lossr + b * NN;
  const float* dn_p = distb + (size_t)n * MM;
  float dn[8];
  #pragma unroll
  for (int i = 0; i < 8; i++) dn[i] = sane(__builtin_nontemporal_load(dn_p + t + 256 * i));
  float tacc[8] = {0, 0, 0, 0, 0, 0, 0, 0};
  const int4* i1v = (const int4*)(sidx1b + n * KK1);
  int4 i1a = i1v[0], i1b = i1v[1];
  int rj[7] = {i1a.y & 2047, i1a.z & 2047, i1a.w & 2047,
               i1b.x & 2047, i1b.y & 2047, i1b.z & 2047, i1b.w & 2047};
  #pragma unroll
  for (int j = 0; j < 7; j++){
    const float* srp = scoresb + (size_t)rj[j] * MM;
    #pragma unroll
    for (int i = 0; i < 8; i++) tacc[i] += srp[t + 256 * i];
  }
  #pragma unroll
  for (int i = 0; i < 8; i++) Trow[t + 256 * i] = tacc[i];
  __syncthreads();
  float rloc[8];
  float lmin = 3.4e38f;
  #pragma unroll
  for (int i = 0; i < 8; i++){
    int m = t + 256 * i;
    const int4* ipv = (const int4*)(idx2b + m * KK1);
    int4 ipa = ipv[0], ipb = ipv[1];
    float S = 0.f;
    S += Trow[ipa.y & 2047];
    S += Trow[ipa.z & 2047];
    S += Trow[ipa.w & 2047];
    S += Trow[ipb.x & 2047];
    S += Trow[ipb.y & 2047];
    S += Trow[ipb.z & 2047];
    S += Trow[ipb.w & 2047];
    float rv = sane(expf(1.0f - S / 7.0f) * dn[i]);
    rloc[i] = rv;
    lmin = fminf(lmin, rv);
  }
  float rmin = blockRed(lmin, red, t, 1);
  float z = 0.f, s0 = 0.f, s1 = 0.f, s2 = 0.f;
  #pragma unroll
  for (int i = 0; i < 8; i++){
    int m = t + 256 * i;
    float p = expf(rmin - rloc[i]);
    z  += p;
    s0 += tgtb[0 * MM + m] * p;
    s1 += tgtb[1 * MM + m] * p;
    s2 += tgtb[2 * MM + m] * p;
  }
  z  = blockRed(z,  red, t, 0);
  s0 = blockRed(s0, red, t, 0);
  s1 = blockRed(s1, red, t, 0);
  s2 = blockRed(s2, red, t, 0);
  if (t == 0){
    float iZ = 1.0f / fmaxf(z, 1e-30f);
    s_corrb[0 * NN + n] = s0 * iZ;
    s_corrb[1 * NN + n] = s1 * iZ;
    s_corrb[2 * NN + n] = s2 * iZ;
    lossb[n] = -logf(fminf(iZ, 1.0f) + 1e-15f);  // pred at onehot == rowmax(rmm) == 1/Z
  }
}

// ---- K5: discriminator MLP — R14: scalar-W2 + e-range wave split (see R14 notes) ---
__global__ __launch_bounds__(256, 4) void k_disc(const float* __restrict__ s_corr, const float* __restrict__ src,
                                                 const float* __restrict__ sknn, const int* __restrict__ sidx,
                                                 const float* __restrict__ W1, const float* __restrict__ b1,
                                                 const float* __restrict__ W2, const float* __restrict__ b2,
                                                 const float* __restrict__ W3, const float* __restrict__ b3,
                                                 float* __restrict__ sArr){
  __shared__ float term[64][129];
  int t = threadIdx.x;
  int b = blockIdx.y;
  int p = t & 63;                      // point within block (lane)
  int n = blockIdx.x * 4 + (p >> 4);   // 4 n-rows per block
  int kk = p & 15;
  int eh = t >> 6;                     // wave id = e-quarter
  int nk = sidx[((b * NN + n) * KK) + kk] & 2047;
  float f[6];
  #pragma unroll
  for (int c = 0; c < 3; c++){
    f[c]     = s_corr[(b * 3 + c) * NN + n] - s_corr[(b * 3 + c) * NN + nk];
    f[3 + c] = src[(b * 3 + c) * NN + n] - sknn[((size_t)(b * NN + n) * KK + kk) * 3 + c];
  }
  // layer 1: per-d expressions verbatim (a = b1[d]; a += f[c]*W1[d*6+c] x6; relu)
  #define L1D(d) ({ float a_ = b1[(d)];              \
                    a_ += f[0] * W1[(d) * 6 + 0];    \
                    a_ += f[1] * W1[(d) * 6 + 1];    \
                    a_ += f[2] * W1[(d) * 6 + 2];    \
                    a_ += f[3] * W1[(d) * 6 + 3];    \
                    a_ += f[4] * W1[(d) * 6 + 4];    \
                    a_ += f[5] * W1[(d) * 6 + 5];    \
                    fmaxf(a_, 0.f); })
  #define HSET(i) f32x4 h##i;                  \
                  h##i.x = L1D(4 * (i) + 0);   \
                  h##i.y = L1D(4 * (i) + 1);   \
                  h##i.z = L1D(4 * (i) + 2);   \
                  h##i.w = L1D(4 * (i) + 3);
  HSET(0) HSET(1) HSET(2) HSET(3) HSET(4) HSET(5) HSET(6) HSET(7)
  HSET(8) HSET(9) HSET(10) HSET(11) HSET(12) HSET(13) HSET(14) HSET(15)
  #undef HSET
  #undef L1D
  // layer 2: this wave's 32 e-chains, e wave-uniform so W2/b2 are scalar loads
  int e0 = __builtin_amdgcn_readfirstlane(eh * 32);
  for (int j = 0; j < 32; j++){
    int e = e0 + j;
    float a = b2[e];
    const f32x4* w4 = (const f32x4*)&W2[e * 64];
    #define QSTEP(i) { f32x4 wv = w4[i]; a += wv.x * h##i.x + wv.y * h##i.y + wv.z * h##i.z + wv.w * h##i.w; }
    QSTEP(0) QSTEP(1) QSTEP(2) QSTEP(3) QSTEP(4) QSTEP(5) QSTEP(6) QSTEP(7)
    QSTEP(8) QSTEP(9) QSTEP(10) QSTEP(11) QSTEP(12) QSTEP(13) QSTEP(14) QSTEP(15)
    #undef QSTEP
    term[p][e] = fmaxf(a, 0.f);
  }
  __syncthreads();
  // layer 3: serial left-fold per point in e-order (verbatim), then 16-lane max
  if (t < 64){
    float sacc = b3[0];
    #pragma unroll 4
    for (int e = 0; e < 128; e++) sacc += W3[e] * term[t][e];
    if (!(fabsf(sacc) < 1e30f)) sacc = -1e30f;
    #pragma unroll
    for (int off = 1; off < 16; off <<= 1) sacc = fmaxf(sacc, __shfl_xor(sacc, off, 16));
    if (kk == 0) sArr[b * NN + n] = sacc;
  }
}

// ---- K6: weight = softmax(s) over n ------------------------------------------------
__global__ __launch_bounds__(256) void k_softw(const float* __restrict__ sArr, float* __restrict__ wArr){
  __shared__ float red[256];
  int b = blockIdx.x, t = threadIdx.x;
  const float* sp = sArr + b * NN;
  float sv[8];
  float mx = -3.4e38f;
  #pragma unroll
  for (int i = 0; i < 8; i++){
    float v = sp[t + 256 * i];
    if (!(fabsf(v) < 1e30f)) v = -1e30f;
    sv[i] = v; mx = fmaxf(mx, v);
  }
  mx = blockRed(mx, red, t, 2);
  float z = 0.f;
  #pragma unroll
  for (int i = 0; i < 8; i++) z += expf(sv[i] - mx);
  z = blockRed(z, red, t, 0);
  float iz = 1.0f / fmaxf(z, 1e-30f);
  #pragma unroll
  for (int i = 0; i < 8; i++) wArr[b * NN + t + 256 * i] = expf(sv[i] - mx) * iz;
}

// ---- K7: stable descending rank -> topi (R15: wave-split + f32x4, exact) -----------
__global__ __launch_bounds__(256) void k_rank(const float* __restrict__ wArr, int* __restrict__ topi){
  __shared__ float wrow[NN];
  __shared__ int pc[4][64];
  int b = blockIdx.y, t = threadIdx.x;
  for (int i = t; i < NN; i += 256) wrow[i] = wArr[b * NN + i];
  __syncthreads();
  int tn = t & 63, tj = t >> 6;
  int n = blockIdx.x * 64 + tn;
  float wn = wrow[n];
  int j0 = tj * 512;
  const f32x4* w4 = (const f32x4*)&wrow[j0];
  int cnt = 0;
  #pragma unroll 4
  for (int q = 0; q < 128; q++){
    f32x4 wv = w4[q];
    int j = j0 + q * 4;
    cnt += (wv.x > wn) || ((wv.x == wn) && (j + 0 < n));
    cnt += (wv.y > wn) || ((wv.y == wn) && (j + 1 < n));
    cnt += (wv.z > wn) || ((wv.z == wn) && (j + 2 < n));
    cnt += (wv.w > wn) || ((wv.w == wn) && (j + 3 < n));
  }
  pc[tj][tn] = cnt;
  __syncthreads();
  if (t < 64){
    int c = pc[0][t] + pc[1][t] + pc[2][t] + pc[3][t];
    if (c < KEY) topi[b * KEY + c] = blockIdx.x * 64 + t;
  }
}

// ---- K8: weighted centroids, H, 3x3 SVD (f64 Jacobi), R/t --------------------------
__device__ __forceinline__ double det3d(const double A[3][3]){
  return A[0][0] * (A[1][1] * A[2][2] - A[1][2] * A[2][1])
       - A[0][1] * (A[1][0] * A[2][2] - A[1][2] * A[2][0])
       + A[0][2] * (A[1][0] * A[2][1] - A[1][1] * A[2][0]);
}

__global__ __launch_bounds__(256) void k_rigid(const float* __restrict__ src, const float* __restrict__ s_corr,
                                               const float* __restrict__ wArr, float* __restrict__ Rt,
                                               float* __restrict__ out){
  __shared__ float red[256];
  int b = blockIdx.x, t = threadIdx.x;
  float wsum = 0, a0 = 0, a1 = 0, a2 = 0, c0 = 0, c1 = 0, c2 = 0;
  for (int n = t; n < NN; n += 256){
    float wv = wArr[b * NN + n];
    float s0 = src[(b * 3 + 0) * NN + n];
    float s1 = src[(b * 3 + 1) * NN + n];
    float s2 = src[(b * 3 + 2) * NN + n];
    float q0 = s_corr[(b * 3 + 0) * NN + n];
    float q1 = s_corr[(b * 3 + 1) * NN + n];
    float q2 = s_corr[(b * 3 + 2) * NN + n];
    wsum += wv; a0 += wv * s0; a1 += wv * s1; a2 += wv * s2;
    c0 += wv * q0; c1 += wv * q1; c2 += wv * q2;
  }
  wsum = blockRed(wsum, red, t, 0);
  a0 = blockRed(a0, red, t, 0); a1 = blockRed(a1, red, t, 0); a2 = blockRed(a2, red, t, 0);
  c0 = blockRed(c0, red, t, 0); c1 = blockRed(c1, red, t, 0); c2 = blockRed(c2, red, t, 0);
  float inv = 1.0f / fmaxf(wsum, 1e-30f);
  float cs0 = a0 * inv, cs1 = a1 * inv, cs2 = a2 * inv;
  float ct0 = c0 * inv, ct1 = c1 * inv, ct2 = c2 * inv;
  float h[9] = {0, 0, 0, 0, 0, 0, 0, 0, 0};
  for (int n = t; n < NN; n += 256){
    float wv = wArr[b * NN + n];
    float ds0 = src[(b * 3 + 0) * NN + n] - cs0;
    float ds1 = src[(b * 3 + 1) * NN + n] - cs1;
    float ds2 = src[(b * 3 + 2) * NN + n] - cs2;
    float dc0 = s_corr[(b * 3 + 0) * NN + n] - ct0;
    float dc1 = s_corr[(b * 3 + 1) * NN + n] - ct1;
    float dc2 = s_corr[(b * 3 + 2) * NN + n] - ct2;
    h[0] += wv * ds0 * dc0; h[1] += wv * ds0 * dc1; h[2] += wv * ds0 * dc2;
    h[3] += wv * ds1 * dc0; h[4] += wv * ds1 * dc1; h[5] += wv * ds1 * dc2;
    h[6] += wv * ds2 * dc0; h[7] += wv * ds2 * dc1; h[8] += wv * ds2 * dc2;
  }
  for (int i = 0; i < 9; i++) h[i] = blockRed(h[i], red, t, 0);
  if (t == 0){
    double Hm[3][3];
    for (int i = 0; i < 3; i++)
      for (int j = 0; j < 3; j++) Hm[i][j] = (double)h[i * 3 + j];
    double Km[3][3], V[3][3] = {{1, 0, 0}, {0, 1, 0}, {0, 0, 1}};
    for (int i = 0; i < 3; i++)
      for (int j = 0; j < 3; j++){
        double s = 0;
        for (int a = 0; a < 3; a++) s += Hm[a][i] * Hm[a][j];
        Km[i][j] = s;
      }
    double ksc = fabs(Km[0][0]) + fabs(Km[1][1]) + fabs(Km[2][2]) + 1e-300;
    for (int sweep = 0; sweep < 60; sweep++){
      int p = 0, q = 1; double mx = fabs(Km[0][1]);
      if (fabs(Km[0][2]) > mx){ mx = fabs(Km[0][2]); p = 0; q = 2; }
      if (fabs(Km[1][2]) > mx){ mx = fabs(Km[1][2]); p = 1; q = 2; }
      if (mx <= 1e-15 * ksc) break;
      double app = Km[p][p], aqq = Km[q][q], apq = Km[p][q];
      double tau = (aqq - app) / (2.0 * apq);
      double tt = ((tau >= 0) ? 1.0 : -1.0) / (fabs(tau) + sqrt(1.0 + tau * tau));
      double cc = 1.0 / sqrt(1.0 + tt * tt), sn = tt * cc;
      for (int k2 = 0; k2 < 3; k2++){
        double akp = Km[k2][p], akq = Km[k2][q];
        Km[k2][p] = cc * akp - sn * akq; Km[k2][q] = sn * akp + cc * akq;
      }
      for (int k2 = 0; k2 < 3; k2++){
        double apk = Km[p][k2], aqk = Km[q][k2];
        Km[p][k2] = cc * apk - sn * aqk; Km[q][k2] = sn * apk + cc * aqk;
      }
      for (int k2 = 0; k2 < 3; k2++){
        double vkp = V[k2][p], vkq = V[k2][q];
        V[k2][p] = cc * vkp - sn * vkq; V[k2][q] = sn * vkp + cc * vkq;
      }
    }
    double lam[3] = {Km[0][0], Km[1][1], Km[2][2]};
    int id0 = 0, id1 = 1, id2 = 2, tmp;
    if (lam[id0] < lam[id1]){ tmp = id0; id0 = id1; id1 = tmp; }
    if (lam[id0] < lam[id2]){ tmp = id0; id0 = id2; id2 = tmp; }
    if (lam[id1] < lam[id2]){ tmp = id1; id1 = id2; id2 = tmp; }
    int idx[3] = {id0, id1, id2};
    double Vs[3][3], U[3][3] = {{0, 0, 0}, {0, 0, 0}, {0, 0, 0}};
    for (int jj = 0; jj < 3; jj++){
      int j = idx[jj];
      for (int i2 = 0; i2 < 3; i2++) Vs[i2][jj] = V[i2][j];
      double u0 = 0, u1 = 0, u2 = 0;
      for (int i2 = 0; i2 < 3; i2++){
        u0 += Hm[0][i2] * V[i2][j];
        u1 += Hm[1][i2] * V[i2][j];
        u2 += Hm[2][i2] * V[i2][j];
      }
      double nrm = sqrt(u0 * u0 + u1 * u1 + u2 * u2);
      if (nrm > 1e-20){
        U[0][jj] = u0 / nrm; U[1][jj] = u1 / nrm; U[2][jj] = u2 / nrm;
      } else {
        double x0 = U[1][0] * U[2][1] - U[2][0] * U[1][1];
        double x1 = U[2][0] * U[0][1] - U[0][0] * U[2][1];
        double x2 = U[0][0] * U[1][1] - U[1][0] * U[0][1];
        double nn2 = sqrt(x0 * x0 + x1 * x1 + x2 * x2);
        if (nn2 < 1e-20){ x0 = 1; x1 = 0; x2 = 0; nn2 = 1; }
        U[0][jj] = x0 / nn2; U[1][jj] = x1 / nn2; U[2][jj] = x2 / nn2;
      }
    }
    double dd = det3d(U) * det3d(Vs);
    double Rm[3][3];
    for (int i2 = 0; i2 < 3; i2++)
      for (int k2 = 0; k2 < 3; k2++)
        Rm[i2][k2] = Vs[i2][0] * U[k2][0] + Vs[i2][1] * U[k2][1] + dd * Vs[i2][2] * U[k2][2];
    double cs[3] = {cs0, cs1, cs2}, ct[3] = {ct0, ct1, ct2};
    double tv[3];
    for (int i2 = 0; i2 < 3; i2++)
      tv[i2] = ct[i2] - (Rm[i2][0] * cs[0] + Rm[i2][1] * cs[1] + Rm[i2][2] * cs[2]);
    for (int i2 = 0; i2 < 3; i2++)
      for (int k2 = 0; k2 < 3; k2++){
        Rt[b * 12 + i2 * 3 + k2] = (float)Rm[i2][k2];
        out[b * 9 + i2 * 3 + k2] = (float)Rm[i2][k2];
      }
    for (int i2 = 0; i2 < 3; i2++){
      Rt[b * 12 + 9 + i2] = (float)tv[i2];
      out[18 + b * 3 + i2] = (float)tv[i2];
    }
  }
}

// ---- K10: gather keypoint outputs, with src_transformed fused inline ---------------
__global__ __launch_bounds__(256) void k_out(const int* __restrict__ topi, const int* __restrict__ sidx,
                                             const float* __restrict__ src, const float* __restrict__ s_corr,
                                             const float* __restrict__ Rt, float* __restrict__ out){
  int b = blockIdx.y, t = threadIdx.x;
  int rr = t >> 4, kk = t & 15;
  int r = blockIdx.x * 16 + rr;
  int ns = topi[b * KEY + r] & 2047;
  int nk = sidx[(b * NN + ns) * KK + kk] & 2047;
  const float* R = Rt + b * 12;
  float sns0 = src[(b * 3 + 0) * NN + ns];
  float sns1 = src[(b * 3 + 1) * NN + ns];
  float sns2 = src[(b * 3 + 2) * NN + ns];
  float snk0 = src[(b * 3 + 0) * NN + nk];
  float snk1 = src[(b * 3 + 1) * NN + nk];
  float snk2 = src[(b * 3 + 2) * NN + nk];
  float* o_sk  = out + 24;
  float* o_tk  = out + 6168;
  float* o_skk = out + 12312;
  float* o_tkk = out + 110616;
  #pragma unroll
  for (int c = 0; c < 3; c++){
    float cv  = s_corr[(b * 3 + c) * NN + ns];
    float ck  = s_corr[(b * 3 + c) * NN + nk];
    o_tkk[(((b * 3 + c) * KEY + r) * KK) + kk] = cv - ck;
    float sv  = R[c * 3 + 0] * sns0 + R[c * 3 + 1] * sns1 + R[c * 3 + 2] * sns2 + R[9 + c];
    float sk2 = R[c * 3 + 0] * snk0 + R[c * 3 + 1] * snk1 + R[c * 3 + 2] * snk2 + R[9 + c];
    o_skk[(((b * 3 + c) * KEY + r) * KK) + kk] = sv - sk2;
    if (kk == 0){
      o_sk[(b * 3 + c) * KEY + r] = sns0 * (c == 0) + sns1 * (c == 1) + sns2 * (c == 2);
      o_tk[(b * 3 + c) * KEY + r] = cv;
    }
  }
}

// ---- K11: loss_scl -----------------------------------------------------------------
__global__ __launch_bounds__(256) void k_loss(const float* __restrict__ loss_row, const int* __restrict__ topi,
                                              float* __restrict__ out){
  __shared__ float red[256];
  int t = threadIdx.x;
  float acc = 0.f;
  for (int i = t; i < BB * KEY; i += 256){
    int b = i >> 10, r = i & 1023;
    int n = topi[b * KEY + r] & 2047;
    acc += loss_row[b * NN + n];
  }
  acc = blockRed(acc, red, t, 0);
  if (t == 0) out[208920] = acc / 2048.0f;
}

extern "C" void kernel_launch(void* const* d_in, const int* in_sizes, int n_in,
                              void* d_out, int out_size, void* d_ws, size_t ws_size,
                              hipStream_t stream){
  const float* src  = (const float*)d_in[0];
  const float* tgt  = (const float*)d_in[1];
  const float* semb = (const float*)d_in[2];
  const float* temb = (const float*)d_in[3];
  const float* sknn = (const float*)d_in[4];
  const float* W1 = (const float*)d_in[6];
  const float* b1 = (const float*)d_in[7];
  const float* W2 = (const float*)d_in[8];
  const float* b2 = (const float*)d_in[9];
  const float* W3 = (const float*)d_in[10];
  const float* b3 = (const float*)d_in[11];
  const int* sidx  = (const int*)d_in[12];
  const int* sidx1 = (const int*)d_in[13];
  const int* idx2  = (const int*)d_in[14];
  float* out = (float*)d_out;

  // workspace layout (peak ~84 MB; harness allocates 256 MiB per fill evidence)
  char* w = (char*)d_ws;
  u16* Ah = (u16*)(w);                               // 4 MB each (B,N,C) bf16 split
  u16* Al = Ah + (size_t)BB * NN * CC;
  u16* Bh = Al + (size_t)BB * NN * CC;
  u16* Bl = Bh + (size_t)BB * MM * CC;
  float* dist = (float*)(Bl + (size_t)BB * MM * CC); // 33.55 MB (B,N,M) f32
  float* scores = dist + (size_t)BB * NN * MM;       // 33.55 MB (B,N,M) f32
  char* tail = (char*)(scores + (size_t)BB * NN * MM);
  float* xx = (float*)tail;                          // B*N
  float* yy = xx + BB * NN;                          // B*M
  float* mnA = yy + BB * MM;                         // B*N
  float* Zr = mnA + BB * NN;                         // B*N
  float* s_corr = Zr + BB * NN;                      // B*3*N
  float* loss_row = s_corr + BB * 3 * NN;            // B*N
  float* sArr = loss_row + BB * NN;                  // B*N
  float* wArr = sArr + BB * NN;                      // B*N
  int* topi = (int*)(wArr + BB * NN);                // B*KEY
  float* Rt = (float*)(topi + BB * KEY);             // B*12

  k_trans<<<dim3(16, 64, 4), dim3(32, 8), 0, stream>>>(semb, temb, Ah, Al, Bh, Bl);
  k_sq<<<dim3(16, 2), 256, 0, stream>>>(semb, temb, xx, yy);
  k_gemm<<<dim3(16, 16, BB), 256, 0, stream>>>(Ah, Al, Bh, Bl, xx, yy, dist);
  k_rowstats<<<dim3(NN, BB), 256, 0, stream>>>(dist, mnA, Zr, scores);
  k_fused<<<dim3(NN, BB), 256, 0, stream>>>(dist, scores, sidx1, idx2, tgt, s_corr, loss_row);
  k_disc<<<dim3(NN / 4, BB), 256, 0, stream>>>(s_corr, src, sknn, sidx, W1, b1, W2, b2, W3, b3, sArr);
  k_softw<<<BB, 256, 0, stream>>>(sArr, wArr);
  k_rank<<<dim3(32, BB), 256, 0, stream>>>(wArr, topi);
  k_rigid<<<BB, 256, 0, stream>>>(src, s_corr, wArr, Rt, out);
  k_out<<<dim3(64, BB), 256, 0, stream>>>(topi, sidx, src, s_corr, Rt, out);
  k_loss<<<1, 256, 0, stream>>>(loss_row, topi, out);
}

// Round 8
// 280.525 us; speedup vs baseline: 1.9662x; 1.0032x over previous
//
#include <hip/hip_runtime.h>
#include <stdint.h>

typedef unsigned short u16;

#define BB 2
#define NN 2048
#define MM 2048
#define CC 512
#define KK 16
#define KK1 8
#define KEY 1024

typedef __attribute__((ext_vector_type(8))) short bf16x8;
typedef __attribute__((ext_vector_type(4))) float f32x4;

__device__ __forceinline__ float b2f(u16 u){ return __uint_as_float(((uint32_t)u) << 16); }
__device__ __forceinline__ u16 f2b(float f){
  uint32_t x = __float_as_uint(f);
  uint32_t r = x + 0x7FFFu + ((x >> 16) & 1u);
  return (u16)(r >> 16);
}
__device__ __forceinline__ float sane(float v){ return (fabsf(v) < 1e30f) ? v : 1e30f; }

// async global->LDS 16B per lane: LDS dest = wave-uniform base + lane*16 (HW rule)
__device__ __forceinline__ void gload_lds16(const u16* g, u16* l){
  __builtin_amdgcn_global_load_lds((const __attribute__((address_space(1))) uint32_t*)g,
                                   (__attribute__((address_space(3))) uint32_t*)l, 16, 0, 0);
}

// all-thread block reduction, 256 threads. op: 0=sum 1=min 2=max
__device__ __forceinline__ float blockRed(float v, float* red, int t, int op){
  red[t] = v; __syncthreads();
  #pragma unroll
  for (int s = 128; s > 0; s >>= 1){
    if (t < s){
      float a = red[t], b = red[t + s];
      red[t] = (op == 0) ? (a + b) : ((op == 1) ? fminf(a, b) : fmaxf(a, b));
    }
    __syncthreads();
  }
  float r = red[0]; __syncthreads();
  return r;
}

// ---- K0: transpose f32 (B,C,N) -> split-bf16 (B,N,C) hi/lo pairs -------------------
__global__ __launch_bounds__(256) void k_trans(const float* __restrict__ semb, const float* __restrict__ temb,
                                               u16* __restrict__ Ah, u16* __restrict__ Al,
                                               u16* __restrict__ Bh, u16* __restrict__ Bl){
  __shared__ float tile[32][33];
  int b = blockIdx.z & 1, which = blockIdx.z >> 1;
  const float* in = which ? temb : semb;
  u16* oh = which ? Bh : Ah;
  u16* ol = which ? Bl : Al;
  int c0 = blockIdx.x * 32, n0 = blockIdx.y * 32;
  int tx = threadIdx.x, ty = threadIdx.y;
  #pragma unroll
  for (int i = 0; i < 4; i++){
    int r = ty + 8 * i;
    tile[r][tx] = in[((b * CC + c0 + r) * NN) + n0 + tx];
  }
  __syncthreads();
  #pragma unroll
  for (int i = 0; i < 4; i++){
    int r = ty + 8 * i;
    float v = tile[tx][r];
    u16 hi = f2b(v);
    float lo = v - b2f(hi);
    size_t o = ((size_t)(b * NN + n0 + r) * CC) + c0 + tx;
    oh[o] = hi;
    ol[o] = f2b(lo);
  }
}

// ---- K1: exact f32 row squared norms (R19: exact serial c-loop — R18 lesson: no FP
// change ahead of a discrete selection; only bit-identical transforms) --------------
__global__ __launch_bounds__(256) void k_sq(const float* __restrict__ semb, const float* __restrict__ temb,
                                            float* __restrict__ xx, float* __restrict__ yy){
  int which = blockIdx.y;
  const float* in = which ? temb : semb;
  float* out = which ? yy : xx;
  int gid = blockIdx.x * 256 + threadIdx.x;   // 0..4095
  int b = gid >> 11, n = gid & 2047;
  float acc = 0.f;
  for (int c = 0; c < CC; c++){
    float v = in[((size_t)(b * CC + c)) * NN + n];
    acc += v * v;
  }
  out[gid] = acc;
}

// ---- K2: dist = xx - 2*A.B^T + yy, split-bf16 MFMA (hi*hi + hi*lo + lo*hi) ---------
// R20: staging via global_load_lds (async direct-to-LDS, 16B/lane). Layout is linear
// in ch=t+256s so wave-uniform-base+lane*16 reproduces the exact old LDS image ->
// identical ds_read/MFMA stream -> bit-identical dist. Removes the VGPR round-trip
// (16 loads + 16 LDS stores -> 16 load_lds issues); m151 measured 874 vs 646 TF for
// this exact structural swap at 128^2 tiles.
__global__ __launch_bounds__(256) void k_gemm(const u16* __restrict__ Ah, const u16* __restrict__ Al,
                                              const u16* __restrict__ Bh, const u16* __restrict__ Bl,
                                              const float* __restrict__ xx, const float* __restrict__ yy,
                                              float* __restrict__ dist){
  __shared__ __align__(16) u16 lAh[128 * 64];
  __shared__ __align__(16) u16 lAl[128 * 64];
  __shared__ __align__(16) u16 lBh[128 * 64];
  __shared__ __align__(16) u16 lBl[128 * 64];
  int bz = blockIdx.z;
  const u16* Ahb = Ah + (size_t)bz * NN * CC;
  const u16* Alb = Al + (size_t)bz * NN * CC;
  const u16* Bhb = Bh + (size_t)bz * MM * CC;
  const u16* Blb = Bl + (size_t)bz * MM * CC;
  const float* xxb = xx + bz * NN;
  const float* yyb = yy + bz * MM;
  float* distb = dist + (size_t)bz * NN * MM;
  int n0 = blockIdx.y * 128, m0 = blockIdx.x * 128;
  int t = threadIdx.x;
  f32x4 acc[4][4];
  #pragma unroll
  for (int i = 0; i < 4; i++)
    #pragma unroll
    for (int j = 0; j < 4; j++){ f32x4 z = {0.f, 0.f, 0.f, 0.f}; acc[i][j] = z; }
  int w = t >> 6, lane = t & 63, lr = lane & 15, quad = lane >> 4;
  int wn = (w >> 1) * 64, wm = (w & 1) * 64;
  for (int kt = 0; kt < 8; kt++){
    int k0 = kt * 64;
    __syncthreads();   // all waves done reading previous tile's LDS
    #pragma unroll
    for (int s = 0; s < 4; s++){
      int ch = t + 256 * s;
      int rn = ch >> 3, k8 = (ch & 7) * 8;
      size_t oa = (size_t)(n0 + rn) * CC + k0 + k8;
      size_t ob = (size_t)(m0 + rn) * CC + k0 + k8;
      int ldsoff = ((t >> 6) * 64 + 256 * s) * 8;   // wave-uniform (u16 elems)
      gload_lds16(Ahb + oa, &lAh[ldsoff]);
      gload_lds16(Alb + oa, &lAl[ldsoff]);
      gload_lds16(Bhb + ob, &lBh[ldsoff]);
      gload_lds16(Blb + ob, &lBl[ldsoff]);
    }
    __syncthreads();   // vmcnt drained -> LDS tile ready
    #pragma unroll
    for (int kk = 0; kk < 2; kk++){
      int off = kk * 32 + quad * 8;
      bf16x8 afh[4], afl[4], bfh[4], bfl[4];
      #pragma unroll
      for (int i = 0; i < 4; i++){
        int ra = (wn + i * 16 + lr) * 64 + off;
        afh[i] = *(const bf16x8*)&lAh[ra];
        afl[i] = *(const bf16x8*)&lAl[ra];
      }
      #pragma unroll
      for (int j = 0; j < 4; j++){
        int rb = (wm + j * 16 + lr) * 64 + off;
        bfh[j] = *(const bf16x8*)&lBh[rb];
        bfl[j] = *(const bf16x8*)&lBl[rb];
      }
      #pragma unroll
      for (int i = 0; i < 4; i++)
        #pragma unroll
        for (int j = 0; j < 4; j++){
          acc[i][j] = __builtin_amdgcn_mfma_f32_16x16x32_bf16(afh[i], bfh[j], acc[i][j], 0, 0, 0);
          acc[i][j] = __builtin_amdgcn_mfma_f32_16x16x32_bf16(afh[i], bfl[j], acc[i][j], 0, 0, 0);
          acc[i][j] = __builtin_amdgcn_mfma_f32_16x16x32_bf16(afl[i], bfh[j], acc[i][j], 0, 0, 0);
        }
    }
  }
  #pragma unroll
  for (int i = 0; i < 4; i++){
    int nbase = n0 + wn + i * 16 + quad * 4;
    #pragma unroll
    for (int j = 0; j < 4; j++){
      int m = m0 + wm + j * 16 + lr;
      float yv = yyb[m];
      #pragma unroll
      for (int r = 0; r < 4; r++){
        distb[((size_t)(nbase + r)) * MM + m] = xxb[nbase + r] + yv - 2.0f * acc[i][j][r];
      }
    }
  }
}

// ---- K3: per-row min, softmax denom, AND scores row (R17) --------------------------
__global__ __launch_bounds__(256) void k_rowstats(const float* __restrict__ dist,
                                                  float* __restrict__ mnA, float* __restrict__ Zr,
                                                  float* __restrict__ scores){
  __shared__ float red[256];
  int row = blockIdx.x, b = blockIdx.y, t = threadIdx.x;
  const float* dr = dist + ((size_t)b * NN + row) * MM;
  float* sr = scores + ((size_t)b * NN + row) * MM;
  float d[8];
  float mn = 3.4e38f;
  #pragma unroll
  for (int i = 0; i < 8; i++){ d[i] = sane(dr[t + 256 * i]); mn = fminf(mn, d[i]); }
  mn = blockRed(mn, red, t, 1);
  float p[8];
  float z = 0.f;
  #pragma unroll
  for (int i = 0; i < 8; i++){ p[i] = expf(mn - d[i]); z += p[i]; }
  z = blockRed(z, red, t, 0);
  float zc = fmaxf(z, 1e-30f);
  if (t == 0){ mnA[b * NN + row] = mn; Zr[b * NN + row] = zc; }
  float iz = 1.0f / zc;
  #pragma unroll
  for (int i = 0; i < 8; i++) sr[t + 256 * i] = p[i] * iz;
}

// ---- K4: fused T/S/refined/rmm/src_corr/loss per row n (grid y = batch) ------------
// int4 index loads kept (bit-identical); R19's nontemporal dist load REVERTED
// (post-mortem: dur 43.8->47.2, FETCH up — hint hurt L2 reuse of freshly-written rows).
__global__ __launch_bounds__(256) void k_fused(const float* __restrict__ dist, const float* __restrict__ scores,
                                               const int* __restrict__ sidx1,
                                               const int* __restrict__ idx2, const float* __restrict__ tgt,
                                               float* __restrict__ s_corr, float* __restrict__ lossr){
  __shared__ float Trow[MM];
  __shared__ float red[256];
  int n = blockIdx.x, b = blockIdx.y, t = threadIdx.x;
  const float* distb = dist + (size_t)b * NN * MM;
  const float* scoresb = scores + (size_t)b * NN * MM;
  const int* sidx1b = sidx1 + (size_t)b * NN * KK1;
  const int* idx2b = idx2 + (size_t)b * MM * KK1;
  const float* tgtb = tgt + (size_t)b * 3 * MM;
  float* s_corrb = s_corr + (size_t)b * 3 * NN;
  float* lossb = lossr + b * NN;
  const float* dn_p = distb + (size_t)n * MM;
  float dn[8];
  #pragma unroll
  for (int i = 0; i < 8; i++) dn[i] = sane(dn_p[t + 256 * i]);
  float tacc[8] = {0, 0, 0, 0, 0, 0, 0, 0};
  const int4* i1v = (const int4*)(sidx1b + n * KK1);
  int4 i1a = i1v[0], i1b = i1v[1];
  int rj[7] = {i1a.y & 2047, i1a.z & 2047, i1a.w & 2047,
               i1b.x & 2047, i1b.y & 2047, i1b.z & 2047, i1b.w & 2047};
  #pragma unroll
  for (int j = 0; j < 7; j++){
    const float* srp = scoresb + (size_t)rj[j] * MM;
    #pragma unroll
    for (int i = 0; i < 8; i++) tacc[i] += srp[t + 256 * i];
  }
  #pragma unroll
  for (int i = 0; i < 8; i++) Trow[t + 256 * i] = tacc[i];
  __syncthreads();
  float rloc[8];
  float lmin = 3.4e38f;
  #pragma unroll
  for (int i = 0; i < 8; i++){
    int m = t + 256 * i;
    const int4* ipv = (const int4*)(idx2b + m * KK1);
    int4 ipa = ipv[0], ipb = ipv[1];
    float S = 0.f;
    S += Trow[ipa.y & 2047];
    S += Trow[ipa.z & 2047];
    S += Trow[ipa.w & 2047];
    S += Trow[ipb.x & 2047];
    S += Trow[ipb.y & 2047];
    S += Trow[ipb.z & 2047];
    S += Trow[ipb.w & 2047];
    float rv = sane(expf(1.0f - S / 7.0f) * dn[i]);
    rloc[i] = rv;
    lmin = fminf(lmin, rv);
  }
  float rmin = blockRed(lmin, red, t, 1);
  float z = 0.f, s0 = 0.f, s1 = 0.f, s2 = 0.f;
  #pragma unroll
  for (int i = 0; i < 8; i++){
    int m = t + 256 * i;
    float p = expf(rmin - rloc[i]);
    z  += p;
    s0 += tgtb[0 * MM + m] * p;
    s1 += tgtb[1 * MM + m] * p;
    s2 += tgtb[2 * MM + m] * p;
  }
  z  = blockRed(z,  red, t, 0);
  s0 = blockRed(s0, red, t, 0);
  s1 = blockRed(s1, red, t, 0);
  s2 = blockRed(s2, red, t, 0);
  if (t == 0){
    float iZ = 1.0f / fmaxf(z, 1e-30f);
    s_corrb[0 * NN + n] = s0 * iZ;
    s_corrb[1 * NN + n] = s1 * iZ;
    s_corrb[2 * NN + n] = s2 * iZ;
    lossb[n] = -logf(fminf(iZ, 1.0f) + 1e-15f);  // pred at onehot == rowmax(rmm) == 1/Z
  }
}

// ---- K5: discriminator MLP — R14: scalar-W2 + e-range wave split (see R14 notes) ---
__global__ __launch_bounds__(256, 4) void k_disc(const float* __restrict__ s_corr, const float* __restrict__ src,
                                                 const float* __restrict__ sknn, const int* __restrict__ sidx,
                                                 const float* __restrict__ W1, const float* __restrict__ b1,
                                                 const float* __restrict__ W2, const float* __restrict__ b2,
                                                 const float* __restrict__ W3, const float* __restrict__ b3,
                                                 float* __restrict__ sArr){
  __shared__ float term[64][129];
  int t = threadIdx.x;
  int b = blockIdx.y;
  int p = t & 63;                      // point within block (lane)
  int n = blockIdx.x * 4 + (p >> 4);   // 4 n-rows per block
  int kk = p & 15;
  int eh = t >> 6;                     // wave id = e-quarter
  int nk = sidx[((b * NN + n) * KK) + kk] & 2047;
  float f[6];
  #pragma unroll
  for (int c = 0; c < 3; c++){
    f[c]     = s_corr[(b * 3 + c) * NN + n] - s_corr[(b * 3 + c) * NN + nk];
    f[3 + c] = src[(b * 3 + c) * NN + n] - sknn[((size_t)(b * NN + n) * KK + kk) * 3 + c];
  }
  // layer 1: per-d expressions verbatim (a = b1[d]; a += f[c]*W1[d*6+c] x6; relu)
  #define L1D(d) ({ float a_ = b1[(d)];              \
                    a_ += f[0] * W1[(d) * 6 + 0];    \
                    a_ += f[1] * W1[(d) * 6 + 1];    \
                    a_ += f[2] * W1[(d) * 6 + 2];    \
                    a_ += f[3] * W1[(d) * 6 + 3];    \
                    a_ += f[4] * W1[(d) * 6 + 4];    \
                    a_ += f[5] * W1[(d) * 6 + 5];    \
                    fmaxf(a_, 0.f); })
  #define HSET(i) f32x4 h##i;                  \
                  h##i.x = L1D(4 * (i) + 0);   \
                  h##i.y = L1D(4 * (i) + 1);   \
                  h##i.z = L1D(4 * (i) + 2);   \
                  h##i.w = L1D(4 * (i) + 3);
  HSET(0) HSET(1) HSET(2) HSET(3) HSET(4) HSET(5) HSET(6) HSET(7)
  HSET(8) HSET(9) HSET(10) HSET(11) HSET(12) HSET(13) HSET(14) HSET(15)
  #undef HSET
  #undef L1D
  // layer 2: this wave's 32 e-chains, e wave-uniform so W2/b2 are scalar loads
  int e0 = __builtin_amdgcn_readfirstlane(eh * 32);
  for (int j = 0; j < 32; j++){
    int e = e0 + j;
    float a = b2[e];
    const f32x4* w4 = (const f32x4*)&W2[e * 64];
    #define QSTEP(i) { f32x4 wv = w4[i]; a += wv.x * h##i.x + wv.y * h##i.y + wv.z * h##i.z + wv.w * h##i.w; }
    QSTEP(0) QSTEP(1) QSTEP(2) QSTEP(3) QSTEP(4) QSTEP(5) QSTEP(6) QSTEP(7)
    QSTEP(8) QSTEP(9) QSTEP(10) QSTEP(11) QSTEP(12) QSTEP(13) QSTEP(14) QSTEP(15)
    #undef QSTEP
    term[p][e] = fmaxf(a, 0.f);
  }
  __syncthreads();
  // layer 3: serial left-fold per point in e-order (verbatim), then 16-lane max
  if (t < 64){
    float sacc = b3[0];
    #pragma unroll 4
    for (int e = 0; e < 128; e++) sacc += W3[e] * term[t][e];
    if (!(fabsf(sacc) < 1e30f)) sacc = -1e30f;
    #pragma unroll
    for (int off = 1; off < 16; off <<= 1) sacc = fmaxf(sacc, __shfl_xor(sacc, off, 16));
    if (kk == 0) sArr[b * NN + n] = sacc;
  }
}

// ---- K6: weight = softmax(s) over n ------------------------------------------------
__global__ __launch_bounds__(256) void k_softw(const float* __restrict__ sArr, float* __restrict__ wArr){
  __shared__ float red[256];
  int b = blockIdx.x, t = threadIdx.x;
  const float* sp = sArr + b * NN;
  float sv[8];
  float mx = -3.4e38f;
  #pragma unroll
  for (int i = 0; i < 8; i++){
    float v = sp[t + 256 * i];
    if (!(fabsf(v) < 1e30f)) v = -1e30f;
    sv[i] = v; mx = fmaxf(mx, v);
  }
  mx = blockRed(mx, red, t, 2);
  float z = 0.f;
  #pragma unroll
  for (int i = 0; i < 8; i++) z += expf(sv[i] - mx);
  z = blockRed(z, red, t, 0);
  float iz = 1.0f / fmaxf(z, 1e-30f);
  #pragma unroll
  for (int i = 0; i < 8; i++) wArr[b * NN + t + 256 * i] = expf(sv[i] - mx) * iz;
}

// ---- K7: stable descending rank -> topi (R15: wave-split + f32x4, exact) -----------
__global__ __launch_bounds__(256) void k_rank(const float* __restrict__ wArr, int* __restrict__ topi){
  __shared__ float wrow[NN];
  __shared__ int pc[4][64];
  int b = blockIdx.y, t = threadIdx.x;
  for (int i = t; i < NN; i += 256) wrow[i] = wArr[b * NN + i];
  __syncthreads();
  int tn = t & 63, tj = t >> 6;
  int n = blockIdx.x * 64 + tn;
  float wn = wrow[n];
  int j0 = tj * 512;
  const f32x4* w4 = (const f32x4*)&wrow[j0];
  int cnt = 0;
  #pragma unroll 4
  for (int q = 0; q < 128; q++){
    f32x4 wv = w4[q];
    int j = j0 + q * 4;
    cnt += (wv.x > wn) || ((wv.x == wn) && (j + 0 < n));
    cnt += (wv.y > wn) || ((wv.y == wn) && (j + 1 < n));
    cnt += (wv.z > wn) || ((wv.z == wn) && (j + 2 < n));
    cnt += (wv.w > wn) || ((wv.w == wn) && (j + 3 < n));
  }
  pc[tj][tn] = cnt;
  __syncthreads();
  if (t < 64){
    int c = pc[0][t] + pc[1][t] + pc[2][t] + pc[3][t];
    if (c < KEY) topi[b * KEY + c] = blockIdx.x * 64 + t;
  }
}

// ---- K8: weighted centroids, H, 3x3 SVD (f64 Jacobi), R/t --------------------------
__device__ __forceinline__ double det3d(const double A[3][3]){
  return A[0][0] * (A[1][1] * A[2][2] - A[1][2] * A[2][1])
       - A[0][1] * (A[1][0] * A[2][2] - A[1][2] * A[2][0])
       + A[0][2] * (A[1][0] * A[2][1] - A[1][1] * A[2][0]);
}

__global__ __launch_bounds__(256) void k_rigid(const float* __restrict__ src, const float* __restrict__ s_corr,
                                               const float* __restrict__ wArr, float* __restrict__ Rt,
                                               float* __restrict__ out){
  __shared__ float red[256];
  int b = blockIdx.x, t = threadIdx.x;
  float wsum = 0, a0 = 0, a1 = 0, a2 = 0, c0 = 0, c1 = 0, c2 = 0;
  for (int n = t; n < NN; n += 256){
    float wv = wArr[b * NN + n];
    float s0 = src[(b * 3 + 0) * NN + n];
    float s1 = src[(b * 3 + 1) * NN + n];
    float s2 = src[(b * 3 + 2) * NN + n];
    float q0 = s_corr[(b * 3 + 0) * NN + n];
    float q1 = s_corr[(b * 3 + 1) * NN + n];
    float q2 = s_corr[(b * 3 + 2) * NN + n];
    wsum += wv; a0 += wv * s0; a1 += wv * s1; a2 += wv * s2;
    c0 += wv * q0; c1 += wv * q1; c2 += wv * q2;
  }
  wsum = blockRed(wsum, red, t, 0);
  a0 = blockRed(a0, red, t, 0); a1 = blockRed(a1, red, t, 0); a2 = blockRed(a2, red, t, 0);
  c0 = blockRed(c0, red, t, 0); c1 = blockRed(c1, red, t, 0); c2 = blockRed(c2, red, t, 0);
  float inv = 1.0f / fmaxf(wsum, 1e-30f);
  float cs0 = a0 * inv, cs1 = a1 * inv, cs2 = a2 * inv;
  float ct0 = c0 * inv, ct1 = c1 * inv, ct2 = c2 * inv;
  float h[9] = {0, 0, 0, 0, 0, 0, 0, 0, 0};
  for (int n = t; n < NN; n += 256){
    float wv = wArr[b * NN + n];
    float ds0 = src[(b * 3 + 0) * NN + n] - cs0;
    float ds1 = src[(b * 3 + 1) * NN + n] - cs1;
    float ds2 = src[(b * 3 + 2) * NN + n] - cs2;
    float dc0 = s_corr[(b * 3 + 0) * NN + n] - ct0;
    float dc1 = s_corr[(b * 3 + 1) * NN + n] - ct1;
    float dc2 = s_corr[(b * 3 + 2) * NN + n] - ct2;
    h[0] += wv * ds0 * dc0; h[1] += wv * ds0 * dc1; h[2] += wv * ds0 * dc2;
    h[3] += wv * ds1 * dc0; h[4] += wv * ds1 * dc1; h[5] += wv * ds1 * dc2;
    h[6] += wv * ds2 * dc0; h[7] += wv * ds2 * dc1; h[8] += wv * ds2 * dc2;
  }
  for (int i = 0; i < 9; i++) h[i] = blockRed(h[i], red, t, 0);
  if (t == 0){
    double Hm[3][3];
    for (int i = 0; i < 3; i++)
      for (int j = 0; j < 3; j++) Hm[i][j] = (double)h[i * 3 + j];
    double Km[3][3], V[3][3] = {{1, 0, 0}, {0, 1, 0}, {0, 0, 1}};
    for (int i = 0; i < 3; i++)
      for (int j = 0; j < 3; j++){
        double s = 0;
        for (int a = 0; a < 3; a++) s += Hm[a][i] * Hm[a][j];
        Km[i][j] = s;
      }
    double ksc = fabs(Km[0][0]) + fabs(Km[1][1]) + fabs(Km[2][2]) + 1e-300;
    for (int sweep = 0; sweep < 60; sweep++){
      int p = 0, q = 1; double mx = fabs(Km[0][1]);
      if (fabs(Km[0][2]) > mx){ mx = fabs(Km[0][2]); p = 0; q = 2; }
      if (fabs(Km[1][2]) > mx){ mx = fabs(Km[1][2]); p = 1; q = 2; }
      if (mx <= 1e-15 * ksc) break;
      double app = Km[p][p], aqq = Km[q][q], apq = Km[p][q];
      double tau = (aqq - app) / (2.0 * apq);
      double tt = ((tau >= 0) ? 1.0 : -1.0) / (fabs(tau) + sqrt(1.0 + tau * tau));
      double cc = 1.0 / sqrt(1.0 + tt * tt), sn = tt * cc;
      for (int k2 = 0; k2 < 3; k2++){
        double akp = Km[k2][p], akq = Km[k2][q];
        Km[k2][p] = cc * akp - sn * akq; Km[k2][q] = sn * akp + cc * akq;
      }
      for (int k2 = 0; k2 < 3; k2++){
        double apk = Km[p][k2], aqk = Km[q][k2];
        Km[p][k2] = cc * apk - sn * aqk; Km[q][k2] = sn * apk + cc * aqk;
      }
      for (int k2 = 0; k2 < 3; k2++){
        double vkp = V[k2][p], vkq = V[k2][q];
        V[k2][p] = cc * vkp - sn * vkq; V[k2][q] = sn * vkp + cc * vkq;
      }
    }
    double lam[3] = {Km[0][0], Km[1][1], Km[2][2]};
    int id0 = 0, id1 = 1, id2 = 2, tmp;
    if (lam[id0] < lam[id1]){ tmp = id0; id0 = id1; id1 = tmp; }
    if (lam[id0] < lam[id2]){ tmp = id0; id0 = id2; id2 = tmp; }
    if (lam[id1] < lam[id2]){ tmp = id1; id1 = id2; id2 = tmp; }
    int idx[3] = {id0, id1, id2};
    double Vs[3][3], U[3][3] = {{0, 0, 0}, {0, 0, 0}, {0, 0, 0}};
    for (int jj = 0; jj < 3; jj++){
      int j = idx[jj];
      for (int i2 = 0; i2 < 3; i2++) Vs[i2][jj] = V[i2][j];
      double u0 = 0, u1 = 0, u2 = 0;
      for (int i2 = 0; i2 < 3; i2++){
        u0 += Hm[0][i2] * V[i2][j];
        u1 += Hm[1][i2] * V[i2][j];
        u2 += Hm[2][i2] * V[i2][j];
      }
      double nrm = sqrt(u0 * u0 + u1 * u1 + u2 * u2);
      if (nrm > 1e-20){
        U[0][jj] = u0 / nrm; U[1][jj] = u1 / nrm; U[2][jj] = u2 / nrm;
      } else {
        double x0 = U[1][0] * U[2][1] - U[2][0] * U[1][1];
        double x1 = U[2][0] * U[0][1] - U[0][0] * U[2][1];
        double x2 = U[0][0] * U[1][1] - U[1][0] * U[0][1];
        double nn2 = sqrt(x0 * x0 + x1 * x1 + x2 * x2);
        if (nn2 < 1e-20){ x0 = 1; x1 = 0; x2 = 0; nn2 = 1; }
        U[0][jj] = x0 / nn2; U[1][jj] = x1 / nn2; U[2][jj] = x2 / nn2;
      }
    }
    double dd = det3d(U) * det3d(Vs);
    double Rm[3][3];
    for (int i2 = 0; i2 < 3; i2++)
      for (int k2 = 0; k2 < 3; k2++)
        Rm[i2][k2] = Vs[i2][0] * U[k2][0] + Vs[i2][1] * U[k2][1] + dd * Vs[i2][2] * U[k2][2];
    double cs[3] = {cs0, cs1, cs2}, ct[3] = {ct0, ct1, ct2};
    double tv[3];
    for (int i2 = 0; i2 < 3; i2++)
      tv[i2] = ct[i2] - (Rm[i2][0] * cs[0] + Rm[i2][1] * cs[1] + Rm[i2][2] * cs[2]);
    for (int i2 = 0; i2 < 3; i2++)
      for (int k2 = 0; k2 < 3; k2++){
        Rt[b * 12 + i2 * 3 + k2] = (float)Rm[i2][k2];
        out[b * 9 + i2 * 3 + k2] = (float)Rm[i2][k2];
      }
    for (int i2 = 0; i2 < 3; i2++){
      Rt[b * 12 + 9 + i2] = (float)tv[i2];
      out[18 + b * 3 + i2] = (float)tv[i2];
    }
  }
}

// ---- K10: gather keypoint outputs, with src_transformed fused inline ---------------
__global__ __launch_bounds__(256) void k_out(const int* __restrict__ topi, const int* __restrict__ sidx,
                                             const float* __restrict__ src, const float* __restrict__ s_corr,
                                             const float* __restrict__ Rt, float* __restrict__ out){
  int b = blockIdx.y, t = threadIdx.x;
  int rr = t >> 4, kk = t & 15;
  int r = blockIdx.x * 16 + rr;
  int ns = topi[b * KEY + r] & 2047;
  int nk = sidx[(b * NN + ns) * KK + kk] & 2047;
  const float* R = Rt + b * 12;
  float sns0 = src[(b * 3 + 0) * NN + ns];
  float sns1 = src[(b * 3 + 1) * NN + ns];
  float sns2 = src[(b * 3 + 2) * NN + ns];
  float snk0 = src[(b * 3 + 0) * NN + nk];
  float snk1 = src[(b * 3 + 1) * NN + nk];
  float snk2 = src[(b * 3 + 2) * NN + nk];
  float* o_sk  = out + 24;
  float* o_tk  = out + 6168;
  float* o_skk = out + 12312;
  float* o_tkk = out + 110616;
  #pragma unroll
  for (int c = 0; c < 3; c++){
    float cv  = s_corr[(b * 3 + c) * NN + ns];
    float ck  = s_corr[(b * 3 + c) * NN + nk];
    o_tkk[(((b * 3 + c) * KEY + r) * KK) + kk] = cv - ck;
    float sv  = R[c * 3 + 0] * sns0 + R[c * 3 + 1] * sns1 + R[c * 3 + 2] * sns2 + R[9 + c];
    float sk2 = R[c * 3 + 0] * snk0 + R[c * 3 + 1] * snk1 + R[c * 3 + 2] * snk2 + R[9 + c];
    o_skk[(((b * 3 + c) * KEY + r) * KK) + kk] = sv - sk2;
    if (kk == 0){
      o_sk[(b * 3 + c) * KEY + r] = sns0 * (c == 0) + sns1 * (c == 1) + sns2 * (c == 2);
      o_tk[(b * 3 + c) * KEY + r] = cv;
    }
  }
}

// ---- K11: loss_scl -----------------------------------------------------------------
__global__ __launch_bounds__(256) void k_loss(const float* __restrict__ loss_row, const int* __restrict__ topi,
                                              float* __restrict__ out){
  __shared__ float red[256];
  int t = threadIdx.x;
  float acc = 0.f;
  for (int i = t; i < BB * KEY; i += 256){
    int b = i >> 10, r = i & 1023;
    int n = topi[b * KEY + r] & 2047;
    acc += loss_row[b * NN + n];
  }
  acc = blockRed(acc, red, t, 0);
  if (t == 0) out[208920] = acc / 2048.0f;
}

extern "C" void kernel_launch(void* const* d_in, const int* in_sizes, int n_in,
                              void* d_out, int out_size, void* d_ws, size_t ws_size,
                              hipStream_t stream){
  const float* src  = (const float*)d_in[0];
  const float* tgt  = (const float*)d_in[1];
  const float* semb = (const float*)d_in[2];
  const float* temb = (const float*)d_in[3];
  const float* sknn = (const float*)d_in[4];
  const float* W1 = (const float*)d_in[6];
  const float* b1 = (const float*)d_in[7];
  const float* W2 = (const float*)d_in[8];
  const float* b2 = (const float*)d_in[9];
  const float* W3 = (const float*)d_in[10];
  const float* b3 = (const float*)d_in[11];
  const int* sidx  = (const int*)d_in[12];
  const int* sidx1 = (const int*)d_in[13];
  const int* idx2  = (const int*)d_in[14];
  float* out = (float*)d_out;

  // workspace layout (peak ~84 MB; harness allocates 256 MiB per fill evidence)
  char* w = (char*)d_ws;
  u16* Ah = (u16*)(w);                               // 4 MB each (B,N,C) bf16 split
  u16* Al = Ah + (size_t)BB * NN * CC;
  u16* Bh = Al + (size_t)BB * NN * CC;
  u16* Bl = Bh + (size_t)BB * MM * CC;
  float* dist = (float*)(Bl + (size_t)BB * MM * CC); // 33.55 MB (B,N,M) f32
  float* scores = dist + (size_t)BB * NN * MM;       // 33.55 MB (B,N,M) f32
  char* tail = (char*)(scores + (size_t)BB * NN * MM);
  float* xx = (float*)tail;                          // B*N
  float* yy = xx + BB * NN;                          // B*M
  float* mnA = yy + BB * MM;                         // B*N
  float* Zr = mnA + BB * NN;                         // B*N
  float* s_corr = Zr + BB * NN;                      // B*3*N
  float* loss_row = s_corr + BB * 3 * NN;            // B*N
  float* sArr = loss_row + BB * NN;                  // B*N
  float* wArr = sArr + BB * NN;                      // B*N
  int* topi = (int*)(wArr + BB * NN);                // B*KEY
  float* Rt = (float*)(topi + BB * KEY);             // B*12

  k_trans<<<dim3(16, 64, 4), dim3(32, 8), 0, stream>>>(semb, temb, Ah, Al, Bh, Bl);
  k_sq<<<dim3(16, 2), 256, 0, stream>>>(semb, temb, xx, yy);
  k_gemm<<<dim3(16, 16, BB), 256, 0, stream>>>(Ah, Al, Bh, Bl, xx, yy, dist);
  k_rowstats<<<dim3(NN, BB), 256, 0, stream>>>(dist, mnA, Zr, scores);
  k_fused<<<dim3(NN, BB), 256, 0, stream>>>(dist, scores, sidx1, idx2, tgt, s_corr, loss_row);
  k_disc<<<dim3(NN / 4, BB), 256, 0, stream>>>(s_corr, src, sknn, sidx, W1, b1, W2, b2, W3, b3, sArr);
  k_softw<<<BB, 256, 0, stream>>>(sArr, wArr);
  k_rank<<<dim3(32, BB), 256, 0, stream>>>(wArr, topi);
  k_rigid<<<BB, 256, 0, stream>>>(src, s_corr, wArr, Rt, out);
  k_out<<<dim3(64, BB), 256, 0, stream>>>(topi, sidx, src, s_corr, Rt, out);
  k_loss<<<1, 256, 0, stream>>>(loss_row, topi, out);
}

// Round 9
// 272.812 us; speedup vs baseline: 2.0218x; 1.0283x over previous
//
#include <hip/hip_runtime.h>
#include <stdint.h>

typedef unsigned short u16;

#define BB 2
#define NN 2048
#define MM 2048
#define CC 512
#define KK 16
#define KK1 8
#define KEY 1024

typedef __attribute__((ext_vector_type(8))) short bf16x8;
typedef __attribute__((ext_vector_type(4))) float f32x4;

__device__ __forceinline__ float b2f(u16 u){ return __uint_as_float(((uint32_t)u) << 16); }
__device__ __forceinline__ u16 f2b(float f){
  uint32_t x = __float_as_uint(f);
  uint32_t r = x + 0x7FFFu + ((x >> 16) & 1u);
  return (u16)(r >> 16);
}
__device__ __forceinline__ float sane(float v){ return (fabsf(v) < 1e30f) ? v : 1e30f; }

// async global->LDS 16B per lane: LDS dest = wave-uniform base + lane*16 (HW rule)
__device__ __forceinline__ void gload_lds16(const u16* g, u16* l){
  __builtin_amdgcn_global_load_lds((const __attribute__((address_space(1))) uint32_t*)g,
                                   (__attribute__((address_space(3))) uint32_t*)l, 16, 0, 0);
}

// all-thread block reduction, 256 threads. op: 0=sum 1=min 2=max
__device__ __forceinline__ float blockRed(float v, float* red, int t, int op){
  red[t] = v; __syncthreads();
  #pragma unroll
  for (int s = 128; s > 0; s >>= 1){
    if (t < s){
      float a = red[t], b = red[t + s];
      red[t] = (op == 0) ? (a + b) : ((op == 1) ? fminf(a, b) : fmaxf(a, b));
    }
    __syncthreads();
  }
  float r = red[0]; __syncthreads();
  return r;
}

// exact block min (min is associative+commutative; inputs sane()-filtered so no NaN;
// ±0 ties only feed expf(x-y) where both zero signs give identical bits). 1 barrier.
__device__ __forceinline__ float blockMinExact(float v, float* wmin, int t){
  #pragma unroll
  for (int off = 1; off < 64; off <<= 1) v = fminf(v, __shfl_xor(v, off));
  if ((t & 63) == 0) wmin[t >> 6] = v;
  __syncthreads();
  return fminf(fminf(wmin[0], wmin[1]), fminf(wmin[2], wmin[3]));
}

// ---- K0: transpose f32 (B,C,N) -> split-bf16 (B,N,C) hi/lo pairs -------------------
__global__ __launch_bounds__(256) void k_trans(const float* __restrict__ semb, const float* __restrict__ temb,
                                               u16* __restrict__ Ah, u16* __restrict__ Al,
                                               u16* __restrict__ Bh, u16* __restrict__ Bl){
  __shared__ float tile[32][33];
  int b = blockIdx.z & 1, which = blockIdx.z >> 1;
  const float* in = which ? temb : semb;
  u16* oh = which ? Bh : Ah;
  u16* ol = which ? Bl : Al;
  int c0 = blockIdx.x * 32, n0 = blockIdx.y * 32;
  int tx = threadIdx.x, ty = threadIdx.y;
  #pragma unroll
  for (int i = 0; i < 4; i++){
    int r = ty + 8 * i;
    tile[r][tx] = in[((b * CC + c0 + r) * NN) + n0 + tx];
  }
  __syncthreads();
  #pragma unroll
  for (int i = 0; i < 4; i++){
    int r = ty + 8 * i;
    float v = tile[tx][r];
    u16 hi = f2b(v);
    float lo = v - b2f(hi);
    size_t o = ((size_t)(b * NN + n0 + r) * CC) + c0 + tx;
    oh[o] = hi;
    ol[o] = f2b(lo);
  }
}

// ---- K1: exact f32 row squared norms (R18 lesson: no FP change ahead of a discrete
// selection; only bit-identical transforms admissible) -------------------------------
__global__ __launch_bounds__(256) void k_sq(const float* __restrict__ semb, const float* __restrict__ temb,
                                            float* __restrict__ xx, float* __restrict__ yy){
  int which = blockIdx.y;
  const float* in = which ? temb : semb;
  float* out = which ? yy : xx;
  int gid = blockIdx.x * 256 + threadIdx.x;   // 0..4095
  int b = gid >> 11, n = gid & 2047;
  float acc = 0.f;
  for (int c = 0; c < CC; c++){
    float v = in[((size_t)(b * CC + c)) * NN + n];
    acc += v * v;
  }
  out[gid] = acc;
}

// ---- K2: dist = xx - 2*A.B^T + yy, split-bf16 MFMA; gload_lds staging (R20) --------
__global__ __launch_bounds__(256) void k_gemm(const u16* __restrict__ Ah, const u16* __restrict__ Al,
                                              const u16* __restrict__ Bh, const u16* __restrict__ Bl,
                                              const float* __restrict__ xx, const float* __restrict__ yy,
                                              float* __restrict__ dist){
  __shared__ __align__(16) u16 lAh[128 * 64];
  __shared__ __align__(16) u16 lAl[128 * 64];
  __shared__ __align__(16) u16 lBh[128 * 64];
  __shared__ __align__(16) u16 lBl[128 * 64];
  int bz = blockIdx.z;
  const u16* Ahb = Ah + (size_t)bz * NN * CC;
  const u16* Alb = Al + (size_t)bz * NN * CC;
  const u16* Bhb = Bh + (size_t)bz * MM * CC;
  const u16* Blb = Bl + (size_t)bz * MM * CC;
  const float* xxb = xx + bz * NN;
  const float* yyb = yy + bz * MM;
  float* distb = dist + (size_t)bz * NN * MM;
  int n0 = blockIdx.y * 128, m0 = blockIdx.x * 128;
  int t = threadIdx.x;
  f32x4 acc[4][4];
  #pragma unroll
  for (int i = 0; i < 4; i++)
    #pragma unroll
    for (int j = 0; j < 4; j++){ f32x4 z = {0.f, 0.f, 0.f, 0.f}; acc[i][j] = z; }
  int w = t >> 6, lane = t & 63, lr = lane & 15, quad = lane >> 4;
  int wn = (w >> 1) * 64, wm = (w & 1) * 64;
  for (int kt = 0; kt < 8; kt++){
    int k0 = kt * 64;
    __syncthreads();
    #pragma unroll
    for (int s = 0; s < 4; s++){
      int ch = t + 256 * s;
      int rn = ch >> 3, k8 = (ch & 7) * 8;
      size_t oa = (size_t)(n0 + rn) * CC + k0 + k8;
      size_t ob = (size_t)(m0 + rn) * CC + k0 + k8;
      int ldsoff = ((t >> 6) * 64 + 256 * s) * 8;   // wave-uniform (u16 elems)
      gload_lds16(Ahb + oa, &lAh[ldsoff]);
      gload_lds16(Alb + oa, &lAl[ldsoff]);
      gload_lds16(Bhb + ob, &lBh[ldsoff]);
      gload_lds16(Blb + ob, &lBl[ldsoff]);
    }
    __syncthreads();
    #pragma unroll
    for (int kk = 0; kk < 2; kk++){
      int off = kk * 32 + quad * 8;
      bf16x8 afh[4], afl[4], bfh[4], bfl[4];
      #pragma unroll
      for (int i = 0; i < 4; i++){
        int ra = (wn + i * 16 + lr) * 64 + off;
        afh[i] = *(const bf16x8*)&lAh[ra];
        afl[i] = *(const bf16x8*)&lAl[ra];
      }
      #pragma unroll
      for (int j = 0; j < 4; j++){
        int rb = (wm + j * 16 + lr) * 64 + off;
        bfh[j] = *(const bf16x8*)&lBh[rb];
        bfl[j] = *(const bf16x8*)&lBl[rb];
      }
      #pragma unroll
      for (int i = 0; i < 4; i++)
        #pragma unroll
        for (int j = 0; j < 4; j++){
          acc[i][j] = __builtin_amdgcn_mfma_f32_16x16x32_bf16(afh[i], bfh[j], acc[i][j], 0, 0, 0);
          acc[i][j] = __builtin_amdgcn_mfma_f32_16x16x32_bf16(afh[i], bfl[j], acc[i][j], 0, 0, 0);
          acc[i][j] = __builtin_amdgcn_mfma_f32_16x16x32_bf16(afl[i], bfh[j], acc[i][j], 0, 0, 0);
        }
    }
  }
  #pragma unroll
  for (int i = 0; i < 4; i++){
    int nbase = n0 + wn + i * 16 + quad * 4;
    #pragma unroll
    for (int j = 0; j < 4; j++){
      int m = m0 + wm + j * 16 + lr;
      float yv = yyb[m];
      #pragma unroll
      for (int r = 0; r < 4; r++){
        distb[((size_t)(nbase + r)) * MM + m] = xxb[nbase + r] + yv - 2.0f * acc[i][j][r];
      }
    }
  }
}

// ---- K3: per-row min, softmax denom, scores row. R21: mn via exact wave-min --------
__global__ __launch_bounds__(256) void k_rowstats(const float* __restrict__ dist,
                                                  float* __restrict__ mnA, float* __restrict__ Zr,
                                                  float* __restrict__ scores){
  __shared__ float red[256];
  __shared__ float wmin[4];
  int row = blockIdx.x, b = blockIdx.y, t = threadIdx.x;
  const float* dr = dist + ((size_t)b * NN + row) * MM;
  float* sr = scores + ((size_t)b * NN + row) * MM;
  float d[8];
  float mn = 3.4e38f;
  #pragma unroll
  for (int i = 0; i < 8; i++){ d[i] = sane(dr[t + 256 * i]); mn = fminf(mn, d[i]); }
  mn = blockMinExact(mn, wmin, t);
  float p[8];
  float z = 0.f;
  #pragma unroll
  for (int i = 0; i < 8; i++){ p[i] = expf(mn - d[i]); z += p[i]; }
  z = blockRed(z, red, t, 0);
  float zc = fmaxf(z, 1e-30f);
  if (t == 0){ mnA[b * NN + row] = mn; Zr[b * NN + row] = zc; }
  float iz = 1.0f / zc;
  #pragma unroll
  for (int i = 0; i < 8; i++) sr[t + 256 * i] = p[i] * iz;
}

// ---- K4: fused T/S/refined/rmm/src_corr/loss (R21: min via wave-shuffle; 4 sums in
// ONE float4 tree with identical per-component order; red4 overlays dead Trow) -------
__global__ __launch_bounds__(256) void k_fused(const float* __restrict__ dist, const float* __restrict__ scores,
                                               const int* __restrict__ sidx1,
                                               const int* __restrict__ idx2, const float* __restrict__ tgt,
                                               float* __restrict__ s_corr, float* __restrict__ lossr){
  __shared__ float Trow[MM];
  __shared__ float wmin[4];
  int n = blockIdx.x, b = blockIdx.y, t = threadIdx.x;
  const float* distb = dist + (size_t)b * NN * MM;
  const float* scoresb = scores + (size_t)b * NN * MM;
  const int* sidx1b = sidx1 + (size_t)b * NN * KK1;
  const int* idx2b = idx2 + (size_t)b * MM * KK1;
  const float* tgtb = tgt + (size_t)b * 3 * MM;
  float* s_corrb = s_corr + (size_t)b * 3 * NN;
  float* lossb = lossr + b * NN;
  const float* dn_p = distb + (size_t)n * MM;
  float dn[8];
  #pragma unroll
  for (int i = 0; i < 8; i++) dn[i] = sane(dn_p[t + 256 * i]);
  float tacc[8] = {0, 0, 0, 0, 0, 0, 0, 0};
  const int4* i1v = (const int4*)(sidx1b + n * KK1);
  int4 i1a = i1v[0], i1b = i1v[1];
  int rj[7] = {i1a.y & 2047, i1a.z & 2047, i1a.w & 2047,
               i1b.x & 2047, i1b.y & 2047, i1b.z & 2047, i1b.w & 2047};
  #pragma unroll
  for (int j = 0; j < 7; j++){
    const float* srp = scoresb + (size_t)rj[j] * MM;
    #pragma unroll
    for (int i = 0; i < 8; i++) tacc[i] += srp[t + 256 * i];
  }
  #pragma unroll
  for (int i = 0; i < 8; i++) Trow[t + 256 * i] = tacc[i];
  __syncthreads();
  float rloc[8];
  float lmin = 3.4e38f;
  #pragma unroll
  for (int i = 0; i < 8; i++){
    int m = t + 256 * i;
    const int4* ipv = (const int4*)(idx2b + m * KK1);
    int4 ipa = ipv[0], ipb = ipv[1];
    float S = 0.f;
    S += Trow[ipa.y & 2047];
    S += Trow[ipa.z & 2047];
    S += Trow[ipa.w & 2047];
    S += Trow[ipb.x & 2047];
    S += Trow[ipb.y & 2047];
    S += Trow[ipb.z & 2047];
    S += Trow[ipb.w & 2047];
    float rv = sane(expf(1.0f - S / 7.0f) * dn[i]);
    rloc[i] = rv;
    lmin = fminf(lmin, rv);
  }
  // exact min; its barrier also guarantees all Trow reads finished before reuse
  float rmin = blockMinExact(lmin, wmin, t);
  float z = 0.f, s0 = 0.f, s1 = 0.f, s2 = 0.f;
  #pragma unroll
  for (int i = 0; i < 8; i++){
    int m = t + 256 * i;
    float p = expf(rmin - rloc[i]);
    z  += p;
    s0 += tgtb[0 * MM + m] * p;
    s1 += tgtb[1 * MM + m] * p;
    s2 += tgtb[2 * MM + m] * p;
  }
  f32x4* red4 = (f32x4*)Trow;   // Trow dead from here; same tree order per component
  f32x4 v4; v4.x = z; v4.y = s0; v4.z = s1; v4.w = s2;
  red4[t] = v4; __syncthreads();
  #pragma unroll
  for (int s = 128; s > 0; s >>= 1){
    if (t < s){
      f32x4 a = red4[t], c = red4[t + s];
      a.x += c.x; a.y += c.y; a.z += c.z; a.w += c.w;
      red4[t] = a;
    }
    __syncthreads();
  }
  if (t == 0){
    f32x4 r = red4[0];
    float iZ = 1.0f / fmaxf(r.x, 1e-30f);
    s_corrb[0 * NN + n] = r.y * iZ;
    s_corrb[1 * NN + n] = r.z * iZ;
    s_corrb[2 * NN + n] = r.w * iZ;
    lossb[n] = -logf(fminf(iZ, 1.0f) + 1e-15f);  // pred at onehot == rowmax(rmm) == 1/Z
  }
}

// ---- K5: discriminator MLP — R14: scalar-W2 + e-range wave split -------------------
__global__ __launch_bounds__(256, 4) void k_disc(const float* __restrict__ s_corr, const float* __restrict__ src,
                                                 const float* __restrict__ sknn, const int* __restrict__ sidx,
                                                 const float* __restrict__ W1, const float* __restrict__ b1,
                                                 const float* __restrict__ W2, const float* __restrict__ b2,
                                                 const float* __restrict__ W3, const float* __restrict__ b3,
                                                 float* __restrict__ sArr){
  __shared__ float term[64][129];
  int t = threadIdx.x;
  int b = blockIdx.y;
  int p = t & 63;
  int n = blockIdx.x * 4 + (p >> 4);
  int kk = p & 15;
  int eh = t >> 6;
  int nk = sidx[((b * NN + n) * KK) + kk] & 2047;
  float f[6];
  #pragma unroll
  for (int c = 0; c < 3; c++){
    f[c]     = s_corr[(b * 3 + c) * NN + n] - s_corr[(b * 3 + c) * NN + nk];
    f[3 + c] = src[(b * 3 + c) * NN + n] - sknn[((size_t)(b * NN + n) * KK + kk) * 3 + c];
  }
  #define L1D(d) ({ float a_ = b1[(d)];              \
                    a_ += f[0] * W1[(d) * 6 + 0];    \
                    a_ += f[1] * W1[(d) * 6 + 1];    \
                    a_ += f[2] * W1[(d) * 6 + 2];    \
                    a_ += f[3] * W1[(d) * 6 + 3];    \
                    a_ += f[4] * W1[(d) * 6 + 4];    \
                    a_ += f[5] * W1[(d) * 6 + 5];    \
                    fmaxf(a_, 0.f); })
  #define HSET(i) f32x4 h##i;                  \
                  h##i.x = L1D(4 * (i) + 0);   \
                  h##i.y = L1D(4 * (i) + 1);   \
                  h##i.z = L1D(4 * (i) + 2);   \
                  h##i.w = L1D(4 * (i) + 3);
  HSET(0) HSET(1) HSET(2) HSET(3) HSET(4) HSET(5) HSET(6) HSET(7)
  HSET(8) HSET(9) HSET(10) HSET(11) HSET(12) HSET(13) HSET(14) HSET(15)
  #undef HSET
  #undef L1D
  int e0 = __builtin_amdgcn_readfirstlane(eh * 32);
  for (int j = 0; j < 32; j++){
    int e = e0 + j;
    float a = b2[e];
    const f32x4* w4 = (const f32x4*)&W2[e * 64];
    #define QSTEP(i) { f32x4 wv = w4[i]; a += wv.x * h##i.x + wv.y * h##i.y + wv.z * h##i.z + wv.w * h##i.w; }
    QSTEP(0) QSTEP(1) QSTEP(2) QSTEP(3) QSTEP(4) QSTEP(5) QSTEP(6) QSTEP(7)
    QSTEP(8) QSTEP(9) QSTEP(10) QSTEP(11) QSTEP(12) QSTEP(13) QSTEP(14) QSTEP(15)
    #undef QSTEP
    term[p][e] = fmaxf(a, 0.f);
  }
  __syncthreads();
  if (t < 64){
    float sacc = b3[0];
    #pragma unroll 4
    for (int e = 0; e < 128; e++) sacc += W3[e] * term[t][e];
    if (!(fabsf(sacc) < 1e30f)) sacc = -1e30f;
    #pragma unroll
    for (int off = 1; off < 16; off <<= 1) sacc = fmaxf(sacc, __shfl_xor(sacc, off, 16));
    if (kk == 0) sArr[b * NN + n] = sacc;
  }
}

// ---- K6+K7+K8 merged (R21): every block recomputes softmax(sArr) with the VERBATIM
// k_softw code (same inputs + same trees -> bit-identical wrow in all blocks, same
// bits as the old global wArr round-trip); rank body verbatim; block x==0 runs the
// verbatim k_rigid body on wrow. Saves 2 launches + the wArr global round-trip. -----
__device__ __forceinline__ double det3d(const double A[3][3]){
  return A[0][0] * (A[1][1] * A[2][2] - A[1][2] * A[2][1])
       - A[0][1] * (A[1][0] * A[2][2] - A[1][2] * A[2][0])
       + A[0][2] * (A[1][0] * A[2][1] - A[1][1] * A[2][0]);
}

__global__ __launch_bounds__(256) void k_rankrig(const float* __restrict__ sArr, const float* __restrict__ src,
                                                 const float* __restrict__ s_corr, int* __restrict__ topi,
                                                 float* __restrict__ Rt, float* __restrict__ out){
  __shared__ float wrow[NN];
  __shared__ float red[256];
  __shared__ int pc[4][64];
  int b = blockIdx.y, t = threadIdx.x;
  // ---- softmax (verbatim k_softw) -> wrow ----
  const float* sp = sArr + b * NN;
  float sv[8];
  float mx = -3.4e38f;
  #pragma unroll
  for (int i = 0; i < 8; i++){
    float v = sp[t + 256 * i];
    if (!(fabsf(v) < 1e30f)) v = -1e30f;
    sv[i] = v; mx = fmaxf(mx, v);
  }
  mx = blockRed(mx, red, t, 2);
  float z = 0.f;
  #pragma unroll
  for (int i = 0; i < 8; i++) z += expf(sv[i] - mx);
  z = blockRed(z, red, t, 0);
  float iz = 1.0f / fmaxf(z, 1e-30f);
  #pragma unroll
  for (int i = 0; i < 8; i++) wrow[t + 256 * i] = expf(sv[i] - mx) * iz;
  __syncthreads();
  // ---- rank (verbatim R15 body) ----
  int tn = t & 63, tj = t >> 6;
  int n = blockIdx.x * 64 + tn;
  float wn = wrow[n];
  int j0 = tj * 512;
  const f32x4* w4 = (const f32x4*)&wrow[j0];
  int cnt = 0;
  #pragma unroll 4
  for (int q = 0; q < 128; q++){
    f32x4 wv = w4[q];
    int j = j0 + q * 4;
    cnt += (wv.x > wn) || ((wv.x == wn) && (j + 0 < n));
    cnt += (wv.y > wn) || ((wv.y == wn) && (j + 1 < n));
    cnt += (wv.z > wn) || ((wv.z == wn) && (j + 2 < n));
    cnt += (wv.w > wn) || ((wv.w == wn) && (j + 3 < n));
  }
  pc[tj][tn] = cnt;
  __syncthreads();
  if (t < 64){
    int c = pc[0][t] + pc[1][t] + pc[2][t] + pc[3][t];
    if (c < KEY) topi[b * KEY + c] = blockIdx.x * 64 + t;
  }
  if (blockIdx.x != 0) return;
  // ---- rigid (verbatim k_rigid body; wrow[n] in place of wArr[b*NN+n]) ----
  float wsum = 0, a0 = 0, a1 = 0, a2 = 0, c0 = 0, c1 = 0, c2 = 0;
  for (int n2 = t; n2 < NN; n2 += 256){
    float wv = wrow[n2];
    float s0 = src[(b * 3 + 0) * NN + n2];
    float s1 = src[(b * 3 + 1) * NN + n2];
    float s2 = src[(b * 3 + 2) * NN + n2];
    float q0 = s_corr[(b * 3 + 0) * NN + n2];
    float q1 = s_corr[(b * 3 + 1) * NN + n2];
    float q2 = s_corr[(b * 3 + 2) * NN + n2];
    wsum += wv; a0 += wv * s0; a1 += wv * s1; a2 += wv * s2;
    c0 += wv * q0; c1 += wv * q1; c2 += wv * q2;
  }
  wsum = blockRed(wsum, red, t, 0);
  a0 = blockRed(a0, red, t, 0); a1 = blockRed(a1, red, t, 0); a2 = blockRed(a2, red, t, 0);
  c0 = blockRed(c0, red, t, 0); c1 = blockRed(c1, red, t, 0); c2 = blockRed(c2, red, t, 0);
  float inv = 1.0f / fmaxf(wsum, 1e-30f);
  float cs0 = a0 * inv, cs1 = a1 * inv, cs2 = a2 * inv;
  float ct0 = c0 * inv, ct1 = c1 * inv, ct2 = c2 * inv;
  float h[9] = {0, 0, 0, 0, 0, 0, 0, 0, 0};
  for (int n2 = t; n2 < NN; n2 += 256){
    float wv = wrow[n2];
    float ds0 = src[(b * 3 + 0) * NN + n2] - cs0;
    float ds1 = src[(b * 3 + 1) * NN + n2] - cs1;
    float ds2 = src[(b * 3 + 2) * NN + n2] - cs2;
    float dc0 = s_corr[(b * 3 + 0) * NN + n2] - ct0;
    float dc1 = s_corr[(b * 3 + 1) * NN + n2] - ct1;
    float dc2 = s_corr[(b * 3 + 2) * NN + n2] - ct2;
    h[0] += wv * ds0 * dc0; h[1] += wv * ds0 * dc1; h[2] += wv * ds0 * dc2;
    h[3] += wv * ds1 * dc0; h[4] += wv * ds1 * dc1; h[5] += wv * ds1 * dc2;
    h[6] += wv * ds2 * dc0; h[7] += wv * ds2 * dc1; h[8] += wv * ds2 * dc2;
  }
  for (int i = 0; i < 9; i++) h[i] = blockRed(h[i], red, t, 0);
  if (t == 0){
    double Hm[3][3];
    for (int i = 0; i < 3; i++)
      for (int j = 0; j < 3; j++) Hm[i][j] = (double)h[i * 3 + j];
    double Km[3][3], V[3][3] = {{1, 0, 0}, {0, 1, 0}, {0, 0, 1}};
    for (int i = 0; i < 3; i++)
      for (int j = 0; j < 3; j++){
        double s = 0;
        for (int a = 0; a < 3; a++) s += Hm[a][i] * Hm[a][j];
        Km[i][j] = s;
      }
    double ksc = fabs(Km[0][0]) + fabs(Km[1][1]) + fabs(Km[2][2]) + 1e-300;
    for (int sweep = 0; sweep < 60; sweep++){
      int p = 0, q = 1; double mx2 = fabs(Km[0][1]);
      if (fabs(Km[0][2]) > mx2){ mx2 = fabs(Km[0][2]); p = 0; q = 2; }
      if (fabs(Km[1][2]) > mx2){ mx2 = fabs(Km[1][2]); p = 1; q = 2; }
      if (mx2 <= 1e-15 * ksc) break;
      double app = Km[p][p], aqq = Km[q][q], apq = Km[p][q];
      double tau = (aqq - app) / (2.0 * apq);
      double tt = ((tau >= 0) ? 1.0 : -1.0) / (fabs(tau) + sqrt(1.0 + tau * tau));
      double cc = 1.0 / sqrt(1.0 + tt * tt), sn = tt * cc;
      for (int k2 = 0; k2 < 3; k2++){
        double akp = Km[k2][p], akq = Km[k2][q];
        Km[k2][p] = cc * akp - sn * akq; Km[k2][q] = sn * akp + cc * akq;
      }
      for (int k2 = 0; k2 < 3; k2++){
        double apk = Km[p][k2], aqk = Km[q][k2];
        Km[p][k2] = cc * apk - sn * aqk; Km[q][k2] = sn * apk + cc * aqk;
      }
      for (int k2 = 0; k2 < 3; k2++){
        double vkp = V[k2][p], vkq = V[k2][q];
        V[k2][p] = cc * vkp - sn * vkq; V[k2][q] = sn * vkp + cc * vkq;
      }
    }
    double lam[3] = {Km[0][0], Km[1][1], Km[2][2]};
    int id0 = 0, id1 = 1, id2 = 2, tmp;
    if (lam[id0] < lam[id1]){ tmp = id0; id0 = id1; id1 = tmp; }
    if (lam[id0] < lam[id2]){ tmp = id0; id0 = id2; id2 = tmp; }
    if (lam[id1] < lam[id2]){ tmp = id1; id1 = id2; id2 = tmp; }
    int idx[3] = {id0, id1, id2};
    double Vs[3][3], U[3][3] = {{0, 0, 0}, {0, 0, 0}, {0, 0, 0}};
    for (int jj = 0; jj < 3; jj++){
      int j = idx[jj];
      for (int i2 = 0; i2 < 3; i2++) Vs[i2][jj] = V[i2][j];
      double u0 = 0, u1 = 0, u2 = 0;
      for (int i2 = 0; i2 < 3; i2++){
        u0 += Hm[0][i2] * V[i2][j];
        u1 += Hm[1][i2] * V[i2][j];
        u2 += Hm[2][i2] * V[i2][j];
      }
      double nrm = sqrt(u0 * u0 + u1 * u1 + u2 * u2);
      if (nrm > 1e-20){
        U[0][jj] = u0 / nrm; U[1][jj] = u1 / nrm; U[2][jj] = u2 / nrm;
      } else {
        double x0 = U[1][0] * U[2][1] - U[2][0] * U[1][1];
        double x1 = U[2][0] * U[0][1] - U[0][0] * U[2][1];
        double x2 = U[0][0] * U[1][1] - U[1][0] * U[0][1];
        double nn2 = sqrt(x0 * x0 + x1 * x1 + x2 * x2);
        if (nn2 < 1e-20){ x0 = 1; x1 = 0; x2 = 0; nn2 = 1; }
        U[0][jj] = x0 / nn2; U[1][jj] = x1 / nn2; U[2][jj] = x2 / nn2;
      }
    }
    double dd = det3d(U) * det3d(Vs);
    double Rm[3][3];
    for (int i2 = 0; i2 < 3; i2++)
      for (int k2 = 0; k2 < 3; k2++)
        Rm[i2][k2] = Vs[i2][0] * U[k2][0] + Vs[i2][1] * U[k2][1] + dd * Vs[i2][2] * U[k2][2];
    double cs[3] = {cs0, cs1, cs2}, ct[3] = {ct0, ct1, ct2};
    double tv[3];
    for (int i2 = 0; i2 < 3; i2++)
      tv[i2] = ct[i2] - (Rm[i2][0] * cs[0] + Rm[i2][1] * cs[1] + Rm[i2][2] * cs[2]);
    for (int i2 = 0; i2 < 3; i2++)
      for (int k2 = 0; k2 < 3; k2++){
        Rt[b * 12 + i2 * 3 + k2] = (float)Rm[i2][k2];
        out[b * 9 + i2 * 3 + k2] = (float)Rm[i2][k2];
      }
    for (int i2 = 0; i2 < 3; i2++){
      Rt[b * 12 + 9 + i2] = (float)tv[i2];
      out[18 + b * 3 + i2] = (float)tv[i2];
    }
  }
}

// ---- K10 (+K11 merged): keypoint gathers; block x==64,b==0 computes loss_scl -------
__global__ __launch_bounds__(256) void k_out(const int* __restrict__ topi, const int* __restrict__ sidx,
                                             const float* __restrict__ src, const float* __restrict__ s_corr,
                                             const float* __restrict__ Rt, const float* __restrict__ loss_row,
                                             float* __restrict__ out){
  __shared__ float red[256];
  int b = blockIdx.y, t = threadIdx.x;
  if (blockIdx.x == 64){
    if (b != 0) return;
    float acc = 0.f;
    for (int i = t; i < BB * KEY; i += 256){
      int bb = i >> 10, r = i & 1023;
      int n = topi[bb * KEY + r] & 2047;
      acc += loss_row[bb * NN + n];
    }
    acc = blockRed(acc, red, t, 0);
    if (t == 0) out[208920] = acc / 2048.0f;
    return;
  }
  int rr = t >> 4, kk = t & 15;
  int r = blockIdx.x * 16 + rr;
  int ns = topi[b * KEY + r] & 2047;
  int nk = sidx[(b * NN + ns) * KK + kk] & 2047;
  const float* R = Rt + b * 12;
  float sns0 = src[(b * 3 + 0) * NN + ns];
  float sns1 = src[(b * 3 + 1) * NN + ns];
  float sns2 = src[(b * 3 + 2) * NN + ns];
  float snk0 = src[(b * 3 + 0) * NN + nk];
  float snk1 = src[(b * 3 + 1) * NN + nk];
  float snk2 = src[(b * 3 + 2) * NN + nk];
  float* o_sk  = out + 24;
  float* o_tk  = out + 6168;
  float* o_skk = out + 12312;
  float* o_tkk = out + 110616;
  #pragma unroll
  for (int c = 0; c < 3; c++){
    float cv  = s_corr[(b * 3 + c) * NN + ns];
    float ck  = s_corr[(b * 3 + c) * NN + nk];
    o_tkk[(((b * 3 + c) * KEY + r) * KK) + kk] = cv - ck;
    float sv  = R[c * 3 + 0] * sns0 + R[c * 3 + 1] * sns1 + R[c * 3 + 2] * sns2 + R[9 + c];
    float sk2 = R[c * 3 + 0] * snk0 + R[c * 3 + 1] * snk1 + R[c * 3 + 2] * snk2 + R[9 + c];
    o_skk[(((b * 3 + c) * KEY + r) * KK) + kk] = sv - sk2;
    if (kk == 0){
      o_sk[(b * 3 + c) * KEY + r] = sns0 * (c == 0) + sns1 * (c == 1) + sns2 * (c == 2);
      o_tk[(b * 3 + c) * KEY + r] = cv;
    }
  }
}

extern "C" void kernel_launch(void* const* d_in, const int* in_sizes, int n_in,
                              void* d_out, int out_size, void* d_ws, size_t ws_size,
                              hipStream_t stream){
  const float* src  = (const float*)d_in[0];
  const float* tgt  = (const float*)d_in[1];
  const float* semb = (const float*)d_in[2];
  const float* temb = (const float*)d_in[3];
  const float* sknn = (const float*)d_in[4];
  const float* W1 = (const float*)d_in[6];
  const float* b1 = (const float*)d_in[7];
  const float* W2 = (const float*)d_in[8];
  const float* b2 = (const float*)d_in[9];
  const float* W3 = (const float*)d_in[10];
  const float* b3 = (const float*)d_in[11];
  const int* sidx  = (const int*)d_in[12];
  const int* sidx1 = (const int*)d_in[13];
  const int* idx2  = (const int*)d_in[14];
  float* out = (float*)d_out;

  // workspace layout (peak ~84 MB; harness allocates 256 MiB per fill evidence)
  char* w = (char*)d_ws;
  u16* Ah = (u16*)(w);                               // 4 MB each (B,N,C) bf16 split
  u16* Al = Ah + (size_t)BB * NN * CC;
  u16* Bh = Al + (size_t)BB * NN * CC;
  u16* Bl = Bh + (size_t)BB * MM * CC;
  float* dist = (float*)(Bl + (size_t)BB * MM * CC); // 33.55 MB (B,N,M) f32
  float* scores = dist + (size_t)BB * NN * MM;       // 33.55 MB (B,N,M) f32
  char* tail = (char*)(scores + (size_t)BB * NN * MM);
  float* xx = (float*)tail;                          // B*N
  float* yy = xx + BB * NN;                          // B*M
  float* mnA = yy + BB * MM;                         // B*N
  float* Zr = mnA + BB * NN;                         // B*N
  float* s_corr = Zr + BB * NN;                      // B*3*N
  float* loss_row = s_corr + BB * 3 * NN;            // B*N
  float* sArr = loss_row + BB * NN;                  // B*N
  int* topi = (int*)(sArr + BB * NN);                // B*KEY
  float* Rt = (float*)(topi + BB * KEY);             // B*12

  k_trans<<<dim3(16, 64, 4), dim3(32, 8), 0, stream>>>(semb, temb, Ah, Al, Bh, Bl);
  k_sq<<<dim3(16, 2), 256, 0, stream>>>(semb, temb, xx, yy);
  k_gemm<<<dim3(16, 16, BB), 256, 0, stream>>>(Ah, Al, Bh, Bl, xx, yy, dist);
  k_rowstats<<<dim3(NN, BB), 256, 0, stream>>>(dist, mnA, Zr, scores);
  k_fused<<<dim3(NN, BB), 256, 0, stream>>>(dist, scores, sidx1, idx2, tgt, s_corr, loss_row);
  k_disc<<<dim3(NN / 4, BB), 256, 0, stream>>>(s_corr, src, sknn, sidx, W1, b1, W2, b2, W3, b3, sArr);
  k_rankrig<<<dim3(32, BB), 256, 0, stream>>>(sArr, src, s_corr, topi, Rt, out);
  k_out<<<dim3(65, BB), 256, 0, stream>>>(topi, sidx, src, s_corr, Rt, loss_row, out);
}

// Round 10
// 264.388 us; speedup vs baseline: 2.0862x; 1.0319x over previous
//
#include <hip/hip_runtime.h>
#include <stdint.h>

typedef unsigned short u16;

#define BB 2
#define NN 2048
#define MM 2048
#define CC 512
#define KK 16
#define KK1 8
#define KEY 1024

typedef __attribute__((ext_vector_type(8))) short bf16x8;
typedef __attribute__((ext_vector_type(4))) float f32x4;

__device__ __forceinline__ float b2f(u16 u){ return __uint_as_float(((uint32_t)u) << 16); }
__device__ __forceinline__ u16 f2b(float f){
  uint32_t x = __float_as_uint(f);
  uint32_t r = x + 0x7FFFu + ((x >> 16) & 1u);
  return (u16)(r >> 16);
}
__device__ __forceinline__ float sane(float v){ return (fabsf(v) < 1e30f) ? v : 1e30f; }

// async global->LDS 16B per lane: LDS dest = wave-uniform base + lane*16 (HW rule)
__device__ __forceinline__ void gload_lds16(const u16* g, u16* l){
  __builtin_amdgcn_global_load_lds((const __attribute__((address_space(1))) uint32_t*)g,
                                   (__attribute__((address_space(3))) uint32_t*)l, 16, 0, 0);
}

// all-thread block reduction, 256 threads. op: 0=sum 1=min 2=max
__device__ __forceinline__ float blockRed(float v, float* red, int t, int op){
  red[t] = v; __syncthreads();
  #pragma unroll
  for (int s = 128; s > 0; s >>= 1){
    if (t < s){
      float a = red[t], b = red[t + s];
      red[t] = (op == 0) ? (a + b) : ((op == 1) ? fminf(a, b) : fmaxf(a, b));
    }
    __syncthreads();
  }
  float r = red[0]; __syncthreads();
  return r;
}

// exact block min (min is associative+commutative; inputs sane()-filtered so no NaN;
// ±0 ties only feed expf(x-y) where both zero signs give identical bits). 1 barrier.
__device__ __forceinline__ float blockMinExact(float v, float* wmin, int t){
  #pragma unroll
  for (int off = 1; off < 64; off <<= 1) v = fminf(v, __shfl_xor(v, off));
  if ((t & 63) == 0) wmin[t >> 6] = v;
  __syncthreads();
  return fminf(fminf(wmin[0], wmin[1]), fminf(wmin[2], wmin[3]));
}

// ---- K0: transpose f32 (B,C,N) -> split-bf16 (B,N,C) hi/lo pairs -------------------
__global__ __launch_bounds__(256) void k_trans(const float* __restrict__ semb, const float* __restrict__ temb,
                                               u16* __restrict__ Ah, u16* __restrict__ Al,
                                               u16* __restrict__ Bh, u16* __restrict__ Bl){
  __shared__ float tile[32][33];
  int b = blockIdx.z & 1, which = blockIdx.z >> 1;
  const float* in = which ? temb : semb;
  u16* oh = which ? Bh : Ah;
  u16* ol = which ? Bl : Al;
  int c0 = blockIdx.x * 32, n0 = blockIdx.y * 32;
  int tx = threadIdx.x, ty = threadIdx.y;
  #pragma unroll
  for (int i = 0; i < 4; i++){
    int r = ty + 8 * i;
    tile[r][tx] = in[((b * CC + c0 + r) * NN) + n0 + tx];
  }
  __syncthreads();
  #pragma unroll
  for (int i = 0; i < 4; i++){
    int r = ty + 8 * i;
    float v = tile[tx][r];
    u16 hi = f2b(v);
    float lo = v - b2f(hi);
    size_t o = ((size_t)(b * NN + n0 + r) * CC) + c0 + tx;
    oh[o] = hi;
    ol[o] = f2b(lo);
  }
}

// ---- K1: exact f32 row squared norms (R18 lesson: no FP change ahead of a discrete
// selection; only bit-identical transforms admissible) -------------------------------
__global__ __launch_bounds__(256) void k_sq(const float* __restrict__ semb, const float* __restrict__ temb,
                                            float* __restrict__ xx, float* __restrict__ yy){
  int which = blockIdx.y;
  const float* in = which ? temb : semb;
  float* out = which ? yy : xx;
  int gid = blockIdx.x * 256 + threadIdx.x;   // 0..4095
  int b = gid >> 11, n = gid & 2047;
  float acc = 0.f;
  for (int c = 0; c < CC; c++){
    float v = in[((size_t)(b * CC + c)) * NN + n];
    acc += v * v;
  }
  out[gid] = acc;
}

// ---- K2: dist = xx - 2*A.B^T + yy, split-bf16 MFMA; gload_lds staging (R20) --------
__global__ __launch_bounds__(256) void k_gemm(const u16* __restrict__ Ah, const u16* __restrict__ Al,
                                              const u16* __restrict__ Bh, const u16* __restrict__ Bl,
                                              const float* __restrict__ xx, const float* __restrict__ yy,
                                              float* __restrict__ dist){
  __shared__ __align__(16) u16 lAh[128 * 64];
  __shared__ __align__(16) u16 lAl[128 * 64];
  __shared__ __align__(16) u16 lBh[128 * 64];
  __shared__ __align__(16) u16 lBl[128 * 64];
  int bz = blockIdx.z;
  const u16* Ahb = Ah + (size_t)bz * NN * CC;
  const u16* Alb = Al + (size_t)bz * NN * CC;
  const u16* Bhb = Bh + (size_t)bz * MM * CC;
  const u16* Blb = Bl + (size_t)bz * MM * CC;
  const float* xxb = xx + bz * NN;
  const float* yyb = yy + bz * MM;
  float* distb = dist + (size_t)bz * NN * MM;
  int n0 = blockIdx.y * 128, m0 = blockIdx.x * 128;
  int t = threadIdx.x;
  f32x4 acc[4][4];
  #pragma unroll
  for (int i = 0; i < 4; i++)
    #pragma unroll
    for (int j = 0; j < 4; j++){ f32x4 z = {0.f, 0.f, 0.f, 0.f}; acc[i][j] = z; }
  int w = t >> 6, lane = t & 63, lr = lane & 15, quad = lane >> 4;
  int wn = (w >> 1) * 64, wm = (w & 1) * 64;
  for (int kt = 0; kt < 8; kt++){
    int k0 = kt * 64;
    __syncthreads();
    #pragma unroll
    for (int s = 0; s < 4; s++){
      int ch = t + 256 * s;
      int rn = ch >> 3, k8 = (ch & 7) * 8;
      size_t oa = (size_t)(n0 + rn) * CC + k0 + k8;
      size_t ob = (size_t)(m0 + rn) * CC + k0 + k8;
      int ldsoff = ((t >> 6) * 64 + 256 * s) * 8;   // wave-uniform (u16 elems)
      gload_lds16(Ahb + oa, &lAh[ldsoff]);
      gload_lds16(Alb + oa, &lAl[ldsoff]);
      gload_lds16(Bhb + ob, &lBh[ldsoff]);
      gload_lds16(Blb + ob, &lBl[ldsoff]);
    }
    __syncthreads();
    #pragma unroll
    for (int kk = 0; kk < 2; kk++){
      int off = kk * 32 + quad * 8;
      bf16x8 afh[4], afl[4], bfh[4], bfl[4];
      #pragma unroll
      for (int i = 0; i < 4; i++){
        int ra = (wn + i * 16 + lr) * 64 + off;
        afh[i] = *(const bf16x8*)&lAh[ra];
        afl[i] = *(const bf16x8*)&lAl[ra];
      }
      #pragma unroll
      for (int j = 0; j < 4; j++){
        int rb = (wm + j * 16 + lr) * 64 + off;
        bfh[j] = *(const bf16x8*)&lBh[rb];
        bfl[j] = *(const bf16x8*)&lBl[rb];
      }
      #pragma unroll
      for (int i = 0; i < 4; i++)
        #pragma unroll
        for (int j = 0; j < 4; j++){
          acc[i][j] = __builtin_amdgcn_mfma_f32_16x16x32_bf16(afh[i], bfh[j], acc[i][j], 0, 0, 0);
          acc[i][j] = __builtin_amdgcn_mfma_f32_16x16x32_bf16(afh[i], bfl[j], acc[i][j], 0, 0, 0);
          acc[i][j] = __builtin_amdgcn_mfma_f32_16x16x32_bf16(afl[i], bfh[j], acc[i][j], 0, 0, 0);
        }
    }
  }
  #pragma unroll
  for (int i = 0; i < 4; i++){
    int nbase = n0 + wn + i * 16 + quad * 4;
    #pragma unroll
    for (int j = 0; j < 4; j++){
      int m = m0 + wm + j * 16 + lr;
      float yv = yyb[m];
      #pragma unroll
      for (int r = 0; r < 4; r++){
        distb[((size_t)(nbase + r)) * MM + m] = xxb[nbase + r] + yv - 2.0f * acc[i][j][r];
      }
    }
  }
}

// ---- K3: per-row min, softmax denom, scores row (R17/R21) --------------------------
__global__ __launch_bounds__(256) void k_rowstats(const float* __restrict__ dist,
                                                  float* __restrict__ mnA, float* __restrict__ Zr,
                                                  float* __restrict__ scores){
  __shared__ float red[256];
  __shared__ float wmin[4];
  int row = blockIdx.x, b = blockIdx.y, t = threadIdx.x;
  const float* dr = dist + ((size_t)b * NN + row) * MM;
  float* sr = scores + ((size_t)b * NN + row) * MM;
  float d[8];
  float mn = 3.4e38f;
  #pragma unroll
  for (int i = 0; i < 8; i++){ d[i] = sane(dr[t + 256 * i]); mn = fminf(mn, d[i]); }
  mn = blockMinExact(mn, wmin, t);
  float p[8];
  float z = 0.f;
  #pragma unroll
  for (int i = 0; i < 8; i++){ p[i] = expf(mn - d[i]); z += p[i]; }
  z = blockRed(z, red, t, 0);
  float zc = fmaxf(z, 1e-30f);
  if (t == 0){ mnA[b * NN + row] = mn; Zr[b * NN + row] = zc; }
  float iz = 1.0f / zc;
  #pragma unroll
  for (int i = 0; i < 8; i++) sr[t + 256 * i] = p[i] * iz;
}

// ---- K4: fused T/S/refined/rmm/src_corr/loss (R21 structure) -----------------------
__global__ __launch_bounds__(256) void k_fused(const float* __restrict__ dist, const float* __restrict__ scores,
                                               const int* __restrict__ sidx1,
                                               const int* __restrict__ idx2, const float* __restrict__ tgt,
                                               float* __restrict__ s_corr, float* __restrict__ lossr){
  __shared__ float Trow[MM];
  __shared__ float wmin[4];
  int n = blockIdx.x, b = blockIdx.y, t = threadIdx.x;
  const float* distb = dist + (size_t)b * NN * MM;
  const float* scoresb = scores + (size_t)b * NN * MM;
  const int* sidx1b = sidx1 + (size_t)b * NN * KK1;
  const int* idx2b = idx2 + (size_t)b * MM * KK1;
  const float* tgtb = tgt + (size_t)b * 3 * MM;
  float* s_corrb = s_corr + (size_t)b * 3 * NN;
  float* lossb = lossr + b * NN;
  const float* dn_p = distb + (size_t)n * MM;
  float dn[8];
  #pragma unroll
  for (int i = 0; i < 8; i++) dn[i] = sane(dn_p[t + 256 * i]);
  float tacc[8] = {0, 0, 0, 0, 0, 0, 0, 0};
  const int4* i1v = (const int4*)(sidx1b + n * KK1);
  int4 i1a = i1v[0], i1b = i1v[1];
  int rj[7] = {i1a.y & 2047, i1a.z & 2047, i1a.w & 2047,
               i1b.x & 2047, i1b.y & 2047, i1b.z & 2047, i1b.w & 2047};
  #pragma unroll
  for (int j = 0; j < 7; j++){
    const float* srp = scoresb + (size_t)rj[j] * MM;
    #pragma unroll
    for (int i = 0; i < 8; i++) tacc[i] += srp[t + 256 * i];
  }
  #pragma unroll
  for (int i = 0; i < 8; i++) Trow[t + 256 * i] = tacc[i];
  __syncthreads();
  float rloc[8];
  float lmin = 3.4e38f;
  #pragma unroll
  for (int i = 0; i < 8; i++){
    int m = t + 256 * i;
    const int4* ipv = (const int4*)(idx2b + m * KK1);
    int4 ipa = ipv[0], ipb = ipv[1];
    float S = 0.f;
    S += Trow[ipa.y & 2047];
    S += Trow[ipa.z & 2047];
    S += Trow[ipa.w & 2047];
    S += Trow[ipb.x & 2047];
    S += Trow[ipb.y & 2047];
    S += Trow[ipb.z & 2047];
    S += Trow[ipb.w & 2047];
    float rv = sane(expf(1.0f - S / 7.0f) * dn[i]);
    rloc[i] = rv;
    lmin = fminf(lmin, rv);
  }
  // exact min; its barrier also guarantees all Trow reads finished before reuse
  float rmin = blockMinExact(lmin, wmin, t);
  float z = 0.f, s0 = 0.f, s1 = 0.f, s2 = 0.f;
  #pragma unroll
  for (int i = 0; i < 8; i++){
    int m = t + 256 * i;
    float p = expf(rmin - rloc[i]);
    z  += p;
    s0 += tgtb[0 * MM + m] * p;
    s1 += tgtb[1 * MM + m] * p;
    s2 += tgtb[2 * MM + m] * p;
  }
  f32x4* red4 = (f32x4*)Trow;   // Trow dead from here; same tree order per component
  f32x4 v4; v4.x = z; v4.y = s0; v4.z = s1; v4.w = s2;
  red4[t] = v4; __syncthreads();
  #pragma unroll
  for (int s = 128; s > 0; s >>= 1){
    if (t < s){
      f32x4 a = red4[t], c = red4[t + s];
      a.x += c.x; a.y += c.y; a.z += c.z; a.w += c.w;
      red4[t] = a;
    }
    __syncthreads();
  }
  if (t == 0){
    f32x4 r = red4[0];
    float iZ = 1.0f / fmaxf(r.x, 1e-30f);
    s_corrb[0 * NN + n] = r.y * iZ;
    s_corrb[1 * NN + n] = r.z * iZ;
    s_corrb[2 * NN + n] = r.w * iZ;
    lossb[n] = -logf(fminf(iZ, 1.0f) + 1e-15f);  // pred at onehot == rowmax(rmm) == 1/Z
  }
}

// ---- K5: discriminator MLP — R14: scalar-W2 + e-range wave split -------------------
__global__ __launch_bounds__(256, 4) void k_disc(const float* __restrict__ s_corr, const float* __restrict__ src,
                                                 const float* __restrict__ sknn, const int* __restrict__ sidx,
                                                 const float* __restrict__ W1, const float* __restrict__ b1,
                                                 const float* __restrict__ W2, const float* __restrict__ b2,
                                                 const float* __restrict__ W3, const float* __restrict__ b3,
                                                 float* __restrict__ sArr){
  __shared__ float term[64][129];
  int t = threadIdx.x;
  int b = blockIdx.y;
  int p = t & 63;
  int n = blockIdx.x * 4 + (p >> 4);
  int kk = p & 15;
  int eh = t >> 6;
  int nk = sidx[((b * NN + n) * KK) + kk] & 2047;
  float f[6];
  #pragma unroll
  for (int c = 0; c < 3; c++){
    f[c]     = s_corr[(b * 3 + c) * NN + n] - s_corr[(b * 3 + c) * NN + nk];
    f[3 + c] = src[(b * 3 + c) * NN + n] - sknn[((size_t)(b * NN + n) * KK + kk) * 3 + c];
  }
  #define L1D(d) ({ float a_ = b1[(d)];              \
                    a_ += f[0] * W1[(d) * 6 + 0];    \
                    a_ += f[1] * W1[(d) * 6 + 1];    \
                    a_ += f[2] * W1[(d) * 6 + 2];    \
                    a_ += f[3] * W1[(d) * 6 + 3];    \
                    a_ += f[4] * W1[(d) * 6 + 4];    \
                    a_ += f[5] * W1[(d) * 6 + 5];    \
                    fmaxf(a_, 0.f); })
  #define HSET(i) f32x4 h##i;                  \
                  h##i.x = L1D(4 * (i) + 0);   \
                  h##i.y = L1D(4 * (i) + 1);   \
                  h##i.z = L1D(4 * (i) + 2);   \
                  h##i.w = L1D(4 * (i) + 3);
  HSET(0) HSET(1) HSET(2) HSET(3) HSET(4) HSET(5) HSET(6) HSET(7)
  HSET(8) HSET(9) HSET(10) HSET(11) HSET(12) HSET(13) HSET(14) HSET(15)
  #undef HSET
  #undef L1D
  int e0 = __builtin_amdgcn_readfirstlane(eh * 32);
  for (int j = 0; j < 32; j++){
    int e = e0 + j;
    float a = b2[e];
    const f32x4* w4 = (const f32x4*)&W2[e * 64];
    #define QSTEP(i) { f32x4 wv = w4[i]; a += wv.x * h##i.x + wv.y * h##i.y + wv.z * h##i.z + wv.w * h##i.w; }
    QSTEP(0) QSTEP(1) QSTEP(2) QSTEP(3) QSTEP(4) QSTEP(5) QSTEP(6) QSTEP(7)
    QSTEP(8) QSTEP(9) QSTEP(10) QSTEP(11) QSTEP(12) QSTEP(13) QSTEP(14) QSTEP(15)
    #undef QSTEP
    term[p][e] = fmaxf(a, 0.f);
  }
  __syncthreads();
  if (t < 64){
    float sacc = b3[0];
    #pragma unroll 4
    for (int e = 0; e < 128; e++) sacc += W3[e] * term[t][e];
    if (!(fabsf(sacc) < 1e30f)) sacc = -1e30f;
    #pragma unroll
    for (int off = 1; off < 16; off <<= 1) sacc = fmaxf(sacc, __shfl_xor(sacc, off, 16));
    if (kk == 0) sArr[b * NN + n] = sacc;
  }
}

// ---- K6+K7+K8 merged. R22: SVD tail rewritten with NAMED SCALARS + static pivot
// cases. R21's version indexed Km[k2][p]/V[i2][j]/lam[id] with RUNTIME indices ->
// all five 3x3 f64 matrices lived in SCRATCH (rule #20; VGPR_Count=32 was the tell)
// -> 43-116us of single-lane scratch thrash. Same arithmetic per pivot case ->
// same values; R/t feed only continuous outputs (threshold 0.128, no discrete
// selection downstream), so exact bitwise identity is not required on this path.
__global__ __launch_bounds__(256) void k_rankrig(const float* __restrict__ sArr, const float* __restrict__ src,
                                                 const float* __restrict__ s_corr, int* __restrict__ topi,
                                                 float* __restrict__ Rt, float* __restrict__ out){
  __shared__ float wrow[NN];
  __shared__ float red[256];
  __shared__ int pc[4][64];
  int b = blockIdx.y, t = threadIdx.x;
  // ---- softmax (verbatim k_softw) -> wrow ----
  const float* sp = sArr + b * NN;
  float sv[8];
  float mx = -3.4e38f;
  #pragma unroll
  for (int i = 0; i < 8; i++){
    float v = sp[t + 256 * i];
    if (!(fabsf(v) < 1e30f)) v = -1e30f;
    sv[i] = v; mx = fmaxf(mx, v);
  }
  mx = blockRed(mx, red, t, 2);
  float z = 0.f;
  #pragma unroll
  for (int i = 0; i < 8; i++) z += expf(sv[i] - mx);
  z = blockRed(z, red, t, 0);
  float iz = 1.0f / fmaxf(z, 1e-30f);
  #pragma unroll
  for (int i = 0; i < 8; i++) wrow[t + 256 * i] = expf(sv[i] - mx) * iz;
  __syncthreads();
  // ---- rank (verbatim R15 body) ----
  int tn = t & 63, tj = t >> 6;
  int n = blockIdx.x * 64 + tn;
  float wn = wrow[n];
  int j0 = tj * 512;
  const f32x4* w4 = (const f32x4*)&wrow[j0];
  int cnt = 0;
  #pragma unroll 4
  for (int q = 0; q < 128; q++){
    f32x4 wv = w4[q];
    int j = j0 + q * 4;
    cnt += (wv.x > wn) || ((wv.x == wn) && (j + 0 < n));
    cnt += (wv.y > wn) || ((wv.y == wn) && (j + 1 < n));
    cnt += (wv.z > wn) || ((wv.z == wn) && (j + 2 < n));
    cnt += (wv.w > wn) || ((wv.w == wn) && (j + 3 < n));
  }
  pc[tj][tn] = cnt;
  __syncthreads();
  if (t < 64){
    int c = pc[0][t] + pc[1][t] + pc[2][t] + pc[3][t];
    if (c < KEY) topi[b * KEY + c] = blockIdx.x * 64 + t;
  }
  if (blockIdx.x != 0) return;
  // ---- rigid: centroids + H (unchanged block reductions) ----
  float wsum = 0, a0 = 0, a1 = 0, a2 = 0, c0 = 0, c1 = 0, c2 = 0;
  for (int n2 = t; n2 < NN; n2 += 256){
    float wv = wrow[n2];
    float s0 = src[(b * 3 + 0) * NN + n2];
    float s1 = src[(b * 3 + 1) * NN + n2];
    float s2 = src[(b * 3 + 2) * NN + n2];
    float q0 = s_corr[(b * 3 + 0) * NN + n2];
    float q1 = s_corr[(b * 3 + 1) * NN + n2];
    float q2 = s_corr[(b * 3 + 2) * NN + n2];
    wsum += wv; a0 += wv * s0; a1 += wv * s1; a2 += wv * s2;
    c0 += wv * q0; c1 += wv * q1; c2 += wv * q2;
  }
  wsum = blockRed(wsum, red, t, 0);
  a0 = blockRed(a0, red, t, 0); a1 = blockRed(a1, red, t, 0); a2 = blockRed(a2, red, t, 0);
  c0 = blockRed(c0, red, t, 0); c1 = blockRed(c1, red, t, 0); c2 = blockRed(c2, red, t, 0);
  float inv = 1.0f / fmaxf(wsum, 1e-30f);
  float cs0 = a0 * inv, cs1 = a1 * inv, cs2 = a2 * inv;
  float ct0 = c0 * inv, ct1 = c1 * inv, ct2 = c2 * inv;
  float h[9] = {0, 0, 0, 0, 0, 0, 0, 0, 0};
  for (int n2 = t; n2 < NN; n2 += 256){
    float wv = wrow[n2];
    float ds0 = src[(b * 3 + 0) * NN + n2] - cs0;
    float ds1 = src[(b * 3 + 1) * NN + n2] - cs1;
    float ds2 = src[(b * 3 + 2) * NN + n2] - cs2;
    float dc0 = s_corr[(b * 3 + 0) * NN + n2] - ct0;
    float dc1 = s_corr[(b * 3 + 1) * NN + n2] - ct1;
    float dc2 = s_corr[(b * 3 + 2) * NN + n2] - ct2;
    h[0] += wv * ds0 * dc0; h[1] += wv * ds0 * dc1; h[2] += wv * ds0 * dc2;
    h[3] += wv * ds1 * dc0; h[4] += wv * ds1 * dc1; h[5] += wv * ds1 * dc2;
    h[6] += wv * ds2 * dc0; h[7] += wv * ds2 * dc1; h[8] += wv * ds2 * dc2;
  }
  for (int i = 0; i < 9; i++) h[i] = blockRed(h[i], red, t, 0);
  if (t == 0){
    // ---- all-register 3x3 SVD (static pivot enumeration) ----
    double Hm00 = (double)h[0], Hm01 = (double)h[1], Hm02 = (double)h[2];
    double Hm10 = (double)h[3], Hm11 = (double)h[4], Hm12 = (double)h[5];
    double Hm20 = (double)h[6], Hm21 = (double)h[7], Hm22 = (double)h[8];
    // K = H^T H (full 9 scalars: two-sided rotations make K transiently asymmetric)
    double k00 = Hm00 * Hm00 + Hm10 * Hm10 + Hm20 * Hm20;
    double k01 = Hm00 * Hm01 + Hm10 * Hm11 + Hm20 * Hm21;
    double k02 = Hm00 * Hm02 + Hm10 * Hm12 + Hm20 * Hm22;
    double k10 = Hm01 * Hm00 + Hm11 * Hm10 + Hm21 * Hm20;
    double k11 = Hm01 * Hm01 + Hm11 * Hm11 + Hm21 * Hm21;
    double k12 = Hm01 * Hm02 + Hm11 * Hm12 + Hm21 * Hm22;
    double k20 = Hm02 * Hm00 + Hm12 * Hm10 + Hm22 * Hm20;
    double k21 = Hm02 * Hm01 + Hm12 * Hm11 + Hm22 * Hm21;
    double k22 = Hm02 * Hm02 + Hm12 * Hm12 + Hm22 * Hm22;
    double v00 = 1, v01 = 0, v02 = 0, v10 = 0, v11 = 1, v12 = 0, v20 = 0, v21 = 0, v22 = 1;
    double ksc = fabs(k00) + fabs(k11) + fabs(k22) + 1e-300;
    #define ROT2(A, B) { double ra = A, rb = B; A = cc2 * ra - sn * rb; B = sn * ra + cc2 * rb; }
    for (int sweep = 0; sweep < 60; sweep++){
      double m01 = fabs(k01), m02 = fabs(k02), m12 = fabs(k12);
      int cse = 0; double mx2 = m01;
      if (m02 > mx2){ mx2 = m02; cse = 1; }
      if (m12 > mx2){ mx2 = m12; cse = 2; }
      if (mx2 <= 1e-15 * ksc) break;
      double app, aqq, apq;
      if (cse == 0){ app = k00; aqq = k11; apq = k01; }
      else if (cse == 1){ app = k00; aqq = k22; apq = k02; }
      else { app = k11; aqq = k22; apq = k12; }
      double tau = (aqq - app) / (2.0 * apq);
      double tt = ((tau >= 0) ? 1.0 : -1.0) / (fabs(tau) + sqrt(1.0 + tau * tau));
      double cc2 = 1.0 / sqrt(1.0 + tt * tt), sn = tt * cc2;
      if (cse == 0){        // (p,q)=(0,1)
        ROT2(k00, k01) ROT2(k10, k11) ROT2(k20, k21)   // cols p,q
        ROT2(k00, k10) ROT2(k01, k11) ROT2(k02, k12)   // rows p,q
        ROT2(v00, v01) ROT2(v10, v11) ROT2(v20, v21)
      } else if (cse == 1){ // (p,q)=(0,2)
        ROT2(k00, k02) ROT2(k10, k12) ROT2(k20, k22)
        ROT2(k00, k20) ROT2(k01, k21) ROT2(k02, k22)
        ROT2(v00, v02) ROT2(v10, v12) ROT2(v20, v22)
      } else {              // (p,q)=(1,2)
        ROT2(k01, k02) ROT2(k11, k12) ROT2(k21, k22)
        ROT2(k10, k20) ROT2(k11, k21) ROT2(k12, k22)
        ROT2(v01, v02) ROT2(v11, v12) ROT2(v21, v22)
      }
    }
    #undef ROT2
    // sort eigenvalues desc, carrying indices (same comparisons as before)
    double l0 = k00, l1 = k11, l2 = k22; int id0 = 0, id1 = 1, id2 = 2;
    double lt; int it;
    if (l0 < l1){ lt = l0; l0 = l1; l1 = lt; it = id0; id0 = id1; id1 = it; }
    if (l0 < l2){ lt = l0; l0 = l2; l2 = lt; it = id0; id0 = id2; id2 = it; }
    if (l1 < l2){ lt = l1; l1 = l2; l2 = lt; it = id1; id1 = id2; id2 = it; }
    double Vs00, Vs10, Vs20, Vs01, Vs11, Vs21, Vs02, Vs12, Vs22;
    double u00 = 0, u10 = 0, u20 = 0, u01 = 0, u11 = 0, u21 = 0, u02 = 0, u12 = 0, u22 = 0;
    #define GETCOL(j, cA, cB, cC) { if ((j) == 0){ cA = v00; cB = v10; cC = v20; } \
                                    else if ((j) == 1){ cA = v01; cB = v11; cC = v21; } \
                                    else { cA = v02; cB = v12; cC = v22; } }
    // jj = 0
    {
      double cA, cB, cC; GETCOL(id0, cA, cB, cC);
      Vs00 = cA; Vs10 = cB; Vs20 = cC;
      double uu0 = 0, uu1 = 0, uu2 = 0;
      uu0 += Hm00 * cA; uu0 += Hm01 * cB; uu0 += Hm02 * cC;
      uu1 += Hm10 * cA; uu1 += Hm11 * cB; uu1 += Hm12 * cC;
      uu2 += Hm20 * cA; uu2 += Hm21 * cB; uu2 += Hm22 * cC;
      double nrm = sqrt(uu0 * uu0 + uu1 * uu1 + uu2 * uu2);
      if (nrm > 1e-20){ u00 = uu0 / nrm; u10 = uu1 / nrm; u20 = uu2 / nrm; }
      else {
        double x0 = u10 * u21 - u20 * u11;
        double x1 = u20 * u01 - u00 * u21;
        double x2 = u00 * u11 - u10 * u01;
        double nn2 = sqrt(x0 * x0 + x1 * x1 + x2 * x2);
        if (nn2 < 1e-20){ x0 = 1; x1 = 0; x2 = 0; nn2 = 1; }
        u00 = x0 / nn2; u10 = x1 / nn2; u20 = x2 / nn2;
      }
    }
    // jj = 1
    {
      double cA, cB, cC; GETCOL(id1, cA, cB, cC);
      Vs01 = cA; Vs11 = cB; Vs21 = cC;
      double uu0 = 0, uu1 = 0, uu2 = 0;
      uu0 += Hm00 * cA; uu0 += Hm01 * cB; uu0 += Hm02 * cC;
      uu1 += Hm10 * cA; uu1 += Hm11 * cB; uu1 += Hm12 * cC;
      uu2 += Hm20 * cA; uu2 += Hm21 * cB; uu2 += Hm22 * cC;
      double nrm = sqrt(uu0 * uu0 + uu1 * uu1 + uu2 * uu2);
      if (nrm > 1e-20){ u01 = uu0 / nrm; u11 = uu1 / nrm; u21 = uu2 / nrm; }
      else {
        double x0 = u10 * u21 - u20 * u11;
        double x1 = u20 * u01 - u00 * u21;
        double x2 = u00 * u11 - u10 * u01;
        double nn2 = sqrt(x0 * x0 + x1 * x1 + x2 * x2);
        if (nn2 < 1e-20){ x0 = 1; x1 = 0; x2 = 0; nn2 = 1; }
        u01 = x0 / nn2; u11 = x1 / nn2; u21 = x2 / nn2;
      }
    }
    // jj = 2
    {
      double cA, cB, cC; GETCOL(id2, cA, cB, cC);
      Vs02 = cA; Vs12 = cB; Vs22 = cC;
      double uu0 = 0, uu1 = 0, uu2 = 0;
      uu0 += Hm00 * cA; uu0 += Hm01 * cB; uu0 += Hm02 * cC;
      uu1 += Hm10 * cA; uu1 += Hm11 * cB; uu1 += Hm12 * cC;
      uu2 += Hm20 * cA; uu2 += Hm21 * cB; uu2 += Hm22 * cC;
      double nrm = sqrt(uu0 * uu0 + uu1 * uu1 + uu2 * uu2);
      if (nrm > 1e-20){ u02 = uu0 / nrm; u12 = uu1 / nrm; u22 = uu2 / nrm; }
      else {
        double x0 = u10 * u21 - u20 * u11;
        double x1 = u20 * u01 - u00 * u21;
        double x2 = u00 * u11 - u10 * u01;
        double nn2 = sqrt(x0 * x0 + x1 * x1 + x2 * x2);
        if (nn2 < 1e-20){ x0 = 1; x1 = 0; x2 = 0; nn2 = 1; }
        u02 = x0 / nn2; u12 = x1 / nn2; u22 = x2 / nn2;
      }
    }
    #undef GETCOL
    double ddU = u00 * (u11 * u22 - u12 * u21) - u01 * (u10 * u22 - u12 * u20) + u02 * (u10 * u21 - u11 * u20);
    double ddV = Vs00 * (Vs11 * Vs22 - Vs12 * Vs21) - Vs01 * (Vs10 * Vs22 - Vs12 * Vs20) + Vs02 * (Vs10 * Vs21 - Vs11 * Vs20);
    double dd = ddU * ddV;
    double Rm00 = Vs00 * u00 + Vs01 * u01 + dd * Vs02 * u02;
    double Rm01 = Vs00 * u10 + Vs01 * u11 + dd * Vs02 * u12;
    double Rm02 = Vs00 * u20 + Vs01 * u21 + dd * Vs02 * u22;
    double Rm10 = Vs10 * u00 + Vs11 * u01 + dd * Vs12 * u02;
    double Rm11 = Vs10 * u10 + Vs11 * u11 + dd * Vs12 * u12;
    double Rm12 = Vs10 * u20 + Vs11 * u21 + dd * Vs12 * u22;
    double Rm20 = Vs20 * u00 + Vs21 * u01 + dd * Vs22 * u02;
    double Rm21 = Vs20 * u10 + Vs21 * u11 + dd * Vs22 * u12;
    double Rm22 = Vs20 * u20 + Vs21 * u21 + dd * Vs22 * u22;
    double csd0 = cs0, csd1 = cs1, csd2 = cs2;
    double ctd0 = ct0, ctd1 = ct1, ctd2 = ct2;
    double tv0 = ctd0 - (Rm00 * csd0 + Rm01 * csd1 + Rm02 * csd2);
    double tv1 = ctd1 - (Rm10 * csd0 + Rm11 * csd1 + Rm12 * csd2);
    double tv2 = ctd2 - (Rm20 * csd0 + Rm21 * csd1 + Rm22 * csd2);
    Rt[b * 12 + 0] = (float)Rm00; out[b * 9 + 0] = (float)Rm00;
    Rt[b * 12 + 1] = (float)Rm01; out[b * 9 + 1] = (float)Rm01;
    Rt[b * 12 + 2] = (float)Rm02; out[b * 9 + 2] = (float)Rm02;
    Rt[b * 12 + 3] = (float)Rm10; out[b * 9 + 3] = (float)Rm10;
    Rt[b * 12 + 4] = (float)Rm11; out[b * 9 + 4] = (float)Rm11;
    Rt[b * 12 + 5] = (float)Rm12; out[b * 9 + 5] = (float)Rm12;
    Rt[b * 12 + 6] = (float)Rm20; out[b * 9 + 6] = (float)Rm20;
    Rt[b * 12 + 7] = (float)Rm21; out[b * 9 + 7] = (float)Rm21;
    Rt[b * 12 + 8] = (float)Rm22; out[b * 9 + 8] = (float)Rm22;
    Rt[b * 12 + 9]  = (float)tv0; out[18 + b * 3 + 0] = (float)tv0;
    Rt[b * 12 + 10] = (float)tv1; out[18 + b * 3 + 1] = (float)tv1;
    Rt[b * 12 + 11] = (float)tv2; out[18 + b * 3 + 2] = (float)tv2;
  }
}

// ---- K10 (+K11 merged): keypoint gathers; block x==64,b==0 computes loss_scl -------
__global__ __launch_bounds__(256) void k_out(const int* __restrict__ topi, const int* __restrict__ sidx,
                                             const float* __restrict__ src, const float* __restrict__ s_corr,
                                             const float* __restrict__ Rt, const float* __restrict__ loss_row,
                                             float* __restrict__ out){
  __shared__ float red[256];
  int b = blockIdx.y, t = threadIdx.x;
  if (blockIdx.x == 64){
    if (b != 0) return;
    float acc = 0.f;
    for (int i = t; i < BB * KEY; i += 256){
      int bb = i >> 10, r = i & 1023;
      int n = topi[bb * KEY + r] & 2047;
      acc += loss_row[bb * NN + n];
    }
    acc = blockRed(acc, red, t, 0);
    if (t == 0) out[208920] = acc / 2048.0f;
    return;
  }
  int rr = t >> 4, kk = t & 15;
  int r = blockIdx.x * 16 + rr;
  int ns = topi[b * KEY + r] & 2047;
  int nk = sidx[(b * NN + ns) * KK + kk] & 2047;
  const float* R = Rt + b * 12;
  float sns0 = src[(b * 3 + 0) * NN + ns];
  float sns1 = src[(b * 3 + 1) * NN + ns];
  float sns2 = src[(b * 3 + 2) * NN + ns];
  float snk0 = src[(b * 3 + 0) * NN + nk];
  float snk1 = src[(b * 3 + 1) * NN + nk];
  float snk2 = src[(b * 3 + 2) * NN + nk];
  float* o_sk  = out + 24;
  float* o_tk  = out + 6168;
  float* o_skk = out + 12312;
  float* o_tkk = out + 110616;
  #pragma unroll
  for (int c = 0; c < 3; c++){
    float cv  = s_corr[(b * 3 + c) * NN + ns];
    float ck  = s_corr[(b * 3 + c) * NN + nk];
    o_tkk[(((b * 3 + c) * KEY + r) * KK) + kk] = cv - ck;
    float sv  = R[c * 3 + 0] * sns0 + R[c * 3 + 1] * sns1 + R[c * 3 + 2] * sns2 + R[9 + c];
    float sk2 = R[c * 3 + 0] * snk0 + R[c * 3 + 1] * snk1 + R[c * 3 + 2] * snk2 + R[9 + c];
    o_skk[(((b * 3 + c) * KEY + r) * KK) + kk] = sv - sk2;
    if (kk == 0){
      o_sk[(b * 3 + c) * KEY + r] = sns0 * (c == 0) + sns1 * (c == 1) + sns2 * (c == 2);
      o_tk[(b * 3 + c) * KEY + r] = cv;
    }
  }
}

extern "C" void kernel_launch(void* const* d_in, const int* in_sizes, int n_in,
                              void* d_out, int out_size, void* d_ws, size_t ws_size,
                              hipStream_t stream){
  const float* src  = (const float*)d_in[0];
  const float* tgt  = (const float*)d_in[1];
  const float* semb = (const float*)d_in[2];
  const float* temb = (const float*)d_in[3];
  const float* sknn = (const float*)d_in[4];
  const float* W1 = (const float*)d_in[6];
  const float* b1 = (const float*)d_in[7];
  const float* W2 = (const float*)d_in[8];
  const float* b2 = (const float*)d_in[9];
  const float* W3 = (const float*)d_in[10];
  const float* b3 = (const float*)d_in[11];
  const int* sidx  = (const int*)d_in[12];
  const int* sidx1 = (const int*)d_in[13];
  const int* idx2  = (const int*)d_in[14];
  float* out = (float*)d_out;

  // workspace layout (peak ~84 MB; harness allocates 256 MiB per fill evidence)
  char* w = (char*)d_ws;
  u16* Ah = (u16*)(w);                               // 4 MB each (B,N,C) bf16 split
  u16* Al = Ah + (size_t)BB * NN * CC;
  u16* Bh = Al + (size_t)BB * NN * CC;
  u16* Bl = Bh + (size_t)BB * MM * CC;
  float* dist = (float*)(Bl + (size_t)BB * MM * CC); // 33.55 MB (B,N,M) f32
  float* scores = dist + (size_t)BB * NN * MM;       // 33.55 MB (B,N,M) f32
  char* tail = (char*)(scores + (size_t)BB * NN * MM);
  float* xx = (float*)tail;                          // B*N
  float* yy = xx + BB * NN;                          // B*M
  float* mnA = yy + BB * MM;                         // B*N
  float* Zr = mnA + BB * NN;                         // B*N
  float* s_corr = Zr + BB * NN;                      // B*3*N
  float* loss_row = s_corr + BB * 3 * NN;            // B*N
  float* sArr = loss_row + BB * NN;                  // B*N
  int* topi = (int*)(sArr + BB * NN);                // B*KEY
  float* Rt = (float*)(topi + BB * KEY);             // B*12

  k_trans<<<dim3(16, 64, 4), dim3(32, 8), 0, stream>>>(semb, temb, Ah, Al, Bh, Bl);
  k_sq<<<dim3(16, 2), 256, 0, stream>>>(semb, temb, xx, yy);
  k_gemm<<<dim3(16, 16, BB), 256, 0, stream>>>(Ah, Al, Bh, Bl, xx, yy, dist);
  k_rowstats<<<dim3(NN, BB), 256, 0, stream>>>(dist, mnA, Zr, scores);
  k_fused<<<dim3(NN, BB), 256, 0, stream>>>(dist, scores, sidx1, idx2, tgt, s_corr, loss_row);
  k_disc<<<dim3(NN / 4, BB), 256, 0, stream>>>(s_corr, src, sknn, sidx, W1, b1, W2, b2, W3, b3, sArr);
  k_rankrig<<<dim3(32, BB), 256, 0, stream>>>(sArr, src, s_corr, topi, Rt, out);
  k_out<<<dim3(65, BB), 256, 0, stream>>>(topi, sidx, src, s_corr, Rt, loss_row, out);
}

// Round 11
// 261.899 us; speedup vs baseline: 2.1060x; 1.0095x over previous
//
#include <hip/hip_runtime.h>
#include <stdint.h>

typedef unsigned short u16;

#define BB 2
#define NN 2048
#define MM 2048
#define CC 512
#define KK 16
#define KK1 8
#define KEY 1024

typedef __attribute__((ext_vector_type(8))) short bf16x8;
typedef __attribute__((ext_vector_type(4))) float f32x4;

__device__ __forceinline__ float b2f(u16 u){ return __uint_as_float(((uint32_t)u) << 16); }
__device__ __forceinline__ u16 f2b(float f){
  uint32_t x = __float_as_uint(f);
  uint32_t r = x + 0x7FFFu + ((x >> 16) & 1u);
  return (u16)(r >> 16);
}
__device__ __forceinline__ float sane(float v){ return (fabsf(v) < 1e30f) ? v : 1e30f; }

// async global->LDS 16B per lane: LDS dest = wave-uniform base + lane*16 (HW rule)
__device__ __forceinline__ void gload_lds16(const u16* g, u16* l){
  __builtin_amdgcn_global_load_lds((const __attribute__((address_space(1))) uint32_t*)g,
                                   (__attribute__((address_space(3))) uint32_t*)l, 16, 0, 0);
}

// all-thread block reduction, 256 threads. op: 0=sum 1=min 2=max
__device__ __forceinline__ float blockRed(float v, float* red, int t, int op){
  red[t] = v; __syncthreads();
  #pragma unroll
  for (int s = 128; s > 0; s >>= 1){
    if (t < s){
      float a = red[t], b = red[t + s];
      red[t] = (op == 0) ? (a + b) : ((op == 1) ? fminf(a, b) : fmaxf(a, b));
    }
    __syncthreads();
  }
  float r = red[0]; __syncthreads();
  return r;
}

// 4-wide sum tree; per-component order identical to 4 separate blockReds -> each
// component's result is bit-identical to blockRed(v, red, t, 0).
__device__ __forceinline__ f32x4 blockRed4(f32x4 v, f32x4* red4, int t){
  red4[t] = v; __syncthreads();
  #pragma unroll
  for (int s = 128; s > 0; s >>= 1){
    if (t < s){
      f32x4 a = red4[t], c = red4[t + s];
      a.x += c.x; a.y += c.y; a.z += c.z; a.w += c.w;
      red4[t] = a;
    }
    __syncthreads();
  }
  f32x4 r = red4[0]; __syncthreads();
  return r;
}

// exact block min (min is associative+commutative; inputs sane()-filtered so no NaN;
// ±0 ties only feed expf(x-y) where both zero signs give identical bits). 1 barrier.
__device__ __forceinline__ float blockMinExact(float v, float* wmin, int t){
  #pragma unroll
  for (int off = 1; off < 64; off <<= 1) v = fminf(v, __shfl_xor(v, off));
  if ((t & 63) == 0) wmin[t >> 6] = v;
  __syncthreads();
  return fminf(fminf(wmin[0], wmin[1]), fminf(wmin[2], wmin[3]));
}

// ---- K0: transpose f32 (B,C,N) -> split-bf16 (B,N,C) hi/lo pairs -------------------
__global__ __launch_bounds__(256) void k_trans(const float* __restrict__ semb, const float* __restrict__ temb,
                                               u16* __restrict__ Ah, u16* __restrict__ Al,
                                               u16* __restrict__ Bh, u16* __restrict__ Bl){
  __shared__ float tile[32][33];
  int b = blockIdx.z & 1, which = blockIdx.z >> 1;
  const float* in = which ? temb : semb;
  u16* oh = which ? Bh : Ah;
  u16* ol = which ? Bl : Al;
  int c0 = blockIdx.x * 32, n0 = blockIdx.y * 32;
  int tx = threadIdx.x, ty = threadIdx.y;
  #pragma unroll
  for (int i = 0; i < 4; i++){
    int r = ty + 8 * i;
    tile[r][tx] = in[((b * CC + c0 + r) * NN) + n0 + tx];
  }
  __syncthreads();
  #pragma unroll
  for (int i = 0; i < 4; i++){
    int r = ty + 8 * i;
    float v = tile[tx][r];
    u16 hi = f2b(v);
    float lo = v - b2f(hi);
    size_t o = ((size_t)(b * NN + n0 + r) * CC) + c0 + tx;
    oh[o] = hi;
    ol[o] = f2b(lo);
  }
}

// ---- K1: exact f32 row squared norms (R18 lesson: no FP change ahead of a discrete
// selection; only bit-identical transforms admissible) -------------------------------
__global__ __launch_bounds__(256) void k_sq(const float* __restrict__ semb, const float* __restrict__ temb,
                                            float* __restrict__ xx, float* __restrict__ yy){
  int which = blockIdx.y;
  const float* in = which ? temb : semb;
  float* out = which ? yy : xx;
  int gid = blockIdx.x * 256 + threadIdx.x;   // 0..4095
  int b = gid >> 11, n = gid & 2047;
  float acc = 0.f;
  for (int c = 0; c < CC; c++){
    float v = in[((size_t)(b * CC + c)) * NN + n];
    acc += v * v;
  }
  out[gid] = acc;
}

// ---- K2: dist = xx - 2*A.B^T + yy, split-bf16 MFMA; gload_lds staging (R20) --------
__global__ __launch_bounds__(256) void k_gemm(const u16* __restrict__ Ah, const u16* __restrict__ Al,
                                              const u16* __restrict__ Bh, const u16* __restrict__ Bl,
                                              const float* __restrict__ xx, const float* __restrict__ yy,
                                              float* __restrict__ dist){
  __shared__ __align__(16) u16 lAh[128 * 64];
  __shared__ __align__(16) u16 lAl[128 * 64];
  __shared__ __align__(16) u16 lBh[128 * 64];
  __shared__ __align__(16) u16 lBl[128 * 64];
  int bz = blockIdx.z;
  const u16* Ahb = Ah + (size_t)bz * NN * CC;
  const u16* Alb = Al + (size_t)bz * NN * CC;
  const u16* Bhb = Bh + (size_t)bz * MM * CC;
  const u16* Blb = Bl + (size_t)bz * MM * CC;
  const float* xxb = xx + bz * NN;
  const float* yyb = yy + bz * MM;
  float* distb = dist + (size_t)bz * NN * MM;
  int n0 = blockIdx.y * 128, m0 = blockIdx.x * 128;
  int t = threadIdx.x;
  f32x4 acc[4][4];
  #pragma unroll
  for (int i = 0; i < 4; i++)
    #pragma unroll
    for (int j = 0; j < 4; j++){ f32x4 z = {0.f, 0.f, 0.f, 0.f}; acc[i][j] = z; }
  int w = t >> 6, lane = t & 63, lr = lane & 15, quad = lane >> 4;
  int wn = (w >> 1) * 64, wm = (w & 1) * 64;
  for (int kt = 0; kt < 8; kt++){
    int k0 = kt * 64;
    __syncthreads();
    #pragma unroll
    for (int s = 0; s < 4; s++){
      int ch = t + 256 * s;
      int rn = ch >> 3, k8 = (ch & 7) * 8;
      size_t oa = (size_t)(n0 + rn) * CC + k0 + k8;
      size_t ob = (size_t)(m0 + rn) * CC + k0 + k8;
      int ldsoff = ((t >> 6) * 64 + 256 * s) * 8;   // wave-uniform (u16 elems)
      gload_lds16(Ahb + oa, &lAh[ldsoff]);
      gload_lds16(Alb + oa, &lAl[ldsoff]);
      gload_lds16(Bhb + ob, &lBh[ldsoff]);
      gload_lds16(Blb + ob, &lBl[ldsoff]);
    }
    __syncthreads();
    #pragma unroll
    for (int kk = 0; kk < 2; kk++){
      int off = kk * 32 + quad * 8;
      bf16x8 afh[4], afl[4], bfh[4], bfl[4];
      #pragma unroll
      for (int i = 0; i < 4; i++){
        int ra = (wn + i * 16 + lr) * 64 + off;
        afh[i] = *(const bf16x8*)&lAh[ra];
        afl[i] = *(const bf16x8*)&lAl[ra];
      }
      #pragma unroll
      for (int j = 0; j < 4; j++){
        int rb = (wm + j * 16 + lr) * 64 + off;
        bfh[j] = *(const bf16x8*)&lBh[rb];
        bfl[j] = *(const bf16x8*)&lBl[rb];
      }
      #pragma unroll
      for (int i = 0; i < 4; i++)
        #pragma unroll
        for (int j = 0; j < 4; j++){
          acc[i][j] = __builtin_amdgcn_mfma_f32_16x16x32_bf16(afh[i], bfh[j], acc[i][j], 0, 0, 0);
          acc[i][j] = __builtin_amdgcn_mfma_f32_16x16x32_bf16(afh[i], bfl[j], acc[i][j], 0, 0, 0);
          acc[i][j] = __builtin_amdgcn_mfma_f32_16x16x32_bf16(afl[i], bfh[j], acc[i][j], 0, 0, 0);
        }
    }
  }
  #pragma unroll
  for (int i = 0; i < 4; i++){
    int nbase = n0 + wn + i * 16 + quad * 4;
    #pragma unroll
    for (int j = 0; j < 4; j++){
      int m = m0 + wm + j * 16 + lr;
      float yv = yyb[m];
      #pragma unroll
      for (int r = 0; r < 4; r++){
        distb[((size_t)(nbase + r)) * MM + m] = xxb[nbase + r] + yv - 2.0f * acc[i][j][r];
      }
    }
  }
}

// ---- K3: per-row min, softmax denom, scores row (R17/R21) --------------------------
__global__ __launch_bounds__(256) void k_rowstats(const float* __restrict__ dist,
                                                  float* __restrict__ mnA, float* __restrict__ Zr,
                                                  float* __restrict__ scores){
  __shared__ float red[256];
  __shared__ float wmin[4];
  int row = blockIdx.x, b = blockIdx.y, t = threadIdx.x;
  const float* dr = dist + ((size_t)b * NN + row) * MM;
  float* sr = scores + ((size_t)b * NN + row) * MM;
  float d[8];
  float mn = 3.4e38f;
  #pragma unroll
  for (int i = 0; i < 8; i++){ d[i] = sane(dr[t + 256 * i]); mn = fminf(mn, d[i]); }
  mn = blockMinExact(mn, wmin, t);
  float p[8];
  float z = 0.f;
  #pragma unroll
  for (int i = 0; i < 8; i++){ p[i] = expf(mn - d[i]); z += p[i]; }
  z = blockRed(z, red, t, 0);
  float zc = fmaxf(z, 1e-30f);
  if (t == 0){ mnA[b * NN + row] = mn; Zr[b * NN + row] = zc; }
  float iz = 1.0f / zc;
  #pragma unroll
  for (int i = 0; i < 8; i++) sr[t + 256 * i] = p[i] * iz;
}

// ---- K4: fused T/S/refined/rmm/src_corr/loss (R21 structure) -----------------------
__global__ __launch_bounds__(256) void k_fused(const float* __restrict__ dist, const float* __restrict__ scores,
                                               const int* __restrict__ sidx1,
                                               const int* __restrict__ idx2, const float* __restrict__ tgt,
                                               float* __restrict__ s_corr, float* __restrict__ lossr){
  __shared__ float Trow[MM];
  __shared__ float wmin[4];
  int n = blockIdx.x, b = blockIdx.y, t = threadIdx.x;
  const float* distb = dist + (size_t)b * NN * MM;
  const float* scoresb = scores + (size_t)b * NN * MM;
  const int* sidx1b = sidx1 + (size_t)b * NN * KK1;
  const int* idx2b = idx2 + (size_t)b * MM * KK1;
  const float* tgtb = tgt + (size_t)b * 3 * MM;
  float* s_corrb = s_corr + (size_t)b * 3 * NN;
  float* lossb = lossr + b * NN;
  const float* dn_p = distb + (size_t)n * MM;
  float dn[8];
  #pragma unroll
  for (int i = 0; i < 8; i++) dn[i] = sane(dn_p[t + 256 * i]);
  float tacc[8] = {0, 0, 0, 0, 0, 0, 0, 0};
  const int4* i1v = (const int4*)(sidx1b + n * KK1);
  int4 i1a = i1v[0], i1b = i1v[1];
  int rj[7] = {i1a.y & 2047, i1a.z & 2047, i1a.w & 2047,
               i1b.x & 2047, i1b.y & 2047, i1b.z & 2047, i1b.w & 2047};
  #pragma unroll
  for (int j = 0; j < 7; j++){
    const float* srp = scoresb + (size_t)rj[j] * MM;
    #pragma unroll
    for (int i = 0; i < 8; i++) tacc[i] += srp[t + 256 * i];
  }
  #pragma unroll
  for (int i = 0; i < 8; i++) Trow[t + 256 * i] = tacc[i];
  __syncthreads();
  float rloc[8];
  float lmin = 3.4e38f;
  #pragma unroll
  for (int i = 0; i < 8; i++){
    int m = t + 256 * i;
    const int4* ipv = (const int4*)(idx2b + m * KK1);
    int4 ipa = ipv[0], ipb = ipv[1];
    float S = 0.f;
    S += Trow[ipa.y & 2047];
    S += Trow[ipa.z & 2047];
    S += Trow[ipa.w & 2047];
    S += Trow[ipb.x & 2047];
    S += Trow[ipb.y & 2047];
    S += Trow[ipb.z & 2047];
    S += Trow[ipb.w & 2047];
    float rv = sane(expf(1.0f - S / 7.0f) * dn[i]);
    rloc[i] = rv;
    lmin = fminf(lmin, rv);
  }
  // exact min; its barrier also guarantees all Trow reads finished before reuse
  float rmin = blockMinExact(lmin, wmin, t);
  float z = 0.f, s0 = 0.f, s1 = 0.f, s2 = 0.f;
  #pragma unroll
  for (int i = 0; i < 8; i++){
    int m = t + 256 * i;
    float p = expf(rmin - rloc[i]);
    z  += p;
    s0 += tgtb[0 * MM + m] * p;
    s1 += tgtb[1 * MM + m] * p;
    s2 += tgtb[2 * MM + m] * p;
  }
  f32x4 v4; v4.x = z; v4.y = s0; v4.z = s1; v4.w = s2;
  f32x4 r = blockRed4(v4, (f32x4*)Trow, t);   // Trow dead; identical tree order
  if (t == 0){
    float iZ = 1.0f / fmaxf(r.x, 1e-30f);
    s_corrb[0 * NN + n] = r.y * iZ;
    s_corrb[1 * NN + n] = r.z * iZ;
    s_corrb[2 * NN + n] = r.w * iZ;
    lossb[n] = -logf(fminf(iZ, 1.0f) + 1e-15f);  // pred at onehot == rowmax(rmm) == 1/Z
  }
}

// ---- K5: discriminator MLP — R14: scalar-W2 + e-range wave split -------------------
__global__ __launch_bounds__(256, 4) void k_disc(const float* __restrict__ s_corr, const float* __restrict__ src,
                                                 const float* __restrict__ sknn, const int* __restrict__ sidx,
                                                 const float* __restrict__ W1, const float* __restrict__ b1,
                                                 const float* __restrict__ W2, const float* __restrict__ b2,
                                                 const float* __restrict__ W3, const float* __restrict__ b3,
                                                 float* __restrict__ sArr){
  __shared__ float term[64][129];
  int t = threadIdx.x;
  int b = blockIdx.y;
  int p = t & 63;
  int n = blockIdx.x * 4 + (p >> 4);
  int kk = p & 15;
  int eh = t >> 6;
  int nk = sidx[((b * NN + n) * KK) + kk] & 2047;
  float f[6];
  #pragma unroll
  for (int c = 0; c < 3; c++){
    f[c]     = s_corr[(b * 3 + c) * NN + n] - s_corr[(b * 3 + c) * NN + nk];
    f[3 + c] = src[(b * 3 + c) * NN + n] - sknn[((size_t)(b * NN + n) * KK + kk) * 3 + c];
  }
  #define L1D(d) ({ float a_ = b1[(d)];              \
                    a_ += f[0] * W1[(d) * 6 + 0];    \
                    a_ += f[1] * W1[(d) * 6 + 1];    \
                    a_ += f[2] * W1[(d) * 6 + 2];    \
                    a_ += f[3] * W1[(d) * 6 + 3];    \
                    a_ += f[4] * W1[(d) * 6 + 4];    \
                    a_ += f[5] * W1[(d) * 6 + 5];    \
                    fmaxf(a_, 0.f); })
  #define HSET(i) f32x4 h##i;                  \
                  h##i.x = L1D(4 * (i) + 0);   \
                  h##i.y = L1D(4 * (i) + 1);   \
                  h##i.z = L1D(4 * (i) + 2);   \
                  h##i.w = L1D(4 * (i) + 3);
  HSET(0) HSET(1) HSET(2) HSET(3) HSET(4) HSET(5) HSET(6) HSET(7)
  HSET(8) HSET(9) HSET(10) HSET(11) HSET(12) HSET(13) HSET(14) HSET(15)
  #undef HSET
  #undef L1D
  int e0 = __builtin_amdgcn_readfirstlane(eh * 32);
  for (int j = 0; j < 32; j++){
    int e = e0 + j;
    float a = b2[e];
    const f32x4* w4 = (const f32x4*)&W2[e * 64];
    #define QSTEP(i) { f32x4 wv = w4[i]; a += wv.x * h##i.x + wv.y * h##i.y + wv.z * h##i.z + wv.w * h##i.w; }
    QSTEP(0) QSTEP(1) QSTEP(2) QSTEP(3) QSTEP(4) QSTEP(5) QSTEP(6) QSTEP(7)
    QSTEP(8) QSTEP(9) QSTEP(10) QSTEP(11) QSTEP(12) QSTEP(13) QSTEP(14) QSTEP(15)
    #undef QSTEP
    term[p][e] = fmaxf(a, 0.f);
  }
  __syncthreads();
  if (t < 64){
    float sacc = b3[0];
    #pragma unroll 4
    for (int e = 0; e < 128; e++) sacc += W3[e] * term[t][e];
    if (!(fabsf(sacc) < 1e30f)) sacc = -1e30f;
    #pragma unroll
    for (int off = 1; off < 16; off <<= 1) sacc = fmaxf(sacc, __shfl_xor(sacc, off, 16));
    if (kk == 0) sArr[b * NN + n] = sacc;
  }
}

// ---- K6+K7+K8 merged. R23: SVD tail in f32 (threshold 1e-6f, cap 30 sweeps) and
// rigid reductions via blockRed4 (bit-identical component order, 120 -> ~50 barriers).
// R22 post-mortem: named-scalar f64 SVD was 53us — single-lane f64 div/sqrt chains
// with zero latency hiding dominate. R/t feed ONLY continuous outputs (thr 0.128);
// f32 SVD error ~1e-5, and R = sum_j v_j (H v_j)^T / sigma_j is gauge-invariant in
// near-degenerate subspaces -> no conditioning blowup. Discrete paths untouched.
__device__ __forceinline__ double det3d(const double A[3][3]){
  return A[0][0] * (A[1][1] * A[2][2] - A[1][2] * A[2][1])
       - A[0][1] * (A[1][0] * A[2][2] - A[1][2] * A[2][0])
       + A[0][2] * (A[1][0] * A[2][1] - A[1][1] * A[2][0]);
}

__global__ __launch_bounds__(256) void k_rankrig(const float* __restrict__ sArr, const float* __restrict__ src,
                                                 const float* __restrict__ s_corr, int* __restrict__ topi,
                                                 float* __restrict__ Rt, float* __restrict__ out){
  __shared__ float wrow[NN];
  __shared__ float red[256];
  __shared__ f32x4 red4[256];
  __shared__ int pc[4][64];
  int b = blockIdx.y, t = threadIdx.x;
  // ---- softmax (verbatim k_softw) -> wrow (feeds rank -> topi: DISCRETE, verbatim) --
  const float* sp = sArr + b * NN;
  float sv[8];
  float mx = -3.4e38f;
  #pragma unroll
  for (int i = 0; i < 8; i++){
    float v = sp[t + 256 * i];
    if (!(fabsf(v) < 1e30f)) v = -1e30f;
    sv[i] = v; mx = fmaxf(mx, v);
  }
  mx = blockRed(mx, red, t, 2);
  float z = 0.f;
  #pragma unroll
  for (int i = 0; i < 8; i++) z += expf(sv[i] - mx);
  z = blockRed(z, red, t, 0);
  float iz = 1.0f / fmaxf(z, 1e-30f);
  #pragma unroll
  for (int i = 0; i < 8; i++) wrow[t + 256 * i] = expf(sv[i] - mx) * iz;
  __syncthreads();
  // ---- rank (verbatim R15 body) ----
  int tn = t & 63, tj = t >> 6;
  int n = blockIdx.x * 64 + tn;
  float wn = wrow[n];
  int j0 = tj * 512;
  const f32x4* w4 = (const f32x4*)&wrow[j0];
  int cnt = 0;
  #pragma unroll 4
  for (int q = 0; q < 128; q++){
    f32x4 wv = w4[q];
    int j = j0 + q * 4;
    cnt += (wv.x > wn) || ((wv.x == wn) && (j + 0 < n));
    cnt += (wv.y > wn) || ((wv.y == wn) && (j + 1 < n));
    cnt += (wv.z > wn) || ((wv.z == wn) && (j + 2 < n));
    cnt += (wv.w > wn) || ((wv.w == wn) && (j + 3 < n));
  }
  pc[tj][tn] = cnt;
  __syncthreads();
  if (t < 64){
    int c = pc[0][t] + pc[1][t] + pc[2][t] + pc[3][t];
    if (c < KEY) topi[b * KEY + c] = blockIdx.x * 64 + t;
  }
  if (blockIdx.x != 0) return;
  // ---- rigid: centroids + H via blockRed4 (bit-identical sums, fewer barriers) ----
  float wsum = 0, a0 = 0, a1 = 0, a2 = 0, c0 = 0, c1 = 0, c2 = 0;
  for (int n2 = t; n2 < NN; n2 += 256){
    float wv = wrow[n2];
    float s0 = src[(b * 3 + 0) * NN + n2];
    float s1 = src[(b * 3 + 1) * NN + n2];
    float s2 = src[(b * 3 + 2) * NN + n2];
    float q0 = s_corr[(b * 3 + 0) * NN + n2];
    float q1 = s_corr[(b * 3 + 1) * NN + n2];
    float q2 = s_corr[(b * 3 + 2) * NN + n2];
    wsum += wv; a0 += wv * s0; a1 += wv * s1; a2 += wv * s2;
    c0 += wv * q0; c1 += wv * q1; c2 += wv * q2;
  }
  f32x4 pk1; pk1.x = wsum; pk1.y = a0; pk1.z = a1; pk1.w = a2;
  pk1 = blockRed4(pk1, red4, t);
  f32x4 pk2; pk2.x = c0; pk2.y = c1; pk2.z = c2; pk2.w = 0.f;
  pk2 = blockRed4(pk2, red4, t);
  wsum = pk1.x; a0 = pk1.y; a1 = pk1.z; a2 = pk1.w;
  c0 = pk2.x; c1 = pk2.y; c2 = pk2.z;
  float inv = 1.0f / fmaxf(wsum, 1e-30f);
  float cs0 = a0 * inv, cs1 = a1 * inv, cs2 = a2 * inv;
  float ct0 = c0 * inv, ct1 = c1 * inv, ct2 = c2 * inv;
  float h[9] = {0, 0, 0, 0, 0, 0, 0, 0, 0};
  for (int n2 = t; n2 < NN; n2 += 256){
    float wv = wrow[n2];
    float ds0 = src[(b * 3 + 0) * NN + n2] - cs0;
    float ds1 = src[(b * 3 + 1) * NN + n2] - cs1;
    float ds2 = src[(b * 3 + 2) * NN + n2] - cs2;
    float dc0 = s_corr[(b * 3 + 0) * NN + n2] - ct0;
    float dc1 = s_corr[(b * 3 + 1) * NN + n2] - ct1;
    float dc2 = s_corr[(b * 3 + 2) * NN + n2] - ct2;
    h[0] += wv * ds0 * dc0; h[1] += wv * ds0 * dc1; h[2] += wv * ds0 * dc2;
    h[3] += wv * ds1 * dc0; h[4] += wv * ds1 * dc1; h[5] += wv * ds1 * dc2;
    h[6] += wv * ds2 * dc0; h[7] += wv * ds2 * dc1; h[8] += wv * ds2 * dc2;
  }
  f32x4 ph1; ph1.x = h[0]; ph1.y = h[1]; ph1.z = h[2]; ph1.w = h[3];
  ph1 = blockRed4(ph1, red4, t);
  f32x4 ph2; ph2.x = h[4]; ph2.y = h[5]; ph2.z = h[6]; ph2.w = h[7];
  ph2 = blockRed4(ph2, red4, t);
  float h8 = blockRed(h[8], red, t, 0);
  if (t == 0){
    // ---- all-register 3x3 SVD, f32 (static pivot enumeration) ----
    float Hm00 = ph1.x, Hm01 = ph1.y, Hm02 = ph1.z;
    float Hm10 = ph1.w, Hm11 = ph2.x, Hm12 = ph2.y;
    float Hm20 = ph2.z, Hm21 = ph2.w, Hm22 = h8;
    float k00 = Hm00 * Hm00 + Hm10 * Hm10 + Hm20 * Hm20;
    float k01 = Hm00 * Hm01 + Hm10 * Hm11 + Hm20 * Hm21;
    float k02 = Hm00 * Hm02 + Hm10 * Hm12 + Hm20 * Hm22;
    float k10 = k01, k11 = Hm01 * Hm01 + Hm11 * Hm11 + Hm21 * Hm21;
    float k12 = Hm01 * Hm02 + Hm11 * Hm12 + Hm21 * Hm22;
    float k20 = k02, k21 = k12;
    float k22 = Hm02 * Hm02 + Hm12 * Hm12 + Hm22 * Hm22;
    float v00 = 1, v01 = 0, v02 = 0, v10 = 0, v11 = 1, v12 = 0, v20 = 0, v21 = 0, v22 = 1;
    float ksc = fabsf(k00) + fabsf(k11) + fabsf(k22) + 1e-30f;
    #define ROT2(A, B) { float ra = A, rb = B; A = cc2 * ra - sn * rb; B = sn * ra + cc2 * rb; }
    for (int sweep = 0; sweep < 30; sweep++){
      float m01 = fabsf(k01), m02 = fabsf(k02), m12 = fabsf(k12);
      int cse = 0; float mx2 = m01;
      if (m02 > mx2){ mx2 = m02; cse = 1; }
      if (m12 > mx2){ mx2 = m12; cse = 2; }
      if (mx2 <= 1e-6f * ksc) break;
      float app, aqq, apq;
      if (cse == 0){ app = k00; aqq = k11; apq = k01; }
      else if (cse == 1){ app = k00; aqq = k22; apq = k02; }
      else { app = k11; aqq = k22; apq = k12; }
      float tau = (aqq - app) / (2.0f * apq);
      float tt = ((tau >= 0) ? 1.0f : -1.0f) / (fabsf(tau) + sqrtf(1.0f + tau * tau));
      float cc2 = 1.0f / sqrtf(1.0f + tt * tt), sn = tt * cc2;
      if (cse == 0){        // (p,q)=(0,1)
        ROT2(k00, k01) ROT2(k10, k11) ROT2(k20, k21)   // cols p,q
        ROT2(k00, k10) ROT2(k01, k11) ROT2(k02, k12)   // rows p,q
        ROT2(v00, v01) ROT2(v10, v11) ROT2(v20, v21)
      } else if (cse == 1){ // (p,q)=(0,2)
        ROT2(k00, k02) ROT2(k10, k12) ROT2(k20, k22)
        ROT2(k00, k20) ROT2(k01, k21) ROT2(k02, k22)
        ROT2(v00, v02) ROT2(v10, v12) ROT2(v20, v22)
      } else {              // (p,q)=(1,2)
        ROT2(k01, k02) ROT2(k11, k12) ROT2(k21, k22)
        ROT2(k10, k20) ROT2(k11, k21) ROT2(k12, k22)
        ROT2(v01, v02) ROT2(v11, v12) ROT2(v21, v22)
      }
    }
    #undef ROT2
    // sort eigenvalues desc, carrying indices
    float l0 = k00, l1 = k11, l2 = k22; int id0 = 0, id1 = 1, id2 = 2;
    float lt; int it;
    if (l0 < l1){ lt = l0; l0 = l1; l1 = lt; it = id0; id0 = id1; id1 = it; }
    if (l0 < l2){ lt = l0; l0 = l2; l2 = lt; it = id0; id0 = id2; id2 = it; }
    if (l1 < l2){ lt = l1; l1 = l2; l2 = lt; it = id1; id1 = id2; id2 = it; }
    float Vs00, Vs10, Vs20, Vs01, Vs11, Vs21, Vs02, Vs12, Vs22;
    float u00 = 0, u10 = 0, u20 = 0, u01 = 0, u11 = 0, u21 = 0, u02 = 0, u12 = 0, u22 = 0;
    #define GETCOL(j, cA, cB, cC) { if ((j) == 0){ cA = v00; cB = v10; cC = v20; } \
                                    else if ((j) == 1){ cA = v01; cB = v11; cC = v21; } \
                                    else { cA = v02; cB = v12; cC = v22; } }
    // jj = 0
    {
      float cA, cB, cC; GETCOL(id0, cA, cB, cC);
      Vs00 = cA; Vs10 = cB; Vs20 = cC;
      float uu0 = Hm00 * cA + Hm01 * cB + Hm02 * cC;
      float uu1 = Hm10 * cA + Hm11 * cB + Hm12 * cC;
      float uu2 = Hm20 * cA + Hm21 * cB + Hm22 * cC;
      float nrm = sqrtf(uu0 * uu0 + uu1 * uu1 + uu2 * uu2);
      if (nrm > 1e-20f){ u00 = uu0 / nrm; u10 = uu1 / nrm; u20 = uu2 / nrm; }
      else { u00 = 1; u10 = 0; u20 = 0; }
    }
    // jj = 1
    {
      float cA, cB, cC; GETCOL(id1, cA, cB, cC);
      Vs01 = cA; Vs11 = cB; Vs21 = cC;
      float uu0 = Hm00 * cA + Hm01 * cB + Hm02 * cC;
      float uu1 = Hm10 * cA + Hm11 * cB + Hm12 * cC;
      float uu2 = Hm20 * cA + Hm21 * cB + Hm22 * cC;
      float nrm = sqrtf(uu0 * uu0 + uu1 * uu1 + uu2 * uu2);
      if (nrm > 1e-20f){ u01 = uu0 / nrm; u11 = uu1 / nrm; u21 = uu2 / nrm; }
      else {
        float x0 = u10 * u21 - u20 * u11;
        float x1 = u20 * u01 - u00 * u21;
        float x2 = u00 * u11 - u10 * u01;
        float nn2 = sqrtf(x0 * x0 + x1 * x1 + x2 * x2);
        if (nn2 < 1e-20f){ x0 = 1; x1 = 0; x2 = 0; nn2 = 1; }
        u01 = x0 / nn2; u11 = x1 / nn2; u21 = x2 / nn2;
      }
    }
    // jj = 2
    {
      float cA, cB, cC; GETCOL(id2, cA, cB, cC);
      Vs02 = cA; Vs12 = cB; Vs22 = cC;
      float uu0 = Hm00 * cA + Hm01 * cB + Hm02 * cC;
      float uu1 = Hm10 * cA + Hm11 * cB + Hm12 * cC;
      float uu2 = Hm20 * cA + Hm21 * cB + Hm22 * cC;
      float nrm = sqrtf(uu0 * uu0 + uu1 * uu1 + uu2 * uu2);
      if (nrm > 1e-20f){ u02 = uu0 / nrm; u12 = uu1 / nrm; u22 = uu2 / nrm; }
      else {
        float x0 = u10 * u21 - u20 * u11;
        float x1 = u20 * u01 - u00 * u21;
        float x2 = u00 * u11 - u10 * u01;
        float nn2 = sqrtf(x0 * x0 + x1 * x1 + x2 * x2);
        if (nn2 < 1e-20f){ x0 = 1; x1 = 0; x2 = 0; nn2 = 1; }
        u02 = x0 / nn2; u12 = x1 / nn2; u22 = x2 / nn2;
      }
    }
    #undef GETCOL
    float ddU = u00 * (u11 * u22 - u12 * u21) - u01 * (u10 * u22 - u12 * u20) + u02 * (u10 * u21 - u11 * u20);
    float ddV = Vs00 * (Vs11 * Vs22 - Vs12 * Vs21) - Vs01 * (Vs10 * Vs22 - Vs12 * Vs20) + Vs02 * (Vs10 * Vs21 - Vs11 * Vs20);
    float dd = ddU * ddV;
    float Rm00 = Vs00 * u00 + Vs01 * u01 + dd * Vs02 * u02;
    float Rm01 = Vs00 * u10 + Vs01 * u11 + dd * Vs02 * u12;
    float Rm02 = Vs00 * u20 + Vs01 * u21 + dd * Vs02 * u22;
    float Rm10 = Vs10 * u00 + Vs11 * u01 + dd * Vs12 * u02;
    float Rm11 = Vs10 * u10 + Vs11 * u11 + dd * Vs12 * u12;
    float Rm12 = Vs10 * u20 + Vs11 * u21 + dd * Vs12 * u22;
    float Rm20 = Vs20 * u00 + Vs21 * u01 + dd * Vs22 * u02;
    float Rm21 = Vs20 * u10 + Vs21 * u11 + dd * Vs22 * u12;
    float Rm22 = Vs20 * u20 + Vs21 * u21 + dd * Vs22 * u22;
    float tv0 = ct0 - (Rm00 * cs0 + Rm01 * cs1 + Rm02 * cs2);
    float tv1 = ct1 - (Rm10 * cs0 + Rm11 * cs1 + Rm12 * cs2);
    float tv2 = ct2 - (Rm20 * cs0 + Rm21 * cs1 + Rm22 * cs2);
    Rt[b * 12 + 0] = Rm00; out[b * 9 + 0] = Rm00;
    Rt[b * 12 + 1] = Rm01; out[b * 9 + 1] = Rm01;
    Rt[b * 12 + 2] = Rm02; out[b * 9 + 2] = Rm02;
    Rt[b * 12 + 3] = Rm10; out[b * 9 + 3] = Rm10;
    Rt[b * 12 + 4] = Rm11; out[b * 9 + 4] = Rm11;
    Rt[b * 12 + 5] = Rm12; out[b * 9 + 5] = Rm12;
    Rt[b * 12 + 6] = Rm20; out[b * 9 + 6] = Rm20;
    Rt[b * 12 + 7] = Rm21; out[b * 9 + 7] = Rm21;
    Rt[b * 12 + 8] = Rm22; out[b * 9 + 8] = Rm22;
    Rt[b * 12 + 9]  = tv0; out[18 + b * 3 + 0] = tv0;
    Rt[b * 12 + 10] = tv1; out[18 + b * 3 + 1] = tv1;
    Rt[b * 12 + 11] = tv2; out[18 + b * 3 + 2] = tv2;
  }
}

// ---- K10 (+K11 merged): keypoint gathers; block x==64,b==0 computes loss_scl -------
__global__ __launch_bounds__(256) void k_out(const int* __restrict__ topi, const int* __restrict__ sidx,
                                             const float* __restrict__ src, const float* __restrict__ s_corr,
                                             const float* __restrict__ Rt, const float* __restrict__ loss_row,
                                             float* __restrict__ out){
  __shared__ float red[256];
  int b = blockIdx.y, t = threadIdx.x;
  if (blockIdx.x == 64){
    if (b != 0) return;
    float acc = 0.f;
    for (int i = t; i < BB * KEY; i += 256){
      int bb = i >> 10, r = i & 1023;
      int n = topi[bb * KEY + r] & 2047;
      acc += loss_row[bb * NN + n];
    }
    acc = blockRed(acc, red, t, 0);
    if (t == 0) out[208920] = acc / 2048.0f;
    return;
  }
  int rr = t >> 4, kk = t & 15;
  int r = blockIdx.x * 16 + rr;
  int ns = topi[b * KEY + r] & 2047;
  int nk = sidx[(b * NN + ns) * KK + kk] & 2047;
  const float* R = Rt + b * 12;
  float sns0 = src[(b * 3 + 0) * NN + ns];
  float sns1 = src[(b * 3 + 1) * NN + ns];
  float sns2 = src[(b * 3 + 2) * NN + ns];
  float snk0 = src[(b * 3 + 0) * NN + nk];
  float snk1 = src[(b * 3 + 1) * NN + nk];
  float snk2 = src[(b * 3 + 2) * NN + nk];
  float* o_sk  = out + 24;
  float* o_tk  = out + 6168;
  float* o_skk = out + 12312;
  float* o_tkk = out + 110616;
  #pragma unroll
  for (int c = 0; c < 3; c++){
    float cv  = s_corr[(b * 3 + c) * NN + ns];
    float ck  = s_corr[(b * 3 + c) * NN + nk];
    o_tkk[(((b * 3 + c) * KEY + r) * KK) + kk] = cv - ck;
    float sv  = R[c * 3 + 0] * sns0 + R[c * 3 + 1] * sns1 + R[c * 3 + 2] * sns2 + R[9 + c];
    float sk2 = R[c * 3 + 0] * snk0 + R[c * 3 + 1] * snk1 + R[c * 3 + 2] * snk2 + R[9 + c];
    o_skk[(((b * 3 + c) * KEY + r) * KK) + kk] = sv - sk2;
    if (kk == 0){
      o_sk[(b * 3 + c) * KEY + r] = sns0 * (c == 0) + sns1 * (c == 1) + sns2 * (c == 2);
      o_tk[(b * 3 + c) * KEY + r] = cv;
    }
  }
}

extern "C" void kernel_launch(void* const* d_in, const int* in_sizes, int n_in,
                              void* d_out, int out_size, void* d_ws, size_t ws_size,
                              hipStream_t stream){
  const float* src  = (const float*)d_in[0];
  const float* tgt  = (const float*)d_in[1];
  const float* semb = (const float*)d_in[2];
  const float* temb = (const float*)d_in[3];
  const float* sknn = (const float*)d_in[4];
  const float* W1 = (const float*)d_in[6];
  const float* b1 = (const float*)d_in[7];
  const float* W2 = (const float*)d_in[8];
  const float* b2 = (const float*)d_in[9];
  const float* W3 = (const float*)d_in[10];
  const float* b3 = (const float*)d_in[11];
  const int* sidx  = (const int*)d_in[12];
  const int* sidx1 = (const int*)d_in[13];
  const int* idx2  = (const int*)d_in[14];
  float* out = (float*)d_out;

  // workspace layout (peak ~84 MB; harness allocates 256 MiB per fill evidence)
  char* w = (char*)d_ws;
  u16* Ah = (u16*)(w);                               // 4 MB each (B,N,C) bf16 split
  u16* Al = Ah + (size_t)BB * NN * CC;
  u16* Bh = Al + (size_t)BB * NN * CC;
  u16* Bl = Bh + (size_t)BB * MM * CC;
  float* dist = (float*)(Bl + (size_t)BB * MM * CC); // 33.55 MB (B,N,M) f32
  float* scores = dist + (size_t)BB * NN * MM;       // 33.55 MB (B,N,M) f32
  char* tail = (char*)(scores + (size_t)BB * NN * MM);
  float* xx = (float*)tail;                          // B*N
  float* yy = xx + BB * NN;                          // B*M
  float* mnA = yy + BB * MM;                         // B*N
  float* Zr = mnA + BB * NN;                         // B*N
  float* s_corr = Zr + BB * NN;                      // B*3*N
  float* loss_row = s_corr + BB * 3 * NN;            // B*N
  float* sArr = loss_row + BB * NN;                  // B*N
  int* topi = (int*)(sArr + BB * NN);                // B*KEY
  float* Rt = (float*)(topi + BB * KEY);             // B*12

  k_trans<<<dim3(16, 64, 4), dim3(32, 8), 0, stream>>>(semb, temb, Ah, Al, Bh, Bl);
  k_sq<<<dim3(16, 2), 256, 0, stream>>>(semb, temb, xx, yy);
  k_gemm<<<dim3(16, 16, BB), 256, 0, stream>>>(Ah, Al, Bh, Bl, xx, yy, dist);
  k_rowstats<<<dim3(NN, BB), 256, 0, stream>>>(dist, mnA, Zr, scores);
  k_fused<<<dim3(NN, BB), 256, 0, stream>>>(dist, scores, sidx1, idx2, tgt, s_corr, loss_row);
  k_disc<<<dim3(NN / 4, BB), 256, 0, stream>>>(s_corr, src, sknn, sidx, W1, b1, W2, b2, W3, b3, sArr);
  k_rankrig<<<dim3(32, BB), 256, 0, stream>>>(sArr, src, s_corr, topi, Rt, out);
  k_out<<<dim3(65, BB), 256, 0, stream>>>(topi, sidx, src, s_corr, Rt, loss_row, out);
}

// Round 12
// 260.036 us; speedup vs baseline: 2.1211x; 1.0072x over previous
//
#include <hip/hip_runtime.h>
#include <stdint.h>

typedef unsigned short u16;

#define BB 2
#define NN 2048
#define MM 2048
#define CC 512
#define KK 16
#define KK1 8
#define KEY 1024

typedef __attribute__((ext_vector_type(8))) short bf16x8;
typedef __attribute__((ext_vector_type(4))) float f32x4;

__device__ __forceinline__ float b2f(u16 u){ return __uint_as_float(((uint32_t)u) << 16); }
__device__ __forceinline__ u16 f2b(float f){
  uint32_t x = __float_as_uint(f);
  uint32_t r = x + 0x7FFFu + ((x >> 16) & 1u);
  return (u16)(r >> 16);
}
__device__ __forceinline__ float sane(float v){ return (fabsf(v) < 1e30f) ? v : 1e30f; }

// async global->LDS 16B per lane: LDS dest = wave-uniform base + lane*16 (HW rule)
__device__ __forceinline__ void gload_lds16(const u16* g, u16* l){
  __builtin_amdgcn_global_load_lds((const __attribute__((address_space(1))) uint32_t*)g,
                                   (__attribute__((address_space(3))) uint32_t*)l, 16, 0, 0);
}

// all-thread block reduction, 256 threads. op: 0=sum 1=min 2=max
__device__ __forceinline__ float blockRed(float v, float* red, int t, int op){
  red[t] = v; __syncthreads();
  #pragma unroll
  for (int s = 128; s > 0; s >>= 1){
    if (t < s){
      float a = red[t], b = red[t + s];
      red[t] = (op == 0) ? (a + b) : ((op == 1) ? fminf(a, b) : fmaxf(a, b));
    }
    __syncthreads();
  }
  float r = red[0]; __syncthreads();
  return r;
}

// 4-wide sum tree; per-component order identical to 4 separate blockReds -> each
// component's result is bit-identical to blockRed(v, red, t, 0).
__device__ __forceinline__ f32x4 blockRed4(f32x4 v, f32x4* red4, int t){
  red4[t] = v; __syncthreads();
  #pragma unroll
  for (int s = 128; s > 0; s >>= 1){
    if (t < s){
      f32x4 a = red4[t], c = red4[t + s];
      a.x += c.x; a.y += c.y; a.z += c.z; a.w += c.w;
      red4[t] = a;
    }
    __syncthreads();
  }
  f32x4 r = red4[0]; __syncthreads();
  return r;
}

// exact block min (min is associative+commutative; inputs sane()-filtered so no NaN;
// ±0 ties only feed expf(x-y) where both zero signs give identical bits). 1 barrier.
__device__ __forceinline__ float blockMinExact(float v, float* wmin, int t){
  #pragma unroll
  for (int off = 1; off < 64; off <<= 1) v = fminf(v, __shfl_xor(v, off));
  if ((t & 63) == 0) wmin[t >> 6] = v;
  __syncthreads();
  return fminf(fminf(wmin[0], wmin[1]), fminf(wmin[2], wmin[3]));
}

// ---- K0: transpose f32 (B,C,N) -> split-bf16 (B,N,C) hi/lo pairs -------------------
__global__ __launch_bounds__(256) void k_trans(const float* __restrict__ semb, const float* __restrict__ temb,
                                               u16* __restrict__ Ah, u16* __restrict__ Al,
                                               u16* __restrict__ Bh, u16* __restrict__ Bl){
  __shared__ float tile[32][33];
  int b = blockIdx.z & 1, which = blockIdx.z >> 1;
  const float* in = which ? temb : semb;
  u16* oh = which ? Bh : Ah;
  u16* ol = which ? Bl : Al;
  int c0 = blockIdx.x * 32, n0 = blockIdx.y * 32;
  int tx = threadIdx.x, ty = threadIdx.y;
  #pragma unroll
  for (int i = 0; i < 4; i++){
    int r = ty + 8 * i;
    tile[r][tx] = in[((b * CC + c0 + r) * NN) + n0 + tx];
  }
  __syncthreads();
  #pragma unroll
  for (int i = 0; i < 4; i++){
    int r = ty + 8 * i;
    float v = tile[tx][r];
    u16 hi = f2b(v);
    float lo = v - b2f(hi);
    size_t o = ((size_t)(b * NN + n0 + r) * CC) + c0 + tx;
    oh[o] = hi;
    ol[o] = f2b(lo);
  }
}

// ---- K1: exact f32 row squared norms (R18 lesson: no FP change ahead of a discrete
// selection; only bit-identical transforms admissible) -------------------------------
__global__ __launch_bounds__(256) void k_sq(const float* __restrict__ semb, const float* __restrict__ temb,
                                            float* __restrict__ xx, float* __restrict__ yy){
  int which = blockIdx.y;
  const float* in = which ? temb : semb;
  float* out = which ? yy : xx;
  int gid = blockIdx.x * 256 + threadIdx.x;   // 0..4095
  int b = gid >> 11, n = gid & 2047;
  float acc = 0.f;
  for (int c = 0; c < CC; c++){
    float v = in[((size_t)(b * CC + c)) * NN + n];
    acc += v * v;
  }
  out[gid] = acc;
}

// ---- K2: dist = xx - 2*A.B^T + yy, split-bf16 MFMA; gload_lds staging (R20) --------
__global__ __launch_bounds__(256) void k_gemm(const u16* __restrict__ Ah, const u16* __restrict__ Al,
                                              const u16* __restrict__ Bh, const u16* __restrict__ Bl,
                                              const float* __restrict__ xx, const float* __restrict__ yy,
                                              float* __restrict__ dist){
  __shared__ __align__(16) u16 lAh[128 * 64];
  __shared__ __align__(16) u16 lAl[128 * 64];
  __shared__ __align__(16) u16 lBh[128 * 64];
  __shared__ __align__(16) u16 lBl[128 * 64];
  int bz = blockIdx.z;
  const u16* Ahb = Ah + (size_t)bz * NN * CC;
  const u16* Alb = Al + (size_t)bz * NN * CC;
  const u16* Bhb = Bh + (size_t)bz * MM * CC;
  const u16* Blb = Bl + (size_t)bz * MM * CC;
  const float* xxb = xx + bz * NN;
  const float* yyb = yy + bz * MM;
  float* distb = dist + (size_t)bz * NN * MM;
  int n0 = blockIdx.y * 128, m0 = blockIdx.x * 128;
  int t = threadIdx.x;
  f32x4 acc[4][4];
  #pragma unroll
  for (int i = 0; i < 4; i++)
    #pragma unroll
    for (int j = 0; j < 4; j++){ f32x4 z = {0.f, 0.f, 0.f, 0.f}; acc[i][j] = z; }
  int w = t >> 6, lane = t & 63, lr = lane & 15, quad = lane >> 4;
  int wn = (w >> 1) * 64, wm = (w & 1) * 64;
  for (int kt = 0; kt < 8; kt++){
    int k0 = kt * 64;
    __syncthreads();
    #pragma unroll
    for (int s = 0; s < 4; s++){
      int ch = t + 256 * s;
      int rn = ch >> 3, k8 = (ch & 7) * 8;
      size_t oa = (size_t)(n0 + rn) * CC + k0 + k8;
      size_t ob = (size_t)(m0 + rn) * CC + k0 + k8;
      int ldsoff = ((t >> 6) * 64 + 256 * s) * 8;   // wave-uniform (u16 elems)
      gload_lds16(Ahb + oa, &lAh[ldsoff]);
      gload_lds16(Alb + oa, &lAl[ldsoff]);
      gload_lds16(Bhb + ob, &lBh[ldsoff]);
      gload_lds16(Blb + ob, &lBl[ldsoff]);
    }
    __syncthreads();
    #pragma unroll
    for (int kk = 0; kk < 2; kk++){
      int off = kk * 32 + quad * 8;
      bf16x8 afh[4], afl[4], bfh[4], bfl[4];
      #pragma unroll
      for (int i = 0; i < 4; i++){
        int ra = (wn + i * 16 + lr) * 64 + off;
        afh[i] = *(const bf16x8*)&lAh[ra];
        afl[i] = *(const bf16x8*)&lAl[ra];
      }
      #pragma unroll
      for (int j = 0; j < 4; j++){
        int rb = (wm + j * 16 + lr) * 64 + off;
        bfh[j] = *(const bf16x8*)&lBh[rb];
        bfl[j] = *(const bf16x8*)&lBl[rb];
      }
      #pragma unroll
      for (int i = 0; i < 4; i++)
        #pragma unroll
        for (int j = 0; j < 4; j++){
          acc[i][j] = __builtin_amdgcn_mfma_f32_16x16x32_bf16(afh[i], bfh[j], acc[i][j], 0, 0, 0);
          acc[i][j] = __builtin_amdgcn_mfma_f32_16x16x32_bf16(afh[i], bfl[j], acc[i][j], 0, 0, 0);
          acc[i][j] = __builtin_amdgcn_mfma_f32_16x16x32_bf16(afl[i], bfh[j], acc[i][j], 0, 0, 0);
        }
    }
  }
  #pragma unroll
  for (int i = 0; i < 4; i++){
    int nbase = n0 + wn + i * 16 + quad * 4;
    #pragma unroll
    for (int j = 0; j < 4; j++){
      int m = m0 + wm + j * 16 + lr;
      float yv = yyb[m];
      #pragma unroll
      for (int r = 0; r < 4; r++){
        distb[((size_t)(nbase + r)) * MM + m] = xxb[nbase + r] + yv - 2.0f * acc[i][j][r];
      }
    }
  }
}

// ---- K3: per-row min, softmax denom, scores row. R24: __launch_bounds__(256,4)
// raises the VGPR cap (was compiled tight) so the 8 row loads + 8 stores pipeline;
// regalloc/scheduling do not alter the FP DAG -> bit-identical. ---------------------
__global__ __launch_bounds__(256, 4) void k_rowstats(const float* __restrict__ dist,
                                                     float* __restrict__ mnA, float* __restrict__ Zr,
                                                     float* __restrict__ scores){
  __shared__ float red[256];
  __shared__ float wmin[4];
  int row = blockIdx.x, b = blockIdx.y, t = threadIdx.x;
  const float* dr = dist + ((size_t)b * NN + row) * MM;
  float* sr = scores + ((size_t)b * NN + row) * MM;
  float d[8];
  float mn = 3.4e38f;
  #pragma unroll
  for (int i = 0; i < 8; i++){ d[i] = sane(dr[t + 256 * i]); mn = fminf(mn, d[i]); }
  mn = blockMinExact(mn, wmin, t);
  float p[8];
  float z = 0.f;
  #pragma unroll
  for (int i = 0; i < 8; i++){ p[i] = expf(mn - d[i]); z += p[i]; }
  z = blockRed(z, red, t, 0);
  float zc = fmaxf(z, 1e-30f);
  if (t == 0){ mnA[b * NN + row] = mn; Zr[b * NN + row] = zc; }
  float iz = 1.0f / zc;
  #pragma unroll
  for (int i = 0; i < 8; i++) sr[t + 256 * i] = p[i] * iz;
}

// ---- K4: fused T/S/refined/rmm/src_corr/loss. R24 diagnosis: VGPR_Count was 32 with
// >=24 live data regs -> the ~56 independent scores-row loads could NOT stay in
// flight -> latency-bound at 2.6 TB/s (33% HBM) despite 69% occupancy.
// __launch_bounds__(256,4) permits up to 128 VGPR while guaranteeing 16 waves/CU.
// Pure regalloc/scheduling change: FP DAG untouched -> bit-identical outputs. -------
__global__ __launch_bounds__(256, 4) void k_fused(const float* __restrict__ dist, const float* __restrict__ scores,
                                                  const int* __restrict__ sidx1,
                                                  const int* __restrict__ idx2, const float* __restrict__ tgt,
                                                  float* __restrict__ s_corr, float* __restrict__ lossr){
  __shared__ float Trow[MM];
  __shared__ float wmin[4];
  int n = blockIdx.x, b = blockIdx.y, t = threadIdx.x;
  const float* distb = dist + (size_t)b * NN * MM;
  const float* scoresb = scores + (size_t)b * NN * MM;
  const int* sidx1b = sidx1 + (size_t)b * NN * KK1;
  const int* idx2b = idx2 + (size_t)b * MM * KK1;
  const float* tgtb = tgt + (size_t)b * 3 * MM;
  float* s_corrb = s_corr + (size_t)b * 3 * NN;
  float* lossb = lossr + b * NN;
  const float* dn_p = distb + (size_t)n * MM;
  float dn[8];
  #pragma unroll
  for (int i = 0; i < 8; i++) dn[i] = sane(dn_p[t + 256 * i]);
  float tacc[8] = {0, 0, 0, 0, 0, 0, 0, 0};
  const int4* i1v = (const int4*)(sidx1b + n * KK1);
  int4 i1a = i1v[0], i1b = i1v[1];
  int rj[7] = {i1a.y & 2047, i1a.z & 2047, i1a.w & 2047,
               i1b.x & 2047, i1b.y & 2047, i1b.z & 2047, i1b.w & 2047};
  #pragma unroll
  for (int j = 0; j < 7; j++){
    const float* srp = scoresb + (size_t)rj[j] * MM;
    #pragma unroll
    for (int i = 0; i < 8; i++) tacc[i] += srp[t + 256 * i];
  }
  #pragma unroll
  for (int i = 0; i < 8; i++) Trow[t + 256 * i] = tacc[i];
  __syncthreads();
  float rloc[8];
  float lmin = 3.4e38f;
  #pragma unroll
  for (int i = 0; i < 8; i++){
    int m = t + 256 * i;
    const int4* ipv = (const int4*)(idx2b + m * KK1);
    int4 ipa = ipv[0], ipb = ipv[1];
    float S = 0.f;
    S += Trow[ipa.y & 2047];
    S += Trow[ipa.z & 2047];
    S += Trow[ipa.w & 2047];
    S += Trow[ipb.x & 2047];
    S += Trow[ipb.y & 2047];
    S += Trow[ipb.z & 2047];
    S += Trow[ipb.w & 2047];
    float rv = sane(expf(1.0f - S / 7.0f) * dn[i]);
    rloc[i] = rv;
    lmin = fminf(lmin, rv);
  }
  // exact min; its barrier also guarantees all Trow reads finished before reuse
  float rmin = blockMinExact(lmin, wmin, t);
  float z = 0.f, s0 = 0.f, s1 = 0.f, s2 = 0.f;
  #pragma unroll
  for (int i = 0; i < 8; i++){
    int m = t + 256 * i;
    float p = expf(rmin - rloc[i]);
    z  += p;
    s0 += tgtb[0 * MM + m] * p;
    s1 += tgtb[1 * MM + m] * p;
    s2 += tgtb[2 * MM + m] * p;
  }
  f32x4 v4; v4.x = z; v4.y = s0; v4.z = s1; v4.w = s2;
  f32x4 r = blockRed4(v4, (f32x4*)Trow, t);   // Trow dead; identical tree order
  if (t == 0){
    float iZ = 1.0f / fmaxf(r.x, 1e-30f);
    s_corrb[0 * NN + n] = r.y * iZ;
    s_corrb[1 * NN + n] = r.z * iZ;
    s_corrb[2 * NN + n] = r.w * iZ;
    lossb[n] = -logf(fminf(iZ, 1.0f) + 1e-15f);  // pred at onehot == rowmax(rmm) == 1/Z
  }
}

// ---- K5: discriminator MLP — R14: scalar-W2 + e-range wave split -------------------
__global__ __launch_bounds__(256, 4) void k_disc(const float* __restrict__ s_corr, const float* __restrict__ src,
                                                 const float* __restrict__ sknn, const int* __restrict__ sidx,
                                                 const float* __restrict__ W1, const float* __restrict__ b1,
                                                 const float* __restrict__ W2, const float* __restrict__ b2,
                                                 const float* __restrict__ W3, const float* __restrict__ b3,
                                                 float* __restrict__ sArr){
  __shared__ float term[64][129];
  int t = threadIdx.x;
  int b = blockIdx.y;
  int p = t & 63;
  int n = blockIdx.x * 4 + (p >> 4);
  int kk = p & 15;
  int eh = t >> 6;
  int nk = sidx[((b * NN + n) * KK) + kk] & 2047;
  float f[6];
  #pragma unroll
  for (int c = 0; c < 3; c++){
    f[c]     = s_corr[(b * 3 + c) * NN + n] - s_corr[(b * 3 + c) * NN + nk];
    f[3 + c] = src[(b * 3 + c) * NN + n] - sknn[((size_t)(b * NN + n) * KK + kk) * 3 + c];
  }
  #define L1D(d) ({ float a_ = b1[(d)];              \
                    a_ += f[0] * W1[(d) * 6 + 0];    \
                    a_ += f[1] * W1[(d) * 6 + 1];    \
                    a_ += f[2] * W1[(d) * 6 + 2];    \
                    a_ += f[3] * W1[(d) * 6 + 3];    \
                    a_ += f[4] * W1[(d) * 6 + 4];    \
                    a_ += f[5] * W1[(d) * 6 + 5];    \
                    fmaxf(a_, 0.f); })
  #define HSET(i) f32x4 h##i;                  \
                  h##i.x = L1D(4 * (i) + 0);   \
                  h##i.y = L1D(4 * (i) + 1);   \
                  h##i.z = L1D(4 * (i) + 2);   \
                  h##i.w = L1D(4 * (i) + 3);
  HSET(0) HSET(1) HSET(2) HSET(3) HSET(4) HSET(5) HSET(6) HSET(7)
  HSET(8) HSET(9) HSET(10) HSET(11) HSET(12) HSET(13) HSET(14) HSET(15)
  #undef HSET
  #undef L1D
  int e0 = __builtin_amdgcn_readfirstlane(eh * 32);
  for (int j = 0; j < 32; j++){
    int e = e0 + j;
    float a = b2[e];
    const f32x4* w4 = (const f32x4*)&W2[e * 64];
    #define QSTEP(i) { f32x4 wv = w4[i]; a += wv.x * h##i.x + wv.y * h##i.y + wv.z * h##i.z + wv.w * h##i.w; }
    QSTEP(0) QSTEP(1) QSTEP(2) QSTEP(3) QSTEP(4) QSTEP(5) QSTEP(6) QSTEP(7)
    QSTEP(8) QSTEP(9) QSTEP(10) QSTEP(11) QSTEP(12) QSTEP(13) QSTEP(14) QSTEP(15)
    #undef QSTEP
    term[p][e] = fmaxf(a, 0.f);
  }
  __syncthreads();
  if (t < 64){
    float sacc = b3[0];
    #pragma unroll 4
    for (int e = 0; e < 128; e++) sacc += W3[e] * term[t][e];
    if (!(fabsf(sacc) < 1e30f)) sacc = -1e30f;
    #pragma unroll
    for (int off = 1; off < 16; off <<= 1) sacc = fmaxf(sacc, __shfl_xor(sacc, off, 16));
    if (kk == 0) sArr[b * NN + n] = sacc;
  }
}

// ---- K6+K7+K8 merged (R21/R22/R23 structure; f32 SVD, named scalars) ---------------
__global__ __launch_bounds__(256) void k_rankrig(const float* __restrict__ sArr, const float* __restrict__ src,
                                                 const float* __restrict__ s_corr, int* __restrict__ topi,
                                                 float* __restrict__ Rt, float* __restrict__ out){
  __shared__ float wrow[NN];
  __shared__ float red[256];
  __shared__ f32x4 red4[256];
  __shared__ int pc[4][64];
  int b = blockIdx.y, t = threadIdx.x;
  // ---- softmax (verbatim k_softw) -> wrow (feeds rank -> topi: DISCRETE, verbatim) --
  const float* sp = sArr + b * NN;
  float sv[8];
  float mx = -3.4e38f;
  #pragma unroll
  for (int i = 0; i < 8; i++){
    float v = sp[t + 256 * i];
    if (!(fabsf(v) < 1e30f)) v = -1e30f;
    sv[i] = v; mx = fmaxf(mx, v);
  }
  mx = blockRed(mx, red, t, 2);
  float z = 0.f;
  #pragma unroll
  for (int i = 0; i < 8; i++) z += expf(sv[i] - mx);
  z = blockRed(z, red, t, 0);
  float iz = 1.0f / fmaxf(z, 1e-30f);
  #pragma unroll
  for (int i = 0; i < 8; i++) wrow[t + 256 * i] = expf(sv[i] - mx) * iz;
  __syncthreads();
  // ---- rank (verbatim R15 body) ----
  int tn = t & 63, tj = t >> 6;
  int n = blockIdx.x * 64 + tn;
  float wn = wrow[n];
  int j0 = tj * 512;
  const f32x4* w4 = (const f32x4*)&wrow[j0];
  int cnt = 0;
  #pragma unroll 4
  for (int q = 0; q < 128; q++){
    f32x4 wv = w4[q];
    int j = j0 + q * 4;
    cnt += (wv.x > wn) || ((wv.x == wn) && (j + 0 < n));
    cnt += (wv.y > wn) || ((wv.y == wn) && (j + 1 < n));
    cnt += (wv.z > wn) || ((wv.z == wn) && (j + 2 < n));
    cnt += (wv.w > wn) || ((wv.w == wn) && (j + 3 < n));
  }
  pc[tj][tn] = cnt;
  __syncthreads();
  if (t < 64){
    int c = pc[0][t] + pc[1][t] + pc[2][t] + pc[3][t];
    if (c < KEY) topi[b * KEY + c] = blockIdx.x * 64 + t;
  }
  if (blockIdx.x != 0) return;
  // ---- rigid: centroids + H via blockRed4 (bit-identical sums) ----
  float wsum = 0, a0 = 0, a1 = 0, a2 = 0, c0 = 0, c1 = 0, c2 = 0;
  for (int n2 = t; n2 < NN; n2 += 256){
    float wv = wrow[n2];
    float s0 = src[(b * 3 + 0) * NN + n2];
    float s1 = src[(b * 3 + 1) * NN + n2];
    float s2 = src[(b * 3 + 2) * NN + n2];
    float q0 = s_corr[(b * 3 + 0) * NN + n2];
    float q1 = s_corr[(b * 3 + 1) * NN + n2];
    float q2 = s_corr[(b * 3 + 2) * NN + n2];
    wsum += wv; a0 += wv * s0; a1 += wv * s1; a2 += wv * s2;
    c0 += wv * q0; c1 += wv * q1; c2 += wv * q2;
  }
  f32x4 pk1; pk1.x = wsum; pk1.y = a0; pk1.z = a1; pk1.w = a2;
  pk1 = blockRed4(pk1, red4, t);
  f32x4 pk2; pk2.x = c0; pk2.y = c1; pk2.z = c2; pk2.w = 0.f;
  pk2 = blockRed4(pk2, red4, t);
  wsum = pk1.x; a0 = pk1.y; a1 = pk1.z; a2 = pk1.w;
  c0 = pk2.x; c1 = pk2.y; c2 = pk2.z;
  float inv = 1.0f / fmaxf(wsum, 1e-30f);
  float cs0 = a0 * inv, cs1 = a1 * inv, cs2 = a2 * inv;
  float ct0 = c0 * inv, ct1 = c1 * inv, ct2 = c2 * inv;
  float h[9] = {0, 0, 0, 0, 0, 0, 0, 0, 0};
  for (int n2 = t; n2 < NN; n2 += 256){
    float wv = wrow[n2];
    float ds0 = src[(b * 3 + 0) * NN + n2] - cs0;
    float ds1 = src[(b * 3 + 1) * NN + n2] - cs1;
    float ds2 = src[(b * 3 + 2) * NN + n2] - cs2;
    float dc0 = s_corr[(b * 3 + 0) * NN + n2] - ct0;
    float dc1 = s_corr[(b * 3 + 1) * NN + n2] - ct1;
    float dc2 = s_corr[(b * 3 + 2) * NN + n2] - ct2;
    h[0] += wv * ds0 * dc0; h[1] += wv * ds0 * dc1; h[2] += wv * ds0 * dc2;
    h[3] += wv * ds1 * dc0; h[4] += wv * ds1 * dc1; h[5] += wv * ds1 * dc2;
    h[6] += wv * ds2 * dc0; h[7] += wv * ds2 * dc1; h[8] += wv * ds2 * dc2;
  }
  f32x4 ph1; ph1.x = h[0]; ph1.y = h[1]; ph1.z = h[2]; ph1.w = h[3];
  ph1 = blockRed4(ph1, red4, t);
  f32x4 ph2; ph2.x = h[4]; ph2.y = h[5]; ph2.z = h[6]; ph2.w = h[7];
  ph2 = blockRed4(ph2, red4, t);
  float h8 = blockRed(h[8], red, t, 0);
  if (t == 0){
    // ---- all-register 3x3 SVD, f32 (static pivot enumeration) ----
    float Hm00 = ph1.x, Hm01 = ph1.y, Hm02 = ph1.z;
    float Hm10 = ph1.w, Hm11 = ph2.x, Hm12 = ph2.y;
    float Hm20 = ph2.z, Hm21 = ph2.w, Hm22 = h8;
    float k00 = Hm00 * Hm00 + Hm10 * Hm10 + Hm20 * Hm20;
    float k01 = Hm00 * Hm01 + Hm10 * Hm11 + Hm20 * Hm21;
    float k02 = Hm00 * Hm02 + Hm10 * Hm12 + Hm20 * Hm22;
    float k10 = k01, k11 = Hm01 * Hm01 + Hm11 * Hm11 + Hm21 * Hm21;
    float k12 = Hm01 * Hm02 + Hm11 * Hm12 + Hm21 * Hm22;
    float k20 = k02, k21 = k12;
    float k22 = Hm02 * Hm02 + Hm12 * Hm12 + Hm22 * Hm22;
    float v00 = 1, v01 = 0, v02 = 0, v10 = 0, v11 = 1, v12 = 0, v20 = 0, v21 = 0, v22 = 1;
    float ksc = fabsf(k00) + fabsf(k11) + fabsf(k22) + 1e-30f;
    #define ROT2(A, B) { float ra = A, rb = B; A = cc2 * ra - sn * rb; B = sn * ra + cc2 * rb; }
    for (int sweep = 0; sweep < 30; sweep++){
      float m01 = fabsf(k01), m02 = fabsf(k02), m12 = fabsf(k12);
      int cse = 0; float mx2 = m01;
      if (m02 > mx2){ mx2 = m02; cse = 1; }
      if (m12 > mx2){ mx2 = m12; cse = 2; }
      if (mx2 <= 1e-6f * ksc) break;
      float app, aqq, apq;
      if (cse == 0){ app = k00; aqq = k11; apq = k01; }
      else if (cse == 1){ app = k00; aqq = k22; apq = k02; }
      else { app = k11; aqq = k22; apq = k12; }
      float tau = (aqq - app) / (2.0f * apq);
      float tt = ((tau >= 0) ? 1.0f : -1.0f) / (fabsf(tau) + sqrtf(1.0f + tau * tau));
      float cc2 = 1.0f / sqrtf(1.0f + tt * tt), sn = tt * cc2;
      if (cse == 0){        // (p,q)=(0,1)
        ROT2(k00, k01) ROT2(k10, k11) ROT2(k20, k21)
        ROT2(k00, k10) ROT2(k01, k11) ROT2(k02, k12)
        ROT2(v00, v01) ROT2(v10, v11) ROT2(v20, v21)
      } else if (cse == 1){ // (p,q)=(0,2)
        ROT2(k00, k02) ROT2(k10, k12) ROT2(k20, k22)
        ROT2(k00, k20) ROT2(k01, k21) ROT2(k02, k22)
        ROT2(v00, v02) ROT2(v10, v12) ROT2(v20, v22)
      } else {              // (p,q)=(1,2)
        ROT2(k01, k02) ROT2(k11, k12) ROT2(k21, k22)
        ROT2(k10, k20) ROT2(k11, k21) ROT2(k12, k22)
        ROT2(v01, v02) ROT2(v11, v12) ROT2(v21, v22)
      }
    }
    #undef ROT2
    float l0 = k00, l1 = k11, l2 = k22; int id0 = 0, id1 = 1, id2 = 2;
    float lt; int it;
    if (l0 < l1){ lt = l0; l0 = l1; l1 = lt; it = id0; id0 = id1; id1 = it; }
    if (l0 < l2){ lt = l0; l0 = l2; l2 = lt; it = id0; id0 = id2; id2 = it; }
    if (l1 < l2){ lt = l1; l1 = l2; l2 = lt; it = id1; id1 = id2; id2 = it; }
    float Vs00, Vs10, Vs20, Vs01, Vs11, Vs21, Vs02, Vs12, Vs22;
    float u00 = 0, u10 = 0, u20 = 0, u01 = 0, u11 = 0, u21 = 0, u02 = 0, u12 = 0, u22 = 0;
    #define GETCOL(j, cA, cB, cC) { if ((j) == 0){ cA = v00; cB = v10; cC = v20; } \
                                    else if ((j) == 1){ cA = v01; cB = v11; cC = v21; } \
                                    else { cA = v02; cB = v12; cC = v22; } }
    {
      float cA, cB, cC; GETCOL(id0, cA, cB, cC);
      Vs00 = cA; Vs10 = cB; Vs20 = cC;
      float uu0 = Hm00 * cA + Hm01 * cB + Hm02 * cC;
      float uu1 = Hm10 * cA + Hm11 * cB + Hm12 * cC;
      float uu2 = Hm20 * cA + Hm21 * cB + Hm22 * cC;
      float nrm = sqrtf(uu0 * uu0 + uu1 * uu1 + uu2 * uu2);
      if (nrm > 1e-20f){ u00 = uu0 / nrm; u10 = uu1 / nrm; u20 = uu2 / nrm; }
      else { u00 = 1; u10 = 0; u20 = 0; }
    }
    {
      float cA, cB, cC; GETCOL(id1, cA, cB, cC);
      Vs01 = cA; Vs11 = cB; Vs21 = cC;
      float uu0 = Hm00 * cA + Hm01 * cB + Hm02 * cC;
      float uu1 = Hm10 * cA + Hm11 * cB + Hm12 * cC;
      float uu2 = Hm20 * cA + Hm21 * cB + Hm22 * cC;
      float nrm = sqrtf(uu0 * uu0 + uu1 * uu1 + uu2 * uu2);
      if (nrm > 1e-20f){ u01 = uu0 / nrm; u11 = uu1 / nrm; u21 = uu2 / nrm; }
      else {
        float x0 = u10 * u21 - u20 * u11;
        float x1 = u20 * u01 - u00 * u21;
        float x2 = u00 * u11 - u10 * u01;
        float nn2 = sqrtf(x0 * x0 + x1 * x1 + x2 * x2);
        if (nn2 < 1e-20f){ x0 = 1; x1 = 0; x2 = 0; nn2 = 1; }
        u01 = x0 / nn2; u11 = x1 / nn2; u21 = x2 / nn2;
      }
    }
    {
      float cA, cB, cC; GETCOL(id2, cA, cB, cC);
      Vs02 = cA; Vs12 = cB; Vs22 = cC;
      float uu0 = Hm00 * cA + Hm01 * cB + Hm02 * cC;
      float uu1 = Hm10 * cA + Hm11 * cB + Hm12 * cC;
      float uu2 = Hm20 * cA + Hm21 * cB + Hm22 * cC;
      float nrm = sqrtf(uu0 * uu0 + uu1 * uu1 + uu2 * uu2);
      if (nrm > 1e-20f){ u02 = uu0 / nrm; u12 = uu1 / nrm; u22 = uu2 / nrm; }
      else {
        float x0 = u10 * u21 - u20 * u11;
        float x1 = u20 * u01 - u00 * u21;
        float x2 = u00 * u11 - u10 * u01;
        float nn2 = sqrtf(x0 * x0 + x1 * x1 + x2 * x2);
        if (nn2 < 1e-20f){ x0 = 1; x1 = 0; x2 = 0; nn2 = 1; }
        u02 = x0 / nn2; u12 = x1 / nn2; u22 = x2 / nn2;
      }
    }
    #undef GETCOL
    float ddU = u00 * (u11 * u22 - u12 * u21) - u01 * (u10 * u22 - u12 * u20) + u02 * (u10 * u21 - u11 * u20);
    float ddV = Vs00 * (Vs11 * Vs22 - Vs12 * Vs21) - Vs01 * (Vs10 * Vs22 - Vs12 * Vs20) + Vs02 * (Vs10 * Vs21 - Vs11 * Vs20);
    float dd = ddU * ddV;
    float Rm00 = Vs00 * u00 + Vs01 * u01 + dd * Vs02 * u02;
    float Rm01 = Vs00 * u10 + Vs01 * u11 + dd * Vs02 * u12;
    float Rm02 = Vs00 * u20 + Vs01 * u21 + dd * Vs02 * u22;
    float Rm10 = Vs10 * u00 + Vs11 * u01 + dd * Vs12 * u02;
    float Rm11 = Vs10 * u10 + Vs11 * u11 + dd * Vs12 * u12;
    float Rm12 = Vs10 * u20 + Vs11 * u21 + dd * Vs12 * u22;
    float Rm20 = Vs20 * u00 + Vs21 * u01 + dd * Vs22 * u02;
    float Rm21 = Vs20 * u10 + Vs21 * u11 + dd * Vs22 * u12;
    float Rm22 = Vs20 * u20 + Vs21 * u21 + dd * Vs22 * u22;
    float tv0 = ct0 - (Rm00 * cs0 + Rm01 * cs1 + Rm02 * cs2);
    float tv1 = ct1 - (Rm10 * cs0 + Rm11 * cs1 + Rm12 * cs2);
    float tv2 = ct2 - (Rm20 * cs0 + Rm21 * cs1 + Rm22 * cs2);
    Rt[b * 12 + 0] = Rm00; out[b * 9 + 0] = Rm00;
    Rt[b * 12 + 1] = Rm01; out[b * 9 + 1] = Rm01;
    Rt[b * 12 + 2] = Rm02; out[b * 9 + 2] = Rm02;
    Rt[b * 12 + 3] = Rm10; out[b * 9 + 3] = Rm10;
    Rt[b * 12 + 4] = Rm11; out[b * 9 + 4] = Rm11;
    Rt[b * 12 + 5] = Rm12; out[b * 9 + 5] = Rm12;
    Rt[b * 12 + 6] = Rm20; out[b * 9 + 6] = Rm20;
    Rt[b * 12 + 7] = Rm21; out[b * 9 + 7] = Rm21;
    Rt[b * 12 + 8] = Rm22; out[b * 9 + 8] = Rm22;
    Rt[b * 12 + 9]  = tv0; out[18 + b * 3 + 0] = tv0;
    Rt[b * 12 + 10] = tv1; out[18 + b * 3 + 1] = tv1;
    Rt[b * 12 + 11] = tv2; out[18 + b * 3 + 2] = tv2;
  }
}

// ---- K10 (+K11 merged): keypoint gathers; block x==64,b==0 computes loss_scl -------
__global__ __launch_bounds__(256) void k_out(const int* __restrict__ topi, const int* __restrict__ sidx,
                                             const float* __restrict__ src, const float* __restrict__ s_corr,
                                             const float* __restrict__ Rt, const float* __restrict__ loss_row,
                                             float* __restrict__ out){
  __shared__ float red[256];
  int b = blockIdx.y, t = threadIdx.x;
  if (blockIdx.x == 64){
    if (b != 0) return;
    float acc = 0.f;
    for (int i = t; i < BB * KEY; i += 256){
      int bb = i >> 10, r = i & 1023;
      int n = topi[bb * KEY + r] & 2047;
      acc += loss_row[bb * NN + n];
    }
    acc = blockRed(acc, red, t, 0);
    if (t == 0) out[208920] = acc / 2048.0f;
    return;
  }
  int rr = t >> 4, kk = t & 15;
  int r = blockIdx.x * 16 + rr;
  int ns = topi[b * KEY + r] & 2047;
  int nk = sidx[(b * NN + ns) * KK + kk] & 2047;
  const float* R = Rt + b * 12;
  float sns0 = src[(b * 3 + 0) * NN + ns];
  float sns1 = src[(b * 3 + 1) * NN + ns];
  float sns2 = src[(b * 3 + 2) * NN + ns];
  float snk0 = src[(b * 3 + 0) * NN + nk];
  float snk1 = src[(b * 3 + 1) * NN + nk];
  float snk2 = src[(b * 3 + 2) * NN + nk];
  float* o_sk  = out + 24;
  float* o_tk  = out + 6168;
  float* o_skk = out + 12312;
  float* o_tkk = out + 110616;
  #pragma unroll
  for (int c = 0; c < 3; c++){
    float cv  = s_corr[(b * 3 + c) * NN + ns];
    float ck  = s_corr[(b * 3 + c) * NN + nk];
    o_tkk[(((b * 3 + c) * KEY + r) * KK) + kk] = cv - ck;
    float sv  = R[c * 3 + 0] * sns0 + R[c * 3 + 1] * sns1 + R[c * 3 + 2] * sns2 + R[9 + c];
    float sk2 = R[c * 3 + 0] * snk0 + R[c * 3 + 1] * snk1 + R[c * 3 + 2] * snk2 + R[9 + c];
    o_skk[(((b * 3 + c) * KEY + r) * KK) + kk] = sv - sk2;
    if (kk == 0){
      o_sk[(b * 3 + c) * KEY + r] = sns0 * (c == 0) + sns1 * (c == 1) + sns2 * (c == 2);
      o_tk[(b * 3 + c) * KEY + r] = cv;
    }
  }
}

extern "C" void kernel_launch(void* const* d_in, const int* in_sizes, int n_in,
                              void* d_out, int out_size, void* d_ws, size_t ws_size,
                              hipStream_t stream){
  const float* src  = (const float*)d_in[0];
  const float* tgt  = (const float*)d_in[1];
  const float* semb = (const float*)d_in[2];
  const float* temb = (const float*)d_in[3];
  const float* sknn = (const float*)d_in[4];
  const float* W1 = (const float*)d_in[6];
  const float* b1 = (const float*)d_in[7];
  const float* W2 = (const float*)d_in[8];
  const float* b2 = (const float*)d_in[9];
  const float* W3 = (const float*)d_in[10];
  const float* b3 = (const float*)d_in[11];
  const int* sidx  = (const int*)d_in[12];
  const int* sidx1 = (const int*)d_in[13];
  const int* idx2  = (const int*)d_in[14];
  float* out = (float*)d_out;

  // workspace layout (peak ~84 MB; harness allocates 256 MiB per fill evidence)
  char* w = (char*)d_ws;
  u16* Ah = (u16*)(w);                               // 4 MB each (B,N,C) bf16 split
  u16* Al = Ah + (size_t)BB * NN * CC;
  u16* Bh = Al + (size_t)BB * NN * CC;
  u16* Bl = Bh + (size_t)BB * MM * CC;
  float* dist = (float*)(Bl + (size_t)BB * MM * CC); // 33.55 MB (B,N,M) f32
  float* scores = dist + (size_t)BB * NN * MM;       // 33.55 MB (B,N,M) f32
  char* tail = (char*)(scores + (size_t)BB * NN * MM);
  float* xx = (float*)tail;                          // B*N
  float* yy = xx + BB * NN;                          // B*M
  float* mnA = yy + BB * MM;                         // B*N
  float* Zr = mnA + BB * NN;                         // B*N
  float* s_corr = Zr + BB * NN;                      // B*3*N
  float* loss_row = s_corr + BB * 3 * NN;            // B*N
  float* sArr = loss_row + BB * NN;                  // B*N
  int* topi = (int*)(sArr + BB * NN);                // B*KEY
  float* Rt = (float*)(topi + BB * KEY);             // B*12

  k_trans<<<dim3(16, 64, 4), dim3(32, 8), 0, stream>>>(semb, temb, Ah, Al, Bh, Bl);
  k_sq<<<dim3(16, 2), 256, 0, stream>>>(semb, temb, xx, yy);
  k_gemm<<<dim3(16, 16, BB), 256, 0, stream>>>(Ah, Al, Bh, Bl, xx, yy, dist);
  k_rowstats<<<dim3(NN, BB), 256, 0, stream>>>(dist, mnA, Zr, scores);
  k_fused<<<dim3(NN, BB), 256, 0, stream>>>(dist, scores, sidx1, idx2, tgt, s_corr, loss_row);
  k_disc<<<dim3(NN / 4, BB), 256, 0, stream>>>(s_corr, src, sknn, sidx, W1, b1, W2, b2, W3, b3, sArr);
  k_rankrig<<<dim3(32, BB), 256, 0, stream>>>(sArr, src, s_corr, topi, Rt, out);
  k_out<<<dim3(65, BB), 256, 0, stream>>>(topi, sidx, src, s_corr, Rt, loss_row, out);
}

// Round 13
// 258.057 us; speedup vs baseline: 2.1374x; 1.0077x over previous
//
#include <hip/hip_runtime.h>
#include <stdint.h>

typedef unsigned short u16;

#define BB 2
#define NN 2048
#define MM 2048
#define CC 512
#define KK 16
#define KK1 8
#define KEY 1024

typedef __attribute__((ext_vector_type(8))) short bf16x8;
typedef __attribute__((ext_vector_type(4))) float f32x4;

__device__ __forceinline__ float b2f(u16 u){ return __uint_as_float(((uint32_t)u) << 16); }
__device__ __forceinline__ u16 f2b(float f){
  uint32_t x = __float_as_uint(f);
  uint32_t r = x + 0x7FFFu + ((x >> 16) & 1u);
  return (u16)(r >> 16);
}
__device__ __forceinline__ float sane(float v){ return (fabsf(v) < 1e30f) ? v : 1e30f; }

// async global->LDS 16B per lane: LDS dest = wave-uniform base + lane*16 (HW rule)
__device__ __forceinline__ void gload_lds16(const u16* g, u16* l){
  __builtin_amdgcn_global_load_lds((const __attribute__((address_space(1))) uint32_t*)g,
                                   (__attribute__((address_space(3))) uint32_t*)l, 16, 0, 0);
}

// all-thread block reduction, 256 threads. op: 0=sum 1=min 2=max
__device__ __forceinline__ float blockRed(float v, float* red, int t, int op){
  red[t] = v; __syncthreads();
  #pragma unroll
  for (int s = 128; s > 0; s >>= 1){
    if (t < s){
      float a = red[t], b = red[t + s];
      red[t] = (op == 0) ? (a + b) : ((op == 1) ? fminf(a, b) : fmaxf(a, b));
    }
    __syncthreads();
  }
  float r = red[0]; __syncthreads();
  return r;
}

// 4-wide sum tree; per-component order identical to 4 separate blockReds -> each
// component's result is bit-identical to blockRed(v, red, t, 0).
__device__ __forceinline__ f32x4 blockRed4(f32x4 v, f32x4* red4, int t){
  red4[t] = v; __syncthreads();
  #pragma unroll
  for (int s = 128; s > 0; s >>= 1){
    if (t < s){
      f32x4 a = red4[t], c = red4[t + s];
      a.x += c.x; a.y += c.y; a.z += c.z; a.w += c.w;
      red4[t] = a;
    }
    __syncthreads();
  }
  f32x4 r = red4[0]; __syncthreads();
  return r;
}

// exact block min (min is associative+commutative; inputs sane()-filtered so no NaN;
// ±0 ties only feed expf(x-y) where both zero signs give identical bits). 1 barrier.
__device__ __forceinline__ float blockMinExact(float v, float* wmin, int t){
  #pragma unroll
  for (int off = 1; off < 64; off <<= 1) v = fminf(v, __shfl_xor(v, off));
  if ((t & 63) == 0) wmin[t >> 6] = v;
  __syncthreads();
  return fminf(fminf(wmin[0], wmin[1]), fminf(wmin[2], wmin[3]));
}

// ---- K0: transpose f32 (B,C,N) -> split-bf16 (B,N,C) hi/lo pairs -------------------
__global__ __launch_bounds__(256) void k_trans(const float* __restrict__ semb, const float* __restrict__ temb,
                                               u16* __restrict__ Ah, u16* __restrict__ Al,
                                               u16* __restrict__ Bh, u16* __restrict__ Bl){
  __shared__ float tile[32][33];
  int b = blockIdx.z & 1, which = blockIdx.z >> 1;
  const float* in = which ? temb : semb;
  u16* oh = which ? Bh : Ah;
  u16* ol = which ? Bl : Al;
  int c0 = blockIdx.x * 32, n0 = blockIdx.y * 32;
  int tx = threadIdx.x, ty = threadIdx.y;
  #pragma unroll
  for (int i = 0; i < 4; i++){
    int r = ty + 8 * i;
    tile[r][tx] = in[((b * CC + c0 + r) * NN) + n0 + tx];
  }
  __syncthreads();
  #pragma unroll
  for (int i = 0; i < 4; i++){
    int r = ty + 8 * i;
    float v = tile[tx][r];
    u16 hi = f2b(v);
    float lo = v - b2f(hi);
    size_t o = ((size_t)(b * NN + n0 + r) * CC) + c0 + tx;
    oh[o] = hi;
    ol[o] = f2b(lo);
  }
}

// ---- K1: exact f32 row squared norms (R18 lesson: no FP change ahead of a discrete
// selection; only bit-identical transforms admissible) -------------------------------
__global__ __launch_bounds__(256) void k_sq(const float* __restrict__ semb, const float* __restrict__ temb,
                                            float* __restrict__ xx, float* __restrict__ yy){
  int which = blockIdx.y;
  const float* in = which ? temb : semb;
  float* out = which ? yy : xx;
  int gid = blockIdx.x * 256 + threadIdx.x;   // 0..4095
  int b = gid >> 11, n = gid & 2047;
  float acc = 0.f;
  for (int c = 0; c < CC; c++){
    float v = in[((size_t)(b * CC + c)) * NN + n];
    acc += v * v;
  }
  out[gid] = acc;
}

// ---- K2: dist = xx - 2*A.B^T + yy, split-bf16 MFMA; gload_lds staging (R20) --------
__global__ __launch_bounds__(256) void k_gemm(const u16* __restrict__ Ah, const u16* __restrict__ Al,
                                              const u16* __restrict__ Bh, const u16* __restrict__ Bl,
                                              const float* __restrict__ xx, const float* __restrict__ yy,
                                              float* __restrict__ dist){
  __shared__ __align__(16) u16 lAh[128 * 64];
  __shared__ __align__(16) u16 lAl[128 * 64];
  __shared__ __align__(16) u16 lBh[128 * 64];
  __shared__ __align__(16) u16 lBl[128 * 64];
  int bz = blockIdx.z;
  const u16* Ahb = Ah + (size_t)bz * NN * CC;
  const u16* Alb = Al + (size_t)bz * NN * CC;
  const u16* Bhb = Bh + (size_t)bz * MM * CC;
  const u16* Blb = Bl + (size_t)bz * MM * CC;
  const float* xxb = xx + bz * NN;
  const float* yyb = yy + bz * MM;
  float* distb = dist + (size_t)bz * NN * MM;
  int n0 = blockIdx.y * 128, m0 = blockIdx.x * 128;
  int t = threadIdx.x;
  f32x4 acc[4][4];
  #pragma unroll
  for (int i = 0; i < 4; i++)
    #pragma unroll
    for (int j = 0; j < 4; j++){ f32x4 z = {0.f, 0.f, 0.f, 0.f}; acc[i][j] = z; }
  int w = t >> 6, lane = t & 63, lr = lane & 15, quad = lane >> 4;
  int wn = (w >> 1) * 64, wm = (w & 1) * 64;
  for (int kt = 0; kt < 8; kt++){
    int k0 = kt * 64;
    __syncthreads();
    #pragma unroll
    for (int s = 0; s < 4; s++){
      int ch = t + 256 * s;
      int rn = ch >> 3, k8 = (ch & 7) * 8;
      size_t oa = (size_t)(n0 + rn) * CC + k0 + k8;
      size_t ob = (size_t)(m0 + rn) * CC + k0 + k8;
      int ldsoff = ((t >> 6) * 64 + 256 * s) * 8;   // wave-uniform (u16 elems)
      gload_lds16(Ahb + oa, &lAh[ldsoff]);
      gload_lds16(Alb + oa, &lAl[ldsoff]);
      gload_lds16(Bhb + ob, &lBh[ldsoff]);
      gload_lds16(Blb + ob, &lBl[ldsoff]);
    }
    __syncthreads();
    #pragma unroll
    for (int kk = 0; kk < 2; kk++){
      int off = kk * 32 + quad * 8;
      bf16x8 afh[4], afl[4], bfh[4], bfl[4];
      #pragma unroll
      for (int i = 0; i < 4; i++){
        int ra = (wn + i * 16 + lr) * 64 + off;
        afh[i] = *(const bf16x8*)&lAh[ra];
        afl[i] = *(const bf16x8*)&lAl[ra];
      }
      #pragma unroll
      for (int j = 0; j < 4; j++){
        int rb = (wm + j * 16 + lr) * 64 + off;
        bfh[j] = *(const bf16x8*)&lBh[rb];
        bfl[j] = *(const bf16x8*)&lBl[rb];
      }
      #pragma unroll
      for (int i = 0; i < 4; i++)
        #pragma unroll
        for (int j = 0; j < 4; j++){
          acc[i][j] = __builtin_amdgcn_mfma_f32_16x16x32_bf16(afh[i], bfh[j], acc[i][j], 0, 0, 0);
          acc[i][j] = __builtin_amdgcn_mfma_f32_16x16x32_bf16(afh[i], bfl[j], acc[i][j], 0, 0, 0);
          acc[i][j] = __builtin_amdgcn_mfma_f32_16x16x32_bf16(afl[i], bfh[j], acc[i][j], 0, 0, 0);
        }
    }
  }
  #pragma unroll
  for (int i = 0; i < 4; i++){
    int nbase = n0 + wn + i * 16 + quad * 4;
    #pragma unroll
    for (int j = 0; j < 4; j++){
      int m = m0 + wm + j * 16 + lr;
      float yv = yyb[m];
      #pragma unroll
      for (int r = 0; r < 4; r++){
        distb[((size_t)(nbase + r)) * MM + m] = xxb[nbase + r] + yv - 2.0f * acc[i][j][r];
      }
    }
  }
}

// ---- K3: per-row min, softmax denom, scores row (R17/R21/R24) ----------------------
__global__ __launch_bounds__(256, 4) void k_rowstats(const float* __restrict__ dist,
                                                     float* __restrict__ mnA, float* __restrict__ Zr,
                                                     float* __restrict__ scores){
  __shared__ float red[256];
  __shared__ float wmin[4];
  int row = blockIdx.x, b = blockIdx.y, t = threadIdx.x;
  const float* dr = dist + ((size_t)b * NN + row) * MM;
  float* sr = scores + ((size_t)b * NN + row) * MM;
  float d[8];
  float mn = 3.4e38f;
  #pragma unroll
  for (int i = 0; i < 8; i++){ d[i] = sane(dr[t + 256 * i]); mn = fminf(mn, d[i]); }
  mn = blockMinExact(mn, wmin, t);
  float p[8];
  float z = 0.f;
  #pragma unroll
  for (int i = 0; i < 8; i++){ p[i] = expf(mn - d[i]); z += p[i]; }
  z = blockRed(z, red, t, 0);
  float zc = fmaxf(z, 1e-30f);
  if (t == 0){ mnA[b * NN + row] = mn; Zr[b * NN + row] = zc; }
  float iz = 1.0f / zc;
  #pragma unroll
  for (int i = 0; i < 8; i++) sr[t + 256 * i] = p[i] * iz;
}

// ---- K4: fused T/S/refined/rmm/src_corr/loss. R25: R24's launch_bounds hint FAILED
// (VGPR stayed 32 — allocator ignores hints when the chained 'tacc += load' shape
// only needs a small rolling window). Force deep MLP by SOURCE STRUCTURE: stage all
// 7 score rows into named registers va[7][8] (static indices after unroll, rule #20
// ok), THEN accumulate in the exact original j-order (left fold from 0) -> tacc is
// bit-identical; ~56 loads issued before first use. --------------------------------
__global__ __launch_bounds__(256, 4) void k_fused(const float* __restrict__ dist, const float* __restrict__ scores,
                                                  const int* __restrict__ sidx1,
                                                  const int* __restrict__ idx2, const float* __restrict__ tgt,
                                                  float* __restrict__ s_corr, float* __restrict__ lossr){
  __shared__ float Trow[MM];
  __shared__ float wmin[4];
  int n = blockIdx.x, b = blockIdx.y, t = threadIdx.x;
  const float* distb = dist + (size_t)b * NN * MM;
  const float* scoresb = scores + (size_t)b * NN * MM;
  const int* sidx1b = sidx1 + (size_t)b * NN * KK1;
  const int* idx2b = idx2 + (size_t)b * MM * KK1;
  const float* tgtb = tgt + (size_t)b * 3 * MM;
  float* s_corrb = s_corr + (size_t)b * 3 * NN;
  float* lossb = lossr + b * NN;
  const float* dn_p = distb + (size_t)n * MM;
  float dn[8];
  #pragma unroll
  for (int i = 0; i < 8; i++) dn[i] = sane(dn_p[t + 256 * i]);
  const int4* i1v = (const int4*)(sidx1b + n * KK1);
  int4 i1a = i1v[0], i1b = i1v[1];
  int rj[7] = {i1a.y & 2047, i1a.z & 2047, i1a.w & 2047,
               i1b.x & 2047, i1b.y & 2047, i1b.z & 2047, i1b.w & 2047};
  // stage all 7 rows into registers (all loads independent -> deep pipeline)
  float va[7][8];
  #pragma unroll
  for (int j = 0; j < 7; j++){
    const float* srp = scoresb + (size_t)rj[j] * MM;
    #pragma unroll
    for (int i = 0; i < 8; i++) va[j][i] = srp[t + 256 * i];
  }
  // accumulate in the ORIGINAL j-order (left fold from 0) -> bit-identical tacc
  float tacc[8];
  #pragma unroll
  for (int i = 0; i < 8; i++){
    float s = 0.f;
    #pragma unroll
    for (int j = 0; j < 7; j++) s += va[j][i];
    tacc[i] = s;
  }
  #pragma unroll
  for (int i = 0; i < 8; i++) Trow[t + 256 * i] = tacc[i];
  __syncthreads();
  float rloc[8];
  float lmin = 3.4e38f;
  #pragma unroll
  for (int i = 0; i < 8; i++){
    int m = t + 256 * i;
    const int4* ipv = (const int4*)(idx2b + m * KK1);
    int4 ipa = ipv[0], ipb = ipv[1];
    float S = 0.f;
    S += Trow[ipa.y & 2047];
    S += Trow[ipa.z & 2047];
    S += Trow[ipa.w & 2047];
    S += Trow[ipb.x & 2047];
    S += Trow[ipb.y & 2047];
    S += Trow[ipb.z & 2047];
    S += Trow[ipb.w & 2047];
    float rv = sane(expf(1.0f - S / 7.0f) * dn[i]);
    rloc[i] = rv;
    lmin = fminf(lmin, rv);
  }
  // exact min; its barrier also guarantees all Trow reads finished before reuse
  float rmin = blockMinExact(lmin, wmin, t);
  float z = 0.f, s0 = 0.f, s1 = 0.f, s2 = 0.f;
  #pragma unroll
  for (int i = 0; i < 8; i++){
    int m = t + 256 * i;
    float p = expf(rmin - rloc[i]);
    z  += p;
    s0 += tgtb[0 * MM + m] * p;
    s1 += tgtb[1 * MM + m] * p;
    s2 += tgtb[2 * MM + m] * p;
  }
  f32x4 v4; v4.x = z; v4.y = s0; v4.z = s1; v4.w = s2;
  f32x4 r = blockRed4(v4, (f32x4*)Trow, t);   // Trow dead; identical tree order
  if (t == 0){
    float iZ = 1.0f / fmaxf(r.x, 1e-30f);
    s_corrb[0 * NN + n] = r.y * iZ;
    s_corrb[1 * NN + n] = r.z * iZ;
    s_corrb[2 * NN + n] = r.w * iZ;
    lossb[n] = -logf(fminf(iZ, 1.0f) + 1e-15f);  // pred at onehot == rowmax(rmm) == 1/Z
  }
}

// ---- K5: discriminator MLP — R14: scalar-W2 + e-range wave split -------------------
__global__ __launch_bounds__(256, 4) void k_disc(const float* __restrict__ s_corr, const float* __restrict__ src,
                                                 const float* __restrict__ sknn, const int* __restrict__ sidx,
                                                 const float* __restrict__ W1, const float* __restrict__ b1,
                                                 const float* __restrict__ W2, const float* __restrict__ b2,
                                                 const float* __restrict__ W3, const float* __restrict__ b3,
                                                 float* __restrict__ sArr){
  __shared__ float term[64][129];
  int t = threadIdx.x;
  int b = blockIdx.y;
  int p = t & 63;
  int n = blockIdx.x * 4 + (p >> 4);
  int kk = p & 15;
  int eh = t >> 6;
  int nk = sidx[((b * NN + n) * KK) + kk] & 2047;
  float f[6];
  #pragma unroll
  for (int c = 0; c < 3; c++){
    f[c]     = s_corr[(b * 3 + c) * NN + n] - s_corr[(b * 3 + c) * NN + nk];
    f[3 + c] = src[(b * 3 + c) * NN + n] - sknn[((size_t)(b * NN + n) * KK + kk) * 3 + c];
  }
  #define L1D(d) ({ float a_ = b1[(d)];              \
                    a_ += f[0] * W1[(d) * 6 + 0];    \
                    a_ += f[1] * W1[(d) * 6 + 1];    \
                    a_ += f[2] * W1[(d) * 6 + 2];    \
                    a_ += f[3] * W1[(d) * 6 + 3];    \
                    a_ += f[4] * W1[(d) * 6 + 4];    \
                    a_ += f[5] * W1[(d) * 6 + 5];    \
                    fmaxf(a_, 0.f); })
  #define HSET(i) f32x4 h##i;                  \
                  h##i.x = L1D(4 * (i) + 0);   \
                  h##i.y = L1D(4 * (i) + 1);   \
                  h##i.z = L1D(4 * (i) + 2);   \
                  h##i.w = L1D(4 * (i) + 3);
  HSET(0) HSET(1) HSET(2) HSET(3) HSET(4) HSET(5) HSET(6) HSET(7)
  HSET(8) HSET(9) HSET(10) HSET(11) HSET(12) HSET(13) HSET(14) HSET(15)
  #undef HSET
  #undef L1D
  int e0 = __builtin_amdgcn_readfirstlane(eh * 32);
  for (int j = 0; j < 32; j++){
    int e = e0 + j;
    float a = b2[e];
    const f32x4* w4 = (const f32x4*)&W2[e * 64];
    #define QSTEP(i) { f32x4 wv = w4[i]; a += wv.x * h##i.x + wv.y * h##i.y + wv.z * h##i.z + wv.w * h##i.w; }
    QSTEP(0) QSTEP(1) QSTEP(2) QSTEP(3) QSTEP(4) QSTEP(5) QSTEP(6) QSTEP(7)
    QSTEP(8) QSTEP(9) QSTEP(10) QSTEP(11) QSTEP(12) QSTEP(13) QSTEP(14) QSTEP(15)
    #undef QSTEP
    term[p][e] = fmaxf(a, 0.f);
  }
  __syncthreads();
  if (t < 64){
    float sacc = b3[0];
    #pragma unroll 4
    for (int e = 0; e < 128; e++) sacc += W3[e] * term[t][e];
    if (!(fabsf(sacc) < 1e30f)) sacc = -1e30f;
    #pragma unroll
    for (int off = 1; off < 16; off <<= 1) sacc = fmaxf(sacc, __shfl_xor(sacc, off, 16));
    if (kk == 0) sArr[b * NN + n] = sacc;
  }
}

// ---- K6+K7+K8 merged (R21/R22/R23 structure; f32 SVD, named scalars) ---------------
__global__ __launch_bounds__(256) void k_rankrig(const float* __restrict__ sArr, const float* __restrict__ src,
                                                 const float* __restrict__ s_corr, int* __restrict__ topi,
                                                 float* __restrict__ Rt, float* __restrict__ out){
  __shared__ float wrow[NN];
  __shared__ float red[256];
  __shared__ f32x4 red4[256];
  __shared__ int pc[4][64];
  int b = blockIdx.y, t = threadIdx.x;
  // ---- softmax (verbatim k_softw) -> wrow (feeds rank -> topi: DISCRETE, verbatim) --
  const float* sp = sArr + b * NN;
  float sv[8];
  float mx = -3.4e38f;
  #pragma unroll
  for (int i = 0; i < 8; i++){
    float v = sp[t + 256 * i];
    if (!(fabsf(v) < 1e30f)) v = -1e30f;
    sv[i] = v; mx = fmaxf(mx, v);
  }
  mx = blockRed(mx, red, t, 2);
  float z = 0.f;
  #pragma unroll
  for (int i = 0; i < 8; i++) z += expf(sv[i] - mx);
  z = blockRed(z, red, t, 0);
  float iz = 1.0f / fmaxf(z, 1e-30f);
  #pragma unroll
  for (int i = 0; i < 8; i++) wrow[t + 256 * i] = expf(sv[i] - mx) * iz;
  __syncthreads();
  // ---- rank (verbatim R15 body) ----
  int tn = t & 63, tj = t >> 6;
  int n = blockIdx.x * 64 + tn;
  float wn = wrow[n];
  int j0 = tj * 512;
  const f32x4* w4 = (const f32x4*)&wrow[j0];
  int cnt = 0;
  #pragma unroll 4
  for (int q = 0; q < 128; q++){
    f32x4 wv = w4[q];
    int j = j0 + q * 4;
    cnt += (wv.x > wn) || ((wv.x == wn) && (j + 0 < n));
    cnt += (wv.y > wn) || ((wv.y == wn) && (j + 1 < n));
    cnt += (wv.z > wn) || ((wv.z == wn) && (j + 2 < n));
    cnt += (wv.w > wn) || ((wv.w == wn) && (j + 3 < n));
  }
  pc[tj][tn] = cnt;
  __syncthreads();
  if (t < 64){
    int c = pc[0][t] + pc[1][t] + pc[2][t] + pc[3][t];
    if (c < KEY) topi[b * KEY + c] = blockIdx.x * 64 + t;
  }
  if (blockIdx.x != 0) return;
  // ---- rigid: centroids + H via blockRed4 (bit-identical sums) ----
  float wsum = 0, a0 = 0, a1 = 0, a2 = 0, c0 = 0, c1 = 0, c2 = 0;
  for (int n2 = t; n2 < NN; n2 += 256){
    float wv = wrow[n2];
    float s0 = src[(b * 3 + 0) * NN + n2];
    float s1 = src[(b * 3 + 1) * NN + n2];
    float s2 = src[(b * 3 + 2) * NN + n2];
    float q0 = s_corr[(b * 3 + 0) * NN + n2];
    float q1 = s_corr[(b * 3 + 1) * NN + n2];
    float q2 = s_corr[(b * 3 + 2) * NN + n2];
    wsum += wv; a0 += wv * s0; a1 += wv * s1; a2 += wv * s2;
    c0 += wv * q0; c1 += wv * q1; c2 += wv * q2;
  }
  f32x4 pk1; pk1.x = wsum; pk1.y = a0; pk1.z = a1; pk1.w = a2;
  pk1 = blockRed4(pk1, red4, t);
  f32x4 pk2; pk2.x = c0; pk2.y = c1; pk2.z = c2; pk2.w = 0.f;
  pk2 = blockRed4(pk2, red4, t);
  wsum = pk1.x; a0 = pk1.y; a1 = pk1.z; a2 = pk1.w;
  c0 = pk2.x; c1 = pk2.y; c2 = pk2.z;
  float inv = 1.0f / fmaxf(wsum, 1e-30f);
  float cs0 = a0 * inv, cs1 = a1 * inv, cs2 = a2 * inv;
  float ct0 = c0 * inv, ct1 = c1 * inv, ct2 = c2 * inv;
  float h[9] = {0, 0, 0, 0, 0, 0, 0, 0, 0};
  for (int n2 = t; n2 < NN; n2 += 256){
    float wv = wrow[n2];
    float ds0 = src[(b * 3 + 0) * NN + n2] - cs0;
    float ds1 = src[(b * 3 + 1) * NN + n2] - cs1;
    float ds2 = src[(b * 3 + 2) * NN + n2] - cs2;
    float dc0 = s_corr[(b * 3 + 0) * NN + n2] - ct0;
    float dc1 = s_corr[(b * 3 + 1) * NN + n2] - ct1;
    float dc2 = s_corr[(b * 3 + 2) * NN + n2] - ct2;
    h[0] += wv * ds0 * dc0; h[1] += wv * ds0 * dc1; h[2] += wv * ds0 * dc2;
    h[3] += wv * ds1 * dc0; h[4] += wv * ds1 * dc1; h[5] += wv * ds1 * dc2;
    h[6] += wv * ds2 * dc0; h[7] += wv * ds2 * dc1; h[8] += wv * ds2 * dc2;
  }
  f32x4 ph1; ph1.x = h[0]; ph1.y = h[1]; ph1.z = h[2]; ph1.w = h[3];
  ph1 = blockRed4(ph1, red4, t);
  f32x4 ph2; ph2.x = h[4]; ph2.y = h[5]; ph2.z = h[6]; ph2.w = h[7];
  ph2 = blockRed4(ph2, red4, t);
  float h8 = blockRed(h[8], red, t, 0);
  if (t == 0){
    // ---- all-register 3x3 SVD, f32 (static pivot enumeration) ----
    float Hm00 = ph1.x, Hm01 = ph1.y, Hm02 = ph1.z;
    float Hm10 = ph1.w, Hm11 = ph2.x, Hm12 = ph2.y;
    float Hm20 = ph2.z, Hm21 = ph2.w, Hm22 = h8;
    float k00 = Hm00 * Hm00 + Hm10 * Hm10 + Hm20 * Hm20;
    float k01 = Hm00 * Hm01 + Hm10 * Hm11 + Hm20 * Hm21;
    float k02 = Hm00 * Hm02 + Hm10 * Hm12 + Hm20 * Hm22;
    float k10 = k01, k11 = Hm01 * Hm01 + Hm11 * Hm11 + Hm21 * Hm21;
    float k12 = Hm01 * Hm02 + Hm11 * Hm12 + Hm21 * Hm22;
    float k20 = k02, k21 = k12;
    float k22 = Hm02 * Hm02 + Hm12 * Hm12 + Hm22 * Hm22;
    float v00 = 1, v01 = 0, v02 = 0, v10 = 0, v11 = 1, v12 = 0, v20 = 0, v21 = 0, v22 = 1;
    float ksc = fabsf(k00) + fabsf(k11) + fabsf(k22) + 1e-30f;
    #define ROT2(A, B) { float ra = A, rb = B; A = cc2 * ra - sn * rb; B = sn * ra + cc2 * rb; }
    for (int sweep = 0; sweep < 30; sweep++){
      float m01 = fabsf(k01), m02 = fabsf(k02), m12 = fabsf(k12);
      int cse = 0; float mx2 = m01;
      if (m02 > mx2){ mx2 = m02; cse = 1; }
      if (m12 > mx2){ mx2 = m12; cse = 2; }
      if (mx2 <= 1e-6f * ksc) break;
      float app, aqq, apq;
      if (cse == 0){ app = k00; aqq = k11; apq = k01; }
      else if (cse == 1){ app = k00; aqq = k22; apq = k02; }
      else { app = k11; aqq = k22; apq = k12; }
      float tau = (aqq - app) / (2.0f * apq);
      float tt = ((tau >= 0) ? 1.0f : -1.0f) / (fabsf(tau) + sqrtf(1.0f + tau * tau));
      float cc2 = 1.0f / sqrtf(1.0f + tt * tt), sn = tt * cc2;
      if (cse == 0){        // (p,q)=(0,1)
        ROT2(k00, k01) ROT2(k10, k11) ROT2(k20, k21)
        ROT2(k00, k10) ROT2(k01, k11) ROT2(k02, k12)
        ROT2(v00, v01) ROT2(v10, v11) ROT2(v20, v21)
      } else if (cse == 1){ // (p,q)=(0,2)
        ROT2(k00, k02) ROT2(k10, k12) ROT2(k20, k22)
        ROT2(k00, k20) ROT2(k01, k21) ROT2(k02, k22)
        ROT2(v00, v02) ROT2(v10, v12) ROT2(v20, v22)
      } else {              // (p,q)=(1,2)
        ROT2(k01, k02) ROT2(k11, k12) ROT2(k21, k22)
        ROT2(k10, k20) ROT2(k11, k21) ROT2(k12, k22)
        ROT2(v01, v02) ROT2(v11, v12) ROT2(v21, v22)
      }
    }
    #undef ROT2
    float l0 = k00, l1 = k11, l2 = k22; int id0 = 0, id1 = 1, id2 = 2;
    float lt; int it;
    if (l0 < l1){ lt = l0; l0 = l1; l1 = lt; it = id0; id0 = id1; id1 = it; }
    if (l0 < l2){ lt = l0; l0 = l2; l2 = lt; it = id0; id0 = id2; id2 = it; }
    if (l1 < l2){ lt = l1; l1 = l2; l2 = lt; it = id1; id1 = id2; id2 = it; }
    float Vs00, Vs10, Vs20, Vs01, Vs11, Vs21, Vs02, Vs12, Vs22;
    float u00 = 0, u10 = 0, u20 = 0, u01 = 0, u11 = 0, u21 = 0, u02 = 0, u12 = 0, u22 = 0;
    #define GETCOL(j, cA, cB, cC) { if ((j) == 0){ cA = v00; cB = v10; cC = v20; } \
                                    else if ((j) == 1){ cA = v01; cB = v11; cC = v21; } \
                                    else { cA = v02; cB = v12; cC = v22; } }
    {
      float cA, cB, cC; GETCOL(id0, cA, cB, cC);
      Vs00 = cA; Vs10 = cB; Vs20 = cC;
      float uu0 = Hm00 * cA + Hm01 * cB + Hm02 * cC;
      float uu1 = Hm10 * cA + Hm11 * cB + Hm12 * cC;
      float uu2 = Hm20 * cA + Hm21 * cB + Hm22 * cC;
      float nrm = sqrtf(uu0 * uu0 + uu1 * uu1 + uu2 * uu2);
      if (nrm > 1e-20f){ u00 = uu0 / nrm; u10 = uu1 / nrm; u20 = uu2 / nrm; }
      else { u00 = 1; u10 = 0; u20 = 0; }
    }
    {
      float cA, cB, cC; GETCOL(id1, cA, cB, cC);
      Vs01 = cA; Vs11 = cB; Vs21 = cC;
      float uu0 = Hm00 * cA + Hm01 * cB + Hm02 * cC;
      float uu1 = Hm10 * cA + Hm11 * cB + Hm12 * cC;
      float uu2 = Hm20 * cA + Hm21 * cB + Hm22 * cC;
      float nrm = sqrtf(uu0 * uu0 + uu1 * uu1 + uu2 * uu2);
      if (nrm > 1e-20f){ u01 = uu0 / nrm; u11 = uu1 / nrm; u21 = uu2 / nrm; }
      else {
        float x0 = u10 * u21 - u20 * u11;
        float x1 = u20 * u01 - u00 * u21;
        float x2 = u00 * u11 - u10 * u01;
        float nn2 = sqrtf(x0 * x0 + x1 * x1 + x2 * x2);
        if (nn2 < 1e-20f){ x0 = 1; x1 = 0; x2 = 0; nn2 = 1; }
        u01 = x0 / nn2; u11 = x1 / nn2; u21 = x2 / nn2;
      }
    }
    {
      float cA, cB, cC; GETCOL(id2, cA, cB, cC);
      Vs02 = cA; Vs12 = cB; Vs22 = cC;
      float uu0 = Hm00 * cA + Hm01 * cB + Hm02 * cC;
      float uu1 = Hm10 * cA + Hm11 * cB + Hm12 * cC;
      float uu2 = Hm20 * cA + Hm21 * cB + Hm22 * cC;
      float nrm = sqrtf(uu0 * uu0 + uu1 * uu1 + uu2 * uu2);
      if (nrm > 1e-20f){ u02 = uu0 / nrm; u12 = uu1 / nrm; u22 = uu2 / nrm; }
      else {
        float x0 = u10 * u21 - u20 * u11;
        float x1 = u20 * u01 - u00 * u21;
        float x2 = u00 * u11 - u10 * u01;
        float nn2 = sqrtf(x0 * x0 + x1 * x1 + x2 * x2);
        if (nn2 < 1e-20f){ x0 = 1; x1 = 0; x2 = 0; nn2 = 1; }
        u02 = x0 / nn2; u12 = x1 / nn2; u22 = x2 / nn2;
      }
    }
    #undef GETCOL
    float ddU = u00 * (u11 * u22 - u12 * u21) - u01 * (u10 * u22 - u12 * u20) + u02 * (u10 * u21 - u11 * u20);
    float ddV = Vs00 * (Vs11 * Vs22 - Vs12 * Vs21) - Vs01 * (Vs10 * Vs22 - Vs12 * Vs20) + Vs02 * (Vs10 * Vs21 - Vs11 * Vs20);
    float dd = ddU * ddV;
    float Rm00 = Vs00 * u00 + Vs01 * u01 + dd * Vs02 * u02;
    float Rm01 = Vs00 * u10 + Vs01 * u11 + dd * Vs02 * u12;
    float Rm02 = Vs00 * u20 + Vs01 * u21 + dd * Vs02 * u22;
    float Rm10 = Vs10 * u00 + Vs11 * u01 + dd * Vs12 * u02;
    float Rm11 = Vs10 * u10 + Vs11 * u11 + dd * Vs12 * u12;
    float Rm12 = Vs10 * u20 + Vs11 * u21 + dd * Vs12 * u22;
    float Rm20 = Vs20 * u00 + Vs21 * u01 + dd * Vs22 * u02;
    float Rm21 = Vs20 * u10 + Vs21 * u11 + dd * Vs22 * u12;
    float Rm22 = Vs20 * u20 + Vs21 * u21 + dd * Vs22 * u22;
    float tv0 = ct0 - (Rm00 * cs0 + Rm01 * cs1 + Rm02 * cs2);
    float tv1 = ct1 - (Rm10 * cs0 + Rm11 * cs1 + Rm12 * cs2);
    float tv2 = ct2 - (Rm20 * cs0 + Rm21 * cs1 + Rm22 * cs2);
    Rt[b * 12 + 0] = Rm00; out[b * 9 + 0] = Rm00;
    Rt[b * 12 + 1] = Rm01; out[b * 9 + 1] = Rm01;
    Rt[b * 12 + 2] = Rm02; out[b * 9 + 2] = Rm02;
    Rt[b * 12 + 3] = Rm10; out[b * 9 + 3] = Rm10;
    Rt[b * 12 + 4] = Rm11; out[b * 9 + 4] = Rm11;
    Rt[b * 12 + 5] = Rm12; out[b * 9 + 5] = Rm12;
    Rt[b * 12 + 6] = Rm20; out[b * 9 + 6] = Rm20;
    Rt[b * 12 + 7] = Rm21; out[b * 9 + 7] = Rm21;
    Rt[b * 12 + 8] = Rm22; out[b * 9 + 8] = Rm22;
    Rt[b * 12 + 9]  = tv0; out[18 + b * 3 + 0] = tv0;
    Rt[b * 12 + 10] = tv1; out[18 + b * 3 + 1] = tv1;
    Rt[b * 12 + 11] = tv2; out[18 + b * 3 + 2] = tv2;
  }
}

// ---- K10 (+K11 merged): keypoint gathers; block x==64,b==0 computes loss_scl -------
__global__ __launch_bounds__(256) void k_out(const int* __restrict__ topi, const int* __restrict__ sidx,
                                             const float* __restrict__ src, const float* __restrict__ s_corr,
                                             const float* __restrict__ Rt, const float* __restrict__ loss_row,
                                             float* __restrict__ out){
  __shared__ float red[256];
  int b = blockIdx.y, t = threadIdx.x;
  if (blockIdx.x == 64){
    if (b != 0) return;
    float acc = 0.f;
    for (int i = t; i < BB * KEY; i += 256){
      int bb = i >> 10, r = i & 1023;
      int n = topi[bb * KEY + r] & 2047;
      acc += loss_row[bb * NN + n];
    }
    acc = blockRed(acc, red, t, 0);
    if (t == 0) out[208920] = acc / 2048.0f;
    return;
  }
  int rr = t >> 4, kk = t & 15;
  int r = blockIdx.x * 16 + rr;
  int ns = topi[b * KEY + r] & 2047;
  int nk = sidx[(b * NN + ns) * KK + kk] & 2047;
  const float* R = Rt + b * 12;
  float sns0 = src[(b * 3 + 0) * NN + ns];
  float sns1 = src[(b * 3 + 1) * NN + ns];
  float sns2 = src[(b * 3 + 2) * NN + ns];
  float snk0 = src[(b * 3 + 0) * NN + nk];
  float snk1 = src[(b * 3 + 1) * NN + nk];
  float snk2 = src[(b * 3 + 2) * NN + nk];
  float* o_sk  = out + 24;
  float* o_tk  = out + 6168;
  float* o_skk = out + 12312;
  float* o_tkk = out + 110616;
  #pragma unroll
  for (int c = 0; c < 3; c++){
    float cv  = s_corr[(b * 3 + c) * NN + ns];
    float ck  = s_corr[(b * 3 + c) * NN + nk];
    o_tkk[(((b * 3 + c) * KEY + r) * KK) + kk] = cv - ck;
    float sv  = R[c * 3 + 0] * sns0 + R[c * 3 + 1] * sns1 + R[c * 3 + 2] * sns2 + R[9 + c];
    float sk2 = R[c * 3 + 0] * snk0 + R[c * 3 + 1] * snk1 + R[c * 3 + 2] * snk2 + R[9 + c];
    o_skk[(((b * 3 + c) * KEY + r) * KK) + kk] = sv - sk2;
    if (kk == 0){
      o_sk[(b * 3 + c) * KEY + r] = sns0 * (c == 0) + sns1 * (c == 1) + sns2 * (c == 2);
      o_tk[(b * 3 + c) * KEY + r] = cv;
    }
  }
}

extern "C" void kernel_launch(void* const* d_in, const int* in_sizes, int n_in,
                              void* d_out, int out_size, void* d_ws, size_t ws_size,
                              hipStream_t stream){
  const float* src  = (const float*)d_in[0];
  const float* tgt  = (const float*)d_in[1];
  const float* semb = (const float*)d_in[2];
  const float* temb = (const float*)d_in[3];
  const float* sknn = (const float*)d_in[4];
  const float* W1 = (const float*)d_in[6];
  const float* b1 = (const float*)d_in[7];
  const float* W2 = (const float*)d_in[8];
  const float* b2 = (const float*)d_in[9];
  const float* W3 = (const float*)d_in[10];
  const float* b3 = (const float*)d_in[11];
  const int* sidx  = (const int*)d_in[12];
  const int* sidx1 = (const int*)d_in[13];
  const int* idx2  = (const int*)d_in[14];
  float* out = (float*)d_out;

  // workspace layout (peak ~84 MB; harness allocates 256 MiB per fill evidence)
  char* w = (char*)d_ws;
  u16* Ah = (u16*)(w);                               // 4 MB each (B,N,C) bf16 split
  u16* Al = Ah + (size_t)BB * NN * CC;
  u16* Bh = Al + (size_t)BB * NN * CC;
  u16* Bl = Bh + (size_t)BB * MM * CC;
  float* dist = (float*)(Bl + (size_t)BB * MM * CC); // 33.55 MB (B,N,M) f32
  float* scores = dist + (size_t)BB * NN * MM;       // 33.55 MB (B,N,M) f32
  char* tail = (char*)(scores + (size_t)BB * NN * MM);
  float* xx = (float*)tail;                          // B*N
  float* yy = xx + BB * NN;                          // B*M
  float* mnA = yy + BB * MM;                         // B*N
  float* Zr = mnA + BB * NN;                         // B*N
  float* s_corr = Zr + BB * NN;                      // B*3*N
  float* loss_row = s_corr + BB * 3 * NN;            // B*N
  float* sArr = loss_row + BB * NN;                  // B*N
  int* topi = (int*)(sArr + BB * NN);                // B*KEY
  float* Rt = (float*)(topi + BB * KEY);             // B*12

  k_trans<<<dim3(16, 64, 4), dim3(32, 8), 0, stream>>>(semb, temb, Ah, Al, Bh, Bl);
  k_sq<<<dim3(16, 2), 256, 0, stream>>>(semb, temb, xx, yy);
  k_gemm<<<dim3(16, 16, BB), 256, 0, stream>>>(Ah, Al, Bh, Bl, xx, yy, dist);
  k_rowstats<<<dim3(NN, BB), 256, 0, stream>>>(dist, mnA, Zr, scores);
  k_fused<<<dim3(NN, BB), 256, 0, stream>>>(dist, scores, sidx1, idx2, tgt, s_corr, loss_row);
  k_disc<<<dim3(NN / 4, BB), 256, 0, stream>>>(s_corr, src, sknn, sidx, W1, b1, W2, b2, W3, b3, sArr);
  k_rankrig<<<dim3(32, BB), 256, 0, stream>>>(sArr, src, s_corr, topi, Rt, out);
  k_out<<<dim3(65, BB), 256, 0, stream>>>(topi, sidx, src, s_corr, Rt, loss_row, out);
}